// Round 3
// baseline (861.827 us; speedup 1.0000x reference)
//
#include <hip/hip_runtime.h>
#include <cmath>

#define NN   3072
#define HIDD 256
#define TK   16
#define FEAT 768   // 3*HID

// ---------------------------------------------------------------- pool
__global__ void pool_kernel(const float* __restrict__ img, float* __restrict__ p) {
    int idx = blockIdx.x * 256 + threadIdx.x;
    if (idx >= NN * 192) return;
    int b = idx / 192, rem = idx % 192;
    int c = rem >> 6, oy = (rem >> 3) & 7, ox = rem & 7;
    const float* base = img + (((size_t)b * 3 + c) * 32 + oy * 4) * 32 + ox * 4;
    float s = 0.f;
#pragma unroll
    for (int iy = 0; iy < 4; iy++)
#pragma unroll
        for (int ix = 0; ix < 4; ix++) s += base[iy * 32 + ix];
    p[idx] = s * 0.0625f;
}

// ---------------------------------------------------------------- big-tile fp32 GEMM
// BMxBN tile, 256 threads = 4 waves, per-wave WMxWN subtile, lane grid 8x8,
// per-lane TM=WM/8 x TN=WN/8. A (and B if TRB) staged K-major with XOR swizzle.
// gridDim.z==1: fused epilogue (alpha,bias,act,acc). Else raw partial to P.
// Requires: M%BM==0, N%BN==0, K%32==0, Kc%32==0.
template<int BM, int BN, int WM, int WN, int TRB>
__global__ __launch_bounds__(256) void gemmT(
        const float* __restrict__ A, const float* __restrict__ B,
        const float* __restrict__ bias, float* __restrict__ C, float* __restrict__ P,
        int M, int Nc, int K, int lda, int ldb, int ldc, int Kc,
        float alpha, int act, int accf) {
    constexpr int TM = WM / 8, TN = WN / 8;
    constexpr int WCOLS = BN / WN;
    __shared__ float As[32][BM + 4];
    __shared__ float Bs[32][BN + 4];
    int tid = threadIdx.x;
    int wave = tid >> 6, lane = tid & 63;
    int qm = wave / WCOLS, qn = wave % WCOLS;
    int lm = lane >> 3, ln = lane & 7;
    int m0 = blockIdx.y * BM, n0 = blockIdx.x * BN;
    int kbeg = blockIdx.z * Kc;
    int kend = min(K, kbeg + Kc);
    float acc[TM][TN] = {};

    for (int k0 = kbeg; k0 < kend; k0 += 32) {
#pragma unroll
        for (int i = 0; i < BM / 32; i++) {
            int q = tid + i * 256;
            int row = q >> 3, kq = q & 7;
            const float4 v = *(const float4*)(A + (size_t)(m0 + row) * lda + k0 + kq * 4);
            int col = row ^ (kq << 2);
            As[kq * 4 + 0][col] = v.x;
            As[kq * 4 + 1][col] = v.y;
            As[kq * 4 + 2][col] = v.z;
            As[kq * 4 + 3][col] = v.w;
        }
        if (TRB) {
#pragma unroll
            for (int i = 0; i < BN / 32; i++) {
                int q = tid + i * 256;
                int row = q >> 3, kq = q & 7;
                const float4 v = *(const float4*)(B + (size_t)(n0 + row) * ldb + k0 + kq * 4);
                int col = row ^ (kq << 2);
                Bs[kq * 4 + 0][col] = v.x;
                Bs[kq * 4 + 1][col] = v.y;
                Bs[kq * 4 + 2][col] = v.z;
                Bs[kq * 4 + 3][col] = v.w;
            }
        } else {
#pragma unroll
            for (int i = 0; i < BN / 32; i++) {
                int q = tid + i * 256;
                int kk2 = q / (BN / 4), n4 = q % (BN / 4);
                *(float4*)&Bs[kk2][n4 * 4] =
                    *(const float4*)(B + (size_t)(k0 + kk2) * ldb + n0 + n4 * 4);
            }
        }
        __syncthreads();
#pragma unroll
        for (int kk = 0; kk < 32; kk++) {
            int swz = kk & 28;  // (kk>>2)<<2
            float a[TM], b[TN];
#pragma unroll
            for (int u = 0; u < TM / 4; u++)
                *(float4*)&a[u * 4] = *(const float4*)&As[kk][(qm * WM + lm * TM + u * 4) ^ swz];
#pragma unroll
            for (int u = 0; u < TN / 4; u++) {
                int cb = qn * WN + ln * TN + u * 4;
                if (TRB) cb ^= swz;
                *(float4*)&b[u * 4] = *(const float4*)&Bs[kk][cb];
            }
#pragma unroll
            for (int i = 0; i < TM; i++)
#pragma unroll
                for (int j = 0; j < TN; j++) acc[i][j] += a[i] * b[j];
        }
        __syncthreads();
    }

    if (gridDim.z == 1) {
#pragma unroll
        for (int i = 0; i < TM; i++) {
            int gm = m0 + qm * WM + lm * TM + i;
#pragma unroll
            for (int u = 0; u < TN / 4; u++) {
                int gn = n0 + qn * WN + ln * TN + u * 4;
                float v[4];
#pragma unroll
                for (int j = 0; j < 4; j++) {
                    float x = alpha * acc[i][u * 4 + j];
                    if (bias) x += bias[gn + j];
                    if (accf) x += C[(size_t)gm * ldc + gn + j];
                    if (act == 1) x = fmaxf(x, 0.f);
                    else if (act == 2) x = tanhf(x);
                    else if (act == 3) x = 1.f / (1.f + expf(-x));
                    v[j] = x;
                }
                *(float4*)&C[(size_t)gm * ldc + gn] = *(float4*)v;
            }
        }
    } else {
        float* Pp = P + (size_t)blockIdx.z * M * Nc;
#pragma unroll
        for (int i = 0; i < TM; i++) {
            int gm = m0 + qm * WM + lm * TM + i;
#pragma unroll
            for (int u = 0; u < TN / 4; u++) {
                int gn = n0 + qn * WN + ln * TN + u * 4;
                *(float4*)&Pp[(size_t)gm * Nc + gn] = *(float4*)&acc[i][u * 4];
            }
        }
    }
}

// epilogue: C = act(alpha*sum_s P[s] + bias + acc*C)
__global__ void gemm_epi(const float* __restrict__ P, const float* __restrict__ bias,
                         float* __restrict__ C, int M, int Nc, int ldc, int KS,
                         float alpha, int act, int acc) {
    int idx = blockIdx.x * 256 + threadIdx.x;
    if (idx >= M * Nc) return;
    int m = idx / Nc, n = idx - m * Nc;
    float v = 0.f;
    for (int s = 0; s < KS; s++) v += P[(size_t)s * M * Nc + idx];
    v *= alpha;
    if (bias) v += bias[n];
    if (acc) v += C[(size_t)m * ldc + n];
    if (act == 1) v = fmaxf(v, 0.f);
    else if (act == 2) v = tanhf(v);
    else if (act == 3) v = 1.f / (1.f + expf(-v));
    C[(size_t)m * ldc + n] = v;
}

// ---------------------------------------------------------------- small GEMM (heads), 64x64, 4x4
__global__ void gemm2(const float* __restrict__ A, const float* __restrict__ B,
                      float* __restrict__ P, int M, int Nc, int K,
                      int lda, int ldb, int Kc) {
    __shared__ float As[32][68];
    __shared__ float Bs[32][68];
    int tid = threadIdx.x;
    int tm = tid >> 4, tn = tid & 15;
    int m0 = blockIdx.y * 64, n0 = blockIdx.x * 64;
    int kbeg = blockIdx.z * Kc;
    int kend = min(K, kbeg + Kc);
    float acc[4][4] = {};
    for (int k0 = kbeg; k0 < kend; k0 += 32) {
#pragma unroll
        for (int i = 0; i < 2; i++) {
            int q = tid + i * 256;
            int m = q >> 3, kq = q & 7;
            float4 v = *(const float4*)(A + (size_t)(m0 + m) * lda + k0 + kq * 4);
            int col = m ^ (kq << 2);
            As[kq * 4 + 0][col] = v.x;
            As[kq * 4 + 1][col] = v.y;
            As[kq * 4 + 2][col] = v.z;
            As[kq * 4 + 3][col] = v.w;
        }
#pragma unroll
        for (int i = 0; i < 2; i++) {
            int q = tid + i * 256;
            int k = q >> 4, nq = q & 15;
            int gn = n0 + nq * 4;
            float4 v;
            const float* src = B + (size_t)(k0 + k) * ldb + gn;
            if (gn + 3 < Nc) {
                v = *(const float4*)src;
            } else {
                v.x = (gn + 0 < Nc) ? src[0] : 0.f;
                v.y = (gn + 1 < Nc) ? src[1] : 0.f;
                v.z = (gn + 2 < Nc) ? src[2] : 0.f;
                v.w = (gn + 3 < Nc) ? src[3] : 0.f;
            }
            *(float4*)&Bs[k][nq * 4] = v;
        }
        __syncthreads();
#pragma unroll
        for (int kk = 0; kk < 32; kk++) {
            int swz = kk & 28;
            float a[4], b[4];
            *(float4*)a = *(const float4*)&As[kk][(tm * 4) ^ swz];
            *(float4*)b = *(const float4*)&Bs[kk][tn * 4];
#pragma unroll
            for (int i = 0; i < 4; i++)
#pragma unroll
                for (int j = 0; j < 4; j++) acc[i][j] += a[i] * b[j];
        }
        __syncthreads();
    }
    float* Pp = P + (size_t)blockIdx.z * M * Nc;
    int gn = n0 + tn * 4;
#pragma unroll
    for (int i = 0; i < 4; i++) {
        int gm = m0 + tm * 4 + i;
        if (gn + 3 < Nc) {
            *(float4*)&Pp[(size_t)gm * Nc + gn] = *(float4*)&acc[i][0];
        } else {
#pragma unroll
            for (int j = 0; j < 4; j++)
                if (gn + j < Nc) Pp[(size_t)gm * Nc + gn + j] = acc[i][j];
        }
    }
}

// ---------------------------------------------------------------- BatchNorm (training stats), per column
__global__ void bn_kernel(float* __restrict__ Y, const float* __restrict__ g,
                          const float* __restrict__ bt) {
    int j = blockIdx.x;
    __shared__ float rs[256], rs2[256];
    float s = 0.f, s2 = 0.f;
    for (int i = threadIdx.x; i < NN; i += 256) {
        float v = Y[(size_t)i * FEAT + j];
        s += v; s2 += v * v;
    }
    rs[threadIdx.x] = s; rs2[threadIdx.x] = s2;
    __syncthreads();
    for (int st = 128; st > 0; st >>= 1) {
        if (threadIdx.x < st) { rs[threadIdx.x] += rs[threadIdx.x + st]; rs2[threadIdx.x] += rs2[threadIdx.x + st]; }
        __syncthreads();
    }
    float mean = rs[0] * (1.f / NN);
    float var = fmaxf(rs2[0] * (1.f / NN) - mean * mean, 0.f);
    float scale = g[j] / sqrtf(var + 1e-5f);
    float shift = bt[j];
    for (int i = threadIdx.x; i < NN; i += 256) {
        size_t o = (size_t)i * FEAT + j;
        Y[o] = (Y[o] - mean) * scale + shift;
    }
}

// ---------------------------------------------------------------- row normalize z
__global__ void rownorm_kernel(float* __restrict__ Z) {
    int i = blockIdx.x;
    __shared__ float rs[256];
    __shared__ float inv;
    float v = Z[(size_t)i * HIDD + threadIdx.x];
    rs[threadIdx.x] = v * v;
    __syncthreads();
    for (int st = 128; st > 0; st >>= 1) {
        if (threadIdx.x < st) rs[threadIdx.x] += rs[threadIdx.x + st];
        __syncthreads();
    }
    if (threadIdx.x == 0) inv = 1.f / (sqrtf(rs[0]) + 1e-8f);
    __syncthreads();
    Z[(size_t)i * HIDD + threadIdx.x] = v * inv;
}

// ---------------------------------------------------------------- top-k per row (k=16)
__global__ void topk_kernel(const float* __restrict__ S, float* __restrict__ hv,
                            int* __restrict__ eidx) {
    int row = blockIdx.x;
    __shared__ float sv[NN];
    __shared__ float rv[256];
    __shared__ int   ri[256];
    const float* srow = S + (size_t)row * NN;
    for (int i = threadIdx.x; i < NN; i += 256) sv[i] = srow[i];
    __syncthreads();
    for (int t = 0; t < TK; t++) {
        float bv = -1e30f; int bi = NN;
        for (int i = threadIdx.x; i < NN; i += 256) {
            float v = sv[i];
            if (v > bv) { bv = v; bi = i; }
        }
        rv[threadIdx.x] = bv; ri[threadIdx.x] = bi;
        __syncthreads();
        for (int st = 128; st > 0; st >>= 1) {
            if (threadIdx.x < st) {
                float ov = rv[threadIdx.x + st]; int oi = ri[threadIdx.x + st];
                if (ov > rv[threadIdx.x] || (ov == rv[threadIdx.x] && oi < ri[threadIdx.x])) {
                    rv[threadIdx.x] = ov; ri[threadIdx.x] = oi;
                }
            }
            __syncthreads();
        }
        if (threadIdx.x == 0) {
            float val = rv[0]; int id = ri[0];
            float sg = 1.f / (1.f + expf(-val));
            hv[row * TK + t] = (sg > 0.5f) ? sg : 0.f;
            eidx[row * TK + t] = id;
            sv[id] = -1e30f;
        }
        __syncthreads();
    }
}

// ---------------------------------------------------------------- edge stats
__global__ void edge_stats(const float* __restrict__ hv, float* __restrict__ De,
                           float* __restrict__ ew) {
    int e = blockIdx.x * 256 + threadIdx.x;
    if (e >= NN) return;
    float s = 0.f;
#pragma unroll
    for (int j = 0; j < TK; j++) s += hv[e * TK + j];
    De[e] = s + 1e-8f;
    ew[e] = s * (1.f / TK);
}

__global__ void scatter_deg(const int* __restrict__ eidx, const float* __restrict__ hv,
                            const float* __restrict__ ew, float* __restrict__ Dv,
                            float* __restrict__ Dv2, int* __restrict__ row_cnt) {
    int t = blockIdx.x * 256 + threadIdx.x;
    if (t >= NN * TK) return;
    int e = t >> 4;
    int v = eidx[t];
    float w = hv[t];
    atomicAdd(&Dv[v], w * ew[e]);
    atomicAdd(&Dv2[v], w);
    atomicAdd(&row_cnt[v], 1);
}

__global__ void deg_fin(const float* __restrict__ Dv, float* __restrict__ Dv2,
                        float* __restrict__ dvis) {
    int v = blockIdx.x * 256 + threadIdx.x;
    if (v >= NN) return;
    dvis[v] = 1.f / sqrtf(Dv[v] + 1e-8f);
    Dv2[v] += 1e-8f;
}

// ---------------------------------------------------------------- CSR build
__global__ void scan_kernel(const int* __restrict__ cnt, int* __restrict__ start) {
    __shared__ int part[256];
    int t = threadIdx.x;
    const int chunk = NN / 256;
    int s = 0;
    for (int i = t * chunk; i < (t + 1) * chunk; i++) s += cnt[i];
    part[t] = s;
    __syncthreads();
    if (t == 0) {
        int a = 0;
        for (int i = 0; i < 256; i++) { int v = part[i]; part[i] = a; a += v; }
    }
    __syncthreads();
    int a = part[t];
    for (int i = t * chunk; i < (t + 1) * chunk; i++) { start[i] = a; a += cnt[i]; }
    if (t == 255) start[NN] = a;
}

__global__ void fill_csr(const int* __restrict__ eidx, const float* __restrict__ hv,
                         const int* __restrict__ start, int* __restrict__ fillc,
                         int* __restrict__ csr_e, float* __restrict__ csr_w) {
    int t = blockIdx.x * 256 + threadIdx.x;
    if (t >= NN * TK) return;
    int e = t >> 4;
    int v = eidx[t];
    int pos = atomicAdd(&fillc[v], 1);
    int pp = start[v] + pos;
    csr_e[pp] = e;
    csr_w[pp] = hv[t];
}

// ---------------------------------------------------------------- sparse H ops
__global__ void edge_gather(const int* __restrict__ eidx, const float* __restrict__ hv,
                            const float* __restrict__ De, const float* __restrict__ dvis,
                            const float* __restrict__ X, float* __restrict__ T,
                            int F, int use_dvis) {
    int e = blockIdx.x;
    int f = blockIdx.y * 256 + threadIdx.x;
    if (f >= F) return;
    float acc = 0.f;
#pragma unroll
    for (int j = 0; j < TK; j++) {
        int v = eidx[e * TK + j];
        float w = hv[e * TK + j];
        if (use_dvis) w *= dvis[v];
        acc += w * X[(size_t)v * F + f];
    }
    T[(size_t)e * F + f] = acc / De[e];
}

__global__ void row_gather(const int* __restrict__ start, const int* __restrict__ csr_e,
                           const float* __restrict__ csr_w, const float* __restrict__ dvis,
                           const float* __restrict__ T, const float* __restrict__ Badd,
                           float alpha, float beta, float* __restrict__ Y,
                           int F, int use_dvis) {
    int v = blockIdx.x;
    int f = blockIdx.y * 256 + threadIdx.x;
    if (f >= F) return;
    int s0 = start[v], s1 = start[v + 1];
    float acc = 0.f;
    for (int p = s0; p < s1; p++) acc += csr_w[p] * T[(size_t)csr_e[p] * F + f];
    float o = alpha * (use_dvis ? dvis[v] : 1.f) * acc;
    if (Badd) o += beta * Badd[(size_t)v * F + f];
    Y[(size_t)v * F + f] = o;
}

// ---------------------------------------------------------------- reductions
__global__ void mse_reduce(const float* __restrict__ a, const float* __restrict__ b,
                           float* __restrict__ sum) {
    __shared__ float rs[256];
    float s = 0.f;
    size_t n = (size_t)NN * FEAT;
    for (size_t i = (size_t)blockIdx.x * 256 + threadIdx.x; i < n; i += (size_t)gridDim.x * 256) {
        float d = a[i] - b[i];
        s += d * d;
    }
    rs[threadIdx.x] = s;
    __syncthreads();
    for (int st = 128; st > 0; st >>= 1) {
        if (threadIdx.x < st) rs[threadIdx.x] += rs[threadIdx.x + st];
        __syncthreads();
    }
    if (threadIdx.x == 0) atomicAdd(sum, rs[0]);
}

__global__ void spectral_cols(const float* __restrict__ r, const float* __restrict__ y,
                              const float* __restrict__ Dv2, float* __restrict__ numb,
                              float* __restrict__ denb) {
    int c = blockIdx.x;
    __shared__ float rn[256], rd[256];
    float sn = 0.f, sd = 0.f;
    for (int i = threadIdx.x; i < NN; i += 256) {
        float rv = r[(size_t)i * 64 + c];
        float d2 = Dv2[i];
        float lcx = d2 * rv - y[(size_t)i * 64 + c];
        sn += rv * lcx;
        sd += d2 * rv * rv;
    }
    rn[threadIdx.x] = sn; rd[threadIdx.x] = sd;
    __syncthreads();
    for (int st = 128; st > 0; st >>= 1) {
        if (threadIdx.x < st) { rn[threadIdx.x] += rn[threadIdx.x + st]; rd[threadIdx.x] += rd[threadIdx.x + st]; }
        __syncthreads();
    }
    if (threadIdx.x == 0) { numb[c] = rn[0]; denb[c] = rd[0] + 1e-8f; }
}

__global__ void finals_kernel(const float* __restrict__ msum, const float* __restrict__ numb,
                              const float* __restrict__ denb, float* __restrict__ out) {
    if (threadIdx.x == 0 && blockIdx.x == 0) {
        float s = 0.f;
        for (int c = 0; c < 64; c++) s += numb[c] / denb[c];
        out[NN + 1] = s * (1.f / 64.f);
        out[NN] = msum[0] * (1.f / ((float)NN * FEAT));
    }
}

// ================================================================ launch
extern "C" void kernel_launch(void* const* d_in, const int* in_sizes, int n_in,
                              void* d_out, int out_size, void* d_ws, size_t ws_size,
                              hipStream_t stream) {
    const float* images = (const float*)d_in[0];
    const float* text   = (const float*)d_in[1];
    const float* signal = (const float*)d_in[2];
    const float* iw1 = (const float*)d_in[3];  const float* ib1 = (const float*)d_in[4];
    const float* iw2 = (const float*)d_in[5];  const float* ib2 = (const float*)d_in[6];
    const float* ig  = (const float*)d_in[7];  const float* ibeta = (const float*)d_in[8];
    const float* tw1 = (const float*)d_in[9];  const float* tb1 = (const float*)d_in[10];
    const float* tw2 = (const float*)d_in[11]; const float* tb2 = (const float*)d_in[12];
    const float* tg  = (const float*)d_in[13]; const float* tbeta = (const float*)d_in[14];
    const float* sw1 = (const float*)d_in[15]; const float* sb1 = (const float*)d_in[16];
    const float* sw2 = (const float*)d_in[17]; const float* sb2 = (const float*)d_in[18];
    const float* sg  = (const float*)d_in[19]; const float* sbeta = (const float*)d_in[20];
    const float* gw  = (const float*)d_in[21]; const float* gb = (const float*)d_in[22];
    const float* c1w = (const float*)d_in[23]; const float* c1b = (const float*)d_in[24];
    const float* c2w = (const float*)d_in[25]; const float* c2b = (const float*)d_in[26];
    const float* rw1 = (const float*)d_in[27]; const float* rb1 = (const float*)d_in[28];
    const float* rw2 = (const float*)d_in[29]; const float* rb2 = (const float*)d_in[30];
    const float* aw1 = (const float*)d_in[31]; const float* ab1 = (const float*)d_in[32];
    const float* aw2 = (const float*)d_in[33]; const float* ab2 = (const float*)d_in[34];
    const float* dw1 = (const float*)d_in[35]; const float* db1 = (const float*)d_in[36];
    const float* dw2 = (const float*)d_in[37]; const float* db2 = (const float*)d_in[38];
    float* out = (float*)d_out;

    float* wsf = (float*)d_ws;
    size_t off = 0;
    auto AF = [&](size_t n) { float* q = wsf + off; off += n; return q; };
    float* feats  = AF((size_t)NN * FEAT);
    float* simbuf = AF((size_t)NN * NN);
    float* p      = AF((size_t)NN * 192);
    float* h      = AF((size_t)NN * HIDD);
    float* z      = AF((size_t)NN * HIDD);
    float* x1     = AF((size_t)NN * HIDD);
    float* x2     = AF((size_t)NN * 128);
    float* r      = AF((size_t)NN * 64);
    float* hv     = AF((size_t)NN * TK);
    float* ew     = AF(NN);
    float* De     = AF(NN);
    float* Dv     = AF(NN);
    float* Dv2    = AF(NN);
    float* dvis   = AF(NN);
    float* csr_w  = AF((size_t)NN * TK);
    float* numb   = AF(64);
    float* denb   = AF(64);
    float* msum   = AF(1);
    int* eidx     = (int*)(wsf + off); off += (size_t)NN * TK;
    int* csr_e    = (int*)(wsf + off); off += (size_t)NN * TK;
    int* row_cnt  = (int*)(wsf + off); off += NN;
    int* row_fill = (int*)(wsf + off); off += NN;
    int* row_start= (int*)(wsf + off); off += NN + 1;

    // sim buffer recycled after top-k:
    float* T1    = simbuf;
    float* T2    = simbuf + (size_t)NN * FEAT;
    float* et    = simbuf + (size_t)2 * NN * FEAT;
    float* recon = simbuf + (size_t)3 * NN * FEAT;  // partial region post-topk
    float* yspec = x2;

    dim3 blk(256);
    // big GEMM: tile 128x64, waves 32x64, fused epi if 1 split
    auto gemmBig = [&](const float* A, const float* B, const float* bias, float* C,
                       int M, int Nc, int K, int lda, int ldb, int ldc,
                       float alpha, int act, int acc, int KS, float* part) {
        int nk = K / 32;
        int ks = KS < nk ? KS : nk;
        int kc = ((nk + ks - 1) / ks) * 32;
        int ksp = (K + kc - 1) / kc;
        gemmT<128, 64, 32, 64, 0><<<dim3(Nc / 64, M / 128, ksp), blk, 0, stream>>>(
            A, B, bias, C, part, M, Nc, K, lda, ldb, ldc, kc, alpha, act, acc);
        if (ksp > 1)
            gemm_epi<<<((size_t)M * Nc + 255) / 256, blk, 0, stream>>>(
                part, bias, C, M, Nc, ldc, ksp, alpha, act, acc);
    };
    // small GEMM (heads)
    auto gemmSm = [&](const float* A, const float* B, const float* bias, float* C,
                      int M, int Nc, int K, int lda, int ldb, int ldc,
                      float alpha, int act, int acc, int KS, float* part) {
        int nk = K / 32;
        int ks = KS < nk ? KS : nk;
        int kc = ((nk + ks - 1) / ks) * 32;
        int ksp = (K + kc - 1) / kc;
        gemm2<<<dim3((Nc + 63) / 64, M / 64, ksp), blk, 0, stream>>>(A, B, part, M, Nc, K, lda, ldb, kc);
        gemm_epi<<<((size_t)M * Nc + 255) / 256, blk, 0, stream>>>(part, bias, C, M, Nc, ldc, ksp, alpha, act, acc);
    };

    const float E1 = 0.60653065971f;  // exp(-0.5)
    const float E2 = 0.36787944117f;  // exp(-1.0)

    // ---- modality MLPs + BN (partials in simbuf: free until sim) ----
    pool_kernel<<<(NN * 192 + 255) / 256, blk, 0, stream>>>(images, p);
    gemmBig(p, iw1, ib1, h, NN, HIDD, 192, 192, HIDD, HIDD, 1.f, 1, 0, 4, simbuf);
    gemmBig(h, iw2, ib2, feats + 0, NN, HIDD, HIDD, HIDD, HIDD, FEAT, 1.f, 0, 0, 4, simbuf);
    bn_kernel<<<HIDD, blk, 0, stream>>>(feats + 0, ig, ibeta);

    gemmBig(text, tw1, tb1, h, NN, HIDD, 768, 768, HIDD, HIDD, 1.f, 1, 0, 4, simbuf);
    gemmBig(h, tw2, tb2, feats + HIDD, NN, HIDD, HIDD, HIDD, HIDD, FEAT, 1.f, 0, 0, 4, simbuf);
    bn_kernel<<<HIDD, blk, 0, stream>>>(feats + HIDD, tg, tbeta);

    gemmBig(signal, sw1, sb1, h, NN, HIDD, 256, 256, HIDD, HIDD, 1.f, 1, 0, 4, simbuf);
    gemmBig(h, sw2, sb2, feats + 2 * HIDD, NN, HIDD, HIDD, HIDD, HIDD, FEAT, 1.f, 0, 0, 4, simbuf);
    bn_kernel<<<HIDD, blk, 0, stream>>>(feats + 2 * HIDD, sg, sbeta);

    // ---- hyperedge generator ----
    gemmBig(feats, gw, gb, z, NN, HIDD, FEAT, FEAT, HIDD, HIDD, 1.f, 2, 0, 4, simbuf);
    rownorm_kernel<<<NN, blk, 0, stream>>>(z);
    // sim = Z @ Z^T, fused store
    gemmT<128, 128, 64, 64, 1><<<dim3(NN / 128, NN / 128, 1), blk, 0, stream>>>(
        z, z, nullptr, simbuf, nullptr, NN, NN, HIDD, HIDD, HIDD, NN, HIDD, 1.f, 0, 0);
    topk_kernel<<<NN, blk, 0, stream>>>(simbuf, hv, eidx);

    // ---- degrees + CSR of H rows ----
    hipMemsetAsync(Dv, 0, 2 * NN * sizeof(float), stream);
    hipMemsetAsync(msum, 0, sizeof(float), stream);
    hipMemsetAsync(row_cnt, 0, 2 * NN * sizeof(int), stream);
    edge_stats<<<NN / 256, blk, 0, stream>>>(hv, De, ew);
    scatter_deg<<<NN * TK / 256, blk, 0, stream>>>(eidx, hv, ew, Dv, Dv2, row_cnt);
    deg_fin<<<NN / 256, blk, 0, stream>>>(Dv, Dv2, dvis);
    scan_kernel<<<1, blk, 0, stream>>>(row_cnt, row_start);
    fill_csr<<<NN * TK / 256, blk, 0, stream>>>(eidx, hv, row_start, row_fill, csr_e, csr_w);

    // ---- cheb conv 1 (F=768 -> 256); partials in recon region (9.4MB, s=3 -> 9MB) ----
    edge_gather<<<dim3(NN, 3), blk, 0, stream>>>(eidx, hv, De, dvis, feats, et, FEAT, 1);
    row_gather<<<dim3(NN, 3), blk, 0, stream>>>(row_start, csr_e, csr_w, dvis, et, nullptr, -1.f, 0.f, T1, FEAT, 1);
    edge_gather<<<dim3(NN, 3), blk, 0, stream>>>(eidx, hv, De, dvis, T1, et, FEAT, 1);
    row_gather<<<dim3(NN, 3), blk, 0, stream>>>(row_start, csr_e, csr_w, dvis, et, feats, -2.f, -1.f, T2, FEAT, 1);
    gemmBig(feats, c1w + 0,                   nullptr, x1, NN, HIDD, FEAT, FEAT, HIDD, HIDD, 1.f, 0, 0, 3, recon);
    gemmBig(T1,    c1w + (size_t)FEAT*HIDD,   nullptr, x1, NN, HIDD, FEAT, FEAT, HIDD, HIDD, E1,  0, 1, 3, recon);
    gemmBig(T2,    c1w + (size_t)2*FEAT*HIDD, c1b,     x1, NN, HIDD, FEAT, FEAT, HIDD, HIDD, E2,  1, 1, 3, recon);

    // ---- cheb conv 2 (F=256 -> 128) ----
    edge_gather<<<dim3(NN, 1), blk, 0, stream>>>(eidx, hv, De, dvis, x1, et, HIDD, 1);
    row_gather<<<dim3(NN, 1), blk, 0, stream>>>(row_start, csr_e, csr_w, dvis, et, nullptr, -1.f, 0.f, T1, HIDD, 1);
    edge_gather<<<dim3(NN, 1), blk, 0, stream>>>(eidx, hv, De, dvis, T1, et, HIDD, 1);
    row_gather<<<dim3(NN, 1), blk, 0, stream>>>(row_start, csr_e, csr_w, dvis, et, x1, -2.f, -1.f, T2, HIDD, 1);
    gemmBig(x1, c2w + 0,                 nullptr, x2, NN, 128, HIDD, HIDD, 128, 128, 1.f, 0, 0, 4, recon);
    gemmBig(T1, c2w + (size_t)HIDD*128,  nullptr, x2, NN, 128, HIDD, HIDD, 128, 128, E1,  0, 1, 4, recon);
    gemmBig(T2, c2w + (size_t)2*HIDD*128, c2b,    x2, NN, 128, HIDD, HIDD, 128, 128, E2,  1, 1, 4, recon);

    // ---- heads ----
    gemmSm(x2, rw1, rb1, h, NN, 64, 128, 128, 64, 64, 1.f, 1, 0, 2, recon);
    gemmSm(h,  rw2, rb2, r, NN, 64, 64, 64, 64, 64, 1.f, 0, 0, 2, recon);
    gemmSm(r,  aw1, ab1, h, NN, 32, 64, 64, 32, 32, 1.f, 1, 0, 2, recon);
    gemmSm(h,  aw2, ab2, out, NN, 1, 32, 32, 1, 1, 1.f, 3, 0, 1, recon);
    gemmBig(r, dw1, db1, h, NN, HIDD, 64, 64, HIDD, HIDD, 1.f, 1, 0, 2, recon);
    gemmBig(h, dw2, db2, recon, NN, FEAT, HIDD, HIDD, FEAT, FEAT, 1.f, 0, 0, 1, nullptr);
    mse_reduce<<<512, blk, 0, stream>>>(recon, feats, msum);

    // ---- spectral cut ----
    edge_gather<<<dim3(NN, 1), blk, 0, stream>>>(eidx, hv, De, dvis, r, et, 64, 0);
    row_gather<<<dim3(NN, 1), blk, 0, stream>>>(row_start, csr_e, csr_w, dvis, et, nullptr, 1.f, 0.f, yspec, 64, 0);
    spectral_cols<<<64, blk, 0, stream>>>(r, yspec, Dv2, numb, denb);
    finals_kernel<<<1, 64, 0, stream>>>(msum, numb, denb, out);
}

// Round 4
// 745.208 us; speedup vs baseline: 1.1565x; 1.1565x over previous
//
#include <hip/hip_runtime.h>
#include <cmath>

#define NN   3072
#define HIDD 256
#define TK   16
#define FEAT 768   // 3*HID

typedef __attribute__((ext_vector_type(8))) short bf16x8;
typedef __attribute__((ext_vector_type(4))) float f32x4;

__device__ inline unsigned short f2bf(float x) {
    unsigned u = __float_as_uint(x);
    unsigned r = (u + 0x7FFFu + ((u >> 16) & 1u)) >> 16;   // RNE
    return (unsigned short)r;
}
__device__ inline float bf2f(unsigned short h) {
    return __uint_as_float(((unsigned)h) << 16);
}

// ---------------------------------------------------------------- pool
__global__ void pool_kernel(const float* __restrict__ img, float* __restrict__ p) {
    int idx = blockIdx.x * 256 + threadIdx.x;
    if (idx >= NN * 192) return;
    int b = idx / 192, rem = idx % 192;
    int c = rem >> 6, oy = (rem >> 3) & 7, ox = rem & 7;
    const float* base = img + (((size_t)b * 3 + c) * 32 + oy * 4) * 32 + ox * 4;
    float s = 0.f;
#pragma unroll
    for (int iy = 0; iy < 4; iy++)
#pragma unroll
        for (int ix = 0; ix < 4; ix++) s += base[iy * 32 + ix];
    p[idx] = s * 0.0625f;
}

// ---------------------------------------------------------------- fp32 GEMM (round-2 config: 64x64, 4x4)
__global__ void gemm2(const float* __restrict__ A, const float* __restrict__ B,
                      float* __restrict__ P, int M, int Nc, int K,
                      int lda, int ldb, int Kc) {
    __shared__ float As[32][68];
    __shared__ float Bs[32][68];
    int tid = threadIdx.x;
    int tm = tid >> 4, tn = tid & 15;
    int m0 = blockIdx.y * 64, n0 = blockIdx.x * 64;
    int kbeg = blockIdx.z * Kc;
    int kend = min(K, kbeg + Kc);
    float acc[4][4] = {};
    for (int k0 = kbeg; k0 < kend; k0 += 32) {
#pragma unroll
        for (int i = 0; i < 2; i++) {
            int q = tid + i * 256;
            int m = q >> 3, kq = q & 7;
            float4 v = *(const float4*)(A + (size_t)(m0 + m) * lda + k0 + kq * 4);
            int col = m ^ (kq << 2);
            As[kq * 4 + 0][col] = v.x;
            As[kq * 4 + 1][col] = v.y;
            As[kq * 4 + 2][col] = v.z;
            As[kq * 4 + 3][col] = v.w;
        }
#pragma unroll
        for (int i = 0; i < 2; i++) {
            int q = tid + i * 256;
            int k = q >> 4, nq = q & 15;
            int gn = n0 + nq * 4;
            float4 v;
            const float* src = B + (size_t)(k0 + k) * ldb + gn;
            if (gn + 3 < Nc) {
                v = *(const float4*)src;
            } else {
                v.x = (gn + 0 < Nc) ? src[0] : 0.f;
                v.y = (gn + 1 < Nc) ? src[1] : 0.f;
                v.z = (gn + 2 < Nc) ? src[2] : 0.f;
                v.w = (gn + 3 < Nc) ? src[3] : 0.f;
            }
            *(float4*)&Bs[k][nq * 4] = v;
        }
        __syncthreads();
#pragma unroll
        for (int kk = 0; kk < 32; kk++) {
            int swz = kk & 28;
            float a[4], b[4];
            *(float4*)a = *(const float4*)&As[kk][(tm * 4) ^ swz];
            *(float4*)b = *(const float4*)&Bs[kk][tn * 4];
#pragma unroll
            for (int i = 0; i < 4; i++)
#pragma unroll
                for (int j = 0; j < 4; j++) acc[i][j] += a[i] * b[j];
        }
        __syncthreads();
    }
    float* Pp = P + (size_t)blockIdx.z * M * Nc;
    int gn = n0 + tn * 4;
#pragma unroll
    for (int i = 0; i < 4; i++) {
        int gm = m0 + tm * 4 + i;
        if (gn + 3 < Nc) {
            *(float4*)&Pp[(size_t)gm * Nc + gn] = *(float4*)&acc[i][0];
        } else {
#pragma unroll
            for (int j = 0; j < 4; j++)
                if (gn + j < Nc) Pp[(size_t)gm * Nc + gn + j] = acc[i][j];
        }
    }
}

// epilogue: C = act(alpha*sum_s P[s] + bias + acc*C)
__global__ void gemm_epi(const float* __restrict__ P, const float* __restrict__ bias,
                         float* __restrict__ C, int M, int Nc, int ldc, int KS,
                         float alpha, int act, int acc) {
    int idx = blockIdx.x * 256 + threadIdx.x;
    if (idx >= M * Nc) return;
    int m = idx / Nc, n = idx - m * Nc;
    float v = 0.f;
    for (int s = 0; s < KS; s++) v += P[(size_t)s * M * Nc + idx];
    v *= alpha;
    if (bias) v += bias[n];
    if (acc) v += C[(size_t)m * ldc + n];
    if (act == 1) v = fmaxf(v, 0.f);
    else if (act == 2) v = tanhf(v);
    else if (act == 3) v = 1.f / (1.f + expf(-v));
    C[(size_t)m * ldc + n] = v;
}

// ---------------------------------------------------------------- sim = Zc @ Zc^T  (split-bf16 MFMA, K=512)
// Zc: [NN][512] bf16 rows = [hi(256) | lo(256)]. 128x128 tile, 4 waves 2x2,
// wave tile 64x64 = 4x4 mfma_16x16x32 frags. LDS XOR-swizzled 16B chunks.
__global__ __launch_bounds__(256) void sim_mfma(const short* __restrict__ Zc,
                                                float* __restrict__ S) {
    __shared__ short As[128 * 64];
    __shared__ short Bs[128 * 64];
    int tid = threadIdx.x;
    int wave = tid >> 6, lane = tid & 63;
    int wm = (wave >> 1) * 64, wn = (wave & 1) * 64;
    int m0 = blockIdx.y * 128, n0 = blockIdx.x * 128;
    int lrow = lane & 15, lk = lane >> 4;
    f32x4 acc[4][4] = {};

    for (int k0 = 0; k0 < 512; k0 += 64) {
#pragma unroll
        for (int i = 0; i < 4; i++) {
            int q = tid + i * 256;
            int row = q >> 3, c = q & 7;
            int dstoff = row * 128 + ((c ^ (row & 7)) << 4);
            const char* pa = (const char*)Zc + (((size_t)(m0 + row) * 512 + k0) << 1) + (c << 4);
            *(float4*)((char*)As + dstoff) = *(const float4*)pa;
            const char* pb = (const char*)Zc + (((size_t)(n0 + row) * 512 + k0) << 1) + (c << 4);
            *(float4*)((char*)Bs + dstoff) = *(const float4*)pb;
        }
        __syncthreads();
#pragma unroll
        for (int kk = 0; kk < 2; kk++) {
            int ck = kk * 4 + lk;
            bf16x8 af[4], bg[4];
#pragma unroll
            for (int t = 0; t < 4; t++) {
                int ra = wm + t * 16 + lrow;
                af[t] = *(const bf16x8*)((const char*)As + ra * 128 + ((ck ^ (ra & 7)) << 4));
                int rb = wn + t * 16 + lrow;
                bg[t] = *(const bf16x8*)((const char*)Bs + rb * 128 + ((ck ^ (rb & 7)) << 4));
            }
#pragma unroll
            for (int i2 = 0; i2 < 4; i2++)
#pragma unroll
                for (int j2 = 0; j2 < 4; j2++)
                    acc[i2][j2] = __builtin_amdgcn_mfma_f32_16x16x32_bf16(
                        af[i2], bg[j2], acc[i2][j2], 0, 0, 0);
        }
        __syncthreads();
    }
    // C/D layout: col = lane&15, row = (lane>>4)*4 + reg
#pragma unroll
    for (int i2 = 0; i2 < 4; i2++) {
#pragma unroll
        for (int j2 = 0; j2 < 4; j2++) {
            int col = n0 + wn + j2 * 16 + lrow;
            int rowb = m0 + wm + i2 * 16 + lk * 4;
#pragma unroll
            for (int rg = 0; rg < 4; rg++)
                S[(size_t)(rowb + rg) * NN + col] = acc[i2][j2][rg];
        }
    }
}

// ---------------------------------------------------------------- BatchNorm (training stats), per column
__global__ void bn_kernel(float* __restrict__ Y, const float* __restrict__ g,
                          const float* __restrict__ bt) {
    int j = blockIdx.x;
    __shared__ float rs[256], rs2[256];
    float s = 0.f, s2 = 0.f;
    for (int i = threadIdx.x; i < NN; i += 256) {
        float v = Y[(size_t)i * FEAT + j];
        s += v; s2 += v * v;
    }
    rs[threadIdx.x] = s; rs2[threadIdx.x] = s2;
    __syncthreads();
    for (int st = 128; st > 0; st >>= 1) {
        if (threadIdx.x < st) { rs[threadIdx.x] += rs[threadIdx.x + st]; rs2[threadIdx.x] += rs2[threadIdx.x + st]; }
        __syncthreads();
    }
    float mean = rs[0] * (1.f / NN);
    float var = fmaxf(rs2[0] * (1.f / NN) - mean * mean, 0.f);
    float scale = g[j] / sqrtf(var + 1e-5f);
    float shift = bt[j];
    for (int i = threadIdx.x; i < NN; i += 256) {
        size_t o = (size_t)i * FEAT + j;
        Y[o] = (Y[o] - mean) * scale + shift;
    }
}

// ---------------------------------------------------------------- row normalize z -> split-bf16 Zc (in place)
__global__ void rownorm_kernel(const float* __restrict__ Zin, short* __restrict__ Zc) {
    int i = blockIdx.x;
    int c = threadIdx.x;
    __shared__ float rs[256];
    __shared__ float inv;
    float v = Zin[(size_t)i * HIDD + c];
    rs[c] = v * v;
    __syncthreads();
    for (int st = 128; st > 0; st >>= 1) {
        if (c < st) rs[c] += rs[c + st];
        __syncthreads();
    }
    if (c == 0) inv = 1.f / (sqrtf(rs[0]) + 1e-8f);
    __syncthreads();
    float vn = v * inv;
    unsigned short hi = f2bf(vn);
    float lo = vn - bf2f(hi);
    // all threads hold values in regs; safe to overwrite (Zc aliases Zin)
    Zc[(size_t)i * 512 + c] = (short)hi;
    Zc[(size_t)i * 512 + 256 + c] = (short)f2bf(lo);
}

// ---------------------------------------------------------------- top-k per row (k=16)
__global__ void topk_kernel(const float* __restrict__ S, float* __restrict__ hv,
                            int* __restrict__ eidx) {
    int row = blockIdx.x;
    __shared__ float sv[NN];
    __shared__ float rv[256];
    __shared__ int   ri[256];
    const float* srow = S + (size_t)row * NN;
    for (int i = threadIdx.x; i < NN; i += 256) sv[i] = srow[i];
    __syncthreads();
    for (int t = 0; t < TK; t++) {
        float bv = -1e30f; int bi = NN;
        for (int i = threadIdx.x; i < NN; i += 256) {
            float v = sv[i];
            if (v > bv) { bv = v; bi = i; }
        }
        rv[threadIdx.x] = bv; ri[threadIdx.x] = bi;
        __syncthreads();
        for (int st = 128; st > 0; st >>= 1) {
            if (threadIdx.x < st) {
                float ov = rv[threadIdx.x + st]; int oi = ri[threadIdx.x + st];
                if (ov > rv[threadIdx.x] || (ov == rv[threadIdx.x] && oi < ri[threadIdx.x])) {
                    rv[threadIdx.x] = ov; ri[threadIdx.x] = oi;
                }
            }
            __syncthreads();
        }
        if (threadIdx.x == 0) {
            float val = rv[0]; int id = ri[0];
            float sg = 1.f / (1.f + expf(-val));
            hv[row * TK + t] = (sg > 0.5f) ? sg : 0.f;
            eidx[row * TK + t] = id;
            sv[id] = -1e30f;
        }
        __syncthreads();
    }
}

// ---------------------------------------------------------------- edge stats
__global__ void edge_stats(const float* __restrict__ hv, float* __restrict__ De,
                           float* __restrict__ ew) {
    int e = blockIdx.x * 256 + threadIdx.x;
    if (e >= NN) return;
    float s = 0.f;
#pragma unroll
    for (int j = 0; j < TK; j++) s += hv[e * TK + j];
    De[e] = s + 1e-8f;
    ew[e] = s * (1.f / TK);
}

__global__ void scatter_deg(const int* __restrict__ eidx, const float* __restrict__ hv,
                            const float* __restrict__ ew, float* __restrict__ Dv,
                            float* __restrict__ Dv2, int* __restrict__ row_cnt) {
    int t = blockIdx.x * 256 + threadIdx.x;
    if (t >= NN * TK) return;
    int e = t >> 4;
    int v = eidx[t];
    float w = hv[t];
    atomicAdd(&Dv[v], w * ew[e]);
    atomicAdd(&Dv2[v], w);
    atomicAdd(&row_cnt[v], 1);
}

__global__ void deg_fin(const float* __restrict__ Dv, float* __restrict__ Dv2,
                        float* __restrict__ dvis) {
    int v = blockIdx.x * 256 + threadIdx.x;
    if (v >= NN) return;
    dvis[v] = 1.f / sqrtf(Dv[v] + 1e-8f);
    Dv2[v] += 1e-8f;
}

// ---------------------------------------------------------------- CSR build
__global__ void scan_kernel(const int* __restrict__ cnt, int* __restrict__ start) {
    __shared__ int part[256];
    int t = threadIdx.x;
    const int chunk = NN / 256;
    int s = 0;
    for (int i = t * chunk; i < (t + 1) * chunk; i++) s += cnt[i];
    part[t] = s;
    __syncthreads();
    if (t == 0) {
        int a = 0;
        for (int i = 0; i < 256; i++) { int v = part[i]; part[i] = a; a += v; }
    }
    __syncthreads();
    int a = part[t];
    for (int i = t * chunk; i < (t + 1) * chunk; i++) { start[i] = a; a += cnt[i]; }
    if (t == 255) start[NN] = a;
}

__global__ void fill_csr(const int* __restrict__ eidx, const float* __restrict__ hv,
                         const int* __restrict__ start, int* __restrict__ fillc,
                         int* __restrict__ csr_e, float* __restrict__ csr_w) {
    int t = blockIdx.x * 256 + threadIdx.x;
    if (t >= NN * TK) return;
    int e = t >> 4;
    int v = eidx[t];
    int pos = atomicAdd(&fillc[v], 1);
    int pp = start[v] + pos;
    csr_e[pp] = e;
    csr_w[pp] = hv[t];
}

// ---------------------------------------------------------------- sparse H ops (float4 lanes)
// block = 256 threads handling epb edges (epb = 256/F4); ld == F for X and T
__global__ void edge_gather4(const int* __restrict__ eidx, const float* __restrict__ hv,
                             const float* __restrict__ De, const float* __restrict__ dvis,
                             const float* __restrict__ X, float* __restrict__ T,
                             int F4, int epb, int use_dvis) {
    int slot = threadIdx.x / F4;
    if (slot >= epb) return;
    int f = threadIdx.x - slot * F4;
    int e = blockIdx.x * epb + slot;
    const int* ei = eidx + e * TK;
    const float* hw = hv + e * TK;
    float ax = 0.f, ay = 0.f, az = 0.f, aw = 0.f;
#pragma unroll
    for (int j = 0; j < TK; j++) {
        int v = ei[j];
        float w = hw[j];
        if (use_dvis) w *= dvis[v];
        const float4 x = *(const float4*)(X + ((size_t)v * F4 + f) * 4);
        ax = fmaf(w, x.x, ax); ay = fmaf(w, x.y, ay);
        az = fmaf(w, x.z, az); aw = fmaf(w, x.w, aw);
    }
    float inv = 1.f / De[e];
    *(float4*)(T + ((size_t)e * F4 + f) * 4) = make_float4(ax * inv, ay * inv, az * inv, aw * inv);
}

__global__ void row_gather4(const int* __restrict__ start, const int* __restrict__ csr_e,
                            const float* __restrict__ csr_w, const float* __restrict__ dvis,
                            const float* __restrict__ T, const float* __restrict__ Badd,
                            float alpha, float beta, float* __restrict__ Y,
                            int F4, int epb, int use_dvis) {
    int slot = threadIdx.x / F4;
    if (slot >= epb) return;
    int f = threadIdx.x - slot * F4;
    int v = blockIdx.x * epb + slot;
    int s0 = start[v], s1 = start[v + 1];
    float ax = 0.f, ay = 0.f, az = 0.f, aw = 0.f;
    for (int p = s0; p < s1; p++) {
        float w = csr_w[p];
        const float4 x = *(const float4*)(T + ((size_t)csr_e[p] * F4 + f) * 4);
        ax = fmaf(w, x.x, ax); ay = fmaf(w, x.y, ay);
        az = fmaf(w, x.z, az); aw = fmaf(w, x.w, aw);
    }
    float sc = alpha * (use_dvis ? dvis[v] : 1.f);
    float4 o = make_float4(ax * sc, ay * sc, az * sc, aw * sc);
    if (Badd) {
        const float4 b = *(const float4*)(Badd + ((size_t)v * F4 + f) * 4);
        o.x += beta * b.x; o.y += beta * b.y; o.z += beta * b.z; o.w += beta * b.w;
    }
    *(float4*)(Y + ((size_t)v * F4 + f) * 4) = o;
}

// ---------------------------------------------------------------- reductions
__global__ void mse_reduce4(const float* __restrict__ a, const float* __restrict__ b,
                            float* __restrict__ sum) {
    __shared__ float rs[256];
    float s = 0.f;
    const int n4 = NN * FEAT / 4;
    for (int i = blockIdx.x * 256 + threadIdx.x; i < n4; i += gridDim.x * 256) {
        const float4 x = *(const float4*)(a + (size_t)i * 4);
        const float4 y = *(const float4*)(b + (size_t)i * 4);
        float dx = x.x - y.x, dy = x.y - y.y, dz = x.z - y.z, dw = x.w - y.w;
        s += dx * dx + dy * dy + dz * dz + dw * dw;
    }
    rs[threadIdx.x] = s;
    __syncthreads();
    for (int st = 128; st > 0; st >>= 1) {
        if (threadIdx.x < st) rs[threadIdx.x] += rs[threadIdx.x + st];
        __syncthreads();
    }
    if (threadIdx.x == 0) atomicAdd(sum, rs[0]);
}

__global__ void spectral_cols(const float* __restrict__ r, const float* __restrict__ y,
                              const float* __restrict__ Dv2, float* __restrict__ numb,
                              float* __restrict__ denb) {
    int c = blockIdx.x;
    __shared__ float rn[256], rd[256];
    float sn = 0.f, sd = 0.f;
    for (int i = threadIdx.x; i < NN; i += 256) {
        float rv = r[(size_t)i * 64 + c];
        float d2 = Dv2[i];
        float lcx = d2 * rv - y[(size_t)i * 64 + c];
        sn += rv * lcx;
        sd += d2 * rv * rv;
    }
    rn[threadIdx.x] = sn; rd[threadIdx.x] = sd;
    __syncthreads();
    for (int st = 128; st > 0; st >>= 1) {
        if (threadIdx.x < st) { rn[threadIdx.x] += rn[threadIdx.x + st]; rd[threadIdx.x] += rd[threadIdx.x + st]; }
        __syncthreads();
    }
    if (threadIdx.x == 0) { numb[c] = rn[0]; denb[c] = rd[0] + 1e-8f; }
}

__global__ void finals_kernel(const float* __restrict__ msum, const float* __restrict__ numb,
                              const float* __restrict__ denb, float* __restrict__ out) {
    if (threadIdx.x == 0 && blockIdx.x == 0) {
        float s = 0.f;
        for (int c = 0; c < 64; c++) s += numb[c] / denb[c];
        out[NN + 1] = s * (1.f / 64.f);
        out[NN] = msum[0] * (1.f / ((float)NN * FEAT));
    }
}

// ================================================================ launch
extern "C" void kernel_launch(void* const* d_in, const int* in_sizes, int n_in,
                              void* d_out, int out_size, void* d_ws, size_t ws_size,
                              hipStream_t stream) {
    const float* images = (const float*)d_in[0];
    const float* text   = (const float*)d_in[1];
    const float* signal = (const float*)d_in[2];
    const float* iw1 = (const float*)d_in[3];  const float* ib1 = (const float*)d_in[4];
    const float* iw2 = (const float*)d_in[5];  const float* ib2 = (const float*)d_in[6];
    const float* ig  = (const float*)d_in[7];  const float* ibeta = (const float*)d_in[8];
    const float* tw1 = (const float*)d_in[9];  const float* tb1 = (const float*)d_in[10];
    const float* tw2 = (const float*)d_in[11]; const float* tb2 = (const float*)d_in[12];
    const float* tg  = (const float*)d_in[13]; const float* tbeta = (const float*)d_in[14];
    const float* sw1 = (const float*)d_in[15]; const float* sb1 = (const float*)d_in[16];
    const float* sw2 = (const float*)d_in[17]; const float* sb2 = (const float*)d_in[18];
    const float* sg  = (const float*)d_in[19]; const float* sbeta = (const float*)d_in[20];
    const float* gw  = (const float*)d_in[21]; const float* gb = (const float*)d_in[22];
    const float* c1w = (const float*)d_in[23]; const float* c1b = (const float*)d_in[24];
    const float* c2w = (const float*)d_in[25]; const float* c2b = (const float*)d_in[26];
    const float* rw1 = (const float*)d_in[27]; const float* rb1 = (const float*)d_in[28];
    const float* rw2 = (const float*)d_in[29]; const float* rb2 = (const float*)d_in[30];
    const float* aw1 = (const float*)d_in[31]; const float* ab1 = (const float*)d_in[32];
    const float* aw2 = (const float*)d_in[33]; const float* ab2 = (const float*)d_in[34];
    const float* dw1 = (const float*)d_in[35]; const float* db1 = (const float*)d_in[36];
    const float* dw2 = (const float*)d_in[37]; const float* db2 = (const float*)d_in[38];
    float* out = (float*)d_out;

    float* wsf = (float*)d_ws;
    size_t off = 0;
    auto AF = [&](size_t n) { float* q = wsf + off; off += n; return q; };
    float* feats  = AF((size_t)NN * FEAT);
    float* simbuf = AF((size_t)NN * NN);
    float* p      = AF((size_t)NN * 192);
    float* h      = AF((size_t)NN * HIDD);
    float* z      = AF((size_t)NN * HIDD);   // reused in place as Zc (bf16 split, same bytes)
    float* x1     = AF((size_t)NN * HIDD);
    float* x2     = AF((size_t)NN * 128);
    float* r      = AF((size_t)NN * 64);
    float* hv     = AF((size_t)NN * TK);
    float* ew     = AF(NN);
    float* De     = AF(NN);
    float* Dv     = AF(NN);
    float* Dv2    = AF(NN);
    float* dvis   = AF(NN);
    float* csr_w  = AF((size_t)NN * TK);
    float* numb   = AF(64);
    float* denb   = AF(64);
    float* msum   = AF(1);
    int* eidx     = (int*)(wsf + off); off += (size_t)NN * TK;
    int* csr_e    = (int*)(wsf + off); off += (size_t)NN * TK;
    int* row_cnt  = (int*)(wsf + off); off += NN;
    int* row_fill = (int*)(wsf + off); off += NN;
    int* row_start= (int*)(wsf + off); off += NN + 1;

    short* Zc = (short*)z;

    // sim buffer recycled after top-k:
    float* T1    = simbuf;
    float* T2    = simbuf + (size_t)NN * FEAT;
    float* et    = simbuf + (size_t)2 * NN * FEAT;
    float* recon = simbuf + (size_t)3 * NN * FEAT;  // also split-K partial region post-topk
    float* yspec = x2;

    dim3 blk(256);
    auto gemm = [&](const float* A, const float* B, const float* bias, float* C,
                    int M, int Nc, int K, int lda, int ldb, int ldc,
                    float alpha, int act, int acc, int KS, float* part) {
        int nk = K / 32;
        int ks = KS < nk ? KS : nk;
        int kc = ((nk + ks - 1) / ks) * 32;
        int ksp = (K + kc - 1) / kc;
        gemm2<<<dim3((Nc + 63) / 64, M / 64, ksp), blk, 0, stream>>>(A, B, part, M, Nc, K, lda, ldb, kc);
        gemm_epi<<<((size_t)M * Nc + 255) / 256, blk, 0, stream>>>(part, bias, C, M, Nc, ldc, ksp, alpha, act, acc);
    };
    auto eg4 = [&](const float* X, float* T, int F, int use_dvis) {
        int F4 = F / 4, epb = 256 / F4 < 1 ? 1 : 256 / F4;
        edge_gather4<<<NN / epb, blk, 0, stream>>>(eidx, hv, De, dvis, X, T, F4, epb, use_dvis);
    };
    auto rg4 = [&](const float* T, const float* Badd, float alpha, float beta, float* Y,
                   int F, int use_dvis) {
        int F4 = F / 4, epb = 256 / F4 < 1 ? 1 : 256 / F4;
        row_gather4<<<NN / epb, blk, 0, stream>>>(row_start, csr_e, csr_w, dvis, T, Badd,
                                                  alpha, beta, Y, F4, epb, use_dvis);
    };

    const float E1 = 0.60653065971f;  // exp(-0.5)
    const float E2 = 0.36787944117f;  // exp(-1.0)

    // ---- modality MLPs + BN (partials in simbuf: free until sim) ----
    pool_kernel<<<(NN * 192 + 255) / 256, blk, 0, stream>>>(images, p);
    gemm(p, iw1, ib1, h, NN, HIDD, 192, 192, HIDD, HIDD, 1.f, 1, 0, 4, simbuf);
    gemm(h, iw2, ib2, feats + 0, NN, HIDD, HIDD, HIDD, HIDD, FEAT, 1.f, 0, 0, 4, simbuf);
    bn_kernel<<<HIDD, blk, 0, stream>>>(feats + 0, ig, ibeta);

    gemm(text, tw1, tb1, h, NN, HIDD, 768, 768, HIDD, HIDD, 1.f, 1, 0, 4, simbuf);
    gemm(h, tw2, tb2, feats + HIDD, NN, HIDD, HIDD, HIDD, HIDD, FEAT, 1.f, 0, 0, 4, simbuf);
    bn_kernel<<<HIDD, blk, 0, stream>>>(feats + HIDD, tg, tbeta);

    gemm(signal, sw1, sb1, h, NN, HIDD, 256, 256, HIDD, HIDD, 1.f, 1, 0, 4, simbuf);
    gemm(h, sw2, sb2, feats + 2 * HIDD, NN, HIDD, HIDD, HIDD, HIDD, FEAT, 1.f, 0, 0, 4, simbuf);
    bn_kernel<<<HIDD, blk, 0, stream>>>(feats + 2 * HIDD, sg, sbeta);

    // ---- hyperedge generator ----
    gemm(feats, gw, gb, z, NN, HIDD, FEAT, FEAT, HIDD, HIDD, 1.f, 2, 0, 4, simbuf);
    rownorm_kernel<<<NN, blk, 0, stream>>>(z, Zc);
    sim_mfma<<<dim3(NN / 128, NN / 128), blk, 0, stream>>>(Zc, simbuf);
    topk_kernel<<<NN, blk, 0, stream>>>(simbuf, hv, eidx);

    // ---- degrees + CSR of H rows ----
    hipMemsetAsync(Dv, 0, 2 * NN * sizeof(float), stream);
    hipMemsetAsync(msum, 0, sizeof(float), stream);
    hipMemsetAsync(row_cnt, 0, 2 * NN * sizeof(int), stream);
    edge_stats<<<NN / 256, blk, 0, stream>>>(hv, De, ew);
    scatter_deg<<<NN * TK / 256, blk, 0, stream>>>(eidx, hv, ew, Dv, Dv2, row_cnt);
    deg_fin<<<NN / 256, blk, 0, stream>>>(Dv, Dv2, dvis);
    scan_kernel<<<1, blk, 0, stream>>>(row_cnt, row_start);
    fill_csr<<<NN * TK / 256, blk, 0, stream>>>(eidx, hv, row_start, row_fill, csr_e, csr_w);

    // ---- cheb conv 1 (F=768 -> 256); partials in recon region ----
    eg4(feats, et, FEAT, 1);
    rg4(et, nullptr, -1.f, 0.f, T1, FEAT, 1);
    eg4(T1, et, FEAT, 1);
    rg4(et, feats, -2.f, -1.f, T2, FEAT, 1);
    gemm(feats, c1w + 0,                   nullptr, x1, NN, HIDD, FEAT, FEAT, HIDD, HIDD, 1.f, 0, 0, 3, recon);
    gemm(T1,    c1w + (size_t)FEAT*HIDD,   nullptr, x1, NN, HIDD, FEAT, FEAT, HIDD, HIDD, E1,  0, 1, 3, recon);
    gemm(T2,    c1w + (size_t)2*FEAT*HIDD, c1b,     x1, NN, HIDD, FEAT, FEAT, HIDD, HIDD, E2,  1, 1, 3, recon);

    // ---- cheb conv 2 (F=256 -> 128) ----
    eg4(x1, et, HIDD, 1);
    rg4(et, nullptr, -1.f, 0.f, T1, HIDD, 1);
    eg4(T1, et, HIDD, 1);
    rg4(et, x1, -2.f, -1.f, T2, HIDD, 1);
    gemm(x1, c2w + 0,                 nullptr, x2, NN, 128, HIDD, HIDD, 128, 128, 1.f, 0, 0, 4, recon);
    gemm(T1, c2w + (size_t)HIDD*128,  nullptr, x2, NN, 128, HIDD, HIDD, 128, 128, E1,  0, 1, 4, recon);
    gemm(T2, c2w + (size_t)2*HIDD*128, c2b,    x2, NN, 128, HIDD, HIDD, 128, 128, E2,  1, 1, 4, recon);

    // ---- heads ----
    gemm(x2, rw1, rb1, h, NN, 64, 128, 128, 64, 64, 1.f, 1, 0, 2, recon);
    gemm(h,  rw2, rb2, r, NN, 64, 64, 64, 64, 64, 1.f, 0, 0, 2, recon);
    gemm(r,  aw1, ab1, h, NN, 32, 64, 64, 32, 32, 1.f, 1, 0, 2, recon);
    gemm(h,  aw2, ab2, out, NN, 1, 32, 32, 1, 1, 1.f, 3, 0, 1, recon);
    gemm(r,  dw1, db1, h, NN, HIDD, 64, 64, HIDD, HIDD, 1.f, 1, 0, 2, recon);
    gemm(h,  dw2, db2, recon, NN, FEAT, HIDD, HIDD, FEAT, FEAT, 1.f, 0, 0, 1, T1);
    mse_reduce4<<<512, blk, 0, stream>>>(recon, feats, msum);

    // ---- spectral cut ----
    eg4(r, et, 64, 0);
    rg4(et, nullptr, 1.f, 0.f, yspec, 64, 0);
    spectral_cols<<<64, blk, 0, stream>>>(r, yspec, Dv2, numb, denb);
    finals_kernel<<<1, 64, 0, stream>>>(msum, numb, denb, out);
}

// Round 5
// 690.736 us; speedup vs baseline: 1.2477x; 1.0789x over previous
//
#include <hip/hip_runtime.h>
#include <cmath>

#define NN   3072
#define HIDD 256
#define TK   16
#define FEAT 768   // 3*HID

typedef __attribute__((ext_vector_type(8))) short bf16x8;
typedef __attribute__((ext_vector_type(4))) float f32x4;

__device__ inline unsigned short f2bf(float x) {
    unsigned u = __float_as_uint(x);
    unsigned r = (u + 0x7FFFu + ((u >> 16) & 1u)) >> 16;   // RNE
    return (unsigned short)r;
}
__device__ inline float bf2f(unsigned short h) {
    return __uint_as_float(((unsigned)h) << 16);
}

// ---------------------------------------------------------------- pool
__global__ void pool_kernel(const float* __restrict__ img, float* __restrict__ p) {
    int idx = blockIdx.x * 256 + threadIdx.x;
    if (idx >= NN * 192) return;
    int b = idx / 192, rem = idx % 192;
    int c = rem >> 6, oy = (rem >> 3) & 7, ox = rem & 7;
    const float* base = img + (((size_t)b * 3 + c) * 32 + oy * 4) * 32 + ox * 4;
    float s = 0.f;
#pragma unroll
    for (int iy = 0; iy < 4; iy++)
#pragma unroll
        for (int ix = 0; ix < 4; ix++) s += base[iy * 32 + ix];
    p[idx] = s * 0.0625f;
}

// ---------------------------------------------------------------- MFMA split-bf16 GEMM (NN layout)
// C = act(alpha*(A@B) + bias + accf*C); A[M x K] fp32, B[K x N] fp32.
// A,B split to bf16 hi/lo on the fly; 3 products (hh, hl, lh) per k-step.
// BM=128, BN=64, 4 waves (2M x 2N), wave tile 64x32, mfma 16x16x32.
// Requires M%128==0, N%64==0, K%32==0, Kc%32==0. gridDim.z==1 -> fused epilogue.
__global__ __launch_bounds__(256) void gemm_mf(
        const float* __restrict__ A, const float* __restrict__ B,
        const float* __restrict__ bias, float* __restrict__ C, float* __restrict__ P,
        int M, int Nc, int K, int lda, int ldb, int ldc, int Kc,
        float alpha, int act, int accf) {
    __shared__ short Ah[128 * 40];
    __shared__ short Al[128 * 40];
    __shared__ short Bh[64 * 40];
    __shared__ short Bl[64 * 40];
    int tid = threadIdx.x, wave = tid >> 6, lane = tid & 63;
    int wm = (wave >> 1) * 64, wn = (wave & 1) * 32;
    int lrow = lane & 15, lk = lane >> 4;
    int m0 = blockIdx.y * 128, n0 = blockIdx.x * 64;
    int kbeg = blockIdx.z * Kc, kend = min(K, kbeg + Kc);
    f32x4 acc[4][2] = {};

    for (int k0 = kbeg; k0 < kend; k0 += 32) {
        // A tile 128x32: 4 float4/thread, row-major k-contig in LDS (stride 40 shorts)
#pragma unroll
        for (int i = 0; i < 4; i++) {
            int q = tid + i * 256;
            int rowm = q >> 3, kq = q & 7;
            float4 vv = *(const float4*)(A + (size_t)(m0 + rowm) * lda + k0 + kq * 4);
            unsigned short h0 = f2bf(vv.x), h1 = f2bf(vv.y), h2 = f2bf(vv.z), h3 = f2bf(vv.w);
            unsigned short l0 = f2bf(vv.x - bf2f(h0)), l1 = f2bf(vv.y - bf2f(h1));
            unsigned short l2 = f2bf(vv.z - bf2f(h2)), l3 = f2bf(vv.w - bf2f(h3));
            *(short4*)&Ah[rowm * 40 + kq * 4] = make_short4((short)h0, (short)h1, (short)h2, (short)h3);
            *(short4*)&Al[rowm * 40 + kq * 4] = make_short4((short)l0, (short)l1, (short)l2, (short)l3);
        }
        // B tile 32k x 64n: 2 float4/thread, stored transposed [n][k]
#pragma unroll
        for (int i = 0; i < 2; i++) {
            int q = tid + i * 256;
            int kk2 = q >> 4, nq = q & 15;
            float4 vv = *(const float4*)(B + (size_t)(k0 + kk2) * ldb + n0 + nq * 4);
            unsigned short h0 = f2bf(vv.x), h1 = f2bf(vv.y), h2 = f2bf(vv.z), h3 = f2bf(vv.w);
            unsigned short l0 = f2bf(vv.x - bf2f(h0)), l1 = f2bf(vv.y - bf2f(h1));
            unsigned short l2 = f2bf(vv.z - bf2f(h2)), l3 = f2bf(vv.w - bf2f(h3));
            Bh[(nq * 4 + 0) * 40 + kk2] = (short)h0;  Bl[(nq * 4 + 0) * 40 + kk2] = (short)l0;
            Bh[(nq * 4 + 1) * 40 + kk2] = (short)h1;  Bl[(nq * 4 + 1) * 40 + kk2] = (short)l1;
            Bh[(nq * 4 + 2) * 40 + kk2] = (short)h2;  Bl[(nq * 4 + 2) * 40 + kk2] = (short)l2;
            Bh[(nq * 4 + 3) * 40 + kk2] = (short)h3;  Bl[(nq * 4 + 3) * 40 + kk2] = (short)l3;
        }
        __syncthreads();
        bf16x8 ah[4], al[4], bh[2], bl[2];
#pragma unroll
        for (int t2 = 0; t2 < 4; t2++) {
            int ra = wm + t2 * 16 + lrow;
            ah[t2] = *(const bf16x8*)&Ah[ra * 40 + lk * 8];
            al[t2] = *(const bf16x8*)&Al[ra * 40 + lk * 8];
        }
#pragma unroll
        for (int u = 0; u < 2; u++) {
            int rb = wn + u * 16 + lrow;
            bh[u] = *(const bf16x8*)&Bh[rb * 40 + lk * 8];
            bl[u] = *(const bf16x8*)&Bl[rb * 40 + lk * 8];
        }
#pragma unroll
        for (int i2 = 0; i2 < 4; i2++)
#pragma unroll
            for (int j2 = 0; j2 < 2; j2++) {
                acc[i2][j2] = __builtin_amdgcn_mfma_f32_16x16x32_bf16(ah[i2], bh[j2], acc[i2][j2], 0, 0, 0);
                acc[i2][j2] = __builtin_amdgcn_mfma_f32_16x16x32_bf16(ah[i2], bl[j2], acc[i2][j2], 0, 0, 0);
                acc[i2][j2] = __builtin_amdgcn_mfma_f32_16x16x32_bf16(al[i2], bh[j2], acc[i2][j2], 0, 0, 0);
            }
        __syncthreads();
    }

    // C/D layout: col = lane&15, row = (lane>>4)*4 + reg (m89-verified)
    if (gridDim.z == 1) {
#pragma unroll
        for (int i2 = 0; i2 < 4; i2++) {
            int gmb = m0 + wm + i2 * 16 + lk * 4;
#pragma unroll
            for (int j2 = 0; j2 < 2; j2++) {
                int gn = n0 + wn + j2 * 16 + lrow;
#pragma unroll
                for (int rg = 0; rg < 4; rg++) {
                    int gm = gmb + rg;
                    float x = alpha * acc[i2][j2][rg];
                    if (bias) x += bias[gn];
                    if (accf) x += C[(size_t)gm * ldc + gn];
                    if (act == 1) x = fmaxf(x, 0.f);
                    else if (act == 2) x = tanhf(x);
                    else if (act == 3) x = 1.f / (1.f + expf(-x));
                    C[(size_t)gm * ldc + gn] = x;
                }
            }
        }
    } else {
        float* Pp = P + (size_t)blockIdx.z * M * Nc;
#pragma unroll
        for (int i2 = 0; i2 < 4; i2++) {
            int gmb = m0 + wm + i2 * 16 + lk * 4;
#pragma unroll
            for (int j2 = 0; j2 < 2; j2++) {
                int gn = n0 + wn + j2 * 16 + lrow;
#pragma unroll
                for (int rg = 0; rg < 4; rg++)
                    Pp[(size_t)(gmb + rg) * Nc + gn] = acc[i2][j2][rg];
            }
        }
    }
}

// ---------------------------------------------------------------- fp32 GEMM (tiny heads only)
__global__ void gemm2(const float* __restrict__ A, const float* __restrict__ B,
                      float* __restrict__ P, int M, int Nc, int K,
                      int lda, int ldb, int Kc) {
    __shared__ float As[32][68];
    __shared__ float Bs[32][68];
    int tid = threadIdx.x;
    int tm = tid >> 4, tn = tid & 15;
    int m0 = blockIdx.y * 64, n0 = blockIdx.x * 64;
    int kbeg = blockIdx.z * Kc;
    int kend = min(K, kbeg + Kc);
    float acc[4][4] = {};
    for (int k0 = kbeg; k0 < kend; k0 += 32) {
#pragma unroll
        for (int i = 0; i < 2; i++) {
            int q = tid + i * 256;
            int m = q >> 3, kq = q & 7;
            float4 v = *(const float4*)(A + (size_t)(m0 + m) * lda + k0 + kq * 4);
            int col = m ^ (kq << 2);
            As[kq * 4 + 0][col] = v.x;
            As[kq * 4 + 1][col] = v.y;
            As[kq * 4 + 2][col] = v.z;
            As[kq * 4 + 3][col] = v.w;
        }
#pragma unroll
        for (int i = 0; i < 2; i++) {
            int q = tid + i * 256;
            int k = q >> 4, nq = q & 15;
            int gn = n0 + nq * 4;
            float4 v;
            const float* src = B + (size_t)(k0 + k) * ldb + gn;
            if (gn + 3 < Nc) {
                v = *(const float4*)src;
            } else {
                v.x = (gn + 0 < Nc) ? src[0] : 0.f;
                v.y = (gn + 1 < Nc) ? src[1] : 0.f;
                v.z = (gn + 2 < Nc) ? src[2] : 0.f;
                v.w = (gn + 3 < Nc) ? src[3] : 0.f;
            }
            *(float4*)&Bs[k][nq * 4] = v;
        }
        __syncthreads();
#pragma unroll
        for (int kk = 0; kk < 32; kk++) {
            int swz = kk & 28;
            float a[4], b[4];
            *(float4*)a = *(const float4*)&As[kk][(tm * 4) ^ swz];
            *(float4*)b = *(const float4*)&Bs[kk][tn * 4];
#pragma unroll
            for (int i = 0; i < 4; i++)
#pragma unroll
                for (int j = 0; j < 4; j++) acc[i][j] += a[i] * b[j];
        }
        __syncthreads();
    }
    float* Pp = P + (size_t)blockIdx.z * M * Nc;
    int gn = n0 + tn * 4;
#pragma unroll
    for (int i = 0; i < 4; i++) {
        int gm = m0 + tm * 4 + i;
        if (gn + 3 < Nc) {
            *(float4*)&Pp[(size_t)gm * Nc + gn] = *(float4*)&acc[i][0];
        } else {
#pragma unroll
            for (int j = 0; j < 4; j++)
                if (gn + j < Nc) Pp[(size_t)gm * Nc + gn + j] = acc[i][j];
        }
    }
}

// epilogue: C = act(alpha*sum_s P[s] + bias + acc*C)
__global__ void gemm_epi(const float* __restrict__ P, const float* __restrict__ bias,
                         float* __restrict__ C, int M, int Nc, int ldc, int KS,
                         float alpha, int act, int acc) {
    int idx = blockIdx.x * 256 + threadIdx.x;
    if (idx >= M * Nc) return;
    int m = idx / Nc, n = idx - m * Nc;
    float v = 0.f;
    for (int s = 0; s < KS; s++) v += P[(size_t)s * M * Nc + idx];
    v *= alpha;
    if (bias) v += bias[n];
    if (acc) v += C[(size_t)m * ldc + n];
    if (act == 1) v = fmaxf(v, 0.f);
    else if (act == 2) v = tanhf(v);
    else if (act == 3) v = 1.f / (1.f + expf(-v));
    C[(size_t)m * ldc + n] = v;
}

// ---------------------------------------------------------------- sim = Zc @ Zc^T  (split-bf16 MFMA, K=512)
__global__ __launch_bounds__(256) void sim_mfma(const short* __restrict__ Zc,
                                                float* __restrict__ S) {
    __shared__ short As[128 * 64];
    __shared__ short Bs[128 * 64];
    int tid = threadIdx.x;
    int wave = tid >> 6, lane = tid & 63;
    int wm = (wave >> 1) * 64, wn = (wave & 1) * 64;
    int m0 = blockIdx.y * 128, n0 = blockIdx.x * 128;
    int lrow = lane & 15, lk = lane >> 4;
    f32x4 acc[4][4] = {};

    for (int k0 = 0; k0 < 512; k0 += 64) {
#pragma unroll
        for (int i = 0; i < 4; i++) {
            int q = tid + i * 256;
            int row = q >> 3, c = q & 7;
            int dstoff = row * 128 + ((c ^ (row & 7)) << 4);
            const char* pa = (const char*)Zc + (((size_t)(m0 + row) * 512 + k0) << 1) + (c << 4);
            *(float4*)((char*)As + dstoff) = *(const float4*)pa;
            const char* pb = (const char*)Zc + (((size_t)(n0 + row) * 512 + k0) << 1) + (c << 4);
            *(float4*)((char*)Bs + dstoff) = *(const float4*)pb;
        }
        __syncthreads();
#pragma unroll
        for (int kk = 0; kk < 2; kk++) {
            int ck = kk * 4 + lk;
            bf16x8 af[4], bg[4];
#pragma unroll
            for (int t = 0; t < 4; t++) {
                int ra = wm + t * 16 + lrow;
                af[t] = *(const bf16x8*)((const char*)As + ra * 128 + ((ck ^ (ra & 7)) << 4));
                int rb = wn + t * 16 + lrow;
                bg[t] = *(const bf16x8*)((const char*)Bs + rb * 128 + ((ck ^ (rb & 7)) << 4));
            }
#pragma unroll
            for (int i2 = 0; i2 < 4; i2++)
#pragma unroll
                for (int j2 = 0; j2 < 4; j2++)
                    acc[i2][j2] = __builtin_amdgcn_mfma_f32_16x16x32_bf16(
                        af[i2], bg[j2], acc[i2][j2], 0, 0, 0);
        }
        __syncthreads();
    }
#pragma unroll
    for (int i2 = 0; i2 < 4; i2++) {
#pragma unroll
        for (int j2 = 0; j2 < 4; j2++) {
            int col = n0 + wn + j2 * 16 + lrow;
            int rowb = m0 + wm + i2 * 16 + lk * 4;
#pragma unroll
            for (int rg = 0; rg < 4; rg++)
                S[(size_t)(rowb + rg) * NN + col] = acc[i2][j2][rg];
        }
    }
}

// ---------------------------------------------------------------- BatchNorm (training stats), per column
__global__ void bn_kernel(float* __restrict__ Y, const float* __restrict__ g,
                          const float* __restrict__ bt) {
    int j = blockIdx.x;
    __shared__ float rs[256], rs2[256];
    float s = 0.f, s2 = 0.f;
    for (int i = threadIdx.x; i < NN; i += 256) {
        float v = Y[(size_t)i * FEAT + j];
        s += v; s2 += v * v;
    }
    rs[threadIdx.x] = s; rs2[threadIdx.x] = s2;
    __syncthreads();
    for (int st = 128; st > 0; st >>= 1) {
        if (threadIdx.x < st) { rs[threadIdx.x] += rs[threadIdx.x + st]; rs2[threadIdx.x] += rs2[threadIdx.x + st]; }
        __syncthreads();
    }
    float mean = rs[0] * (1.f / NN);
    float var = fmaxf(rs2[0] * (1.f / NN) - mean * mean, 0.f);
    float scale = g[j] / sqrtf(var + 1e-5f);
    float shift = bt[j];
    for (int i = threadIdx.x; i < NN; i += 256) {
        size_t o = (size_t)i * FEAT + j;
        Y[o] = (Y[o] - mean) * scale + shift;
    }
}

// ---------------------------------------------------------------- row normalize z -> split-bf16 Zc (in place)
__global__ void rownorm_kernel(const float* __restrict__ Zin, short* __restrict__ Zc) {
    int i = blockIdx.x;
    int c = threadIdx.x;
    __shared__ float rs[256];
    __shared__ float inv;
    float v = Zin[(size_t)i * HIDD + c];
    rs[c] = v * v;
    __syncthreads();
    for (int st = 128; st > 0; st >>= 1) {
        if (c < st) rs[c] += rs[c + st];
        __syncthreads();
    }
    if (c == 0) inv = 1.f / (sqrtf(rs[0]) + 1e-8f);
    __syncthreads();
    float vn = v * inv;
    unsigned short hi = f2bf(vn);
    float lo = vn - bf2f(hi);
    Zc[(size_t)i * 512 + c] = (short)hi;
    Zc[(size_t)i * 512 + 256 + c] = (short)f2bf(lo);
}

// ---------------------------------------------------------------- top-k per row (k=16): 1 wave/row, all in VGPRs
__global__ __launch_bounds__(256) void topk_kernel(const float* __restrict__ S,
                                                   float* __restrict__ hv,
                                                   int* __restrict__ eidx) {
    int lane = threadIdx.x & 63;
    int row = blockIdx.x * 4 + (threadIdx.x >> 6);
    const float4* srow = (const float4*)(S + (size_t)row * NN);
    float v[48];
#pragma unroll
    for (int c = 0; c < 12; c++) {
        float4 q = srow[c * 64 + lane];
        v[c * 4 + 0] = q.x; v[c * 4 + 1] = q.y; v[c * 4 + 2] = q.z; v[c * 4 + 3] = q.w;
    }
    for (int t = 0; t < TK; t++) {
        float bv = -3.4e38f; int bi = 1 << 30;
#pragma unroll
        for (int i = 0; i < 48; i++) {
            int col = ((i >> 2) * 64 + lane) * 4 + (i & 3);
            bool b = (v[i] > bv) || (v[i] == bv && col < bi);
            bv = b ? v[i] : bv;
            bi = b ? col : bi;
        }
#pragma unroll
        for (int s = 1; s < 64; s <<= 1) {
            float ov = __shfl_xor(bv, s);
            int oi = __shfl_xor(bi, s);
            bool b = (ov > bv) || (ov == bv && oi < bi);
            bv = b ? ov : bv;
            bi = b ? oi : bi;
        }
        if (lane == 0) {
            float sg = 1.f / (1.f + expf(-bv));
            hv[row * TK + t] = (sg > 0.5f) ? sg : 0.f;
            eidx[row * TK + t] = bi;
        }
        int f = bi >> 2;
        if ((f & 63) == lane) {
            int li = (f >> 6) * 4 + (bi & 3);
#pragma unroll
            for (int i = 0; i < 48; i++)
                if (i == li) v[i] = -3.4e38f;
        }
    }
}

// ---------------------------------------------------------------- edge stats
__global__ void edge_stats(const float* __restrict__ hv, float* __restrict__ De,
                           float* __restrict__ ew) {
    int e = blockIdx.x * 256 + threadIdx.x;
    if (e >= NN) return;
    float s = 0.f;
#pragma unroll
    for (int j = 0; j < TK; j++) s += hv[e * TK + j];
    De[e] = s + 1e-8f;
    ew[e] = s * (1.f / TK);
}

__global__ void scatter_deg(const int* __restrict__ eidx, const float* __restrict__ hv,
                            const float* __restrict__ ew, float* __restrict__ Dv,
                            float* __restrict__ Dv2, int* __restrict__ row_cnt) {
    int t = blockIdx.x * 256 + threadIdx.x;
    if (t >= NN * TK) return;
    int e = t >> 4;
    int v = eidx[t];
    float w = hv[t];
    atomicAdd(&Dv[v], w * ew[e]);
    atomicAdd(&Dv2[v], w);
    atomicAdd(&row_cnt[v], 1);
}

__global__ void deg_fin(const float* __restrict__ Dv, float* __restrict__ Dv2,
                        float* __restrict__ dvis) {
    int v = blockIdx.x * 256 + threadIdx.x;
    if (v >= NN) return;
    dvis[v] = 1.f / sqrtf(Dv[v] + 1e-8f);
    Dv2[v] += 1e-8f;
}

// ---------------------------------------------------------------- CSR build
__global__ void scan_kernel(const int* __restrict__ cnt, int* __restrict__ start) {
    __shared__ int part[256];
    int t = threadIdx.x;
    const int chunk = NN / 256;
    int s = 0;
    for (int i = t * chunk; i < (t + 1) * chunk; i++) s += cnt[i];
    part[t] = s;
    __syncthreads();
    if (t == 0) {
        int a = 0;
        for (int i = 0; i < 256; i++) { int v = part[i]; part[i] = a; a += v; }
    }
    __syncthreads();
    int a = part[t];
    for (int i = t * chunk; i < (t + 1) * chunk; i++) { start[i] = a; a += cnt[i]; }
    if (t == 255) start[NN] = a;
}

__global__ void fill_csr(const int* __restrict__ eidx, const float* __restrict__ hv,
                         const int* __restrict__ start, int* __restrict__ fillc,
                         int* __restrict__ csr_e, float* __restrict__ csr_w) {
    int t = blockIdx.x * 256 + threadIdx.x;
    if (t >= NN * TK) return;
    int e = t >> 4;
    int v = eidx[t];
    int pos = atomicAdd(&fillc[v], 1);
    int pp = start[v] + pos;
    csr_e[pp] = e;
    csr_w[pp] = hv[t];
}

// ---------------------------------------------------------------- sparse H ops (float4 lanes)
__global__ void edge_gather4(const int* __restrict__ eidx, const float* __restrict__ hv,
                             const float* __restrict__ De, const float* __restrict__ dvis,
                             const float* __restrict__ X, float* __restrict__ T,
                             int F4, int epb, int use_dvis) {
    int slot = threadIdx.x / F4;
    if (slot >= epb) return;
    int f = threadIdx.x - slot * F4;
    int e = blockIdx.x * epb + slot;
    const int* ei = eidx + e * TK;
    const float* hw = hv + e * TK;
    float ax = 0.f, ay = 0.f, az = 0.f, aw = 0.f;
#pragma unroll
    for (int j = 0; j < TK; j++) {
        int v = ei[j];
        float w = hw[j];
        if (use_dvis) w *= dvis[v];
        const float4 x = *(const float4*)(X + ((size_t)v * F4 + f) * 4);
        ax = fmaf(w, x.x, ax); ay = fmaf(w, x.y, ay);
        az = fmaf(w, x.z, az); aw = fmaf(w, x.w, aw);
    }
    float inv = 1.f / De[e];
    *(float4*)(T + ((size_t)e * F4 + f) * 4) = make_float4(ax * inv, ay * inv, az * inv, aw * inv);
}

__global__ void row_gather4(const int* __restrict__ start, const int* __restrict__ csr_e,
                            const float* __restrict__ csr_w, const float* __restrict__ dvis,
                            const float* __restrict__ T, const float* __restrict__ Badd,
                            float alpha, float beta, float* __restrict__ Y,
                            int F4, int epb, int use_dvis) {
    int slot = threadIdx.x / F4;
    if (slot >= epb) return;
    int f = threadIdx.x - slot * F4;
    int v = blockIdx.x * epb + slot;
    int s0 = start[v], s1 = start[v + 1];
    float ax = 0.f, ay = 0.f, az = 0.f, aw = 0.f;
    for (int p = s0; p < s1; p++) {
        float w = csr_w[p];
        const float4 x = *(const float4*)(T + ((size_t)csr_e[p] * F4 + f) * 4);
        ax = fmaf(w, x.x, ax); ay = fmaf(w, x.y, ay);
        az = fmaf(w, x.z, az); aw = fmaf(w, x.w, aw);
    }
    float sc = alpha * (use_dvis ? dvis[v] : 1.f);
    float4 o = make_float4(ax * sc, ay * sc, az * sc, aw * sc);
    if (Badd) {
        const float4 b = *(const float4*)(Badd + ((size_t)v * F4 + f) * 4);
        o.x += beta * b.x; o.y += beta * b.y; o.z += beta * b.z; o.w += beta * b.w;
    }
    *(float4*)(Y + ((size_t)v * F4 + f) * 4) = o;
}

// ---------------------------------------------------------------- reductions
__global__ void mse_reduce4(const float* __restrict__ a, const float* __restrict__ b,
                            float* __restrict__ sum) {
    __shared__ float rs[256];
    float s = 0.f;
    const int n4 = NN * FEAT / 4;
    for (int i = blockIdx.x * 256 + threadIdx.x; i < n4; i += gridDim.x * 256) {
        const float4 x = *(const float4*)(a + (size_t)i * 4);
        const float4 y = *(const float4*)(b + (size_t)i * 4);
        float dx = x.x - y.x, dy = x.y - y.y, dz = x.z - y.z, dw = x.w - y.w;
        s += dx * dx + dy * dy + dz * dz + dw * dw;
    }
    rs[threadIdx.x] = s;
    __syncthreads();
    for (int st = 128; st > 0; st >>= 1) {
        if (threadIdx.x < st) rs[threadIdx.x] += rs[threadIdx.x + st];
        __syncthreads();
    }
    if (threadIdx.x == 0) atomicAdd(sum, rs[0]);
}

__global__ void spectral_cols(const float* __restrict__ r, const float* __restrict__ y,
                              const float* __restrict__ Dv2, float* __restrict__ numb,
                              float* __restrict__ denb) {
    int c = blockIdx.x;
    __shared__ float rn[256], rd[256];
    float sn = 0.f, sd = 0.f;
    for (int i = threadIdx.x; i < NN; i += 256) {
        float rv = r[(size_t)i * 64 + c];
        float d2 = Dv2[i];
        float lcx = d2 * rv - y[(size_t)i * 64 + c];
        sn += rv * lcx;
        sd += d2 * rv * rv;
    }
    rn[threadIdx.x] = sn; rd[threadIdx.x] = sd;
    __syncthreads();
    for (int st = 128; st > 0; st >>= 1) {
        if (threadIdx.x < st) { rn[threadIdx.x] += rn[threadIdx.x + st]; rd[threadIdx.x] += rd[threadIdx.x + st]; }
        __syncthreads();
    }
    if (threadIdx.x == 0) { numb[c] = rn[0]; denb[c] = rd[0] + 1e-8f; }
}

__global__ void finals_kernel(const float* __restrict__ msum, const float* __restrict__ numb,
                              const float* __restrict__ denb, float* __restrict__ out) {
    if (threadIdx.x == 0 && blockIdx.x == 0) {
        float s = 0.f;
        for (int c = 0; c < 64; c++) s += numb[c] / denb[c];
        out[NN + 1] = s * (1.f / 64.f);
        out[NN] = msum[0] * (1.f / ((float)NN * FEAT));
    }
}

// ================================================================ launch
extern "C" void kernel_launch(void* const* d_in, const int* in_sizes, int n_in,
                              void* d_out, int out_size, void* d_ws, size_t ws_size,
                              hipStream_t stream) {
    const float* images = (const float*)d_in[0];
    const float* text   = (const float*)d_in[1];
    const float* signal = (const float*)d_in[2];
    const float* iw1 = (const float*)d_in[3];  const float* ib1 = (const float*)d_in[4];
    const float* iw2 = (const float*)d_in[5];  const float* ib2 = (const float*)d_in[6];
    const float* ig  = (const float*)d_in[7];  const float* ibeta = (const float*)d_in[8];
    const float* tw1 = (const float*)d_in[9];  const float* tb1 = (const float*)d_in[10];
    const float* tw2 = (const float*)d_in[11]; const float* tb2 = (const float*)d_in[12];
    const float* tg  = (const float*)d_in[13]; const float* tbeta = (const float*)d_in[14];
    const float* sw1 = (const float*)d_in[15]; const float* sb1 = (const float*)d_in[16];
    const float* sw2 = (const float*)d_in[17]; const float* sb2 = (const float*)d_in[18];
    const float* sg  = (const float*)d_in[19]; const float* sbeta = (const float*)d_in[20];
    const float* gw  = (const float*)d_in[21]; const float* gb = (const float*)d_in[22];
    const float* c1w = (const float*)d_in[23]; const float* c1b = (const float*)d_in[24];
    const float* c2w = (const float*)d_in[25]; const float* c2b = (const float*)d_in[26];
    const float* rw1 = (const float*)d_in[27]; const float* rb1 = (const float*)d_in[28];
    const float* rw2 = (const float*)d_in[29]; const float* rb2 = (const float*)d_in[30];
    const float* aw1 = (const float*)d_in[31]; const float* ab1 = (const float*)d_in[32];
    const float* aw2 = (const float*)d_in[33]; const float* ab2 = (const float*)d_in[34];
    const float* dw1 = (const float*)d_in[35]; const float* db1 = (const float*)d_in[36];
    const float* dw2 = (const float*)d_in[37]; const float* db2 = (const float*)d_in[38];
    float* out = (float*)d_out;

    float* wsf = (float*)d_ws;
    size_t off = 0;
    auto AF = [&](size_t n) { float* q = wsf + off; off += n; return q; };
    float* feats  = AF((size_t)NN * FEAT);
    float* simbuf = AF((size_t)NN * NN);
    float* p      = AF((size_t)NN * 192);
    float* h      = AF((size_t)NN * HIDD);
    float* z      = AF((size_t)NN * HIDD);   // reused in place as Zc (bf16 split)
    float* x1     = AF((size_t)NN * HIDD);
    float* x2     = AF((size_t)NN * 128);
    float* r      = AF((size_t)NN * 64);
    float* hv     = AF((size_t)NN * TK);
    float* ew     = AF(NN);
    float* De     = AF(NN);
    float* Dv     = AF(NN);
    float* Dv2    = AF(NN);
    float* dvis   = AF(NN);
    float* csr_w  = AF((size_t)NN * TK);
    float* numb   = AF(64);
    float* denb   = AF(64);
    float* msum   = AF(1);
    int* eidx     = (int*)(wsf + off); off += (size_t)NN * TK;
    int* csr_e    = (int*)(wsf + off); off += (size_t)NN * TK;
    int* row_cnt  = (int*)(wsf + off); off += NN;
    int* row_fill = (int*)(wsf + off); off += NN;
    int* row_start= (int*)(wsf + off); off += NN + 1;

    short* Zc = (short*)z;

    // sim buffer recycled after top-k:
    float* T1    = simbuf;
    float* T2    = simbuf + (size_t)NN * FEAT;
    float* et    = simbuf + (size_t)2 * NN * FEAT;
    float* recon = simbuf + (size_t)3 * NN * FEAT;  // split-K partial region post-topk
    float* yspec = x2;

    dim3 blk(256);
    // MFMA GEMM (N%64==0, M=3072)
    auto gemmF = [&](const float* A, const float* B, const float* bias, float* C,
                     int M, int Nc, int K, int lda, int ldb, int ldc,
                     float alpha, int act, int acc, int KS, float* part) {
        int nk = K / 32;
        int ks = KS < nk ? KS : nk; if (ks < 1) ks = 1;
        int kc = ((nk + ks - 1) / ks) * 32;
        int ksp = (K + kc - 1) / kc;
        gemm_mf<<<dim3(Nc / 64, M / 128, ksp), blk, 0, stream>>>(
            A, B, bias, C, part, M, Nc, K, lda, ldb, ldc, kc, alpha, act, acc);
        if (ksp > 1)
            gemm_epi<<<((size_t)M * Nc + 255) / 256, blk, 0, stream>>>(
                part, bias, C, M, Nc, ldc, ksp, alpha, act, acc);
    };
    // fp32 GEMM for tiny-N heads
    auto gemmSm = [&](const float* A, const float* B, const float* bias, float* C,
                      int M, int Nc, int K, int lda, int ldb, int ldc,
                      float alpha, int act, int acc, int KS, float* part) {
        int nk = K / 32;
        int ks = KS < nk ? KS : nk; if (ks < 1) ks = 1;
        int kc = ((nk + ks - 1) / ks) * 32;
        int ksp = (K + kc - 1) / kc;
        gemm2<<<dim3((Nc + 63) / 64, M / 64, ksp), blk, 0, stream>>>(A, B, part, M, Nc, K, lda, ldb, kc);
        gemm_epi<<<((size_t)M * Nc + 255) / 256, blk, 0, stream>>>(part, bias, C, M, Nc, ldc, ksp, alpha, act, acc);
    };
    auto eg4 = [&](const float* X, float* T, int F, int use_dvis) {
        int F4 = F / 4, epb = 256 / F4 < 1 ? 1 : 256 / F4;
        edge_gather4<<<NN / epb, blk, 0, stream>>>(eidx, hv, De, dvis, X, T, F4, epb, use_dvis);
    };
    auto rg4 = [&](const float* T, const float* Badd, float alpha, float beta, float* Y,
                   int F, int use_dvis) {
        int F4 = F / 4, epb = 256 / F4 < 1 ? 1 : 256 / F4;
        row_gather4<<<NN / epb, blk, 0, stream>>>(row_start, csr_e, csr_w, dvis, T, Badd,
                                                  alpha, beta, Y, F4, epb, use_dvis);
    };

    const float E1 = 0.60653065971f;  // exp(-0.5)
    const float E2 = 0.36787944117f;  // exp(-1.0)

    // ---- modality MLPs + BN (partials in simbuf: free until sim) ----
    pool_kernel<<<(NN * 192 + 255) / 256, blk, 0, stream>>>(images, p);
    gemmF(p, iw1, ib1, h, NN, HIDD, 192, 192, HIDD, HIDD, 1.f, 1, 0, 4, simbuf);
    gemmF(h, iw2, ib2, feats + 0, NN, HIDD, HIDD, HIDD, HIDD, FEAT, 1.f, 0, 0, 4, simbuf);
    bn_kernel<<<HIDD, blk, 0, stream>>>(feats + 0, ig, ibeta);

    gemmF(text, tw1, tb1, h, NN, HIDD, 768, 768, HIDD, HIDD, 1.f, 1, 0, 4, simbuf);
    gemmF(h, tw2, tb2, feats + HIDD, NN, HIDD, HIDD, HIDD, HIDD, FEAT, 1.f, 0, 0, 4, simbuf);
    bn_kernel<<<HIDD, blk, 0, stream>>>(feats + HIDD, tg, tbeta);

    gemmF(signal, sw1, sb1, h, NN, HIDD, 256, 256, HIDD, HIDD, 1.f, 1, 0, 4, simbuf);
    gemmF(h, sw2, sb2, feats + 2 * HIDD, NN, HIDD, HIDD, HIDD, HIDD, FEAT, 1.f, 0, 0, 4, simbuf);
    bn_kernel<<<HIDD, blk, 0, stream>>>(feats + 2 * HIDD, sg, sbeta);

    // ---- hyperedge generator ----
    gemmF(feats, gw, gb, z, NN, HIDD, FEAT, FEAT, HIDD, HIDD, 1.f, 2, 0, 4, simbuf);
    rownorm_kernel<<<NN, blk, 0, stream>>>(z, Zc);
    sim_mfma<<<dim3(NN / 128, NN / 128), blk, 0, stream>>>(Zc, simbuf);
    topk_kernel<<<NN / 4, blk, 0, stream>>>(simbuf, hv, eidx);

    // ---- degrees + CSR of H rows ----
    hipMemsetAsync(Dv, 0, 2 * NN * sizeof(float), stream);
    hipMemsetAsync(msum, 0, sizeof(float), stream);
    hipMemsetAsync(row_cnt, 0, 2 * NN * sizeof(int), stream);
    edge_stats<<<NN / 256, blk, 0, stream>>>(hv, De, ew);
    scatter_deg<<<NN * TK / 256, blk, 0, stream>>>(eidx, hv, ew, Dv, Dv2, row_cnt);
    deg_fin<<<NN / 256, blk, 0, stream>>>(Dv, Dv2, dvis);
    scan_kernel<<<1, blk, 0, stream>>>(row_cnt, row_start);
    fill_csr<<<NN * TK / 256, blk, 0, stream>>>(eidx, hv, row_start, row_fill, csr_e, csr_w);

    // ---- cheb conv 1 (F=768 -> 256); partials in recon region (3 x 3.1MB) ----
    eg4(feats, et, FEAT, 1);
    rg4(et, nullptr, -1.f, 0.f, T1, FEAT, 1);
    eg4(T1, et, FEAT, 1);
    rg4(et, feats, -2.f, -1.f, T2, FEAT, 1);
    gemmF(feats, c1w + 0,                   nullptr, x1, NN, HIDD, FEAT, FEAT, HIDD, HIDD, 1.f, 0, 0, 3, recon);
    gemmF(T1,    c1w + (size_t)FEAT*HIDD,   nullptr, x1, NN, HIDD, FEAT, FEAT, HIDD, HIDD, E1,  0, 1, 3, recon);
    gemmF(T2,    c1w + (size_t)2*FEAT*HIDD, c1b,     x1, NN, HIDD, FEAT, FEAT, HIDD, HIDD, E2,  1, 1, 3, recon);

    // ---- cheb conv 2 (F=256 -> 128) ----
    eg4(x1, et, HIDD, 1);
    rg4(et, nullptr, -1.f, 0.f, T1, HIDD, 1);
    eg4(T1, et, HIDD, 1);
    rg4(et, x1, -2.f, -1.f, T2, HIDD, 1);
    gemmF(x1, c2w + 0,                 nullptr, x2, NN, 128, HIDD, HIDD, 128, 128, 1.f, 0, 0, 4, recon);
    gemmF(T1, c2w + (size_t)HIDD*128,  nullptr, x2, NN, 128, HIDD, HIDD, 128, 128, E1,  0, 1, 4, recon);
    gemmF(T2, c2w + (size_t)2*HIDD*128, c2b,    x2, NN, 128, HIDD, HIDD, 128, 128, E2,  1, 1, 4, recon);

    // ---- heads ----
    gemmF(x2, rw1, rb1, h, NN, 64, 128, 128, 64, 64, 1.f, 1, 0, 2, recon);
    gemmF(h,  rw2, rb2, r, NN, 64, 64, 64, 64, 64, 1.f, 0, 0, 2, recon);
    gemmSm(r,  aw1, ab1, h, NN, 32, 64, 64, 32, 32, 1.f, 1, 0, 2, recon);
    gemmSm(h,  aw2, ab2, out, NN, 1, 32, 32, 1, 1, 1.f, 3, 0, 1, recon);
    gemmF(r,  dw1, db1, h, NN, HIDD, 64, 64, HIDD, HIDD, 1.f, 1, 0, 2, recon);
    gemmF(h,  dw2, db2, recon, NN, FEAT, HIDD, HIDD, FEAT, FEAT, 1.f, 0, 0, 1, T1);
    mse_reduce4<<<512, blk, 0, stream>>>(recon, feats, msum);

    // ---- spectral cut ----
    eg4(r, et, 64, 0);
    rg4(et, nullptr, 1.f, 0.f, yspec, 64, 0);
    spectral_cols<<<64, blk, 0, stream>>>(r, yspec, Dv2, numb, denb);
    finals_kernel<<<1, 64, 0, stream>>>(msum, numb, denb, out);
}

// Round 6
// 582.963 us; speedup vs baseline: 1.4784x; 1.1849x over previous
//
#include <hip/hip_runtime.h>
#include <cmath>

#define NN   3072
#define HIDD 256
#define TK   16
#define FEAT 768   // 3*HID

typedef __attribute__((ext_vector_type(8))) short bf16x8;
typedef __attribute__((ext_vector_type(4))) float f32x4;

__device__ inline unsigned short f2bf(float x) {
    unsigned u = __float_as_uint(x);
    unsigned r = (u + 0x7FFFu + ((u >> 16) & 1u)) >> 16;   // RNE
    return (unsigned short)r;
}
__device__ inline float bf2f(unsigned short h) {
    return __uint_as_float(((unsigned)h) << 16);
}

// ---------------------------------------------------------------- pool
__global__ void pool_kernel(const float* __restrict__ img, float* __restrict__ p) {
    int idx = blockIdx.x * 256 + threadIdx.x;
    if (idx >= NN * 192) return;
    int b = idx / 192, rem = idx % 192;
    int c = rem >> 6, oy = (rem >> 3) & 7, ox = rem & 7;
    const float* base = img + (((size_t)b * 3 + c) * 32 + oy * 4) * 32 + ox * 4;
    float s = 0.f;
#pragma unroll
    for (int iy = 0; iy < 4; iy++)
#pragma unroll
        for (int ix = 0; ix < 4; ix++) s += base[iy * 32 + ix];
    p[idx] = s * 0.0625f;
}

// ---------------------------------------------------------------- MFMA split-bf16 GEMM (single source)
__global__ __launch_bounds__(256) void gemm_mf(
        const float* __restrict__ A, const float* __restrict__ B,
        const float* __restrict__ bias, float* __restrict__ C, float* __restrict__ P,
        int M, int Nc, int K, int lda, int ldb, int ldc, int Kc,
        float alpha, int act, int accf) {
    __shared__ short Ah[128 * 40];
    __shared__ short Al[128 * 40];
    __shared__ short Bh[64 * 40];
    __shared__ short Bl[64 * 40];
    int tid = threadIdx.x, wave = tid >> 6, lane = tid & 63;
    int wm = (wave >> 1) * 64, wn = (wave & 1) * 32;
    int lrow = lane & 15, lk = lane >> 4;
    int m0 = blockIdx.y * 128, n0 = blockIdx.x * 64;
    int kbeg = blockIdx.z * Kc, kend = min(K, kbeg + Kc);
    f32x4 acc[4][2] = {};

    for (int k0 = kbeg; k0 < kend; k0 += 32) {
#pragma unroll
        for (int i = 0; i < 4; i++) {
            int q = tid + i * 256;
            int rowm = q >> 3, kq = q & 7;
            float4 vv = *(const float4*)(A + (size_t)(m0 + rowm) * lda + k0 + kq * 4);
            unsigned short h0 = f2bf(vv.x), h1 = f2bf(vv.y), h2 = f2bf(vv.z), h3 = f2bf(vv.w);
            unsigned short l0 = f2bf(vv.x - bf2f(h0)), l1 = f2bf(vv.y - bf2f(h1));
            unsigned short l2 = f2bf(vv.z - bf2f(h2)), l3 = f2bf(vv.w - bf2f(h3));
            *(short4*)&Ah[rowm * 40 + kq * 4] = make_short4((short)h0, (short)h1, (short)h2, (short)h3);
            *(short4*)&Al[rowm * 40 + kq * 4] = make_short4((short)l0, (short)l1, (short)l2, (short)l3);
        }
#pragma unroll
        for (int i = 0; i < 2; i++) {
            int q = tid + i * 256;
            int kk2 = q >> 4, nq = q & 15;
            float4 vv = *(const float4*)(B + (size_t)(k0 + kk2) * ldb + n0 + nq * 4);
            unsigned short h0 = f2bf(vv.x), h1 = f2bf(vv.y), h2 = f2bf(vv.z), h3 = f2bf(vv.w);
            unsigned short l0 = f2bf(vv.x - bf2f(h0)), l1 = f2bf(vv.y - bf2f(h1));
            unsigned short l2 = f2bf(vv.z - bf2f(h2)), l3 = f2bf(vv.w - bf2f(h3));
            Bh[(nq * 4 + 0) * 40 + kk2] = (short)h0;  Bl[(nq * 4 + 0) * 40 + kk2] = (short)l0;
            Bh[(nq * 4 + 1) * 40 + kk2] = (short)h1;  Bl[(nq * 4 + 1) * 40 + kk2] = (short)l1;
            Bh[(nq * 4 + 2) * 40 + kk2] = (short)h2;  Bl[(nq * 4 + 2) * 40 + kk2] = (short)l2;
            Bh[(nq * 4 + 3) * 40 + kk2] = (short)h3;  Bl[(nq * 4 + 3) * 40 + kk2] = (short)l3;
        }
        __syncthreads();
        bf16x8 ah[4], al[4], bh[2], bl[2];
#pragma unroll
        for (int t2 = 0; t2 < 4; t2++) {
            int ra = wm + t2 * 16 + lrow;
            ah[t2] = *(const bf16x8*)&Ah[ra * 40 + lk * 8];
            al[t2] = *(const bf16x8*)&Al[ra * 40 + lk * 8];
        }
#pragma unroll
        for (int u = 0; u < 2; u++) {
            int rb = wn + u * 16 + lrow;
            bh[u] = *(const bf16x8*)&Bh[rb * 40 + lk * 8];
            bl[u] = *(const bf16x8*)&Bl[rb * 40 + lk * 8];
        }
#pragma unroll
        for (int i2 = 0; i2 < 4; i2++)
#pragma unroll
            for (int j2 = 0; j2 < 2; j2++) {
                acc[i2][j2] = __builtin_amdgcn_mfma_f32_16x16x32_bf16(ah[i2], bh[j2], acc[i2][j2], 0, 0, 0);
                acc[i2][j2] = __builtin_amdgcn_mfma_f32_16x16x32_bf16(ah[i2], bl[j2], acc[i2][j2], 0, 0, 0);
                acc[i2][j2] = __builtin_amdgcn_mfma_f32_16x16x32_bf16(al[i2], bh[j2], acc[i2][j2], 0, 0, 0);
            }
        __syncthreads();
    }

    if (gridDim.z == 1) {
#pragma unroll
        for (int i2 = 0; i2 < 4; i2++) {
            int gmb = m0 + wm + i2 * 16 + lk * 4;
#pragma unroll
            for (int j2 = 0; j2 < 2; j2++) {
                int gn = n0 + wn + j2 * 16 + lrow;
#pragma unroll
                for (int rg = 0; rg < 4; rg++) {
                    int gm = gmb + rg;
                    float x = alpha * acc[i2][j2][rg];
                    if (bias) x += bias[gn];
                    if (accf) x += C[(size_t)gm * ldc + gn];
                    if (act == 1) x = fmaxf(x, 0.f);
                    else if (act == 2) x = tanhf(x);
                    else if (act == 3) x = 1.f / (1.f + expf(-x));
                    C[(size_t)gm * ldc + gn] = x;
                }
            }
        }
    } else {
        float* Pp = P + (size_t)blockIdx.z * M * Nc;
#pragma unroll
        for (int i2 = 0; i2 < 4; i2++) {
            int gmb = m0 + wm + i2 * 16 + lk * 4;
#pragma unroll
            for (int j2 = 0; j2 < 2; j2++) {
                int gn = n0 + wn + j2 * 16 + lrow;
#pragma unroll
                for (int rg = 0; rg < 4; rg++)
                    Pp[(size_t)(gmb + rg) * Nc + gn] = acc[i2][j2][rg];
            }
        }
    }
}

// ---------------------------------------------------------------- z-batched MFMA GEMM (3 sources in one launch)
struct MZ {
    const float* A[3];
    const float* Bw[3];
    const float* bias[3];
    float* C[3];
    int K[3];
    int lda[3];
    float scale[3];
};

__global__ __launch_bounds__(256) void gemm_mz(
        MZ mz, float* __restrict__ P, int M, int Nc, int ldb, int ldc,
        int act, int partial) {
    __shared__ short Ah[128 * 40];
    __shared__ short Al[128 * 40];
    __shared__ short Bh[64 * 40];
    __shared__ short Bl[64 * 40];
    int zz = blockIdx.z;
    const float* A = mz.A[zz];
    const float* B = mz.Bw[zz];
    int K = mz.K[zz], lda = mz.lda[zz];
    int tid = threadIdx.x, wave = tid >> 6, lane = tid & 63;
    int wm = (wave >> 1) * 64, wn = (wave & 1) * 32;
    int lrow = lane & 15, lk = lane >> 4;
    int m0 = blockIdx.y * 128, n0 = blockIdx.x * 64;
    f32x4 acc[4][2] = {};

    for (int k0 = 0; k0 < K; k0 += 32) {
#pragma unroll
        for (int i = 0; i < 4; i++) {
            int q = tid + i * 256;
            int rowm = q >> 3, kq = q & 7;
            float4 vv = *(const float4*)(A + (size_t)(m0 + rowm) * lda + k0 + kq * 4);
            unsigned short h0 = f2bf(vv.x), h1 = f2bf(vv.y), h2 = f2bf(vv.z), h3 = f2bf(vv.w);
            unsigned short l0 = f2bf(vv.x - bf2f(h0)), l1 = f2bf(vv.y - bf2f(h1));
            unsigned short l2 = f2bf(vv.z - bf2f(h2)), l3 = f2bf(vv.w - bf2f(h3));
            *(short4*)&Ah[rowm * 40 + kq * 4] = make_short4((short)h0, (short)h1, (short)h2, (short)h3);
            *(short4*)&Al[rowm * 40 + kq * 4] = make_short4((short)l0, (short)l1, (short)l2, (short)l3);
        }
#pragma unroll
        for (int i = 0; i < 2; i++) {
            int q = tid + i * 256;
            int kk2 = q >> 4, nq = q & 15;
            float4 vv = *(const float4*)(B + (size_t)(k0 + kk2) * ldb + n0 + nq * 4);
            unsigned short h0 = f2bf(vv.x), h1 = f2bf(vv.y), h2 = f2bf(vv.z), h3 = f2bf(vv.w);
            unsigned short l0 = f2bf(vv.x - bf2f(h0)), l1 = f2bf(vv.y - bf2f(h1));
            unsigned short l2 = f2bf(vv.z - bf2f(h2)), l3 = f2bf(vv.w - bf2f(h3));
            Bh[(nq * 4 + 0) * 40 + kk2] = (short)h0;  Bl[(nq * 4 + 0) * 40 + kk2] = (short)l0;
            Bh[(nq * 4 + 1) * 40 + kk2] = (short)h1;  Bl[(nq * 4 + 1) * 40 + kk2] = (short)l1;
            Bh[(nq * 4 + 2) * 40 + kk2] = (short)h2;  Bl[(nq * 4 + 2) * 40 + kk2] = (short)l2;
            Bh[(nq * 4 + 3) * 40 + kk2] = (short)h3;  Bl[(nq * 4 + 3) * 40 + kk2] = (short)l3;
        }
        __syncthreads();
        bf16x8 ah[4], al[4], bh[2], bl[2];
#pragma unroll
        for (int t2 = 0; t2 < 4; t2++) {
            int ra = wm + t2 * 16 + lrow;
            ah[t2] = *(const bf16x8*)&Ah[ra * 40 + lk * 8];
            al[t2] = *(const bf16x8*)&Al[ra * 40 + lk * 8];
        }
#pragma unroll
        for (int u = 0; u < 2; u++) {
            int rb = wn + u * 16 + lrow;
            bh[u] = *(const bf16x8*)&Bh[rb * 40 + lk * 8];
            bl[u] = *(const bf16x8*)&Bl[rb * 40 + lk * 8];
        }
#pragma unroll
        for (int i2 = 0; i2 < 4; i2++)
#pragma unroll
            for (int j2 = 0; j2 < 2; j2++) {
                acc[i2][j2] = __builtin_amdgcn_mfma_f32_16x16x32_bf16(ah[i2], bh[j2], acc[i2][j2], 0, 0, 0);
                acc[i2][j2] = __builtin_amdgcn_mfma_f32_16x16x32_bf16(ah[i2], bl[j2], acc[i2][j2], 0, 0, 0);
                acc[i2][j2] = __builtin_amdgcn_mfma_f32_16x16x32_bf16(al[i2], bh[j2], acc[i2][j2], 0, 0, 0);
            }
        __syncthreads();
    }

    if (partial) {
        float sc = mz.scale[zz];
        float* Pp = P + (size_t)zz * M * Nc;
#pragma unroll
        for (int i2 = 0; i2 < 4; i2++) {
            int gmb = m0 + wm + i2 * 16 + lk * 4;
#pragma unroll
            for (int j2 = 0; j2 < 2; j2++) {
                int gn = n0 + wn + j2 * 16 + lrow;
#pragma unroll
                for (int rg = 0; rg < 4; rg++)
                    Pp[(size_t)(gmb + rg) * Nc + gn] = sc * acc[i2][j2][rg];
            }
        }
    } else {
        const float* bias = mz.bias[zz];
        float* C = mz.C[zz];
#pragma unroll
        for (int i2 = 0; i2 < 4; i2++) {
            int gmb = m0 + wm + i2 * 16 + lk * 4;
#pragma unroll
            for (int j2 = 0; j2 < 2; j2++) {
                int gn = n0 + wn + j2 * 16 + lrow;
#pragma unroll
                for (int rg = 0; rg < 4; rg++) {
                    float x = acc[i2][j2][rg];
                    if (bias) x += bias[gn];
                    if (act == 1) x = fmaxf(x, 0.f);
                    C[(size_t)(gmb + rg) * ldc + gn] = x;
                }
            }
        }
    }
}

// ---------------------------------------------------------------- fp32 GEMM (tiny heads only)
__global__ void gemm2(const float* __restrict__ A, const float* __restrict__ B,
                      float* __restrict__ P, int M, int Nc, int K,
                      int lda, int ldb, int Kc) {
    __shared__ float As[32][68];
    __shared__ float Bs[32][68];
    int tid = threadIdx.x;
    int tm = tid >> 4, tn = tid & 15;
    int m0 = blockIdx.y * 64, n0 = blockIdx.x * 64;
    int kbeg = blockIdx.z * Kc;
    int kend = min(K, kbeg + Kc);
    float acc[4][4] = {};
    for (int k0 = kbeg; k0 < kend; k0 += 32) {
#pragma unroll
        for (int i = 0; i < 2; i++) {
            int q = tid + i * 256;
            int m = q >> 3, kq = q & 7;
            float4 v = *(const float4*)(A + (size_t)(m0 + m) * lda + k0 + kq * 4);
            int col = m ^ (kq << 2);
            As[kq * 4 + 0][col] = v.x;
            As[kq * 4 + 1][col] = v.y;
            As[kq * 4 + 2][col] = v.z;
            As[kq * 4 + 3][col] = v.w;
        }
#pragma unroll
        for (int i = 0; i < 2; i++) {
            int q = tid + i * 256;
            int k = q >> 4, nq = q & 15;
            int gn = n0 + nq * 4;
            float4 v;
            const float* src = B + (size_t)(k0 + k) * ldb + gn;
            if (gn + 3 < Nc) {
                v = *(const float4*)src;
            } else {
                v.x = (gn + 0 < Nc) ? src[0] : 0.f;
                v.y = (gn + 1 < Nc) ? src[1] : 0.f;
                v.z = (gn + 2 < Nc) ? src[2] : 0.f;
                v.w = (gn + 3 < Nc) ? src[3] : 0.f;
            }
            *(float4*)&Bs[k][nq * 4] = v;
        }
        __syncthreads();
#pragma unroll
        for (int kk = 0; kk < 32; kk++) {
            int swz = kk & 28;
            float a[4], b[4];
            *(float4*)a = *(const float4*)&As[kk][(tm * 4) ^ swz];
            *(float4*)b = *(const float4*)&Bs[kk][tn * 4];
#pragma unroll
            for (int i = 0; i < 4; i++)
#pragma unroll
                for (int j = 0; j < 4; j++) acc[i][j] += a[i] * b[j];
        }
        __syncthreads();
    }
    float* Pp = P + (size_t)blockIdx.z * M * Nc;
    int gn = n0 + tn * 4;
#pragma unroll
    for (int i = 0; i < 4; i++) {
        int gm = m0 + tm * 4 + i;
        if (gn + 3 < Nc) {
            *(float4*)&Pp[(size_t)gm * Nc + gn] = *(float4*)&acc[i][0];
        } else {
#pragma unroll
            for (int j = 0; j < 4; j++)
                if (gn + j < Nc) Pp[(size_t)gm * Nc + gn + j] = acc[i][j];
        }
    }
}

// epilogue: C = act(alpha*sum_s P[s] + bias + acc*C)
__global__ void gemm_epi(const float* __restrict__ P, const float* __restrict__ bias,
                         float* __restrict__ C, int M, int Nc, int ldc, int KS,
                         float alpha, int act, int acc) {
    int idx = blockIdx.x * 256 + threadIdx.x;
    if (idx >= M * Nc) return;
    int m = idx / Nc, n = idx - m * Nc;
    float v = 0.f;
    for (int s = 0; s < KS; s++) v += P[(size_t)s * M * Nc + idx];
    v *= alpha;
    if (bias) v += bias[n];
    if (acc) v += C[(size_t)m * ldc + n];
    if (act == 1) v = fmaxf(v, 0.f);
    else if (act == 2) v = tanhf(v);
    else if (act == 3) v = 1.f / (1.f + expf(-v));
    C[(size_t)m * ldc + n] = v;
}

// ---------------------------------------------------------------- sim = Zc @ Zc^T  (split-bf16 MFMA, K=512)
__global__ __launch_bounds__(256) void sim_mfma(const short* __restrict__ Zc,
                                                float* __restrict__ S) {
    __shared__ short As[128 * 64];
    __shared__ short Bs[128 * 64];
    int tid = threadIdx.x;
    int wave = tid >> 6, lane = tid & 63;
    int wm = (wave >> 1) * 64, wn = (wave & 1) * 64;
    int m0 = blockIdx.y * 128, n0 = blockIdx.x * 128;
    int lrow = lane & 15, lk = lane >> 4;
    f32x4 acc[4][4] = {};

    for (int k0 = 0; k0 < 512; k0 += 64) {
#pragma unroll
        for (int i = 0; i < 4; i++) {
            int q = tid + i * 256;
            int row = q >> 3, c = q & 7;
            int dstoff = row * 128 + ((c ^ (row & 7)) << 4);
            const char* pa = (const char*)Zc + (((size_t)(m0 + row) * 512 + k0) << 1) + (c << 4);
            *(float4*)((char*)As + dstoff) = *(const float4*)pa;
            const char* pb = (const char*)Zc + (((size_t)(n0 + row) * 512 + k0) << 1) + (c << 4);
            *(float4*)((char*)Bs + dstoff) = *(const float4*)pb;
        }
        __syncthreads();
#pragma unroll
        for (int kk = 0; kk < 2; kk++) {
            int ck = kk * 4 + lk;
            bf16x8 af[4], bg[4];
#pragma unroll
            for (int t = 0; t < 4; t++) {
                int ra = wm + t * 16 + lrow;
                af[t] = *(const bf16x8*)((const char*)As + ra * 128 + ((ck ^ (ra & 7)) << 4));
                int rb = wn + t * 16 + lrow;
                bg[t] = *(const bf16x8*)((const char*)Bs + rb * 128 + ((ck ^ (rb & 7)) << 4));
            }
#pragma unroll
            for (int i2 = 0; i2 < 4; i2++)
#pragma unroll
                for (int j2 = 0; j2 < 4; j2++)
                    acc[i2][j2] = __builtin_amdgcn_mfma_f32_16x16x32_bf16(
                        af[i2], bg[j2], acc[i2][j2], 0, 0, 0);
        }
        __syncthreads();
    }
#pragma unroll
    for (int i2 = 0; i2 < 4; i2++) {
#pragma unroll
        for (int j2 = 0; j2 < 4; j2++) {
            int col = n0 + wn + j2 * 16 + lrow;
            int rowb = m0 + wm + i2 * 16 + lk * 4;
#pragma unroll
            for (int rg = 0; rg < 4; rg++)
                S[(size_t)(rowb + rg) * NN + col] = acc[i2][j2][rg];
        }
    }
}

// ---------------------------------------------------------------- BatchNorm: all 768 feature cols in one launch
__global__ void bn_all(float* __restrict__ Y,
                       const float* __restrict__ g0, const float* __restrict__ g1,
                       const float* __restrict__ g2, const float* __restrict__ b0,
                       const float* __restrict__ b1, const float* __restrict__ b2) {
    int j = blockIdx.x;            // 0..767
    int m = j >> 8, jj = j & 255;
    const float* g = (m == 0) ? g0 : (m == 1) ? g1 : g2;
    const float* bt = (m == 0) ? b0 : (m == 1) ? b1 : b2;
    __shared__ float rs[256], rs2[256];
    float s = 0.f, s2 = 0.f;
    for (int i = threadIdx.x; i < NN; i += 256) {
        float v = Y[(size_t)i * FEAT + j];
        s += v; s2 += v * v;
    }
    rs[threadIdx.x] = s; rs2[threadIdx.x] = s2;
    __syncthreads();
    for (int st = 128; st > 0; st >>= 1) {
        if (threadIdx.x < st) { rs[threadIdx.x] += rs[threadIdx.x + st]; rs2[threadIdx.x] += rs2[threadIdx.x + st]; }
        __syncthreads();
    }
    float mean = rs[0] * (1.f / NN);
    float var = fmaxf(rs2[0] * (1.f / NN) - mean * mean, 0.f);
    float scale = g[jj] / sqrtf(var + 1e-5f);
    float shift = bt[jj];
    for (int i = threadIdx.x; i < NN; i += 256) {
        size_t o = (size_t)i * FEAT + j;
        Y[o] = (Y[o] - mean) * scale + shift;
    }
}

// ---------------------------------------------------------------- row normalize z -> split-bf16 Zc (in place)
__global__ void rownorm_kernel(const float* __restrict__ Zin, short* __restrict__ Zc) {
    int i = blockIdx.x;
    int c = threadIdx.x;
    __shared__ float rs[256];
    __shared__ float inv;
    float v = Zin[(size_t)i * HIDD + c];
    rs[c] = v * v;
    __syncthreads();
    for (int st = 128; st > 0; st >>= 1) {
        if (c < st) rs[c] += rs[c + st];
        __syncthreads();
    }
    if (c == 0) inv = 1.f / (sqrtf(rs[0]) + 1e-8f);
    __syncthreads();
    float vn = v * inv;
    unsigned short hi = f2bf(vn);
    float lo = vn - bf2f(hi);
    Zc[(size_t)i * 512 + c] = (short)hi;
    Zc[(size_t)i * 512 + 256 + c] = (short)f2bf(lo);
}

// ---------------------------------------------------------------- top-k (k=16): 1 wave/row, ILP tree + reverse index scan
__global__ __launch_bounds__(256) void topk_kernel(const float* __restrict__ S,
                                                   float* __restrict__ hv,
                                                   int* __restrict__ eidx) {
    int lane = threadIdx.x & 63;
    int row = blockIdx.x * 4 + (threadIdx.x >> 6);
    const float4* srow = (const float4*)(S + (size_t)row * NN);
    float v[48];
#pragma unroll
    for (int c = 0; c < 12; c++) {
        float4 q = srow[c * 64 + lane];
        v[c * 4 + 0] = q.x; v[c * 4 + 1] = q.y; v[c * 4 + 2] = q.z; v[c * 4 + 3] = q.w;
    }
    const float NEG = -3.4e38f;
    for (int t = 0; t < TK; t++) {
        // value-only tree max (independent fmax ops)
        float m0[24];
#pragma unroll
        for (int i = 0; i < 24; i++) m0[i] = fmaxf(v[i], v[i + 24]);
#pragma unroll
        for (int i = 0; i < 12; i++) m0[i] = fmaxf(m0[i], m0[i + 12]);
#pragma unroll
        for (int i = 0; i < 6; i++) m0[i] = fmaxf(m0[i], m0[i + 6]);
        float m = fmaxf(fmaxf(fmaxf(m0[0], m0[1]), fmaxf(m0[2], m0[3])), fmaxf(m0[4], m0[5]));
#pragma unroll
        for (int s = 1; s < 64; s <<= 1) m = fmaxf(m, __shfl_xor(m, s));
        // lowest matching col: col(i) monotone in i per lane -> reverse scan, 2 ops/elem
        int cand = 0x7FFFFFFF;
#pragma unroll
        for (int i = 47; i >= 0; i--) {
            int col = (i >> 2) * 256 + lane * 4 + (i & 3);
            cand = (v[i] == m) ? col : cand;
        }
#pragma unroll
        for (int s = 1; s < 64; s <<= 1) cand = min(cand, __shfl_xor(cand, s));
        if (lane == 0) {
            float sg = 1.f / (1.f + expf(-m));
            hv[row * TK + t] = (sg > 0.5f) ? sg : 0.f;
            eidx[row * TK + t] = cand;
        }
        // removal (only owner lane)
        int owner = (cand >> 2) & 63;
        int li = ((cand >> 8) << 2) | (cand & 3);
        if (lane == owner) {
#pragma unroll
            for (int i = 0; i < 48; i++)
                if (i == li) v[i] = NEG;
        }
    }
}

// ---------------------------------------------------------------- edge stats (+msum zero)
__global__ void edge_stats(const float* __restrict__ hv, float* __restrict__ De,
                           float* __restrict__ ew, float* __restrict__ msum) {
    int e = blockIdx.x * 256 + threadIdx.x;
    if (e == 0) *msum = 0.f;
    if (e >= NN) return;
    float s = 0.f;
#pragma unroll
    for (int j = 0; j < TK; j++) s += hv[e * TK + j];
    De[e] = s + 1e-8f;
    ew[e] = s * (1.f / TK);
}

__global__ void scatter_deg(const int* __restrict__ eidx, const float* __restrict__ hv,
                            const float* __restrict__ ew, float* __restrict__ Dv,
                            float* __restrict__ Dv2, int* __restrict__ row_cnt) {
    int t = blockIdx.x * 256 + threadIdx.x;
    if (t >= NN * TK) return;
    int e = t >> 4;
    int v = eidx[t];
    float w = hv[t];
    atomicAdd(&Dv[v], w * ew[e]);
    atomicAdd(&Dv2[v], w);
    atomicAdd(&row_cnt[v], 1);
}

__global__ void deg_fin(const float* __restrict__ Dv, float* __restrict__ Dv2,
                        float* __restrict__ dvis) {
    int v = blockIdx.x * 256 + threadIdx.x;
    if (v >= NN) return;
    dvis[v] = 1.f / sqrtf(Dv[v] + 1e-8f);
    Dv2[v] += 1e-8f;
}

// ---------------------------------------------------------------- CSR build
__global__ void scan_kernel(const int* __restrict__ cnt, int* __restrict__ start) {
    __shared__ int part[256];
    int t = threadIdx.x;
    const int chunk = NN / 256;
    int s = 0;
    for (int i = t * chunk; i < (t + 1) * chunk; i++) s += cnt[i];
    part[t] = s;
    __syncthreads();
    if (t == 0) {
        int a = 0;
        for (int i = 0; i < 256; i++) { int v = part[i]; part[i] = a; a += v; }
    }
    __syncthreads();
    int a = part[t];
    for (int i = t * chunk; i < (t + 1) * chunk; i++) { start[i] = a; a += cnt[i]; }
    if (t == 255) start[NN] = a;
}

__global__ void fill_csr(const int* __restrict__ eidx, const float* __restrict__ hv,
                         const int* __restrict__ start, int* __restrict__ fillc,
                         int* __restrict__ csr_e, float* __restrict__ csr_w) {
    int t = blockIdx.x * 256 + threadIdx.x;
    if (t >= NN * TK) return;
    int e = t >> 4;
    int v = eidx[t];
    int pos = atomicAdd(&fillc[v], 1);
    int pp = start[v] + pos;
    csr_e[pp] = e;
    csr_w[pp] = hv[t];
}

// ---------------------------------------------------------------- sparse H ops (float4 lanes)
__global__ void edge_gather4(const int* __restrict__ eidx, const float* __restrict__ hv,
                             const float* __restrict__ De, const float* __restrict__ dvis,
                             const float* __restrict__ X, float* __restrict__ T,
                             int F4, int epb, int use_dvis) {
    int slot = threadIdx.x / F4;
    if (slot >= epb) return;
    int f = threadIdx.x - slot * F4;
    int e = blockIdx.x * epb + slot;
    const int* ei = eidx + e * TK;
    const float* hw = hv + e * TK;
    float ax = 0.f, ay = 0.f, az = 0.f, aw = 0.f;
#pragma unroll
    for (int j = 0; j < TK; j++) {
        int v = ei[j];
        float w = hw[j];
        if (use_dvis) w *= dvis[v];
        const float4 x = *(const float4*)(X + ((size_t)v * F4 + f) * 4);
        ax = fmaf(w, x.x, ax); ay = fmaf(w, x.y, ay);
        az = fmaf(w, x.z, az); aw = fmaf(w, x.w, aw);
    }
    float inv = 1.f / De[e];
    *(float4*)(T + ((size_t)e * F4 + f) * 4) = make_float4(ax * inv, ay * inv, az * inv, aw * inv);
}

__global__ void row_gather4(const int* __restrict__ start, const int* __restrict__ csr_e,
                            const float* __restrict__ csr_w, const float* __restrict__ dvis,
                            const float* __restrict__ T, const float* __restrict__ Badd,
                            float alpha, float beta, float* __restrict__ Y,
                            int F4, int epb, int use_dvis) {
    int slot = threadIdx.x / F4;
    if (slot >= epb) return;
    int f = threadIdx.x - slot * F4;
    int v = blockIdx.x * epb + slot;
    int s0 = start[v], s1 = start[v + 1];
    float ax = 0.f, ay = 0.f, az = 0.f, aw = 0.f;
    for (int p = s0; p < s1; p++) {
        float w = csr_w[p];
        const float4 x = *(const float4*)(T + ((size_t)csr_e[p] * F4 + f) * 4);
        ax = fmaf(w, x.x, ax); ay = fmaf(w, x.y, ay);
        az = fmaf(w, x.z, az); aw = fmaf(w, x.w, aw);
    }
    float sc = alpha * (use_dvis ? dvis[v] : 1.f);
    float4 o = make_float4(ax * sc, ay * sc, az * sc, aw * sc);
    if (Badd) {
        const float4 b = *(const float4*)(Badd + ((size_t)v * F4 + f) * 4);
        o.x += beta * b.x; o.y += beta * b.y; o.z += beta * b.z; o.w += beta * b.w;
    }
    *(float4*)(Y + ((size_t)v * F4 + f) * 4) = o;
}

// ---------------------------------------------------------------- reductions
__global__ void mse_reduce4(const float* __restrict__ a, const float* __restrict__ b,
                            float* __restrict__ sum) {
    __shared__ float rs[256];
    float s = 0.f;
    const int n4 = NN * FEAT / 4;
    for (int i = blockIdx.x * 256 + threadIdx.x; i < n4; i += gridDim.x * 256) {
        const float4 x = *(const float4*)(a + (size_t)i * 4);
        const float4 y = *(const float4*)(b + (size_t)i * 4);
        float dx = x.x - y.x, dy = x.y - y.y, dz = x.z - y.z, dw = x.w - y.w;
        s += dx * dx + dy * dy + dz * dz + dw * dw;
    }
    rs[threadIdx.x] = s;
    __syncthreads();
    for (int st = 128; st > 0; st >>= 1) {
        if (threadIdx.x < st) rs[threadIdx.x] += rs[threadIdx.x + st];
        __syncthreads();
    }
    if (threadIdx.x == 0) atomicAdd(sum, rs[0]);
}

__global__ void spectral_cols(const float* __restrict__ r, const float* __restrict__ y,
                              const float* __restrict__ Dv2, float* __restrict__ numb,
                              float* __restrict__ denb) {
    int c = blockIdx.x;
    __shared__ float rn[256], rd[256];
    float sn = 0.f, sd = 0.f;
    for (int i = threadIdx.x; i < NN; i += 256) {
        float rv = r[(size_t)i * 64 + c];
        float d2 = Dv2[i];
        float lcx = d2 * rv - y[(size_t)i * 64 + c];
        sn += rv * lcx;
        sd += d2 * rv * rv;
    }
    rn[threadIdx.x] = sn; rd[threadIdx.x] = sd;
    __syncthreads();
    for (int st = 128; st > 0; st >>= 1) {
        if (threadIdx.x < st) { rn[threadIdx.x] += rn[threadIdx.x + st]; rd[threadIdx.x] += rd[threadIdx.x + st]; }
        __syncthreads();
    }
    if (threadIdx.x == 0) { numb[c] = rn[0]; denb[c] = rd[0] + 1e-8f; }
}

__global__ void finals_kernel(const float* __restrict__ msum, const float* __restrict__ numb,
                              const float* __restrict__ denb, float* __restrict__ out) {
    if (threadIdx.x == 0 && blockIdx.x == 0) {
        float s = 0.f;
        for (int c = 0; c < 64; c++) s += numb[c] / denb[c];
        out[NN + 1] = s * (1.f / 64.f);
        out[NN] = msum[0] * (1.f / ((float)NN * FEAT));
    }
}

// ================================================================ launch
extern "C" void kernel_launch(void* const* d_in, const int* in_sizes, int n_in,
                              void* d_out, int out_size, void* d_ws, size_t ws_size,
                              hipStream_t stream) {
    const float* images = (const float*)d_in[0];
    const float* text   = (const float*)d_in[1];
    const float* signal = (const float*)d_in[2];
    const float* iw1 = (const float*)d_in[3];  const float* ib1 = (const float*)d_in[4];
    const float* iw2 = (const float*)d_in[5];  const float* ib2 = (const float*)d_in[6];
    const float* ig  = (const float*)d_in[7];  const float* ibeta = (const float*)d_in[8];
    const float* tw1 = (const float*)d_in[9];  const float* tb1 = (const float*)d_in[10];
    const float* tw2 = (const float*)d_in[11]; const float* tb2 = (const float*)d_in[12];
    const float* tg  = (const float*)d_in[13]; const float* tbeta = (const float*)d_in[14];
    const float* sw1 = (const float*)d_in[15]; const float* sb1 = (const float*)d_in[16];
    const float* sw2 = (const float*)d_in[17]; const float* sb2 = (const float*)d_in[18];
    const float* sg  = (const float*)d_in[19]; const float* sbeta = (const float*)d_in[20];
    const float* gw  = (const float*)d_in[21]; const float* gb = (const float*)d_in[22];
    const float* c1w = (const float*)d_in[23]; const float* c1b = (const float*)d_in[24];
    const float* c2w = (const float*)d_in[25]; const float* c2b = (const float*)d_in[26];
    const float* rw1 = (const float*)d_in[27]; const float* rb1 = (const float*)d_in[28];
    const float* rw2 = (const float*)d_in[29]; const float* rb2 = (const float*)d_in[30];
    const float* aw1 = (const float*)d_in[31]; const float* ab1 = (const float*)d_in[32];
    const float* aw2 = (const float*)d_in[33]; const float* ab2 = (const float*)d_in[34];
    const float* dw1 = (const float*)d_in[35]; const float* db1 = (const float*)d_in[36];
    const float* dw2 = (const float*)d_in[37]; const float* db2 = (const float*)d_in[38];
    float* out = (float*)d_out;

    float* wsf = (float*)d_ws;
    size_t off = 0;
    auto AF = [&](size_t n) { float* q = wsf + off; off += n; return q; };
    float* feats  = AF((size_t)NN * FEAT);
    float* simbuf = AF((size_t)NN * NN);
    float* p      = AF((size_t)NN * 192);
    float* h      = AF((size_t)NN * HIDD);
    float* z      = AF((size_t)NN * HIDD);   // reused in place as Zc (bf16 split)
    float* x1     = AF((size_t)NN * HIDD);
    float* x2     = AF((size_t)NN * 128);
    float* r      = AF((size_t)NN * 64);
    float* hv     = AF((size_t)NN * TK);
    float* ew     = AF(NN);
    float* De     = AF(NN);
    float* Dv     = AF(NN);
    float* Dv2    = AF(NN);
    float* dvis   = AF(NN);
    float* csr_w  = AF((size_t)NN * TK);
    float* numb   = AF(64);
    float* denb   = AF(64);
    float* msum   = AF(1);
    int* eidx     = (int*)(wsf + off); off += (size_t)NN * TK;
    int* csr_e    = (int*)(wsf + off); off += (size_t)NN * TK;
    int* row_cnt  = (int*)(wsf + off); off += NN;
    int* row_fill = (int*)(wsf + off); off += NN;
    int* row_start= (int*)(wsf + off); off += NN + 1;

    short* Zc = (short*)z;

    // regions inside simbuf (free until sim / after topk):
    float* h_all = simbuf;                              // 3 x NN x 256 (pre-sim)
    float* T1    = simbuf;
    float* T2    = simbuf + (size_t)NN * FEAT;
    float* et    = simbuf + (size_t)2 * NN * FEAT;
    float* recon = simbuf + (size_t)3 * NN * FEAT;      // split-K / z-partial region
    float* yspec = x2;

    dim3 blk(256);
    auto gemmF = [&](const float* A, const float* B, const float* bias, float* C,
                     int M, int Nc, int K, int lda, int ldb, int ldc,
                     float alpha, int act, int acc, int KS, float* part) {
        int nk = K / 32;
        int ks = KS < nk ? KS : nk; if (ks < 1) ks = 1;
        int kc = ((nk + ks - 1) / ks) * 32;
        int ksp = (K + kc - 1) / kc;
        gemm_mf<<<dim3(Nc / 64, M / 128, ksp), blk, 0, stream>>>(
            A, B, bias, C, part, M, Nc, K, lda, ldb, ldc, kc, alpha, act, acc);
        if (ksp > 1)
            gemm_epi<<<((size_t)M * Nc + 255) / 256, blk, 0, stream>>>(
                part, bias, C, M, Nc, ldc, ksp, alpha, act, acc);
    };
    auto gemmSm = [&](const float* A, const float* B, const float* bias, float* C,
                      int M, int Nc, int K, int lda, int ldb, int ldc,
                      float alpha, int act, int acc, int KS, float* part) {
        int nk = K / 32;
        int ks = KS < nk ? KS : nk; if (ks < 1) ks = 1;
        int kc = ((nk + ks - 1) / ks) * 32;
        int ksp = (K + kc - 1) / kc;
        gemm2<<<dim3((Nc + 63) / 64, M / 64, ksp), blk, 0, stream>>>(A, B, part, M, Nc, K, lda, ldb, kc);
        gemm_epi<<<((size_t)M * Nc + 255) / 256, blk, 0, stream>>>(part, bias, C, M, Nc, ldc, ksp, alpha, act, acc);
    };
    auto eg4 = [&](const float* X, float* T, int F, int use_dvis) {
        int F4 = F / 4, epb = 256 / F4 < 1 ? 1 : 256 / F4;
        edge_gather4<<<NN / epb, blk, 0, stream>>>(eidx, hv, De, dvis, X, T, F4, epb, use_dvis);
    };
    auto rg4 = [&](const float* T, const float* Badd, float alpha, float beta, float* Y,
                   int F, int use_dvis) {
        int F4 = F / 4, epb = 256 / F4 < 1 ? 1 : 256 / F4;
        row_gather4<<<NN / epb, blk, 0, stream>>>(row_start, csr_e, csr_w, dvis, T, Badd,
                                                  alpha, beta, Y, F4, epb, use_dvis);
    };

    const float E1 = 0.60653065971f;  // exp(-0.5)
    const float E2 = 0.36787944117f;  // exp(-1.0)

    // ---- modality MLPs (z-batched) + BN ----
    pool_kernel<<<(NN * 192 + 255) / 256, blk, 0, stream>>>(images, p);
    float* h0 = h_all, *h1 = h_all + (size_t)NN * 256, *h2 = h_all + (size_t)2 * NN * 256;
    {
        MZ mz{};
        mz.A[0] = p;     mz.A[1] = text;  mz.A[2] = signal;
        mz.Bw[0] = iw1;  mz.Bw[1] = tw1;  mz.Bw[2] = sw1;
        mz.bias[0] = ib1; mz.bias[1] = tb1; mz.bias[2] = sb1;
        mz.C[0] = h0;    mz.C[1] = h1;    mz.C[2] = h2;
        mz.K[0] = 192;   mz.K[1] = 768;   mz.K[2] = 256;
        mz.lda[0] = 192; mz.lda[1] = 768; mz.lda[2] = 256;
        gemm_mz<<<dim3(4, 24, 3), blk, 0, stream>>>(mz, nullptr, NN, 256, 256, 256, 1, 0);
    }
    {
        MZ mz{};
        mz.A[0] = h0;    mz.A[1] = h1;    mz.A[2] = h2;
        mz.Bw[0] = iw2;  mz.Bw[1] = tw2;  mz.Bw[2] = sw2;
        mz.bias[0] = ib2; mz.bias[1] = tb2; mz.bias[2] = sb2;
        mz.C[0] = feats; mz.C[1] = feats + 256; mz.C[2] = feats + 512;
        mz.K[0] = mz.K[1] = mz.K[2] = 256;
        mz.lda[0] = mz.lda[1] = mz.lda[2] = 256;
        gemm_mz<<<dim3(4, 24, 3), blk, 0, stream>>>(mz, nullptr, NN, 256, 256, FEAT, 0, 0);
    }
    bn_all<<<FEAT, blk, 0, stream>>>(feats, ig, tg, sg, ibeta, tbeta, sbeta);

    // ---- hyperedge generator (partials at simbuf: h_all dead) ----
    gemmF(feats, gw, gb, z, NN, HIDD, FEAT, FEAT, HIDD, HIDD, 1.f, 2, 0, 4, simbuf);
    rownorm_kernel<<<NN, blk, 0, stream>>>(z, Zc);
    sim_mfma<<<dim3(NN / 128, NN / 128), blk, 0, stream>>>(Zc, simbuf);
    topk_kernel<<<NN / 4, blk, 0, stream>>>(simbuf, hv, eidx);

    // ---- degrees + CSR of H rows ----
    hipMemsetAsync(Dv, 0, 2 * NN * sizeof(float), stream);
    hipMemsetAsync(row_cnt, 0, 2 * NN * sizeof(int), stream);
    edge_stats<<<NN / 256, blk, 0, stream>>>(hv, De, ew, msum);
    scatter_deg<<<NN * TK / 256, blk, 0, stream>>>(eidx, hv, ew, Dv, Dv2, row_cnt);
    deg_fin<<<NN / 256, blk, 0, stream>>>(Dv, Dv2, dvis);
    scan_kernel<<<1, blk, 0, stream>>>(row_cnt, row_start);
    fill_csr<<<NN * TK / 256, blk, 0, stream>>>(eidx, hv, row_start, row_fill, csr_e, csr_w);

    // ---- cheb conv 1 (F=768 -> 256), z-batched 3 terms ----
    eg4(feats, et, FEAT, 1);
    rg4(et, nullptr, -1.f, 0.f, T1, FEAT, 1);
    eg4(T1, et, FEAT, 1);
    rg4(et, feats, -2.f, -1.f, T2, FEAT, 1);
    {
        MZ mz{};
        mz.A[0] = feats; mz.A[1] = T1; mz.A[2] = T2;
        mz.Bw[0] = c1w;  mz.Bw[1] = c1w + (size_t)FEAT * HIDD; mz.Bw[2] = c1w + (size_t)2 * FEAT * HIDD;
        mz.K[0] = mz.K[1] = mz.K[2] = FEAT;
        mz.lda[0] = mz.lda[1] = mz.lda[2] = FEAT;
        mz.scale[0] = 1.f; mz.scale[1] = E1; mz.scale[2] = E2;
        gemm_mz<<<dim3(4, 24, 3), blk, 0, stream>>>(mz, recon, NN, 256, HIDD, HIDD, 0, 1);
        gemm_epi<<<((size_t)NN * 256 + 255) / 256, blk, 0, stream>>>(
            recon, c1b, x1, NN, 256, 256, 3, 1.f, 1, 0);
    }

    // ---- cheb conv 2 (F=256 -> 128), z-batched ----
    eg4(x1, et, HIDD, 1);
    rg4(et, nullptr, -1.f, 0.f, T1, HIDD, 1);
    eg4(T1, et, HIDD, 1);
    rg4(et, x1, -2.f, -1.f, T2, HIDD, 1);
    {
        MZ mz{};
        mz.A[0] = x1; mz.A[1] = T1; mz.A[2] = T2;
        mz.Bw[0] = c2w;  mz.Bw[1] = c2w + (size_t)HIDD * 128; mz.Bw[2] = c2w + (size_t)2 * HIDD * 128;
        mz.K[0] = mz.K[1] = mz.K[2] = HIDD;
        mz.lda[0] = mz.lda[1] = mz.lda[2] = HIDD;
        mz.scale[0] = 1.f; mz.scale[1] = E1; mz.scale[2] = E2;
        gemm_mz<<<dim3(2, 24, 3), blk, 0, stream>>>(mz, recon, NN, 128, 128, 128, 0, 1);
        gemm_epi<<<((size_t)NN * 128 + 255) / 256, blk, 0, stream>>>(
            recon, c2b, x2, NN, 128, 128, 3, 1.f, 1, 0);
    }

    // ---- heads ----
    gemmF(x2, rw1, rb1, h, NN, 64, 128, 128, 64, 64, 1.f, 1, 0, 2, recon);
    gemmF(h,  rw2, rb2, r, NN, 64, 64, 64, 64, 64, 1.f, 0, 0, 2, recon);
    gemmSm(r,  aw1, ab1, h, NN, 32, 64, 64, 32, 32, 1.f, 1, 0, 2, recon);
    gemmSm(h,  aw2, ab2, out, NN, 1, 32, 32, 1, 1, 1.f, 3, 0, 1, recon);
    gemmF(r,  dw1, db1, h, NN, HIDD, 64, 64, HIDD, HIDD, 1.f, 1, 0, 2, recon);
    gemmF(h,  dw2, db2, recon, NN, FEAT, HIDD, HIDD, FEAT, FEAT, 1.f, 0, 0, 1, T1);
    mse_reduce4<<<512, blk, 0, stream>>>(recon, feats, msum);

    // ---- spectral cut ----
    eg4(r, et, 64, 0);
    rg4(et, nullptr, 1.f, 0.f, yspec, 64, 0);
    spectral_cols<<<64, blk, 0, stream>>>(r, yspec, Dv2, numb, denb);
    finals_kernel<<<1, 64, 0, stream>>>(msum, numb, denb, out);
}

// Round 7
// 548.829 us; speedup vs baseline: 1.5703x; 1.0622x over previous
//
#include <hip/hip_runtime.h>
#include <cmath>

#define NN   3072
#define HIDD 256
#define TK   16
#define FEAT 768   // 3*HID

typedef __attribute__((ext_vector_type(8))) short bf16x8;
typedef __attribute__((ext_vector_type(4))) float f32x4;

__device__ inline unsigned short f2bf(float x) {
    unsigned u = __float_as_uint(x);
    unsigned r = (u + 0x7FFFu + ((u >> 16) & 1u)) >> 16;   // RNE
    return (unsigned short)r;
}
__device__ inline float bf2f(unsigned short h) {
    return __uint_as_float(((unsigned)h) << 16);
}

// ---------------------------------------------------------------- pool
__global__ void pool_kernel(const float* __restrict__ img, float* __restrict__ p) {
    int idx = blockIdx.x * 256 + threadIdx.x;
    if (idx >= NN * 192) return;
    int b = idx / 192, rem = idx % 192;
    int c = rem >> 6, oy = (rem >> 3) & 7, ox = rem & 7;
    const float* base = img + (((size_t)b * 3 + c) * 32 + oy * 4) * 32 + ox * 4;
    float s = 0.f;
#pragma unroll
    for (int iy = 0; iy < 4; iy++)
#pragma unroll
        for (int ix = 0; ix < 4; ix++) s += base[iy * 32 + ix];
    p[idx] = s * 0.0625f;
}

// ---------------------------------------------------------------- MFMA split-bf16 GEMM (single source)
__global__ __launch_bounds__(256) void gemm_mf(
        const float* __restrict__ A, const float* __restrict__ B,
        const float* __restrict__ bias, float* __restrict__ C, float* __restrict__ P,
        int M, int Nc, int K, int lda, int ldb, int ldc, int Kc,
        float alpha, int act, int accf) {
    __shared__ short Ah[128 * 40];
    __shared__ short Al[128 * 40];
    __shared__ short Bh[64 * 40];
    __shared__ short Bl[64 * 40];
    int tid = threadIdx.x, wave = tid >> 6, lane = tid & 63;
    int wm = (wave >> 1) * 64, wn = (wave & 1) * 32;
    int lrow = lane & 15, lk = lane >> 4;
    int m0 = blockIdx.y * 128, n0 = blockIdx.x * 64;
    int kbeg = blockIdx.z * Kc, kend = min(K, kbeg + Kc);
    f32x4 acc[4][2] = {};

    for (int k0 = kbeg; k0 < kend; k0 += 32) {
#pragma unroll
        for (int i = 0; i < 4; i++) {
            int q = tid + i * 256;
            int rowm = q >> 3, kq = q & 7;
            float4 vv = *(const float4*)(A + (size_t)(m0 + rowm) * lda + k0 + kq * 4);
            unsigned short h0 = f2bf(vv.x), h1 = f2bf(vv.y), h2 = f2bf(vv.z), h3 = f2bf(vv.w);
            unsigned short l0 = f2bf(vv.x - bf2f(h0)), l1 = f2bf(vv.y - bf2f(h1));
            unsigned short l2 = f2bf(vv.z - bf2f(h2)), l3 = f2bf(vv.w - bf2f(h3));
            *(short4*)&Ah[rowm * 40 + kq * 4] = make_short4((short)h0, (short)h1, (short)h2, (short)h3);
            *(short4*)&Al[rowm * 40 + kq * 4] = make_short4((short)l0, (short)l1, (short)l2, (short)l3);
        }
#pragma unroll
        for (int i = 0; i < 2; i++) {
            int q = tid + i * 256;
            int kk2 = q >> 4, nq = q & 15;
            float4 vv = *(const float4*)(B + (size_t)(k0 + kk2) * ldb + n0 + nq * 4);
            unsigned short h0 = f2bf(vv.x), h1 = f2bf(vv.y), h2 = f2bf(vv.z), h3 = f2bf(vv.w);
            unsigned short l0 = f2bf(vv.x - bf2f(h0)), l1 = f2bf(vv.y - bf2f(h1));
            unsigned short l2 = f2bf(vv.z - bf2f(h2)), l3 = f2bf(vv.w - bf2f(h3));
            Bh[(nq * 4 + 0) * 40 + kk2] = (short)h0;  Bl[(nq * 4 + 0) * 40 + kk2] = (short)l0;
            Bh[(nq * 4 + 1) * 40 + kk2] = (short)h1;  Bl[(nq * 4 + 1) * 40 + kk2] = (short)l1;
            Bh[(nq * 4 + 2) * 40 + kk2] = (short)h2;  Bl[(nq * 4 + 2) * 40 + kk2] = (short)l2;
            Bh[(nq * 4 + 3) * 40 + kk2] = (short)h3;  Bl[(nq * 4 + 3) * 40 + kk2] = (short)l3;
        }
        __syncthreads();
        bf16x8 ah[4], al[4], bh[2], bl[2];
#pragma unroll
        for (int t2 = 0; t2 < 4; t2++) {
            int ra = wm + t2 * 16 + lrow;
            ah[t2] = *(const bf16x8*)&Ah[ra * 40 + lk * 8];
            al[t2] = *(const bf16x8*)&Al[ra * 40 + lk * 8];
        }
#pragma unroll
        for (int u = 0; u < 2; u++) {
            int rb = wn + u * 16 + lrow;
            bh[u] = *(const bf16x8*)&Bh[rb * 40 + lk * 8];
            bl[u] = *(const bf16x8*)&Bl[rb * 40 + lk * 8];
        }
#pragma unroll
        for (int i2 = 0; i2 < 4; i2++)
#pragma unroll
            for (int j2 = 0; j2 < 2; j2++) {
                acc[i2][j2] = __builtin_amdgcn_mfma_f32_16x16x32_bf16(ah[i2], bh[j2], acc[i2][j2], 0, 0, 0);
                acc[i2][j2] = __builtin_amdgcn_mfma_f32_16x16x32_bf16(ah[i2], bl[j2], acc[i2][j2], 0, 0, 0);
                acc[i2][j2] = __builtin_amdgcn_mfma_f32_16x16x32_bf16(al[i2], bh[j2], acc[i2][j2], 0, 0, 0);
            }
        __syncthreads();
    }

    if (gridDim.z == 1) {
#pragma unroll
        for (int i2 = 0; i2 < 4; i2++) {
            int gmb = m0 + wm + i2 * 16 + lk * 4;
#pragma unroll
            for (int j2 = 0; j2 < 2; j2++) {
                int gn = n0 + wn + j2 * 16 + lrow;
#pragma unroll
                for (int rg = 0; rg < 4; rg++) {
                    int gm = gmb + rg;
                    float x = alpha * acc[i2][j2][rg];
                    if (bias) x += bias[gn];
                    if (accf) x += C[(size_t)gm * ldc + gn];
                    if (act == 1) x = fmaxf(x, 0.f);
                    else if (act == 2) x = tanhf(x);
                    else if (act == 3) x = 1.f / (1.f + expf(-x));
                    C[(size_t)gm * ldc + gn] = x;
                }
            }
        }
    } else {
        float* Pp = P + (size_t)blockIdx.z * M * Nc;
#pragma unroll
        for (int i2 = 0; i2 < 4; i2++) {
            int gmb = m0 + wm + i2 * 16 + lk * 4;
#pragma unroll
            for (int j2 = 0; j2 < 2; j2++) {
                int gn = n0 + wn + j2 * 16 + lrow;
#pragma unroll
                for (int rg = 0; rg < 4; rg++)
                    Pp[(size_t)(gmb + rg) * Nc + gn] = acc[i2][j2][rg];
            }
        }
    }
}

// ---------------------------------------------------------------- z-batched MFMA GEMM (3 sources in one launch)
struct MZ {
    const float* A[3];
    const float* Bw[3];
    const float* bias[3];
    float* C[3];
    int K[3];
    int lda[3];
    float scale[3];
};

__global__ __launch_bounds__(256) void gemm_mz(
        MZ mz, float* __restrict__ P, int M, int Nc, int ldb, int ldc,
        int act, int partial) {
    __shared__ short Ah[128 * 40];
    __shared__ short Al[128 * 40];
    __shared__ short Bh[64 * 40];
    __shared__ short Bl[64 * 40];
    int zz = blockIdx.z;
    const float* A = mz.A[zz];
    const float* B = mz.Bw[zz];
    int K = mz.K[zz], lda = mz.lda[zz];
    int tid = threadIdx.x, wave = tid >> 6, lane = tid & 63;
    int wm = (wave >> 1) * 64, wn = (wave & 1) * 32;
    int lrow = lane & 15, lk = lane >> 4;
    int m0 = blockIdx.y * 128, n0 = blockIdx.x * 64;
    f32x4 acc[4][2] = {};

    for (int k0 = 0; k0 < K; k0 += 32) {
#pragma unroll
        for (int i = 0; i < 4; i++) {
            int q = tid + i * 256;
            int rowm = q >> 3, kq = q & 7;
            float4 vv = *(const float4*)(A + (size_t)(m0 + rowm) * lda + k0 + kq * 4);
            unsigned short h0 = f2bf(vv.x), h1 = f2bf(vv.y), h2 = f2bf(vv.z), h3 = f2bf(vv.w);
            unsigned short l0 = f2bf(vv.x - bf2f(h0)), l1 = f2bf(vv.y - bf2f(h1));
            unsigned short l2 = f2bf(vv.z - bf2f(h2)), l3 = f2bf(vv.w - bf2f(h3));
            *(short4*)&Ah[rowm * 40 + kq * 4] = make_short4((short)h0, (short)h1, (short)h2, (short)h3);
            *(short4*)&Al[rowm * 40 + kq * 4] = make_short4((short)l0, (short)l1, (short)l2, (short)l3);
        }
#pragma unroll
        for (int i = 0; i < 2; i++) {
            int q = tid + i * 256;
            int kk2 = q >> 4, nq = q & 15;
            float4 vv = *(const float4*)(B + (size_t)(k0 + kk2) * ldb + n0 + nq * 4);
            unsigned short h0 = f2bf(vv.x), h1 = f2bf(vv.y), h2 = f2bf(vv.z), h3 = f2bf(vv.w);
            unsigned short l0 = f2bf(vv.x - bf2f(h0)), l1 = f2bf(vv.y - bf2f(h1));
            unsigned short l2 = f2bf(vv.z - bf2f(h2)), l3 = f2bf(vv.w - bf2f(h3));
            Bh[(nq * 4 + 0) * 40 + kk2] = (short)h0;  Bl[(nq * 4 + 0) * 40 + kk2] = (short)l0;
            Bh[(nq * 4 + 1) * 40 + kk2] = (short)h1;  Bl[(nq * 4 + 1) * 40 + kk2] = (short)l1;
            Bh[(nq * 4 + 2) * 40 + kk2] = (short)h2;  Bl[(nq * 4 + 2) * 40 + kk2] = (short)l2;
            Bh[(nq * 4 + 3) * 40 + kk2] = (short)h3;  Bl[(nq * 4 + 3) * 40 + kk2] = (short)l3;
        }
        __syncthreads();
        bf16x8 ah[4], al[4], bh[2], bl[2];
#pragma unroll
        for (int t2 = 0; t2 < 4; t2++) {
            int ra = wm + t2 * 16 + lrow;
            ah[t2] = *(const bf16x8*)&Ah[ra * 40 + lk * 8];
            al[t2] = *(const bf16x8*)&Al[ra * 40 + lk * 8];
        }
#pragma unroll
        for (int u = 0; u < 2; u++) {
            int rb = wn + u * 16 + lrow;
            bh[u] = *(const bf16x8*)&Bh[rb * 40 + lk * 8];
            bl[u] = *(const bf16x8*)&Bl[rb * 40 + lk * 8];
        }
#pragma unroll
        for (int i2 = 0; i2 < 4; i2++)
#pragma unroll
            for (int j2 = 0; j2 < 2; j2++) {
                acc[i2][j2] = __builtin_amdgcn_mfma_f32_16x16x32_bf16(ah[i2], bh[j2], acc[i2][j2], 0, 0, 0);
                acc[i2][j2] = __builtin_amdgcn_mfma_f32_16x16x32_bf16(ah[i2], bl[j2], acc[i2][j2], 0, 0, 0);
                acc[i2][j2] = __builtin_amdgcn_mfma_f32_16x16x32_bf16(al[i2], bh[j2], acc[i2][j2], 0, 0, 0);
            }
        __syncthreads();
    }

    if (partial) {
        float sc = mz.scale[zz];
        float* Pp = P + (size_t)zz * M * Nc;
#pragma unroll
        for (int i2 = 0; i2 < 4; i2++) {
            int gmb = m0 + wm + i2 * 16 + lk * 4;
#pragma unroll
            for (int j2 = 0; j2 < 2; j2++) {
                int gn = n0 + wn + j2 * 16 + lrow;
#pragma unroll
                for (int rg = 0; rg < 4; rg++)
                    Pp[(size_t)(gmb + rg) * Nc + gn] = sc * acc[i2][j2][rg];
            }
        }
    } else {
        const float* bias = mz.bias[zz];
        float* C = mz.C[zz];
#pragma unroll
        for (int i2 = 0; i2 < 4; i2++) {
            int gmb = m0 + wm + i2 * 16 + lk * 4;
#pragma unroll
            for (int j2 = 0; j2 < 2; j2++) {
                int gn = n0 + wn + j2 * 16 + lrow;
#pragma unroll
                for (int rg = 0; rg < 4; rg++) {
                    float x = acc[i2][j2][rg];
                    if (bias) x += bias[gn];
                    if (act == 1) x = fmaxf(x, 0.f);
                    C[(size_t)(gmb + rg) * ldc + gn] = x;
                }
            }
        }
    }
}

// ---------------------------------------------------------------- fp32 GEMM (tiny heads only)
__global__ void gemm2(const float* __restrict__ A, const float* __restrict__ B,
                      float* __restrict__ P, int M, int Nc, int K,
                      int lda, int ldb, int Kc) {
    __shared__ float As[32][68];
    __shared__ float Bs[32][68];
    int tid = threadIdx.x;
    int tm = tid >> 4, tn = tid & 15;
    int m0 = blockIdx.y * 64, n0 = blockIdx.x * 64;
    int kbeg = blockIdx.z * Kc;
    int kend = min(K, kbeg + Kc);
    float acc[4][4] = {};
    for (int k0 = kbeg; k0 < kend; k0 += 32) {
#pragma unroll
        for (int i = 0; i < 2; i++) {
            int q = tid + i * 256;
            int m = q >> 3, kq = q & 7;
            float4 v = *(const float4*)(A + (size_t)(m0 + m) * lda + k0 + kq * 4);
            int col = m ^ (kq << 2);
            As[kq * 4 + 0][col] = v.x;
            As[kq * 4 + 1][col] = v.y;
            As[kq * 4 + 2][col] = v.z;
            As[kq * 4 + 3][col] = v.w;
        }
#pragma unroll
        for (int i = 0; i < 2; i++) {
            int q = tid + i * 256;
            int k = q >> 4, nq = q & 15;
            int gn = n0 + nq * 4;
            float4 v;
            const float* src = B + (size_t)(k0 + k) * ldb + gn;
            if (gn + 3 < Nc) {
                v = *(const float4*)src;
            } else {
                v.x = (gn + 0 < Nc) ? src[0] : 0.f;
                v.y = (gn + 1 < Nc) ? src[1] : 0.f;
                v.z = (gn + 2 < Nc) ? src[2] : 0.f;
                v.w = (gn + 3 < Nc) ? src[3] : 0.f;
            }
            *(float4*)&Bs[k][nq * 4] = v;
        }
        __syncthreads();
#pragma unroll
        for (int kk = 0; kk < 32; kk++) {
            int swz = kk & 28;
            float a[4], b[4];
            *(float4*)a = *(const float4*)&As[kk][(tm * 4) ^ swz];
            *(float4*)b = *(const float4*)&Bs[kk][tn * 4];
#pragma unroll
            for (int i = 0; i < 4; i++)
#pragma unroll
                for (int j = 0; j < 4; j++) acc[i][j] += a[i] * b[j];
        }
        __syncthreads();
    }
    float* Pp = P + (size_t)blockIdx.z * M * Nc;
    int gn = n0 + tn * 4;
#pragma unroll
    for (int i = 0; i < 4; i++) {
        int gm = m0 + tm * 4 + i;
        if (gn + 3 < Nc) {
            *(float4*)&Pp[(size_t)gm * Nc + gn] = *(float4*)&acc[i][0];
        } else {
#pragma unroll
            for (int j = 0; j < 4; j++)
                if (gn + j < Nc) Pp[(size_t)gm * Nc + gn + j] = acc[i][j];
        }
    }
}

// epilogue: C = act(alpha*sum_s P[s] + bias + acc*C)
__global__ void gemm_epi(const float* __restrict__ P, const float* __restrict__ bias,
                         float* __restrict__ C, int M, int Nc, int ldc, int KS,
                         float alpha, int act, int acc) {
    int idx = blockIdx.x * 256 + threadIdx.x;
    if (idx >= M * Nc) return;
    int m = idx / Nc, n = idx - m * Nc;
    float v = 0.f;
    for (int s = 0; s < KS; s++) v += P[(size_t)s * M * Nc + idx];
    v *= alpha;
    if (bias) v += bias[n];
    if (acc) v += C[(size_t)m * ldc + n];
    if (act == 1) v = fmaxf(v, 0.f);
    else if (act == 2) v = tanhf(v);
    else if (act == 3) v = 1.f / (1.f + expf(-v));
    C[(size_t)m * ldc + n] = v;
}

// ---------------------------------------------------------------- sim = Zc @ Zc^T  (split-bf16 MFMA, K=512)
__global__ __launch_bounds__(256) void sim_mfma(const short* __restrict__ Zc,
                                                float* __restrict__ S) {
    __shared__ short As[128 * 64];
    __shared__ short Bs[128 * 64];
    int tid = threadIdx.x;
    int wave = tid >> 6, lane = tid & 63;
    int wm = (wave >> 1) * 64, wn = (wave & 1) * 64;
    int m0 = blockIdx.y * 128, n0 = blockIdx.x * 128;
    int lrow = lane & 15, lk = lane >> 4;
    f32x4 acc[4][4] = {};

    for (int k0 = 0; k0 < 512; k0 += 64) {
#pragma unroll
        for (int i = 0; i < 4; i++) {
            int q = tid + i * 256;
            int row = q >> 3, c = q & 7;
            int dstoff = row * 128 + ((c ^ (row & 7)) << 4);
            const char* pa = (const char*)Zc + (((size_t)(m0 + row) * 512 + k0) << 1) + (c << 4);
            *(float4*)((char*)As + dstoff) = *(const float4*)pa;
            const char* pb = (const char*)Zc + (((size_t)(n0 + row) * 512 + k0) << 1) + (c << 4);
            *(float4*)((char*)Bs + dstoff) = *(const float4*)pb;
        }
        __syncthreads();
#pragma unroll
        for (int kk = 0; kk < 2; kk++) {
            int ck = kk * 4 + lk;
            bf16x8 af[4], bg[4];
#pragma unroll
            for (int t = 0; t < 4; t++) {
                int ra = wm + t * 16 + lrow;
                af[t] = *(const bf16x8*)((const char*)As + ra * 128 + ((ck ^ (ra & 7)) << 4));
                int rb = wn + t * 16 + lrow;
                bg[t] = *(const bf16x8*)((const char*)Bs + rb * 128 + ((ck ^ (rb & 7)) << 4));
            }
#pragma unroll
            for (int i2 = 0; i2 < 4; i2++)
#pragma unroll
                for (int j2 = 0; j2 < 4; j2++)
                    acc[i2][j2] = __builtin_amdgcn_mfma_f32_16x16x32_bf16(
                        af[i2], bg[j2], acc[i2][j2], 0, 0, 0);
        }
        __syncthreads();
    }
#pragma unroll
    for (int i2 = 0; i2 < 4; i2++) {
#pragma unroll
        for (int j2 = 0; j2 < 4; j2++) {
            int col = n0 + wn + j2 * 16 + lrow;
            int rowb = m0 + wm + i2 * 16 + lk * 4;
#pragma unroll
            for (int rg = 0; rg < 4; rg++)
                S[(size_t)(rowb + rg) * NN + col] = acc[i2][j2][rg];
        }
    }
}

// ---------------------------------------------------------------- BatchNorm, row-major 3-phase
// stats: 192 blocks x 16 rows; thread owns cols {t, t+256, t+512}
__global__ void bn_stats(const float* __restrict__ Y, float* __restrict__ csum,
                         float* __restrict__ csum2) {
    int t = threadIdx.x;
    float s0 = 0.f, s1 = 0.f, s2v = 0.f;
    float q0 = 0.f, q1 = 0.f, q2 = 0.f;
    int r0 = blockIdx.x * 16;
    for (int i = r0; i < r0 + 16; i++) {
        const float* row = Y + (size_t)i * FEAT;
        float a = row[t], b = row[t + 256], c = row[t + 512];
        s0 += a; q0 += a * a;
        s1 += b; q1 += b * b;
        s2v += c; q2 += c * c;
    }
    atomicAdd(&csum[t], s0);        atomicAdd(&csum2[t], q0);
    atomicAdd(&csum[t + 256], s1);  atomicAdd(&csum2[t + 256], q1);
    atomicAdd(&csum[t + 512], s2v); atomicAdd(&csum2[t + 512], q2);
}

__global__ void bn_fin(const float* __restrict__ csum, const float* __restrict__ csum2,
                       const float* __restrict__ g0, const float* __restrict__ g1,
                       const float* __restrict__ g2, const float* __restrict__ b0,
                       const float* __restrict__ b1, const float* __restrict__ b2,
                       float* __restrict__ scale, float* __restrict__ shift) {
    int j = blockIdx.x * 256 + threadIdx.x;
    if (j >= FEAT) return;
    float mean = csum[j] * (1.f / NN);
    float var = fmaxf(csum2[j] * (1.f / NN) - mean * mean, 0.f);
    int m = j >> 8, jj = j & 255;
    const float* g = (m == 0) ? g0 : (m == 1) ? g1 : g2;
    const float* bt = (m == 0) ? b0 : (m == 1) ? b1 : b2;
    float sc = g[jj] / sqrtf(var + 1e-5f);
    scale[j] = sc;
    shift[j] = bt[jj] - mean * sc;
}

__global__ void bn_norm(float* __restrict__ Y, const float* __restrict__ scale,
                        const float* __restrict__ shift) {
    __shared__ float sc[FEAT], sh[FEAT];
    for (int j = threadIdx.x; j < FEAT; j += 256) { sc[j] = scale[j]; sh[j] = shift[j]; }
    __syncthreads();
    const int n4 = NN * FEAT / 4;
    for (int i = blockIdx.x * 256 + threadIdx.x; i < n4; i += gridDim.x * 256) {
        float4 v = *(const float4*)(Y + (size_t)i * 4);
        int c = (i % 192) * 4;
        v.x = v.x * sc[c + 0] + sh[c + 0];
        v.y = v.y * sc[c + 1] + sh[c + 1];
        v.z = v.z * sc[c + 2] + sh[c + 2];
        v.w = v.w * sc[c + 3] + sh[c + 3];
        *(float4*)(Y + (size_t)i * 4) = v;
    }
}

// ---------------------------------------------------------------- row normalize z -> split-bf16 Zc (in place)
__global__ void rownorm_kernel(const float* __restrict__ Zin, short* __restrict__ Zc) {
    int i = blockIdx.x;
    int c = threadIdx.x;
    __shared__ float rs[256];
    __shared__ float inv;
    float v = Zin[(size_t)i * HIDD + c];
    rs[c] = v * v;
    __syncthreads();
    for (int st = 128; st > 0; st >>= 1) {
        if (c < st) rs[c] += rs[c + st];
        __syncthreads();
    }
    if (c == 0) inv = 1.f / (sqrtf(rs[0]) + 1e-8f);
    __syncthreads();
    float vn = v * inv;
    unsigned short hi = f2bf(vn);
    float lo = vn - bf2f(hi);
    Zc[(size_t)i * 512 + c] = (short)hi;
    Zc[(size_t)i * 512 + 256 + c] = (short)f2bf(lo);
}

// ---------------------------------------------------------------- top-k (k=16): 1 wave/row, ILP tree + reverse index scan
__global__ __launch_bounds__(256) void topk_kernel(const float* __restrict__ S,
                                                   float* __restrict__ hv,
                                                   int* __restrict__ eidx) {
    int lane = threadIdx.x & 63;
    int row = blockIdx.x * 4 + (threadIdx.x >> 6);
    const float4* srow = (const float4*)(S + (size_t)row * NN);
    float v[48];
#pragma unroll
    for (int c = 0; c < 12; c++) {
        float4 q = srow[c * 64 + lane];
        v[c * 4 + 0] = q.x; v[c * 4 + 1] = q.y; v[c * 4 + 2] = q.z; v[c * 4 + 3] = q.w;
    }
    const float NEG = -3.4e38f;
    for (int t = 0; t < TK; t++) {
        float m0[24];
#pragma unroll
        for (int i = 0; i < 24; i++) m0[i] = fmaxf(v[i], v[i + 24]);
#pragma unroll
        for (int i = 0; i < 12; i++) m0[i] = fmaxf(m0[i], m0[i + 12]);
#pragma unroll
        for (int i = 0; i < 6; i++) m0[i] = fmaxf(m0[i], m0[i + 6]);
        float m = fmaxf(fmaxf(fmaxf(m0[0], m0[1]), fmaxf(m0[2], m0[3])), fmaxf(m0[4], m0[5]));
#pragma unroll
        for (int s = 1; s < 64; s <<= 1) m = fmaxf(m, __shfl_xor(m, s));
        int cand = 0x7FFFFFFF;
#pragma unroll
        for (int i = 47; i >= 0; i--) {
            int col = (i >> 2) * 256 + lane * 4 + (i & 3);
            cand = (v[i] == m) ? col : cand;
        }
#pragma unroll
        for (int s = 1; s < 64; s <<= 1) cand = min(cand, __shfl_xor(cand, s));
        if (lane == 0) {
            float sg = 1.f / (1.f + expf(-m));
            hv[row * TK + t] = (sg > 0.5f) ? sg : 0.f;
            eidx[row * TK + t] = cand;
        }
        int owner = (cand >> 2) & 63;
        int li = ((cand >> 8) << 2) | (cand & 3);
        if (lane == owner) {
#pragma unroll
            for (int i = 0; i < 48; i++)
                if (i == li) v[i] = NEG;
        }
    }
}

// ---------------------------------------------------------------- edge stats (+msum zero)
__global__ void edge_stats(const float* __restrict__ hv, float* __restrict__ De,
                           float* __restrict__ ew, float* __restrict__ msum) {
    int e = blockIdx.x * 256 + threadIdx.x;
    if (e == 0) *msum = 0.f;
    if (e >= NN) return;
    float s = 0.f;
#pragma unroll
    for (int j = 0; j < TK; j++) s += hv[e * TK + j];
    De[e] = s + 1e-8f;
    ew[e] = s * (1.f / TK);
}

__global__ void scatter_deg(const int* __restrict__ eidx, const float* __restrict__ hv,
                            const float* __restrict__ ew, float* __restrict__ Dv,
                            float* __restrict__ Dv2, int* __restrict__ row_cnt) {
    int t = blockIdx.x * 256 + threadIdx.x;
    if (t >= NN * TK) return;
    int e = t >> 4;
    int v = eidx[t];
    float w = hv[t];
    atomicAdd(&Dv[v], w * ew[e]);
    atomicAdd(&Dv2[v], w);
    atomicAdd(&row_cnt[v], 1);
}

__global__ void deg_fin(const float* __restrict__ Dv, float* __restrict__ Dv2,
                        float* __restrict__ dvis) {
    int v = blockIdx.x * 256 + threadIdx.x;
    if (v >= NN) return;
    dvis[v] = 1.f / sqrtf(Dv[v] + 1e-8f);
    Dv2[v] += 1e-8f;
}

// ---------------------------------------------------------------- CSR build
__global__ void scan_kernel(const int* __restrict__ cnt, int* __restrict__ start) {
    __shared__ int part[256];
    int t = threadIdx.x;
    const int chunk = NN / 256;
    int s = 0;
    for (int i = t * chunk; i < (t + 1) * chunk; i++) s += cnt[i];
    part[t] = s;
    __syncthreads();
    if (t == 0) {
        int a = 0;
        for (int i = 0; i < 256; i++) { int v = part[i]; part[i] = a; a += v; }
    }
    __syncthreads();
    int a = part[t];
    for (int i = t * chunk; i < (t + 1) * chunk; i++) { start[i] = a; a += cnt[i]; }
    if (t == 255) start[NN] = a;
}

__global__ void fill_csr(const int* __restrict__ eidx, const float* __restrict__ hv,
                         const int* __restrict__ start, int* __restrict__ fillc,
                         int* __restrict__ csr_e, float* __restrict__ csr_w) {
    int t = blockIdx.x * 256 + threadIdx.x;
    if (t >= NN * TK) return;
    int e = t >> 4;
    int v = eidx[t];
    int pos = atomicAdd(&fillc[v], 1);
    int pp = start[v] + pos;
    csr_e[pp] = e;
    csr_w[pp] = hv[t];
}

// ---------------------------------------------------------------- sparse H ops (float4 lanes)
__global__ void edge_gather4(const int* __restrict__ eidx, const float* __restrict__ hv,
                             const float* __restrict__ De, const float* __restrict__ dvis,
                             const float* __restrict__ X, float* __restrict__ T,
                             int F4, int epb, int use_dvis) {
    int slot = threadIdx.x / F4;
    if (slot >= epb) return;
    int f = threadIdx.x - slot * F4;
    int e = blockIdx.x * epb + slot;
    const int* ei = eidx + e * TK;
    const float* hw = hv + e * TK;
    float ax = 0.f, ay = 0.f, az = 0.f, aw = 0.f;
#pragma unroll
    for (int j = 0; j < TK; j++) {
        int v = ei[j];
        float w = hw[j];
        if (use_dvis) w *= dvis[v];
        const float4 x = *(const float4*)(X + ((size_t)v * F4 + f) * 4);
        ax = fmaf(w, x.x, ax); ay = fmaf(w, x.y, ay);
        az = fmaf(w, x.z, az); aw = fmaf(w, x.w, aw);
    }
    float inv = 1.f / De[e];
    *(float4*)(T + ((size_t)e * F4 + f) * 4) = make_float4(ax * inv, ay * inv, az * inv, aw * inv);
}

__global__ void row_gather4(const int* __restrict__ start, const int* __restrict__ csr_e,
                            const float* __restrict__ csr_w, const float* __restrict__ dvis,
                            const float* __restrict__ T, const float* __restrict__ Badd,
                            float alpha, float beta, float* __restrict__ Y,
                            int F4, int epb, int use_dvis) {
    int slot = threadIdx.x / F4;
    if (slot >= epb) return;
    int f = threadIdx.x - slot * F4;
    int v = blockIdx.x * epb + slot;
    int s0 = start[v], s1 = start[v + 1];
    float ax = 0.f, ay = 0.f, az = 0.f, aw = 0.f;
    for (int p = s0; p < s1; p++) {
        float w = csr_w[p];
        const float4 x = *(const float4*)(T + ((size_t)csr_e[p] * F4 + f) * 4);
        ax = fmaf(w, x.x, ax); ay = fmaf(w, x.y, ay);
        az = fmaf(w, x.z, az); aw = fmaf(w, x.w, aw);
    }
    float sc = alpha * (use_dvis ? dvis[v] : 1.f);
    float4 o = make_float4(ax * sc, ay * sc, az * sc, aw * sc);
    if (Badd) {
        const float4 b = *(const float4*)(Badd + ((size_t)v * F4 + f) * 4);
        o.x += beta * b.x; o.y += beta * b.y; o.z += beta * b.z; o.w += beta * b.w;
    }
    *(float4*)(Y + ((size_t)v * F4 + f) * 4) = o;
}

// ---------------------------------------------------------------- reductions
__global__ void mse_reduce4(const float* __restrict__ a, const float* __restrict__ b,
                            float* __restrict__ sum) {
    __shared__ float rs[256];
    float s = 0.f;
    const int n4 = NN * FEAT / 4;
    for (int i = blockIdx.x * 256 + threadIdx.x; i < n4; i += gridDim.x * 256) {
        const float4 x = *(const float4*)(a + (size_t)i * 4);
        const float4 y = *(const float4*)(b + (size_t)i * 4);
        float dx = x.x - y.x, dy = x.y - y.y, dz = x.z - y.z, dw = x.w - y.w;
        s += dx * dx + dy * dy + dz * dz + dw * dw;
    }
    rs[threadIdx.x] = s;
    __syncthreads();
    for (int st = 128; st > 0; st >>= 1) {
        if (threadIdx.x < st) rs[threadIdx.x] += rs[threadIdx.x + st];
        __syncthreads();
    }
    if (threadIdx.x == 0) atomicAdd(sum, rs[0]);
}

__global__ void spectral_cols(const float* __restrict__ r, const float* __restrict__ y,
                              const float* __restrict__ Dv2, float* __restrict__ numb,
                              float* __restrict__ denb) {
    int c = blockIdx.x;
    __shared__ float rn[256], rd[256];
    float sn = 0.f, sd = 0.f;
    for (int i = threadIdx.x; i < NN; i += 256) {
        float rv = r[(size_t)i * 64 + c];
        float d2 = Dv2[i];
        float lcx = d2 * rv - y[(size_t)i * 64 + c];
        sn += rv * lcx;
        sd += d2 * rv * rv;
    }
    rn[threadIdx.x] = sn; rd[threadIdx.x] = sd;
    __syncthreads();
    for (int st = 128; st > 0; st >>= 1) {
        if (threadIdx.x < st) { rn[threadIdx.x] += rn[threadIdx.x + st]; rd[threadIdx.x] += rd[threadIdx.x + st]; }
        __syncthreads();
    }
    if (threadIdx.x == 0) { numb[c] = rn[0]; denb[c] = rd[0] + 1e-8f; }
}

__global__ void finals_kernel(const float* __restrict__ msum, const float* __restrict__ numb,
                              const float* __restrict__ denb, float* __restrict__ out) {
    if (threadIdx.x == 0 && blockIdx.x == 0) {
        float s = 0.f;
        for (int c = 0; c < 64; c++) s += numb[c] / denb[c];
        out[NN + 1] = s * (1.f / 64.f);
        out[NN] = msum[0] * (1.f / ((float)NN * FEAT));
    }
}

// ================================================================ launch
extern "C" void kernel_launch(void* const* d_in, const int* in_sizes, int n_in,
                              void* d_out, int out_size, void* d_ws, size_t ws_size,
                              hipStream_t stream) {
    const float* images = (const float*)d_in[0];
    const float* text   = (const float*)d_in[1];
    const float* signal = (const float*)d_in[2];
    const float* iw1 = (const float*)d_in[3];  const float* ib1 = (const float*)d_in[4];
    const float* iw2 = (const float*)d_in[5];  const float* ib2 = (const float*)d_in[6];
    const float* ig  = (const float*)d_in[7];  const float* ibeta = (const float*)d_in[8];
    const float* tw1 = (const float*)d_in[9];  const float* tb1 = (const float*)d_in[10];
    const float* tw2 = (const float*)d_in[11]; const float* tb2 = (const float*)d_in[12];
    const float* tg  = (const float*)d_in[13]; const float* tbeta = (const float*)d_in[14];
    const float* sw1 = (const float*)d_in[15]; const float* sb1 = (const float*)d_in[16];
    const float* sw2 = (const float*)d_in[17]; const float* sb2 = (const float*)d_in[18];
    const float* sg  = (const float*)d_in[19]; const float* sbeta = (const float*)d_in[20];
    const float* gw  = (const float*)d_in[21]; const float* gb = (const float*)d_in[22];
    const float* c1w = (const float*)d_in[23]; const float* c1b = (const float*)d_in[24];
    const float* c2w = (const float*)d_in[25]; const float* c2b = (const float*)d_in[26];
    const float* rw1 = (const float*)d_in[27]; const float* rb1 = (const float*)d_in[28];
    const float* rw2 = (const float*)d_in[29]; const float* rb2 = (const float*)d_in[30];
    const float* aw1 = (const float*)d_in[31]; const float* ab1 = (const float*)d_in[32];
    const float* aw2 = (const float*)d_in[33]; const float* ab2 = (const float*)d_in[34];
    const float* dw1 = (const float*)d_in[35]; const float* db1 = (const float*)d_in[36];
    const float* dw2 = (const float*)d_in[37]; const float* db2 = (const float*)d_in[38];
    float* out = (float*)d_out;

    float* wsf = (float*)d_ws;
    size_t off = 0;
    auto AF = [&](size_t n) { float* q = wsf + off; off += n; return q; };
    float* feats  = AF((size_t)NN * FEAT);
    float* simbuf = AF((size_t)NN * NN);
    float* p      = AF((size_t)NN * 192);
    float* h      = AF((size_t)NN * HIDD);
    float* z      = AF((size_t)NN * HIDD);   // reused in place as Zc (bf16 split)
    float* x1     = AF((size_t)NN * HIDD);
    float* x2     = AF((size_t)NN * 128);
    float* r      = AF((size_t)NN * 64);
    float* hv     = AF((size_t)NN * TK);
    float* ew     = AF(NN);
    float* De     = AF(NN);
    float* Dv     = AF(NN);
    float* Dv2    = AF(NN);
    float* dvis   = AF(NN);
    float* csr_w  = AF((size_t)NN * TK);
    float* numb   = AF(64);
    float* denb   = AF(64);
    float* msum   = AF(1);
    float* csum   = AF(FEAT);   // csum, csum2 contiguous -> one memset
    float* csum2  = AF(FEAT);
    float* bsc    = AF(FEAT);
    float* bsh    = AF(FEAT);
    int* eidx     = (int*)(wsf + off); off += (size_t)NN * TK;
    int* csr_e    = (int*)(wsf + off); off += (size_t)NN * TK;
    int* row_cnt  = (int*)(wsf + off); off += NN;
    int* row_fill = (int*)(wsf + off); off += NN;
    int* row_start= (int*)(wsf + off); off += NN + 1;

    short* Zc = (short*)z;

    // regions inside simbuf (free until sim / after topk):
    float* h_all = simbuf;                              // 3 x NN x 256 (pre-sim)
    float* T1    = simbuf;
    float* T2    = simbuf + (size_t)NN * FEAT;
    float* et    = simbuf + (size_t)2 * NN * FEAT;
    float* recon = simbuf + (size_t)3 * NN * FEAT;      // split-K / z-partial region
    float* yspec = x2;

    dim3 blk(256);
    auto gemmF = [&](const float* A, const float* B, const float* bias, float* C,
                     int M, int Nc, int K, int lda, int ldb, int ldc,
                     float alpha, int act, int acc, int KS, float* part) {
        int nk = K / 32;
        int ks = KS < nk ? KS : nk; if (ks < 1) ks = 1;
        int kc = ((nk + ks - 1) / ks) * 32;
        int ksp = (K + kc - 1) / kc;
        gemm_mf<<<dim3(Nc / 64, M / 128, ksp), blk, 0, stream>>>(
            A, B, bias, C, part, M, Nc, K, lda, ldb, ldc, kc, alpha, act, acc);
        if (ksp > 1)
            gemm_epi<<<((size_t)M * Nc + 255) / 256, blk, 0, stream>>>(
                part, bias, C, M, Nc, ldc, ksp, alpha, act, acc);
    };
    auto gemmSm = [&](const float* A, const float* B, const float* bias, float* C,
                      int M, int Nc, int K, int lda, int ldb, int ldc,
                      float alpha, int act, int acc, int KS, float* part) {
        int nk = K / 32;
        int ks = KS < nk ? KS : nk; if (ks < 1) ks = 1;
        int kc = ((nk + ks - 1) / ks) * 32;
        int ksp = (K + kc - 1) / kc;
        gemm2<<<dim3((Nc + 63) / 64, M / 64, ksp), blk, 0, stream>>>(A, B, part, M, Nc, K, lda, ldb, kc);
        gemm_epi<<<((size_t)M * Nc + 255) / 256, blk, 0, stream>>>(part, bias, C, M, Nc, ldc, ksp, alpha, act, acc);
    };
    auto eg4 = [&](const float* X, float* T, int F, int use_dvis) {
        int F4 = F / 4, epb = 256 / F4 < 1 ? 1 : 256 / F4;
        edge_gather4<<<NN / epb, dim3(F4 * epb), 0, stream>>>(eidx, hv, De, dvis, X, T, F4, epb, use_dvis);
    };
    auto rg4 = [&](const float* T, const float* Badd, float alpha, float beta, float* Y,
                   int F, int use_dvis) {
        int F4 = F / 4, epb = 256 / F4 < 1 ? 1 : 256 / F4;
        row_gather4<<<NN / epb, dim3(F4 * epb), 0, stream>>>(row_start, csr_e, csr_w, dvis, T, Badd,
                                                             alpha, beta, Y, F4, epb, use_dvis);
    };

    const float E1 = 0.60653065971f;  // exp(-0.5)
    const float E2 = 0.36787944117f;  // exp(-1.0)

    // ---- modality MLPs (z-batched) + BN ----
    pool_kernel<<<(NN * 192 + 255) / 256, blk, 0, stream>>>(images, p);
    hipMemsetAsync(csum, 0, 2 * FEAT * sizeof(float), stream);
    float* h0 = h_all, *h1 = h_all + (size_t)NN * 256, *h2 = h_all + (size_t)2 * NN * 256;
    {
        MZ mz{};
        mz.A[0] = p;     mz.A[1] = text;  mz.A[2] = signal;
        mz.Bw[0] = iw1;  mz.Bw[1] = tw1;  mz.Bw[2] = sw1;
        mz.bias[0] = ib1; mz.bias[1] = tb1; mz.bias[2] = sb1;
        mz.C[0] = h0;    mz.C[1] = h1;    mz.C[2] = h2;
        mz.K[0] = 192;   mz.K[1] = 768;   mz.K[2] = 256;
        mz.lda[0] = 192; mz.lda[1] = 768; mz.lda[2] = 256;
        gemm_mz<<<dim3(4, 24, 3), blk, 0, stream>>>(mz, nullptr, NN, 256, 256, 256, 1, 0);
    }
    {
        MZ mz{};
        mz.A[0] = h0;    mz.A[1] = h1;    mz.A[2] = h2;
        mz.Bw[0] = iw2;  mz.Bw[1] = tw2;  mz.Bw[2] = sw2;
        mz.bias[0] = ib2; mz.bias[1] = tb2; mz.bias[2] = sb2;
        mz.C[0] = feats; mz.C[1] = feats + 256; mz.C[2] = feats + 512;
        mz.K[0] = mz.K[1] = mz.K[2] = 256;
        mz.lda[0] = mz.lda[1] = mz.lda[2] = 256;
        gemm_mz<<<dim3(4, 24, 3), blk, 0, stream>>>(mz, nullptr, NN, 256, 256, FEAT, 0, 0);
    }
    bn_stats<<<NN / 16, blk, 0, stream>>>(feats, csum, csum2);
    bn_fin<<<3, blk, 0, stream>>>(csum, csum2, ig, tg, sg, ibeta, tbeta, sbeta, bsc, bsh);
    bn_norm<<<1024, blk, 0, stream>>>(feats, bsc, bsh);

    // ---- hyperedge generator (partials at simbuf: h_all dead) ----
    gemmF(feats, gw, gb, z, NN, HIDD, FEAT, FEAT, HIDD, HIDD, 1.f, 2, 0, 4, simbuf);
    rownorm_kernel<<<NN, blk, 0, stream>>>(z, Zc);
    sim_mfma<<<dim3(NN / 128, NN / 128), blk, 0, stream>>>(Zc, simbuf);
    topk_kernel<<<NN / 4, blk, 0, stream>>>(simbuf, hv, eidx);

    // ---- degrees + CSR of H rows ----
    hipMemsetAsync(Dv, 0, 2 * NN * sizeof(float), stream);
    hipMemsetAsync(row_cnt, 0, 2 * NN * sizeof(int), stream);
    edge_stats<<<NN / 256, blk, 0, stream>>>(hv, De, ew, msum);
    scatter_deg<<<NN * TK / 256, blk, 0, stream>>>(eidx, hv, ew, Dv, Dv2, row_cnt);
    deg_fin<<<NN / 256, blk, 0, stream>>>(Dv, Dv2, dvis);
    scan_kernel<<<1, blk, 0, stream>>>(row_cnt, row_start);
    fill_csr<<<NN * TK / 256, blk, 0, stream>>>(eidx, hv, row_start, row_fill, csr_e, csr_w);

    // ---- cheb conv 1 (F=768 -> 256), z-batched 3 terms ----
    eg4(feats, et, FEAT, 1);
    rg4(et, nullptr, -1.f, 0.f, T1, FEAT, 1);
    eg4(T1, et, FEAT, 1);
    rg4(et, feats, -2.f, -1.f, T2, FEAT, 1);
    {
        MZ mz{};
        mz.A[0] = feats; mz.A[1] = T1; mz.A[2] = T2;
        mz.Bw[0] = c1w;  mz.Bw[1] = c1w + (size_t)FEAT * HIDD; mz.Bw[2] = c1w + (size_t)2 * FEAT * HIDD;
        mz.K[0] = mz.K[1] = mz.K[2] = FEAT;
        mz.lda[0] = mz.lda[1] = mz.lda[2] = FEAT;
        mz.scale[0] = 1.f; mz.scale[1] = E1; mz.scale[2] = E2;
        gemm_mz<<<dim3(4, 24, 3), blk, 0, stream>>>(mz, recon, NN, 256, HIDD, HIDD, 0, 1);
        gemm_epi<<<((size_t)NN * 256 + 255) / 256, blk, 0, stream>>>(
            recon, c1b, x1, NN, 256, 256, 3, 1.f, 1, 0);
    }

    // ---- cheb conv 2 (F=256 -> 128), z-batched ----
    eg4(x1, et, HIDD, 1);
    rg4(et, nullptr, -1.f, 0.f, T1, HIDD, 1);
    eg4(T1, et, HIDD, 1);
    rg4(et, x1, -2.f, -1.f, T2, HIDD, 1);
    {
        MZ mz{};
        mz.A[0] = x1; mz.A[1] = T1; mz.A[2] = T2;
        mz.Bw[0] = c2w;  mz.Bw[1] = c2w + (size_t)HIDD * 128; mz.Bw[2] = c2w + (size_t)2 * HIDD * 128;
        mz.K[0] = mz.K[1] = mz.K[2] = HIDD;
        mz.lda[0] = mz.lda[1] = mz.lda[2] = HIDD;
        mz.scale[0] = 1.f; mz.scale[1] = E1; mz.scale[2] = E2;
        gemm_mz<<<dim3(2, 24, 3), blk, 0, stream>>>(mz, recon, NN, 128, 128, 128, 0, 1);
        gemm_epi<<<((size_t)NN * 128 + 255) / 256, blk, 0, stream>>>(
            recon, c2b, x2, NN, 128, 128, 3, 1.f, 1, 0);
    }

    // ---- heads ----
    gemmF(x2, rw1, rb1, h, NN, 64, 128, 128, 64, 64, 1.f, 1, 0, 2, recon);
    gemmF(h,  rw2, rb2, r, NN, 64, 64, 64, 64, 64, 1.f, 0, 0, 2, recon);
    gemmSm(r,  aw1, ab1, h, NN, 32, 64, 64, 32, 32, 1.f, 1, 0, 2, recon);
    gemmSm(h,  aw2, ab2, out, NN, 1, 32, 32, 1, 1, 1.f, 3, 0, 1, recon);
    gemmF(r,  dw1, db1, h, NN, HIDD, 64, 64, HIDD, HIDD, 1.f, 1, 0, 2, recon);
    gemmF(h,  dw2, db2, recon, NN, FEAT, HIDD, HIDD, FEAT, FEAT, 1.f, 0, 0, 1, T1);
    mse_reduce4<<<512, blk, 0, stream>>>(recon, feats, msum);

    // ---- spectral cut ----
    eg4(r, et, 64, 0);
    rg4(et, nullptr, 1.f, 0.f, yspec, 64, 0);
    spectral_cols<<<64, blk, 0, stream>>>(r, yspec, Dv2, numb, denb);
    finals_kernel<<<1, 64, 0, stream>>>(msum, numb, denb, out);
}

// Round 8
// 542.407 us; speedup vs baseline: 1.5889x; 1.0118x over previous
//
#include <hip/hip_runtime.h>
#include <cmath>

#define NN   3072
#define HIDD 256
#define TK   16
#define FEAT 768   // 3*HID

typedef __attribute__((ext_vector_type(8))) short bf16x8;
typedef __attribute__((ext_vector_type(4))) float f32x4;

__device__ inline unsigned short f2bf(float x) {
    unsigned u = __float_as_uint(x);
    unsigned r = (u + 0x7FFFu + ((u >> 16) & 1u)) >> 16;   // RNE
    return (unsigned short)r;
}
__device__ inline float bf2f(unsigned short h) {
    return __uint_as_float(((unsigned)h) << 16);
}

// ---------------------------------------------------------------- pool
__global__ void pool_kernel(const float* __restrict__ img, float* __restrict__ p) {
    int idx = blockIdx.x * 256 + threadIdx.x;
    if (idx >= NN * 192) return;
    int b = idx / 192, rem = idx % 192;
    int c = rem >> 6, oy = (rem >> 3) & 7, ox = rem & 7;
    const float* base = img + (((size_t)b * 3 + c) * 32 + oy * 4) * 32 + ox * 4;
    float s = 0.f;
#pragma unroll
    for (int iy = 0; iy < 4; iy++)
#pragma unroll
        for (int ix = 0; ix < 4; ix++) s += base[iy * 32 + ix];
    p[idx] = s * 0.0625f;
}

// ---------------------------------------------------------------- split fp32 rows -> [hi | lo] bf16 (k-contiguous)
__global__ void split_rows(const float* __restrict__ X, short* __restrict__ Xc,
                           int K, int total4) {
    int i = blockIdx.x * 256 + threadIdx.x;
    if (i >= total4) return;
    int K4 = K >> 2;
    int m = i / K4, f = i - m * K4;
    float4 v = *(const float4*)(X + (size_t)m * K + f * 4);
    unsigned short h0 = f2bf(v.x), h1 = f2bf(v.y), h2 = f2bf(v.z), h3 = f2bf(v.w);
    short4 hi = make_short4((short)h0, (short)h1, (short)h2, (short)h3);
    short4 lo = make_short4((short)f2bf(v.x - bf2f(h0)), (short)f2bf(v.y - bf2f(h1)),
                            (short)f2bf(v.z - bf2f(h2)), (short)f2bf(v.w - bf2f(h3)));
    *(short4*)(Xc + (size_t)m * 2 * K + f * 4) = hi;
    *(short4*)(Xc + (size_t)m * 2 * K + K + f * 4) = lo;
}

// ---------------------------------------------------------------- batched weight transpose+split: W[KxN] -> Wc[N][2K]
struct WJ { const float* W; short* Wc; int K; int N; };
struct WJobs { WJ j[13]; };

__global__ void wsplitT(WJobs js) {
    WJ jb = js.j[blockIdx.z];
    int tk = blockIdx.x * 32, tn = blockIdx.y * 32;
    if (tk >= jb.K || tn >= jb.N) return;
    __shared__ float t[32][33];
    int kk = threadIdx.x >> 3, nn = (threadIdx.x & 7) * 4;
    float4 v = *(const float4*)(jb.W + (size_t)(tk + kk) * jb.N + tn + nn);
    t[kk][nn + 0] = v.x; t[kk][nn + 1] = v.y; t[kk][nn + 2] = v.z; t[kk][nn + 3] = v.w;
    __syncthreads();
    int n2 = threadIdx.x >> 3, k2 = (threadIdx.x & 7) * 4;
    float a = t[k2 + 0][n2], b = t[k2 + 1][n2], c = t[k2 + 2][n2], d = t[k2 + 3][n2];
    unsigned short h0 = f2bf(a), h1 = f2bf(b), h2 = f2bf(c), h3 = f2bf(d);
    short4 hi = make_short4((short)h0, (short)h1, (short)h2, (short)h3);
    short4 lo = make_short4((short)f2bf(a - bf2f(h0)), (short)f2bf(b - bf2f(h1)),
                            (short)f2bf(c - bf2f(h2)), (short)f2bf(d - bf2f(h3)));
    size_t rowb = (size_t)(tn + n2) * 2 * jb.K;
    *(short4*)(jb.Wc + rowb + tk + k2) = hi;
    *(short4*)(jb.Wc + rowb + jb.K + tk + k2) = lo;
}

// ---------------------------------------------------------------- pure bf16 NT GEMM (z-batched + split-K)
// A[z]: [M][Ka] bf16 k-contig; B[z]: [N][Ka] bf16 k-contig. C = A·B^T.
struct BT {
    const short* A[3];
    const short* Bw[3];
    const float* bias[3];
    float* Cf[3];
    short* Cc[3];
    int Ka[3];
    float scale[3];
    int ldc;   // Cf row stride
    int ccW;   // Cc logical width (lo offset); row stride 2*ccW
};

__global__ __launch_bounds__(256) void gemm_bt(BT bt, float* __restrict__ P,
        int M, int Nc, int act, int KS, int Kc) {
    __shared__ short As[128 * 64];
    __shared__ short Bs[64 * 64];
    int zz = blockIdx.z, s = 0;
    if (KS > 1) { zz = blockIdx.z / KS; s = blockIdx.z % KS; }
    const short* A = bt.A[zz];
    const short* B = bt.Bw[zz];
    int Ka = bt.Ka[zz];
    int kbeg = s * Kc;
    int kend = (KS > 1) ? min(Ka, kbeg + Kc) : Ka;
    int tid = threadIdx.x, wave = tid >> 6, lane = tid & 63;
    int wm = (wave >> 1) * 64, wn = (wave & 1) * 32;
    int lrow = lane & 15, lk = lane >> 4;
    int m0 = blockIdx.y * 128, n0 = blockIdx.x * 64;
    f32x4 acc[4][2] = {};

    for (int k0 = kbeg; k0 < kend; k0 += 64) {
#pragma unroll
        for (int i = 0; i < 4; i++) {
            int q = tid + i * 256;
            int row = q >> 3, c = q & 7;
            int dst = row * 128 + ((c ^ (row & 7)) << 4);
            *(float4*)((char*)As + dst) =
                *(const float4*)((const char*)A + (((size_t)(m0 + row) * Ka + k0) << 1) + (c << 4));
        }
#pragma unroll
        for (int i = 0; i < 2; i++) {
            int q = tid + i * 256;
            int row = q >> 3, c = q & 7;
            int dst = row * 128 + ((c ^ (row & 7)) << 4);
            *(float4*)((char*)Bs + dst) =
                *(const float4*)((const char*)B + (((size_t)(n0 + row) * Ka + k0) << 1) + (c << 4));
        }
        __syncthreads();
#pragma unroll
        for (int kk = 0; kk < 2; kk++) {
            int ck = kk * 4 + lk;
            bf16x8 af[4], bg[2];
#pragma unroll
            for (int t = 0; t < 4; t++) {
                int ra = wm + t * 16 + lrow;
                af[t] = *(const bf16x8*)((const char*)As + ra * 128 + ((ck ^ (ra & 7)) << 4));
            }
#pragma unroll
            for (int u = 0; u < 2; u++) {
                int rb = wn + u * 16 + lrow;
                bg[u] = *(const bf16x8*)((const char*)Bs + rb * 128 + ((ck ^ (rb & 7)) << 4));
            }
#pragma unroll
            for (int i2 = 0; i2 < 4; i2++)
#pragma unroll
                for (int j2 = 0; j2 < 2; j2++)
                    acc[i2][j2] = __builtin_amdgcn_mfma_f32_16x16x32_bf16(af[i2], bg[j2], acc[i2][j2], 0, 0, 0);
        }
        __syncthreads();
    }

    // C/D layout: col = lane&15, row = (lane>>4)*4 + reg
    if (P) {
        float sc = bt.scale[zz];
        float* Pp = P + (size_t)(zz * KS + s) * M * Nc;
#pragma unroll
        for (int i2 = 0; i2 < 4; i2++) {
            int gmb = m0 + wm + i2 * 16 + lk * 4;
#pragma unroll
            for (int j2 = 0; j2 < 2; j2++) {
                int gn = n0 + wn + j2 * 16 + lrow;
#pragma unroll
                for (int rg = 0; rg < 4; rg++)
                    Pp[(size_t)(gmb + rg) * Nc + gn] = sc * acc[i2][j2][rg];
            }
        }
    } else {
        const float* bias = bt.bias[zz];
        float* Cf = bt.Cf[zz];
        short* Cc = bt.Cc[zz];
#pragma unroll
        for (int i2 = 0; i2 < 4; i2++) {
            int gmb = m0 + wm + i2 * 16 + lk * 4;
#pragma unroll
            for (int j2 = 0; j2 < 2; j2++) {
                int gn = n0 + wn + j2 * 16 + lrow;
#pragma unroll
                for (int rg = 0; rg < 4; rg++) {
                    int gm = gmb + rg;
                    float x = acc[i2][j2][rg];
                    if (bias) x += bias[gn];
                    if (act == 1) x = fmaxf(x, 0.f);
                    else if (act == 2) x = tanhf(x);
                    if (Cf) Cf[(size_t)gm * bt.ldc + gn] = x;
                    if (Cc) {
                        unsigned short hi2 = f2bf(x);
                        Cc[(size_t)gm * 2 * bt.ccW + gn] = (short)hi2;
                        Cc[(size_t)gm * 2 * bt.ccW + bt.ccW + gn] = (short)f2bf(x - bf2f(hi2));
                    }
                }
            }
        }
    }
}

// ---------------------------------------------------------------- MFMA split-bf16 GEMM (fp32 in, heads only)
__global__ __launch_bounds__(256) void gemm_mf(
        const float* __restrict__ A, const float* __restrict__ B,
        const float* __restrict__ bias, float* __restrict__ C, float* __restrict__ P,
        int M, int Nc, int K, int lda, int ldb, int ldc, int Kc,
        float alpha, int act, int accf) {
    __shared__ short Ah[128 * 40];
    __shared__ short Al[128 * 40];
    __shared__ short Bh[64 * 40];
    __shared__ short Bl[64 * 40];
    int tid = threadIdx.x, wave = tid >> 6, lane = tid & 63;
    int wm = (wave >> 1) * 64, wn = (wave & 1) * 32;
    int lrow = lane & 15, lk = lane >> 4;
    int m0 = blockIdx.y * 128, n0 = blockIdx.x * 64;
    int kbeg = blockIdx.z * Kc, kend = min(K, kbeg + Kc);
    f32x4 acc[4][2] = {};

    for (int k0 = kbeg; k0 < kend; k0 += 32) {
#pragma unroll
        for (int i = 0; i < 4; i++) {
            int q = tid + i * 256;
            int rowm = q >> 3, kq = q & 7;
            float4 vv = *(const float4*)(A + (size_t)(m0 + rowm) * lda + k0 + kq * 4);
            unsigned short h0 = f2bf(vv.x), h1 = f2bf(vv.y), h2 = f2bf(vv.z), h3 = f2bf(vv.w);
            unsigned short l0 = f2bf(vv.x - bf2f(h0)), l1 = f2bf(vv.y - bf2f(h1));
            unsigned short l2 = f2bf(vv.z - bf2f(h2)), l3 = f2bf(vv.w - bf2f(h3));
            *(short4*)&Ah[rowm * 40 + kq * 4] = make_short4((short)h0, (short)h1, (short)h2, (short)h3);
            *(short4*)&Al[rowm * 40 + kq * 4] = make_short4((short)l0, (short)l1, (short)l2, (short)l3);
        }
#pragma unroll
        for (int i = 0; i < 2; i++) {
            int q = tid + i * 256;
            int kk2 = q >> 4, nq = q & 15;
            float4 vv = *(const float4*)(B + (size_t)(k0 + kk2) * ldb + n0 + nq * 4);
            unsigned short h0 = f2bf(vv.x), h1 = f2bf(vv.y), h2 = f2bf(vv.z), h3 = f2bf(vv.w);
            unsigned short l0 = f2bf(vv.x - bf2f(h0)), l1 = f2bf(vv.y - bf2f(h1));
            unsigned short l2 = f2bf(vv.z - bf2f(h2)), l3 = f2bf(vv.w - bf2f(h3));
            Bh[(nq * 4 + 0) * 40 + kk2] = (short)h0;  Bl[(nq * 4 + 0) * 40 + kk2] = (short)l0;
            Bh[(nq * 4 + 1) * 40 + kk2] = (short)h1;  Bl[(nq * 4 + 1) * 40 + kk2] = (short)l1;
            Bh[(nq * 4 + 2) * 40 + kk2] = (short)h2;  Bl[(nq * 4 + 2) * 40 + kk2] = (short)l2;
            Bh[(nq * 4 + 3) * 40 + kk2] = (short)h3;  Bl[(nq * 4 + 3) * 40 + kk2] = (short)l3;
        }
        __syncthreads();
        bf16x8 ah[4], al[4], bh[2], bl[2];
#pragma unroll
        for (int t2 = 0; t2 < 4; t2++) {
            int ra = wm + t2 * 16 + lrow;
            ah[t2] = *(const bf16x8*)&Ah[ra * 40 + lk * 8];
            al[t2] = *(const bf16x8*)&Al[ra * 40 + lk * 8];
        }
#pragma unroll
        for (int u = 0; u < 2; u++) {
            int rb = wn + u * 16 + lrow;
            bh[u] = *(const bf16x8*)&Bh[rb * 40 + lk * 8];
            bl[u] = *(const bf16x8*)&Bl[rb * 40 + lk * 8];
        }
#pragma unroll
        for (int i2 = 0; i2 < 4; i2++)
#pragma unroll
            for (int j2 = 0; j2 < 2; j2++) {
                acc[i2][j2] = __builtin_amdgcn_mfma_f32_16x16x32_bf16(ah[i2], bh[j2], acc[i2][j2], 0, 0, 0);
                acc[i2][j2] = __builtin_amdgcn_mfma_f32_16x16x32_bf16(ah[i2], bl[j2], acc[i2][j2], 0, 0, 0);
                acc[i2][j2] = __builtin_amdgcn_mfma_f32_16x16x32_bf16(al[i2], bh[j2], acc[i2][j2], 0, 0, 0);
            }
        __syncthreads();
    }

    if (gridDim.z == 1) {
#pragma unroll
        for (int i2 = 0; i2 < 4; i2++) {
            int gmb = m0 + wm + i2 * 16 + lk * 4;
#pragma unroll
            for (int j2 = 0; j2 < 2; j2++) {
                int gn = n0 + wn + j2 * 16 + lrow;
#pragma unroll
                for (int rg = 0; rg < 4; rg++) {
                    int gm = gmb + rg;
                    float x = alpha * acc[i2][j2][rg];
                    if (bias) x += bias[gn];
                    if (accf) x += C[(size_t)gm * ldc + gn];
                    if (act == 1) x = fmaxf(x, 0.f);
                    else if (act == 2) x = tanhf(x);
                    else if (act == 3) x = 1.f / (1.f + expf(-x));
                    C[(size_t)gm * ldc + gn] = x;
                }
            }
        }
    } else {
        float* Pp = P + (size_t)blockIdx.z * M * Nc;
#pragma unroll
        for (int i2 = 0; i2 < 4; i2++) {
            int gmb = m0 + wm + i2 * 16 + lk * 4;
#pragma unroll
            for (int j2 = 0; j2 < 2; j2++) {
                int gn = n0 + wn + j2 * 16 + lrow;
#pragma unroll
                for (int rg = 0; rg < 4; rg++)
                    Pp[(size_t)(gmb + rg) * Nc + gn] = acc[i2][j2][rg];
            }
        }
    }
}

// ---------------------------------------------------------------- fp32 GEMM (tiny heads only)
__global__ void gemm2(const float* __restrict__ A, const float* __restrict__ B,
                      float* __restrict__ P, int M, int Nc, int K,
                      int lda, int ldb, int Kc) {
    __shared__ float As[32][68];
    __shared__ float Bs[32][68];
    int tid = threadIdx.x;
    int tm = tid >> 4, tn = tid & 15;
    int m0 = blockIdx.y * 64, n0 = blockIdx.x * 64;
    int kbeg = blockIdx.z * Kc;
    int kend = min(K, kbeg + Kc);
    float acc[4][4] = {};
    for (int k0 = kbeg; k0 < kend; k0 += 32) {
#pragma unroll
        for (int i = 0; i < 2; i++) {
            int q = tid + i * 256;
            int m = q >> 3, kq = q & 7;
            float4 v = *(const float4*)(A + (size_t)(m0 + m) * lda + k0 + kq * 4);
            int col = m ^ (kq << 2);
            As[kq * 4 + 0][col] = v.x;
            As[kq * 4 + 1][col] = v.y;
            As[kq * 4 + 2][col] = v.z;
            As[kq * 4 + 3][col] = v.w;
        }
#pragma unroll
        for (int i = 0; i < 2; i++) {
            int q = tid + i * 256;
            int k = q >> 4, nq = q & 15;
            int gn = n0 + nq * 4;
            float4 v;
            const float* src = B + (size_t)(k0 + k) * ldb + gn;
            if (gn + 3 < Nc) {
                v = *(const float4*)src;
            } else {
                v.x = (gn + 0 < Nc) ? src[0] : 0.f;
                v.y = (gn + 1 < Nc) ? src[1] : 0.f;
                v.z = (gn + 2 < Nc) ? src[2] : 0.f;
                v.w = (gn + 3 < Nc) ? src[3] : 0.f;
            }
            *(float4*)&Bs[k][nq * 4] = v;
        }
        __syncthreads();
#pragma unroll
        for (int kk = 0; kk < 32; kk++) {
            int swz = kk & 28;
            float a[4], b[4];
            *(float4*)a = *(const float4*)&As[kk][(tm * 4) ^ swz];
            *(float4*)b = *(const float4*)&Bs[kk][tn * 4];
#pragma unroll
            for (int i = 0; i < 4; i++)
#pragma unroll
                for (int j = 0; j < 4; j++) acc[i][j] += a[i] * b[j];
        }
        __syncthreads();
    }
    float* Pp = P + (size_t)blockIdx.z * M * Nc;
    int gn = n0 + tn * 4;
#pragma unroll
    for (int i = 0; i < 4; i++) {
        int gm = m0 + tm * 4 + i;
        if (gn + 3 < Nc) {
            *(float4*)&Pp[(size_t)gm * Nc + gn] = *(float4*)&acc[i][0];
        } else {
#pragma unroll
            for (int j = 0; j < 4; j++)
                if (gn + j < Nc) Pp[(size_t)gm * Nc + gn + j] = acc[i][j];
        }
    }
}

// epilogue: C = act(alpha*sum_s P[s] + bias + acc*C); optional split-bf16 out
__global__ void gemm_epi(const float* __restrict__ P, const float* __restrict__ bias,
                         float* __restrict__ C, short* __restrict__ Cc,
                         int M, int Nc, int ldc, int ccW, int KS,
                         float alpha, int act, int acc) {
    int idx = blockIdx.x * 256 + threadIdx.x;
    if (idx >= M * Nc) return;
    int m = idx / Nc, n = idx - m * Nc;
    float v = 0.f;
    for (int s = 0; s < KS; s++) v += P[(size_t)s * M * Nc + idx];
    v *= alpha;
    if (bias) v += bias[n];
    if (acc) v += C[(size_t)m * ldc + n];
    if (act == 1) v = fmaxf(v, 0.f);
    else if (act == 2) v = tanhf(v);
    else if (act == 3) v = 1.f / (1.f + expf(-v));
    if (C) C[(size_t)m * ldc + n] = v;
    if (Cc) {
        unsigned short hi = f2bf(v);
        Cc[(size_t)m * 2 * ccW + n] = (short)hi;
        Cc[(size_t)m * 2 * ccW + ccW + n] = (short)f2bf(v - bf2f(hi));
    }
}

// ---------------------------------------------------------------- sim = Zc @ Zc^T  (split-bf16 MFMA, K=512)
__global__ __launch_bounds__(256) void sim_mfma(const short* __restrict__ Zc,
                                                float* __restrict__ S) {
    __shared__ short As[128 * 64];
    __shared__ short Bs[128 * 64];
    int tid = threadIdx.x;
    int wave = tid >> 6, lane = tid & 63;
    int wm = (wave >> 1) * 64, wn = (wave & 1) * 64;
    int m0 = blockIdx.y * 128, n0 = blockIdx.x * 128;
    int lrow = lane & 15, lk = lane >> 4;
    f32x4 acc[4][4] = {};

    for (int k0 = 0; k0 < 512; k0 += 64) {
#pragma unroll
        for (int i = 0; i < 4; i++) {
            int q = tid + i * 256;
            int row = q >> 3, c = q & 7;
            int dstoff = row * 128 + ((c ^ (row & 7)) << 4);
            const char* pa = (const char*)Zc + (((size_t)(m0 + row) * 512 + k0) << 1) + (c << 4);
            *(float4*)((char*)As + dstoff) = *(const float4*)pa;
            const char* pb = (const char*)Zc + (((size_t)(n0 + row) * 512 + k0) << 1) + (c << 4);
            *(float4*)((char*)Bs + dstoff) = *(const float4*)pb;
        }
        __syncthreads();
#pragma unroll
        for (int kk = 0; kk < 2; kk++) {
            int ck = kk * 4 + lk;
            bf16x8 af[4], bg[4];
#pragma unroll
            for (int t = 0; t < 4; t++) {
                int ra = wm + t * 16 + lrow;
                af[t] = *(const bf16x8*)((const char*)As + ra * 128 + ((ck ^ (ra & 7)) << 4));
                int rb = wn + t * 16 + lrow;
                bg[t] = *(const bf16x8*)((const char*)Bs + rb * 128 + ((ck ^ (rb & 7)) << 4));
            }
#pragma unroll
            for (int i2 = 0; i2 < 4; i2++)
#pragma unroll
                for (int j2 = 0; j2 < 4; j2++)
                    acc[i2][j2] = __builtin_amdgcn_mfma_f32_16x16x32_bf16(
                        af[i2], bg[j2], acc[i2][j2], 0, 0, 0);
        }
        __syncthreads();
    }
#pragma unroll
    for (int i2 = 0; i2 < 4; i2++) {
#pragma unroll
        for (int j2 = 0; j2 < 4; j2++) {
            int col = n0 + wn + j2 * 16 + lrow;
            int rowb = m0 + wm + i2 * 16 + lk * 4;
#pragma unroll
            for (int rg = 0; rg < 4; rg++)
                S[(size_t)(rowb + rg) * NN + col] = acc[i2][j2][rg];
        }
    }
}

// ---------------------------------------------------------------- BatchNorm, row-major 3-phase
__global__ void bn_stats(const float* __restrict__ Y, float* __restrict__ csum,
                         float* __restrict__ csum2) {
    int t = threadIdx.x;
    float s0 = 0.f, s1 = 0.f, s2v = 0.f;
    float q0 = 0.f, q1 = 0.f, q2 = 0.f;
    int r0 = blockIdx.x * 16;
    for (int i = r0; i < r0 + 16; i++) {
        const float* row = Y + (size_t)i * FEAT;
        float a = row[t], b = row[t + 256], c = row[t + 512];
        s0 += a; q0 += a * a;
        s1 += b; q1 += b * b;
        s2v += c; q2 += c * c;
    }
    atomicAdd(&csum[t], s0);        atomicAdd(&csum2[t], q0);
    atomicAdd(&csum[t + 256], s1);  atomicAdd(&csum2[t + 256], q1);
    atomicAdd(&csum[t + 512], s2v); atomicAdd(&csum2[t + 512], q2);
}

__global__ void bn_fin(const float* __restrict__ csum, const float* __restrict__ csum2,
                       const float* __restrict__ g0, const float* __restrict__ g1,
                       const float* __restrict__ g2, const float* __restrict__ b0,
                       const float* __restrict__ b1, const float* __restrict__ b2,
                       float* __restrict__ scale, float* __restrict__ shift) {
    int j = blockIdx.x * 256 + threadIdx.x;
    if (j >= FEAT) return;
    float mean = csum[j] * (1.f / NN);
    float var = fmaxf(csum2[j] * (1.f / NN) - mean * mean, 0.f);
    int m = j >> 8, jj = j & 255;
    const float* g = (m == 0) ? g0 : (m == 1) ? g1 : g2;
    const float* bt = (m == 0) ? b0 : (m == 1) ? b1 : b2;
    float sc = g[jj] / sqrtf(var + 1e-5f);
    scale[j] = sc;
    shift[j] = bt[jj] - mean * sc;
}

// normalize + optionally emit split-bf16 copy
__global__ void bn_norm(float* __restrict__ Y, const float* __restrict__ scale,
                        const float* __restrict__ shift, short* __restrict__ Yc) {
    __shared__ float sc[FEAT], sh[FEAT];
    for (int j = threadIdx.x; j < FEAT; j += 256) { sc[j] = scale[j]; sh[j] = shift[j]; }
    __syncthreads();
    const int n4 = NN * FEAT / 4;
    for (int i = blockIdx.x * 256 + threadIdx.x; i < n4; i += gridDim.x * 256) {
        float4 v = *(const float4*)(Y + (size_t)i * 4);
        int m = i / 192;
        int c = (i - m * 192) * 4;
        v.x = v.x * sc[c + 0] + sh[c + 0];
        v.y = v.y * sc[c + 1] + sh[c + 1];
        v.z = v.z * sc[c + 2] + sh[c + 2];
        v.w = v.w * sc[c + 3] + sh[c + 3];
        *(float4*)(Y + (size_t)i * 4) = v;
        if (Yc) {
            unsigned short h0 = f2bf(v.x), h1 = f2bf(v.y), h2 = f2bf(v.z), h3 = f2bf(v.w);
            *(short4*)(Yc + (size_t)m * 1536 + c) =
                make_short4((short)h0, (short)h1, (short)h2, (short)h3);
            *(short4*)(Yc + (size_t)m * 1536 + 768 + c) =
                make_short4((short)f2bf(v.x - bf2f(h0)), (short)f2bf(v.y - bf2f(h1)),
                            (short)f2bf(v.z - bf2f(h2)), (short)f2bf(v.w - bf2f(h3)));
        }
    }
}

// ---------------------------------------------------------------- row normalize z -> split-bf16 Zc (in place)
__global__ void rownorm_kernel(const float* __restrict__ Zin, short* __restrict__ Zc) {
    int i = blockIdx.x;
    int c = threadIdx.x;
    __shared__ float rs[256];
    __shared__ float inv;
    float v = Zin[(size_t)i * HIDD + c];
    rs[c] = v * v;
    __syncthreads();
    for (int st = 128; st > 0; st >>= 1) {
        if (c < st) rs[c] += rs[c + st];
        __syncthreads();
    }
    if (c == 0) inv = 1.f / (sqrtf(rs[0]) + 1e-8f);
    __syncthreads();
    float vn = v * inv;
    unsigned short hi = f2bf(vn);
    float lo = vn - bf2f(hi);
    Zc[(size_t)i * 512 + c] = (short)hi;
    Zc[(size_t)i * 512 + 256 + c] = (short)f2bf(lo);
}

// ---------------------------------------------------------------- top-k (k=16): 1 wave/row, ILP tree + reverse index scan
__global__ __launch_bounds__(256) void topk_kernel(const float* __restrict__ S,
                                                   float* __restrict__ hv,
                                                   int* __restrict__ eidx) {
    int lane = threadIdx.x & 63;
    int row = blockIdx.x * 4 + (threadIdx.x >> 6);
    const float4* srow = (const float4*)(S + (size_t)row * NN);
    float v[48];
#pragma unroll
    for (int c = 0; c < 12; c++) {
        float4 q = srow[c * 64 + lane];
        v[c * 4 + 0] = q.x; v[c * 4 + 1] = q.y; v[c * 4 + 2] = q.z; v[c * 4 + 3] = q.w;
    }
    const float NEG = -3.4e38f;
    for (int t = 0; t < TK; t++) {
        float m0[24];
#pragma unroll
        for (int i = 0; i < 24; i++) m0[i] = fmaxf(v[i], v[i + 24]);
#pragma unroll
        for (int i = 0; i < 12; i++) m0[i] = fmaxf(m0[i], m0[i + 12]);
#pragma unroll
        for (int i = 0; i < 6; i++) m0[i] = fmaxf(m0[i], m0[i + 6]);
        float m = fmaxf(fmaxf(fmaxf(m0[0], m0[1]), fmaxf(m0[2], m0[3])), fmaxf(m0[4], m0[5]));
#pragma unroll
        for (int s = 1; s < 64; s <<= 1) m = fmaxf(m, __shfl_xor(m, s));
        int cand = 0x7FFFFFFF;
#pragma unroll
        for (int i = 47; i >= 0; i--) {
            int col = (i >> 2) * 256 + lane * 4 + (i & 3);
            cand = (v[i] == m) ? col : cand;
        }
#pragma unroll
        for (int s = 1; s < 64; s <<= 1) cand = min(cand, __shfl_xor(cand, s));
        if (lane == 0) {
            float sg = 1.f / (1.f + expf(-m));
            hv[row * TK + t] = (sg > 0.5f) ? sg : 0.f;
            eidx[row * TK + t] = cand;
        }
        int owner = (cand >> 2) & 63;
        int li = ((cand >> 8) << 2) | (cand & 3);
        if (lane == owner) {
#pragma unroll
            for (int i = 0; i < 48; i++)
                if (i == li) v[i] = NEG;
        }
    }
}

// ---------------------------------------------------------------- edge stats (+msum zero)
__global__ void edge_stats(const float* __restrict__ hv, float* __restrict__ De,
                           float* __restrict__ ew, float* __restrict__ msum) {
    int e = blockIdx.x * 256 + threadIdx.x;
    if (e == 0) *msum = 0.f;
    if (e >= NN) return;
    float s = 0.f;
#pragma unroll
    for (int j = 0; j < TK; j++) s += hv[e * TK + j];
    De[e] = s + 1e-8f;
    ew[e] = s * (1.f / TK);
}

__global__ void scatter_deg(const int* __restrict__ eidx, const float* __restrict__ hv,
                            const float* __restrict__ ew, float* __restrict__ Dv,
                            float* __restrict__ Dv2, int* __restrict__ row_cnt) {
    int t = blockIdx.x * 256 + threadIdx.x;
    if (t >= NN * TK) return;
    int e = t >> 4;
    int v = eidx[t];
    float w = hv[t];
    atomicAdd(&Dv[v], w * ew[e]);
    atomicAdd(&Dv2[v], w);
    atomicAdd(&row_cnt[v], 1);
}

__global__ void deg_fin(const float* __restrict__ Dv, float* __restrict__ Dv2,
                        float* __restrict__ dvis) {
    int v = blockIdx.x * 256 + threadIdx.x;
    if (v >= NN) return;
    dvis[v] = 1.f / sqrtf(Dv[v] + 1e-8f);
    Dv2[v] += 1e-8f;
}

// ---------------------------------------------------------------- CSR build
__global__ void scan_kernel(const int* __restrict__ cnt, int* __restrict__ start) {
    __shared__ int part[256];
    int t = threadIdx.x;
    const int chunk = NN / 256;
    int s = 0;
    for (int i = t * chunk; i < (t + 1) * chunk; i++) s += cnt[i];
    part[t] = s;
    __syncthreads();
    if (t == 0) {
        int a = 0;
        for (int i = 0; i < 256; i++) { int v = part[i]; part[i] = a; a += v; }
    }
    __syncthreads();
    int a = part[t];
    for (int i = t * chunk; i < (t + 1) * chunk; i++) { start[i] = a; a += cnt[i]; }
    if (t == 255) start[NN] = a;
}

__global__ void fill_csr(const int* __restrict__ eidx, const float* __restrict__ hv,
                         const int* __restrict__ start, int* __restrict__ fillc,
                         int* __restrict__ csr_e, float* __restrict__ csr_w) {
    int t = blockIdx.x * 256 + threadIdx.x;
    if (t >= NN * TK) return;
    int e = t >> 4;
    int v = eidx[t];
    int pos = atomicAdd(&fillc[v], 1);
    int pp = start[v] + pos;
    csr_e[pp] = e;
    csr_w[pp] = hv[t];
}

// ---------------------------------------------------------------- sparse H ops
// fp32 in, fp32 out
__global__ void edge_gather4(const int* __restrict__ eidx, const float* __restrict__ hv,
                             const float* __restrict__ De, const float* __restrict__ dvis,
                             const float* __restrict__ X, float* __restrict__ T,
                             int F4, int epb, int use_dvis) {
    int slot = threadIdx.x / F4;
    if (slot >= epb) return;
    int f = threadIdx.x - slot * F4;
    int e = blockIdx.x * epb + slot;
    const int* ei = eidx + e * TK;
    const float* hw = hv + e * TK;
    float ax = 0.f, ay = 0.f, az = 0.f, aw = 0.f;
#pragma unroll
    for (int j = 0; j < TK; j++) {
        int v = ei[j];
        float w = hw[j];
        if (use_dvis) w *= dvis[v];
        const float4 x = *(const float4*)(X + ((size_t)v * F4 + f) * 4);
        ax = fmaf(w, x.x, ax); ay = fmaf(w, x.y, ay);
        az = fmaf(w, x.z, az); aw = fmaf(w, x.w, aw);
    }
    float inv = 1.f / De[e];
    *(float4*)(T + ((size_t)e * F4 + f) * 4) = make_float4(ax * inv, ay * inv, az * inv, aw * inv);
}

// split-bf16 in, fp32 out
__global__ void edge_gather4b(const int* __restrict__ eidx, const float* __restrict__ hv,
                              const float* __restrict__ De, const float* __restrict__ dvis,
                              const short* __restrict__ Xc, float* __restrict__ T,
                              int F4, int epb, int use_dvis) {
    int slot = threadIdx.x / F4;
    if (slot >= epb) return;
    int f = threadIdx.x - slot * F4;
    int e = blockIdx.x * epb + slot;
    int F = F4 * 4;
    const int* ei = eidx + e * TK;
    const float* hw = hv + e * TK;
    float ax = 0.f, ay = 0.f, az = 0.f, aw = 0.f;
#pragma unroll
    for (int j = 0; j < TK; j++) {
        int v = ei[j];
        float w = hw[j];
        if (use_dvis) w *= dvis[v];
        const short4 hh = *(const short4*)(Xc + (size_t)v * 2 * F + f * 4);
        const short4 ll = *(const short4*)(Xc + (size_t)v * 2 * F + F + f * 4);
        ax = fmaf(w, bf2f((unsigned short)hh.x) + bf2f((unsigned short)ll.x), ax);
        ay = fmaf(w, bf2f((unsigned short)hh.y) + bf2f((unsigned short)ll.y), ay);
        az = fmaf(w, bf2f((unsigned short)hh.z) + bf2f((unsigned short)ll.z), az);
        aw = fmaf(w, bf2f((unsigned short)hh.w) + bf2f((unsigned short)ll.w), aw);
    }
    float inv = 1.f / De[e];
    *(float4*)(T + ((size_t)e * F4 + f) * 4) = make_float4(ax * inv, ay * inv, az * inv, aw * inv);
}

// fp32 in, fp32 out (yspec)
__global__ void row_gather4(const int* __restrict__ start, const int* __restrict__ csr_e,
                            const float* __restrict__ csr_w, const float* __restrict__ dvis,
                            const float* __restrict__ T, const float* __restrict__ Badd,
                            float alpha, float beta, float* __restrict__ Y,
                            int F4, int epb, int use_dvis) {
    int slot = threadIdx.x / F4;
    if (slot >= epb) return;
    int f = threadIdx.x - slot * F4;
    int v = blockIdx.x * epb + slot;
    int s0 = start[v], s1 = start[v + 1];
    float ax = 0.f, ay = 0.f, az = 0.f, aw = 0.f;
    for (int p = s0; p < s1; p++) {
        float w = csr_w[p];
        const float4 x = *(const float4*)(T + ((size_t)csr_e[p] * F4 + f) * 4);
        ax = fmaf(w, x.x, ax); ay = fmaf(w, x.y, ay);
        az = fmaf(w, x.z, az); aw = fmaf(w, x.w, aw);
    }
    float sc = alpha * (use_dvis ? dvis[v] : 1.f);
    float4 o = make_float4(ax * sc, ay * sc, az * sc, aw * sc);
    if (Badd) {
        const float4 b = *(const float4*)(Badd + ((size_t)v * F4 + f) * 4);
        o.x += beta * b.x; o.y += beta * b.y; o.z += beta * b.z; o.w += beta * b.w;
    }
    *(float4*)(Y + ((size_t)v * F4 + f) * 4) = o;
}

// fp32 in, split-bf16 out (T1c/T2c)
__global__ void row_gather4s(const int* __restrict__ start, const int* __restrict__ csr_e,
                             const float* __restrict__ csr_w, const float* __restrict__ dvis,
                             const float* __restrict__ T, const float* __restrict__ Badd,
                             float alpha, float beta, short* __restrict__ Yc,
                             int F4, int epb, int use_dvis) {
    int slot = threadIdx.x / F4;
    if (slot >= epb) return;
    int f = threadIdx.x - slot * F4;
    int v = blockIdx.x * epb + slot;
    int F = F4 * 4;
    int s0 = start[v], s1 = start[v + 1];
    float ax = 0.f, ay = 0.f, az = 0.f, aw = 0.f;
    for (int p = s0; p < s1; p++) {
        float w = csr_w[p];
        const float4 x = *(const float4*)(T + ((size_t)csr_e[p] * F4 + f) * 4);
        ax = fmaf(w, x.x, ax); ay = fmaf(w, x.y, ay);
        az = fmaf(w, x.z, az); aw = fmaf(w, x.w, aw);
    }
    float sc = alpha * (use_dvis ? dvis[v] : 1.f);
    float4 o = make_float4(ax * sc, ay * sc, az * sc, aw * sc);
    if (Badd) {
        const float4 b = *(const float4*)(Badd + ((size_t)v * F4 + f) * 4);
        o.x += beta * b.x; o.y += beta * b.y; o.z += beta * b.z; o.w += beta * b.w;
    }
    unsigned short h0 = f2bf(o.x), h1 = f2bf(o.y), h2 = f2bf(o.z), h3 = f2bf(o.w);
    *(short4*)(Yc + (size_t)v * 2 * F + f * 4) =
        make_short4((short)h0, (short)h1, (short)h2, (short)h3);
    *(short4*)(Yc + (size_t)v * 2 * F + F + f * 4) =
        make_short4((short)f2bf(o.x - bf2f(h0)), (short)f2bf(o.y - bf2f(h1)),
                    (short)f2bf(o.z - bf2f(h2)), (short)f2bf(o.w - bf2f(h3)));
}

// ---------------------------------------------------------------- reductions
__global__ void mse_reduce4(const float* __restrict__ a, const float* __restrict__ b,
                            float* __restrict__ sum) {
    __shared__ float rs[256];
    float s = 0.f;
    const int n4 = NN * FEAT / 4;
    for (int i = blockIdx.x * 256 + threadIdx.x; i < n4; i += gridDim.x * 256) {
        const float4 x = *(const float4*)(a + (size_t)i * 4);
        const float4 y = *(const float4*)(b + (size_t)i * 4);
        float dx = x.x - y.x, dy = x.y - y.y, dz = x.z - y.z, dw = x.w - y.w;
        s += dx * dx + dy * dy + dz * dz + dw * dw;
    }
    rs[threadIdx.x] = s;
    __syncthreads();
    for (int st = 128; st > 0; st >>= 1) {
        if (threadIdx.x < st) rs[threadIdx.x] += rs[threadIdx.x + st];
        __syncthreads();
    }
    if (threadIdx.x == 0) atomicAdd(sum, rs[0]);
}

__global__ void spectral_cols(const float* __restrict__ r, const float* __restrict__ y,
                              const float* __restrict__ Dv2, float* __restrict__ numb,
                              float* __restrict__ denb) {
    int c = blockIdx.x;
    __shared__ float rn[256], rd[256];
    float sn = 0.f, sd = 0.f;
    for (int i = threadIdx.x; i < NN; i += 256) {
        float rv = r[(size_t)i * 64 + c];
        float d2 = Dv2[i];
        float lcx = d2 * rv - y[(size_t)i * 64 + c];
        sn += rv * lcx;
        sd += d2 * rv * rv;
    }
    rn[threadIdx.x] = sn; rd[threadIdx.x] = sd;
    __syncthreads();
    for (int st = 128; st > 0; st >>= 1) {
        if (threadIdx.x < st) { rn[threadIdx.x] += rn[threadIdx.x + st]; rd[threadIdx.x] += rd[threadIdx.x + st]; }
        __syncthreads();
    }
    if (threadIdx.x == 0) { numb[c] = rn[0]; denb[c] = rd[0] + 1e-8f; }
}

__global__ void finals_kernel(const float* __restrict__ msum, const float* __restrict__ numb,
                              const float* __restrict__ denb, float* __restrict__ out) {
    if (threadIdx.x == 0 && blockIdx.x == 0) {
        float s = 0.f;
        for (int c = 0; c < 64; c++) s += numb[c] / denb[c];
        out[NN + 1] = s * (1.f / 64.f);
        out[NN] = msum[0] * (1.f / ((float)NN * FEAT));
    }
}

// ================================================================ launch
extern "C" void kernel_launch(void* const* d_in, const int* in_sizes, int n_in,
                              void* d_out, int out_size, void* d_ws, size_t ws_size,
                              hipStream_t stream) {
    const float* images = (const float*)d_in[0];
    const float* text   = (const float*)d_in[1];
    const float* signal = (const float*)d_in[2];
    const float* iw1 = (const float*)d_in[3];  const float* ib1 = (const float*)d_in[4];
    const float* iw2 = (const float*)d_in[5];  const float* ib2 = (const float*)d_in[6];
    const float* ig  = (const float*)d_in[7];  const float* ibeta = (const float*)d_in[8];
    const float* tw1 = (const float*)d_in[9];  const float* tb1 = (const float*)d_in[10];
    const float* tw2 = (const float*)d_in[11]; const float* tb2 = (const float*)d_in[12];
    const float* tg  = (const float*)d_in[13]; const float* tbeta = (const float*)d_in[14];
    const float* sw1 = (const float*)d_in[15]; const float* sb1 = (const float*)d_in[16];
    const float* sw2 = (const float*)d_in[17]; const float* sb2 = (const float*)d_in[18];
    const float* sg  = (const float*)d_in[19]; const float* sbeta = (const float*)d_in[20];
    const float* gw  = (const float*)d_in[21]; const float* gb = (const float*)d_in[22];
    const float* c1w = (const float*)d_in[23]; const float* c1b = (const float*)d_in[24];
    const float* c2w = (const float*)d_in[25]; const float* c2b = (const float*)d_in[26];
    const float* rw1 = (const float*)d_in[27]; const float* rb1 = (const float*)d_in[28];
    const float* rw2 = (const float*)d_in[29]; const float* rb2 = (const float*)d_in[30];
    const float* aw1 = (const float*)d_in[31]; const float* ab1 = (const float*)d_in[32];
    const float* aw2 = (const float*)d_in[33]; const float* ab2 = (const float*)d_in[34];
    const float* dw1 = (const float*)d_in[35]; const float* db1 = (const float*)d_in[36];
    const float* dw2 = (const float*)d_in[37]; const float* db2 = (const float*)d_in[38];
    float* out = (float*)d_out;

    float* wsf = (float*)d_ws;
    size_t off = 0;
    auto AF = [&](size_t n) { float* q = wsf + off; off += n; return q; };
    float* feats  = AF((size_t)NN * FEAT);
    float* simbuf = AF((size_t)NN * NN);
    float* p      = AF((size_t)NN * 192);
    float* h      = AF((size_t)NN * HIDD);
    float* z      = AF((size_t)NN * HIDD);
    float* x1     = AF((size_t)NN * HIDD);
    float* x2     = AF((size_t)NN * 128);
    float* r      = AF((size_t)NN * 64);
    float* hv     = AF((size_t)NN * TK);
    float* ew     = AF(NN);
    float* De     = AF(NN);
    float* Dv     = AF(NN);
    float* Dv2    = AF(NN);
    float* dvis   = AF(NN);
    float* csr_w  = AF((size_t)NN * TK);
    float* numb   = AF(64);
    float* denb   = AF(64);
    float* msum   = AF(1);
    float* csum   = AF(FEAT);
    float* csum2  = AF(FEAT);
    float* bsc    = AF(FEAT);
    float* bsh    = AF(FEAT);
    short* x1c    = (short*)AF((size_t)NN * 256);        // [NN][512] shorts
    short* wcbuf  = (short*)AF(1392640);                 // 2,785,280 shorts of weight splits
    int* eidx     = (int*)(wsf + off); off += (size_t)NN * TK;
    int* csr_e    = (int*)(wsf + off); off += (size_t)NN * TK;
    int* row_cnt  = (int*)(wsf + off); off += NN;
    int* row_fill = (int*)(wsf + off); off += NN;
    int* row_start= (int*)(wsf + off); off += NN + 1;

    short* Zc = (short*)z;

    // weight split sub-buffers
    short* wp = wcbuf;
    auto AW = [&](size_t n) { short* q = wp; wp += n; return q; };
    short* iw1c = AW((size_t)256 * 384);
    short* tw1c = AW((size_t)256 * 1536);
    short* sw1c = AW((size_t)256 * 512);
    short* iw2c = AW((size_t)256 * 512);
    short* tw2c = AW((size_t)256 * 512);
    short* sw2c = AW((size_t)256 * 512);
    short* gwc  = AW((size_t)256 * 1536);
    short* c1wc0 = AW((size_t)256 * 1536);
    short* c1wc1 = AW((size_t)256 * 1536);
    short* c1wc2 = AW((size_t)256 * 1536);
    short* c2wc0 = AW((size_t)128 * 512);
    short* c2wc1 = AW((size_t)128 * 512);
    short* c2wc2 = AW((size_t)128 * 512);

    // pre-sim simbuf layout (shorts)
    short* sb = (short*)simbuf;
    short* pc  = sb;
    short* tc  = pc + (size_t)NN * 384;
    short* scb = tc + (size_t)NN * 1536;
    short* hc0 = scb + (size_t)NN * 512;
    short* hc1 = hc0 + (size_t)NN * 512;
    short* hc2 = hc1 + (size_t)NN * 512;
    short* featsc_pre = hc2 + (size_t)NN * 512;
    float* gpart = simbuf;   // gw partials (4 x NN*256 f32) over pc/tc/sc (dead then)

    // post-topk slabs
    const size_t slab = (size_t)NN * FEAT;
    short* T1c = (short*)simbuf;                 // [NN][1536] (or [NN][512] at cheb2)
    short* T2c = (short*)(simbuf + slab);
    float* et  = simbuf + 2 * slab;
    short* featsc2 = (short*)(simbuf + 3 * slab);
    float* part12 = simbuf + 2 * slab;           // cheb1 partials (3 x NN*256)
    float* part22 = simbuf + 3 * slab;           // cheb2 partials (3 x NN*128)
    float* recon = simbuf;                       // slab0, post-cheb
    float* hpart = simbuf + slab;                // head partials
    float* et3 = simbuf + 2 * slab;              // spectral gather
    float* yspec = x2;

    dim3 blk(256);
    auto gemmF = [&](const float* A, const float* B, const float* bias, float* C,
                     int M, int Nc, int K, int lda, int ldb, int ldc,
                     float alpha, int act, int acc, int KS, float* part) {
        int nk = K / 32;
        int ks = KS < nk ? KS : nk; if (ks < 1) ks = 1;
        int kc = ((nk + ks - 1) / ks) * 32;
        int ksp = (K + kc - 1) / kc;
        gemm_mf<<<dim3(Nc / 64, M / 128, ksp), blk, 0, stream>>>(
            A, B, bias, C, part, M, Nc, K, lda, ldb, ldc, kc, alpha, act, acc);
        if (ksp > 1)
            gemm_epi<<<((size_t)M * Nc + 255) / 256, blk, 0, stream>>>(
                part, bias, C, nullptr, M, Nc, ldc, 0, ksp, alpha, act, acc);
    };
    auto gemmSm = [&](const float* A, const float* B, const float* bias, float* C,
                      int M, int Nc, int K, int lda, int ldb, int ldc,
                      float alpha, int act, int acc, int KS, float* part) {
        int nk = K / 32;
        int ks = KS < nk ? KS : nk; if (ks < 1) ks = 1;
        int kc = ((nk + ks - 1) / ks) * 32;
        int ksp = (K + kc - 1) / kc;
        gemm2<<<dim3((Nc + 63) / 64, M / 64, ksp), blk, 0, stream>>>(A, B, part, M, Nc, K, lda, ldb, kc);
        gemm_epi<<<((size_t)M * Nc + 255) / 256, blk, 0, stream>>>(
            part, bias, C, nullptr, M, Nc, ldc, 0, ksp, alpha, act, acc);
    };
    auto eg4 = [&](const float* X, float* T, int F, int use_dvis) {
        int F4 = F / 4, epb = 256 / F4 < 1 ? 1 : 256 / F4;
        edge_gather4<<<NN / epb, dim3(F4 * epb), 0, stream>>>(eidx, hv, De, dvis, X, T, F4, epb, use_dvis);
    };
    auto eg4b = [&](const short* Xc, float* T, int F, int use_dvis) {
        int F4 = F / 4, epb = 256 / F4 < 1 ? 1 : 256 / F4;
        edge_gather4b<<<NN / epb, dim3(F4 * epb), 0, stream>>>(eidx, hv, De, dvis, Xc, T, F4, epb, use_dvis);
    };
    auto rg4 = [&](const float* T, const float* Badd, float alpha, float beta, float* Y,
                   int F, int use_dvis) {
        int F4 = F / 4, epb = 256 / F4 < 1 ? 1 : 256 / F4;
        row_gather4<<<NN / epb, dim3(F4 * epb), 0, stream>>>(row_start, csr_e, csr_w, dvis, T, Badd,
                                                             alpha, beta, Y, F4, epb, use_dvis);
    };
    auto rg4s = [&](const float* T, const float* Badd, float alpha, float beta, short* Yc,
                    int F, int use_dvis) {
        int F4 = F / 4, epb = 256 / F4 < 1 ? 1 : 256 / F4;
        row_gather4s<<<NN / epb, dim3(F4 * epb), 0, stream>>>(row_start, csr_e, csr_w, dvis, T, Badd,
                                                              alpha, beta, Yc, F4, epb, use_dvis);
    };

    const float E1 = 0.60653065971f;  // exp(-0.5)
    const float E2 = 0.36787944117f;  // exp(-1.0)

    // ---- pool + all conversions ----
    pool_kernel<<<(NN * 192 + 255) / 256, blk, 0, stream>>>(images, p);
    {
        WJobs wj{};
        wj.j[0] = {iw1, iw1c, 192, 256};
        wj.j[1] = {tw1, tw1c, 768, 256};
        wj.j[2] = {sw1, sw1c, 256, 256};
        wj.j[3] = {iw2, iw2c, 256, 256};
        wj.j[4] = {tw2, tw2c, 256, 256};
        wj.j[5] = {sw2, sw2c, 256, 256};
        wj.j[6] = {gw,  gwc,  768, 256};
        wj.j[7] = {c1w, c1wc0, 768, 256};
        wj.j[8] = {c1w + (size_t)FEAT * HIDD, c1wc1, 768, 256};
        wj.j[9] = {c1w + (size_t)2 * FEAT * HIDD, c1wc2, 768, 256};
        wj.j[10] = {c2w, c2wc0, 256, 128};
        wj.j[11] = {c2w + (size_t)HIDD * 128, c2wc1, 256, 128};
        wj.j[12] = {c2w + (size_t)2 * HIDD * 128, c2wc2, 256, 128};
        wsplitT<<<dim3(24, 8, 13), blk, 0, stream>>>(wj);
    }
    split_rows<<<(NN * 48 + 255) / 256, blk, 0, stream>>>(p, pc, 192, NN * 48);
    split_rows<<<(NN * 192 + 255) / 256, blk, 0, stream>>>(text, tc, 768, NN * 192);
    split_rows<<<(NN * 64 + 255) / 256, blk, 0, stream>>>(signal, scb, 256, NN * 64);
    hipMemsetAsync(csum, 0, 2 * FEAT * sizeof(float), stream);

    // ---- MLP layer 1 (fused, split-bf16 out) ----
    {
        BT bt{};
        bt.A[0] = pc;   bt.A[1] = tc;   bt.A[2] = scb;
        bt.Bw[0] = iw1c; bt.Bw[1] = tw1c; bt.Bw[2] = sw1c;
        bt.bias[0] = ib1; bt.bias[1] = tb1; bt.bias[2] = sb1;
        bt.Cc[0] = hc0; bt.Cc[1] = hc1; bt.Cc[2] = hc2;
        bt.Ka[0] = 384; bt.Ka[1] = 1536; bt.Ka[2] = 512;
        bt.ccW = 256;
        gemm_bt<<<dim3(4, 24, 3), blk, 0, stream>>>(bt, nullptr, NN, 256, 1, 1, 0);
    }
    // ---- MLP layer 2 (fused, fp32 into feats columns) ----
    {
        BT bt{};
        bt.A[0] = hc0;  bt.A[1] = hc1;  bt.A[2] = hc2;
        bt.Bw[0] = iw2c; bt.Bw[1] = tw2c; bt.Bw[2] = sw2c;
        bt.bias[0] = ib2; bt.bias[1] = tb2; bt.bias[2] = sb2;
        bt.Cf[0] = feats; bt.Cf[1] = feats + 256; bt.Cf[2] = feats + 512;
        bt.Ka[0] = bt.Ka[1] = bt.Ka[2] = 512;
        bt.ldc = FEAT;
        gemm_bt<<<dim3(4, 24, 3), blk, 0, stream>>>(bt, nullptr, NN, 256, 0, 1, 0);
    }
    bn_stats<<<NN / 16, blk, 0, stream>>>(feats, csum, csum2);
    bn_fin<<<3, blk, 0, stream>>>(csum, csum2, ig, tg, sg, ibeta, tbeta, sbeta, bsc, bsh);
    bn_norm<<<1024, blk, 0, stream>>>(feats, bsc, bsh, featsc_pre);

    // ---- hyperedge generator ----
    {
        BT bt{};
        bt.A[0] = featsc_pre; bt.Bw[0] = gwc;
        bt.Ka[0] = 1536; bt.scale[0] = 1.f;
        gemm_bt<<<dim3(4, 24, 4), blk, 0, stream>>>(bt, gpart, NN, 256, 0, 4, 384);
        gemm_epi<<<((size_t)NN * 256 + 255) / 256, blk, 0, stream>>>(
            gpart, gb, z, nullptr, NN, 256, 256, 0, 4, 1.f, 2, 0);
    }
    rownorm_kernel<<<NN, blk, 0, stream>>>(z, Zc);
    sim_mfma<<<dim3(NN / 128, NN / 128), blk, 0, stream>>>(Zc, simbuf);
    topk_kernel<<<NN / 4, blk, 0, stream>>>(simbuf, hv, eidx);

    // ---- degrees + CSR ----
    hipMemsetAsync(Dv, 0, 2 * NN * sizeof(float), stream);
    hipMemsetAsync(row_cnt, 0, 2 * NN * sizeof(int), stream);
    edge_stats<<<NN / 256, blk, 0, stream>>>(hv, De, ew, msum);
    scatter_deg<<<NN * TK / 256, blk, 0, stream>>>(eidx, hv, ew, Dv, Dv2, row_cnt);
    deg_fin<<<NN / 256, blk, 0, stream>>>(Dv, Dv2, dvis);
    scan_kernel<<<1, blk, 0, stream>>>(row_cnt, row_start);
    fill_csr<<<NN * TK / 256, blk, 0, stream>>>(eidx, hv, row_start, row_fill, csr_e, csr_w);

    // ---- cheb conv 1 (F=768 -> 256) ----
    eg4(feats, et, FEAT, 1);
    rg4s(et, nullptr, -1.f, 0.f, T1c, FEAT, 1);
    eg4b(T1c, et, FEAT, 1);
    rg4s(et, feats, -2.f, -1.f, T2c, FEAT, 1);
    split_rows<<<(NN * 192 + 255) / 256, blk, 0, stream>>>(feats, featsc2, 768, NN * 192);
    {
        BT bt{};
        bt.A[0] = featsc2; bt.A[1] = T1c; bt.A[2] = T2c;
        bt.Bw[0] = c1wc0;  bt.Bw[1] = c1wc1; bt.Bw[2] = c1wc2;
        bt.Ka[0] = bt.Ka[1] = bt.Ka[2] = 1536;
        bt.scale[0] = 1.f; bt.scale[1] = E1; bt.scale[2] = E2;
        gemm_bt<<<dim3(4, 24, 3), blk, 0, stream>>>(bt, part12, NN, 256, 0, 1, 0);
        gemm_epi<<<((size_t)NN * 256 + 255) / 256, blk, 0, stream>>>(
            part12, c1b, x1, x1c, NN, 256, 256, 256, 3, 1.f, 1, 0);
    }

    // ---- cheb conv 2 (F=256 -> 128) ----
    eg4(x1, et, HIDD, 1);
    rg4s(et, nullptr, -1.f, 0.f, T1c, HIDD, 1);
    eg4b(T1c, et, HIDD, 1);
    rg4s(et, x1, -2.f, -1.f, T2c, HIDD, 1);
    {
        BT bt{};
        bt.A[0] = x1c; bt.A[1] = T1c; bt.A[2] = T2c;
        bt.Bw[0] = c2wc0; bt.Bw[1] = c2wc1; bt.Bw[2] = c2wc2;
        bt.Ka[0] = bt.Ka[1] = bt.Ka[2] = 512;
        bt.scale[0] = 1.f; bt.scale[1] = E1; bt.scale[2] = E2;
        gemm_bt<<<dim3(2, 24, 3), blk, 0, stream>>>(bt, part22, NN, 128, 0, 1, 0);
        gemm_epi<<<((size_t)NN * 128 + 255) / 256, blk, 0, stream>>>(
            part22, c2b, x2, nullptr, NN, 128, 128, 0, 3, 1.f, 1, 0);
    }

    // ---- heads ----
    gemmF(x2, rw1, rb1, h, NN, 64, 128, 128, 64, 64, 1.f, 1, 0, 2, hpart);
    gemmF(h,  rw2, rb2, r, NN, 64, 64, 64, 64, 64, 1.f, 0, 0, 2, hpart);
    gemmSm(r,  aw1, ab1, h, NN, 32, 64, 64, 32, 32, 1.f, 1, 0, 2, hpart);
    gemmSm(h,  aw2, ab2, out, NN, 1, 32, 32, 1, 1, 1.f, 3, 0, 1, hpart);
    gemmF(r,  dw1, db1, h, NN, HIDD, 64, 64, HIDD, HIDD, 1.f, 1, 0, 2, hpart);
    gemmF(h,  dw2, db2, recon, NN, FEAT, HIDD, HIDD, FEAT, FEAT, 1.f, 0, 0, 1, nullptr);
    mse_reduce4<<<512, blk, 0, stream>>>(recon, feats, msum);

    // ---- spectral cut ----
    eg4(r, et3, 64, 0);
    rg4(et3, nullptr, 1.f, 0.f, yspec, 64, 0);
    spectral_cols<<<64, blk, 0, stream>>>(r, yspec, Dv2, numb, denb);
    finals_kernel<<<1, 64, 0, stream>>>(msum, numb, denb, out);
}

// Round 9
// 510.809 us; speedup vs baseline: 1.6872x; 1.0619x over previous
//
#include <hip/hip_runtime.h>
#include <cmath>

#define NN   3072
#define HIDD 256
#define TK   16
#define FEAT 768   // 3*HID

typedef __attribute__((ext_vector_type(8))) short bf16x8;
typedef __attribute__((ext_vector_type(4))) float f32x4;

__device__ inline unsigned short f2bf(float x) {
    unsigned u = __float_as_uint(x);
    unsigned r = (u + 0x7FFFu + ((u >> 16) & 1u)) >> 16;   // RNE
    return (unsigned short)r;
}
__device__ inline float bf2f(unsigned short h) {
    return __uint_as_float(((unsigned)h) << 16);
}

// ---------------------------------------------------------------- pool
__global__ void pool_kernel(const float* __restrict__ img, float* __restrict__ p) {
    int idx = blockIdx.x * 256 + threadIdx.x;
    if (idx >= NN * 192) return;
    int b = idx / 192, rem = idx % 192;
    int c = rem >> 6, oy = (rem >> 3) & 7, ox = rem & 7;
    const float* base = img + (((size_t)b * 3 + c) * 32 + oy * 4) * 32 + ox * 4;
    float s = 0.f;
#pragma unroll
    for (int iy = 0; iy < 4; iy++)
#pragma unroll
        for (int ix = 0; ix < 4; ix++) s += base[iy * 32 + ix];
    p[idx] = s * 0.0625f;
}

// ---------------------------------------------------------------- split fp32 rows -> [hi | lo] bf16 (k-contiguous)
__global__ void split_rows(const float* __restrict__ X, short* __restrict__ Xc,
                           int K, int total4) {
    int i = blockIdx.x * 256 + threadIdx.x;
    if (i >= total4) return;
    int K4 = K >> 2;
    int m = i / K4, f = i - m * K4;
    float4 v = *(const float4*)(X + (size_t)m * K + f * 4);
    unsigned short h0 = f2bf(v.x), h1 = f2bf(v.y), h2 = f2bf(v.z), h3 = f2bf(v.w);
    short4 hi = make_short4((short)h0, (short)h1, (short)h2, (short)h3);
    short4 lo = make_short4((short)f2bf(v.x - bf2f(h0)), (short)f2bf(v.y - bf2f(h1)),
                            (short)f2bf(v.z - bf2f(h2)), (short)f2bf(v.w - bf2f(h3)));
    *(short4*)(Xc + (size_t)m * 2 * K + f * 4) = hi;
    *(short4*)(Xc + (size_t)m * 2 * K + K + f * 4) = lo;
}

// ---------------------------------------------------------------- batched weight transpose+split: W[KxN] -> Wc[N][2K]
struct WJ { const float* W; short* Wc; int K; int N; };
struct WJobs { WJ j[13]; };

__global__ void wsplitT(WJobs js) {
    WJ jb = js.j[blockIdx.z];
    int tk = blockIdx.x * 32, tn = blockIdx.y * 32;
    if (tk >= jb.K || tn >= jb.N) return;
    __shared__ float t[32][33];
    int kk = threadIdx.x >> 3, nn = (threadIdx.x & 7) * 4;
    float4 v = *(const float4*)(jb.W + (size_t)(tk + kk) * jb.N + tn + nn);
    t[kk][nn + 0] = v.x; t[kk][nn + 1] = v.y; t[kk][nn + 2] = v.z; t[kk][nn + 3] = v.w;
    __syncthreads();
    int n2 = threadIdx.x >> 3, k2 = (threadIdx.x & 7) * 4;
    float a = t[k2 + 0][n2], b = t[k2 + 1][n2], c = t[k2 + 2][n2], d = t[k2 + 3][n2];
    unsigned short h0 = f2bf(a), h1 = f2bf(b), h2 = f2bf(c), h3 = f2bf(d);
    short4 hi = make_short4((short)h0, (short)h1, (short)h2, (short)h3);
    short4 lo = make_short4((short)f2bf(a - bf2f(h0)), (short)f2bf(b - bf2f(h1)),
                            (short)f2bf(c - bf2f(h2)), (short)f2bf(d - bf2f(h3)));
    size_t rowb = (size_t)(tn + n2) * 2 * jb.K;
    *(short4*)(jb.Wc + rowb + tk + k2) = hi;
    *(short4*)(jb.Wc + rowb + jb.K + tk + k2) = lo;
}

// ---------------------------------------------------------------- pure bf16 NT GEMM (z-batched + split-K)
struct BT {
    const short* A[3];
    const short* Bw[3];
    const float* bias[3];
    float* Cf[3];
    short* Cc[3];
    int Ka[3];
    float scale[3];
    int ldc;
    int ccW;
};

__global__ __launch_bounds__(256) void gemm_bt(BT bt, float* __restrict__ P,
        int M, int Nc, int act, int KS, int Kc) {
    __shared__ short As[128 * 64];
    __shared__ short Bs[64 * 64];
    int zz = blockIdx.z, s = 0;
    if (KS > 1) { zz = blockIdx.z / KS; s = blockIdx.z % KS; }
    const short* A = bt.A[zz];
    const short* B = bt.Bw[zz];
    int Ka = bt.Ka[zz];
    int kbeg = s * Kc;
    int kend = (KS > 1) ? min(Ka, kbeg + Kc) : Ka;
    int tid = threadIdx.x, wave = tid >> 6, lane = tid & 63;
    int wm = (wave >> 1) * 64, wn = (wave & 1) * 32;
    int lrow = lane & 15, lk = lane >> 4;
    int m0 = blockIdx.y * 128, n0 = blockIdx.x * 64;
    f32x4 acc[4][2] = {};

    for (int k0 = kbeg; k0 < kend; k0 += 64) {
#pragma unroll
        for (int i = 0; i < 4; i++) {
            int q = tid + i * 256;
            int row = q >> 3, c = q & 7;
            int dst = row * 128 + ((c ^ (row & 7)) << 4);
            *(float4*)((char*)As + dst) =
                *(const float4*)((const char*)A + (((size_t)(m0 + row) * Ka + k0) << 1) + (c << 4));
        }
#pragma unroll
        for (int i = 0; i < 2; i++) {
            int q = tid + i * 256;
            int row = q >> 3, c = q & 7;
            int dst = row * 128 + ((c ^ (row & 7)) << 4);
            *(float4*)((char*)Bs + dst) =
                *(const float4*)((const char*)B + (((size_t)(n0 + row) * Ka + k0) << 1) + (c << 4));
        }
        __syncthreads();
#pragma unroll
        for (int kk = 0; kk < 2; kk++) {
            int ck = kk * 4 + lk;
            bf16x8 af[4], bg[2];
#pragma unroll
            for (int t = 0; t < 4; t++) {
                int ra = wm + t * 16 + lrow;
                af[t] = *(const bf16x8*)((const char*)As + ra * 128 + ((ck ^ (ra & 7)) << 4));
            }
#pragma unroll
            for (int u = 0; u < 2; u++) {
                int rb = wn + u * 16 + lrow;
                bg[u] = *(const bf16x8*)((const char*)Bs + rb * 128 + ((ck ^ (rb & 7)) << 4));
            }
#pragma unroll
            for (int i2 = 0; i2 < 4; i2++)
#pragma unroll
                for (int j2 = 0; j2 < 2; j2++)
                    acc[i2][j2] = __builtin_amdgcn_mfma_f32_16x16x32_bf16(af[i2], bg[j2], acc[i2][j2], 0, 0, 0);
        }
        __syncthreads();
    }

    if (P) {
        float sc = bt.scale[zz];
        float* Pp = P + (size_t)(zz * KS + s) * M * Nc;
#pragma unroll
        for (int i2 = 0; i2 < 4; i2++) {
            int gmb = m0 + wm + i2 * 16 + lk * 4;
#pragma unroll
            for (int j2 = 0; j2 < 2; j2++) {
                int gn = n0 + wn + j2 * 16 + lrow;
#pragma unroll
                for (int rg = 0; rg < 4; rg++)
                    Pp[(size_t)(gmb + rg) * Nc + gn] = sc * acc[i2][j2][rg];
            }
        }
    } else {
        const float* bias = bt.bias[zz];
        float* Cf = bt.Cf[zz];
        short* Cc = bt.Cc[zz];
#pragma unroll
        for (int i2 = 0; i2 < 4; i2++) {
            int gmb = m0 + wm + i2 * 16 + lk * 4;
#pragma unroll
            for (int j2 = 0; j2 < 2; j2++) {
                int gn = n0 + wn + j2 * 16 + lrow;
#pragma unroll
                for (int rg = 0; rg < 4; rg++) {
                    int gm = gmb + rg;
                    float x = acc[i2][j2][rg];
                    if (bias) x += bias[gn];
                    if (act == 1) x = fmaxf(x, 0.f);
                    else if (act == 2) x = tanhf(x);
                    if (Cf) Cf[(size_t)gm * bt.ldc + gn] = x;
                    if (Cc) {
                        unsigned short hi2 = f2bf(x);
                        Cc[(size_t)gm * 2 * bt.ccW + gn] = (short)hi2;
                        Cc[(size_t)gm * 2 * bt.ccW + bt.ccW + gn] = (short)f2bf(x - bf2f(hi2));
                    }
                }
            }
        }
    }
}

// ---------------------------------------------------------------- MFMA split-bf16 GEMM (fp32 in, heads only)
__global__ __launch_bounds__(256) void gemm_mf(
        const float* __restrict__ A, const float* __restrict__ B,
        const float* __restrict__ bias, float* __restrict__ C, float* __restrict__ P,
        int M, int Nc, int K, int lda, int ldb, int ldc, int Kc,
        float alpha, int act, int accf) {
    __shared__ short Ah[128 * 40];
    __shared__ short Al[128 * 40];
    __shared__ short Bh[64 * 40];
    __shared__ short Bl[64 * 40];
    int tid = threadIdx.x, wave = tid >> 6, lane = tid & 63;
    int wm = (wave >> 1) * 64, wn = (wave & 1) * 32;
    int lrow = lane & 15, lk = lane >> 4;
    int m0 = blockIdx.y * 128, n0 = blockIdx.x * 64;
    int kbeg = blockIdx.z * Kc, kend = min(K, kbeg + Kc);
    f32x4 acc[4][2] = {};

    for (int k0 = kbeg; k0 < kend; k0 += 32) {
#pragma unroll
        for (int i = 0; i < 4; i++) {
            int q = tid + i * 256;
            int rowm = q >> 3, kq = q & 7;
            float4 vv = *(const float4*)(A + (size_t)(m0 + rowm) * lda + k0 + kq * 4);
            unsigned short h0 = f2bf(vv.x), h1 = f2bf(vv.y), h2 = f2bf(vv.z), h3 = f2bf(vv.w);
            unsigned short l0 = f2bf(vv.x - bf2f(h0)), l1 = f2bf(vv.y - bf2f(h1));
            unsigned short l2 = f2bf(vv.z - bf2f(h2)), l3 = f2bf(vv.w - bf2f(h3));
            *(short4*)&Ah[rowm * 40 + kq * 4] = make_short4((short)h0, (short)h1, (short)h2, (short)h3);
            *(short4*)&Al[rowm * 40 + kq * 4] = make_short4((short)l0, (short)l1, (short)l2, (short)l3);
        }
#pragma unroll
        for (int i = 0; i < 2; i++) {
            int q = tid + i * 256;
            int kk2 = q >> 4, nq = q & 15;
            float4 vv = *(const float4*)(B + (size_t)(k0 + kk2) * ldb + n0 + nq * 4);
            unsigned short h0 = f2bf(vv.x), h1 = f2bf(vv.y), h2 = f2bf(vv.z), h3 = f2bf(vv.w);
            unsigned short l0 = f2bf(vv.x - bf2f(h0)), l1 = f2bf(vv.y - bf2f(h1));
            unsigned short l2 = f2bf(vv.z - bf2f(h2)), l3 = f2bf(vv.w - bf2f(h3));
            Bh[(nq * 4 + 0) * 40 + kk2] = (short)h0;  Bl[(nq * 4 + 0) * 40 + kk2] = (short)l0;
            Bh[(nq * 4 + 1) * 40 + kk2] = (short)h1;  Bl[(nq * 4 + 1) * 40 + kk2] = (short)l1;
            Bh[(nq * 4 + 2) * 40 + kk2] = (short)h2;  Bl[(nq * 4 + 2) * 40 + kk2] = (short)l2;
            Bh[(nq * 4 + 3) * 40 + kk2] = (short)h3;  Bl[(nq * 4 + 3) * 40 + kk2] = (short)l3;
        }
        __syncthreads();
        bf16x8 ah[4], al[4], bh[2], bl[2];
#pragma unroll
        for (int t2 = 0; t2 < 4; t2++) {
            int ra = wm + t2 * 16 + lrow;
            ah[t2] = *(const bf16x8*)&Ah[ra * 40 + lk * 8];
            al[t2] = *(const bf16x8*)&Al[ra * 40 + lk * 8];
        }
#pragma unroll
        for (int u = 0; u < 2; u++) {
            int rb = wn + u * 16 + lrow;
            bh[u] = *(const bf16x8*)&Bh[rb * 40 + lk * 8];
            bl[u] = *(const bf16x8*)&Bl[rb * 40 + lk * 8];
        }
#pragma unroll
        for (int i2 = 0; i2 < 4; i2++)
#pragma unroll
            for (int j2 = 0; j2 < 2; j2++) {
                acc[i2][j2] = __builtin_amdgcn_mfma_f32_16x16x32_bf16(ah[i2], bh[j2], acc[i2][j2], 0, 0, 0);
                acc[i2][j2] = __builtin_amdgcn_mfma_f32_16x16x32_bf16(ah[i2], bl[j2], acc[i2][j2], 0, 0, 0);
                acc[i2][j2] = __builtin_amdgcn_mfma_f32_16x16x32_bf16(al[i2], bh[j2], acc[i2][j2], 0, 0, 0);
            }
        __syncthreads();
    }

    if (gridDim.z == 1) {
#pragma unroll
        for (int i2 = 0; i2 < 4; i2++) {
            int gmb = m0 + wm + i2 * 16 + lk * 4;
#pragma unroll
            for (int j2 = 0; j2 < 2; j2++) {
                int gn = n0 + wn + j2 * 16 + lrow;
#pragma unroll
                for (int rg = 0; rg < 4; rg++) {
                    int gm = gmb + rg;
                    float x = alpha * acc[i2][j2][rg];
                    if (bias) x += bias[gn];
                    if (accf) x += C[(size_t)gm * ldc + gn];
                    if (act == 1) x = fmaxf(x, 0.f);
                    else if (act == 2) x = tanhf(x);
                    else if (act == 3) x = 1.f / (1.f + expf(-x));
                    C[(size_t)gm * ldc + gn] = x;
                }
            }
        }
    } else {
        float* Pp = P + (size_t)blockIdx.z * M * Nc;
#pragma unroll
        for (int i2 = 0; i2 < 4; i2++) {
            int gmb = m0 + wm + i2 * 16 + lk * 4;
#pragma unroll
            for (int j2 = 0; j2 < 2; j2++) {
                int gn = n0 + wn + j2 * 16 + lrow;
#pragma unroll
                for (int rg = 0; rg < 4; rg++)
                    Pp[(size_t)(gmb + rg) * Nc + gn] = acc[i2][j2][rg];
            }
        }
    }
}

// ---------------------------------------------------------------- fp32 GEMM (tiny heads only)
__global__ void gemm2(const float* __restrict__ A, const float* __restrict__ B,
                      float* __restrict__ P, int M, int Nc, int K,
                      int lda, int ldb, int Kc) {
    __shared__ float As[32][68];
    __shared__ float Bs[32][68];
    int tid = threadIdx.x;
    int tm = tid >> 4, tn = tid & 15;
    int m0 = blockIdx.y * 64, n0 = blockIdx.x * 64;
    int kbeg = blockIdx.z * Kc;
    int kend = min(K, kbeg + Kc);
    float acc[4][4] = {};
    for (int k0 = kbeg; k0 < kend; k0 += 32) {
#pragma unroll
        for (int i = 0; i < 2; i++) {
            int q = tid + i * 256;
            int m = q >> 3, kq = q & 7;
            float4 v = *(const float4*)(A + (size_t)(m0 + m) * lda + k0 + kq * 4);
            int col = m ^ (kq << 2);
            As[kq * 4 + 0][col] = v.x;
            As[kq * 4 + 1][col] = v.y;
            As[kq * 4 + 2][col] = v.z;
            As[kq * 4 + 3][col] = v.w;
        }
#pragma unroll
        for (int i = 0; i < 2; i++) {
            int q = tid + i * 256;
            int k = q >> 4, nq = q & 15;
            int gn = n0 + nq * 4;
            float4 v;
            const float* src = B + (size_t)(k0 + k) * ldb + gn;
            if (gn + 3 < Nc) {
                v = *(const float4*)src;
            } else {
                v.x = (gn + 0 < Nc) ? src[0] : 0.f;
                v.y = (gn + 1 < Nc) ? src[1] : 0.f;
                v.z = (gn + 2 < Nc) ? src[2] : 0.f;
                v.w = (gn + 3 < Nc) ? src[3] : 0.f;
            }
            *(float4*)&Bs[k][nq * 4] = v;
        }
        __syncthreads();
#pragma unroll
        for (int kk = 0; kk < 32; kk++) {
            int swz = kk & 28;
            float a[4], b[4];
            *(float4*)a = *(const float4*)&As[kk][(tm * 4) ^ swz];
            *(float4*)b = *(const float4*)&Bs[kk][tn * 4];
#pragma unroll
            for (int i = 0; i < 4; i++)
#pragma unroll
                for (int j = 0; j < 4; j++) acc[i][j] += a[i] * b[j];
        }
        __syncthreads();
    }
    float* Pp = P + (size_t)blockIdx.z * M * Nc;
    int gn = n0 + tn * 4;
#pragma unroll
    for (int i = 0; i < 4; i++) {
        int gm = m0 + tm * 4 + i;
        if (gn + 3 < Nc) {
            *(float4*)&Pp[(size_t)gm * Nc + gn] = *(float4*)&acc[i][0];
        } else {
#pragma unroll
            for (int j = 0; j < 4; j++)
                if (gn + j < Nc) Pp[(size_t)gm * Nc + gn + j] = acc[i][j];
        }
    }
}

// epilogue
__global__ void gemm_epi(const float* __restrict__ P, const float* __restrict__ bias,
                         float* __restrict__ C, short* __restrict__ Cc,
                         int M, int Nc, int ldc, int ccW, int KS,
                         float alpha, int act, int acc) {
    int idx = blockIdx.x * 256 + threadIdx.x;
    if (idx >= M * Nc) return;
    int m = idx / Nc, n = idx - m * Nc;
    float v = 0.f;
    for (int s = 0; s < KS; s++) v += P[(size_t)s * M * Nc + idx];
    v *= alpha;
    if (bias) v += bias[n];
    if (acc) v += C[(size_t)m * ldc + n];
    if (act == 1) v = fmaxf(v, 0.f);
    else if (act == 2) v = tanhf(v);
    else if (act == 3) v = 1.f / (1.f + expf(-v));
    if (C) C[(size_t)m * ldc + n] = v;
    if (Cc) {
        unsigned short hi = f2bf(v);
        Cc[(size_t)m * 2 * ccW + n] = (short)hi;
        Cc[(size_t)m * 2 * ccW + ccW + n] = (short)f2bf(v - bf2f(hi));
    }
}

// ---------------------------------------------------------------- sim = Zc @ Zc^T
__global__ __launch_bounds__(256) void sim_mfma(const short* __restrict__ Zc,
                                                float* __restrict__ S) {
    __shared__ short As[128 * 64];
    __shared__ short Bs[128 * 64];
    int tid = threadIdx.x;
    int wave = tid >> 6, lane = tid & 63;
    int wm = (wave >> 1) * 64, wn = (wave & 1) * 64;
    int m0 = blockIdx.y * 128, n0 = blockIdx.x * 128;
    int lrow = lane & 15, lk = lane >> 4;
    f32x4 acc[4][4] = {};

    for (int k0 = 0; k0 < 512; k0 += 64) {
#pragma unroll
        for (int i = 0; i < 4; i++) {
            int q = tid + i * 256;
            int row = q >> 3, c = q & 7;
            int dstoff = row * 128 + ((c ^ (row & 7)) << 4);
            const char* pa = (const char*)Zc + (((size_t)(m0 + row) * 512 + k0) << 1) + (c << 4);
            *(float4*)((char*)As + dstoff) = *(const float4*)pa;
            const char* pb = (const char*)Zc + (((size_t)(n0 + row) * 512 + k0) << 1) + (c << 4);
            *(float4*)((char*)Bs + dstoff) = *(const float4*)pb;
        }
        __syncthreads();
#pragma unroll
        for (int kk = 0; kk < 2; kk++) {
            int ck = kk * 4 + lk;
            bf16x8 af[4], bg[4];
#pragma unroll
            for (int t = 0; t < 4; t++) {
                int ra = wm + t * 16 + lrow;
                af[t] = *(const bf16x8*)((const char*)As + ra * 128 + ((ck ^ (ra & 7)) << 4));
                int rb = wn + t * 16 + lrow;
                bg[t] = *(const bf16x8*)((const char*)Bs + rb * 128 + ((ck ^ (rb & 7)) << 4));
            }
#pragma unroll
            for (int i2 = 0; i2 < 4; i2++)
#pragma unroll
                for (int j2 = 0; j2 < 4; j2++)
                    acc[i2][j2] = __builtin_amdgcn_mfma_f32_16x16x32_bf16(
                        af[i2], bg[j2], acc[i2][j2], 0, 0, 0);
        }
        __syncthreads();
    }
#pragma unroll
    for (int i2 = 0; i2 < 4; i2++) {
#pragma unroll
        for (int j2 = 0; j2 < 4; j2++) {
            int col = n0 + wn + j2 * 16 + lrow;
            int rowb = m0 + wm + i2 * 16 + lk * 4;
#pragma unroll
            for (int rg = 0; rg < 4; rg++)
                S[(size_t)(rowb + rg) * NN + col] = acc[i2][j2][rg];
        }
    }
}

// ---------------------------------------------------------------- BatchNorm, row-major 3-phase
__global__ void bn_stats(const float* __restrict__ Y, float* __restrict__ csum,
                         float* __restrict__ csum2) {
    int t = threadIdx.x;
    float s0 = 0.f, s1 = 0.f, s2v = 0.f;
    float q0 = 0.f, q1 = 0.f, q2 = 0.f;
    int r0 = blockIdx.x * 16;
    for (int i = r0; i < r0 + 16; i++) {
        const float* row = Y + (size_t)i * FEAT;
        float a = row[t], b = row[t + 256], c = row[t + 512];
        s0 += a; q0 += a * a;
        s1 += b; q1 += b * b;
        s2v += c; q2 += c * c;
    }
    atomicAdd(&csum[t], s0);        atomicAdd(&csum2[t], q0);
    atomicAdd(&csum[t + 256], s1);  atomicAdd(&csum2[t + 256], q1);
    atomicAdd(&csum[t + 512], s2v); atomicAdd(&csum2[t + 512], q2);
}

__global__ void bn_fin(const float* __restrict__ csum, const float* __restrict__ csum2,
                       const float* __restrict__ g0, const float* __restrict__ g1,
                       const float* __restrict__ g2, const float* __restrict__ b0,
                       const float* __restrict__ b1, const float* __restrict__ b2,
                       float* __restrict__ scale, float* __restrict__ shift) {
    int j = blockIdx.x * 256 + threadIdx.x;
    if (j >= FEAT) return;
    float mean = csum[j] * (1.f / NN);
    float var = fmaxf(csum2[j] * (1.f / NN) - mean * mean, 0.f);
    int m = j >> 8, jj = j & 255;
    const float* g = (m == 0) ? g0 : (m == 1) ? g1 : g2;
    const float* bt = (m == 0) ? b0 : (m == 1) ? b1 : b2;
    float sc = g[jj] / sqrtf(var + 1e-5f);
    scale[j] = sc;
    shift[j] = bt[jj] - mean * sc;
}

__global__ void bn_norm(float* __restrict__ Y, const float* __restrict__ scale,
                        const float* __restrict__ shift, short* __restrict__ Yc) {
    __shared__ float sc[FEAT], sh[FEAT];
    for (int j = threadIdx.x; j < FEAT; j += 256) { sc[j] = scale[j]; sh[j] = shift[j]; }
    __syncthreads();
    const int n4 = NN * FEAT / 4;
    for (int i = blockIdx.x * 256 + threadIdx.x; i < n4; i += gridDim.x * 256) {
        float4 v = *(const float4*)(Y + (size_t)i * 4);
        int m = i / 192;
        int c = (i - m * 192) * 4;
        v.x = v.x * sc[c + 0] + sh[c + 0];
        v.y = v.y * sc[c + 1] + sh[c + 1];
        v.z = v.z * sc[c + 2] + sh[c + 2];
        v.w = v.w * sc[c + 3] + sh[c + 3];
        *(float4*)(Y + (size_t)i * 4) = v;
        if (Yc) {
            unsigned short h0 = f2bf(v.x), h1 = f2bf(v.y), h2 = f2bf(v.z), h3 = f2bf(v.w);
            *(short4*)(Yc + (size_t)m * 1536 + c) =
                make_short4((short)h0, (short)h1, (short)h2, (short)h3);
            *(short4*)(Yc + (size_t)m * 1536 + 768 + c) =
                make_short4((short)f2bf(v.x - bf2f(h0)), (short)f2bf(v.y - bf2f(h1)),
                            (short)f2bf(v.z - bf2f(h2)), (short)f2bf(v.w - bf2f(h3)));
        }
    }
}

// ---------------------------------------------------------------- row normalize z -> split-bf16 Zc (in place)
__global__ void rownorm_kernel(const float* __restrict__ Zin, short* __restrict__ Zc) {
    int i = blockIdx.x;
    int c = threadIdx.x;
    __shared__ float rs[256];
    __shared__ float inv;
    float v = Zin[(size_t)i * HIDD + c];
    rs[c] = v * v;
    __syncthreads();
    for (int st = 128; st > 0; st >>= 1) {
        if (c < st) rs[c] += rs[c + st];
        __syncthreads();
    }
    if (c == 0) inv = 1.f / (sqrtf(rs[0]) + 1e-8f);
    __syncthreads();
    float vn = v * inv;
    unsigned short hi = f2bf(vn);
    float lo = vn - bf2f(hi);
    Zc[(size_t)i * 512 + c] = (short)hi;
    Zc[(size_t)i * 512 + 256 + c] = (short)f2bf(lo);
}

// ---------------------------------------------------------------- top-k stage 1: 4 waves/row, each = exact top-16 of 768-chunk
__global__ __launch_bounds__(256) void topk_s1(const float* __restrict__ S,
                                               float* __restrict__ cval,
                                               int* __restrict__ ccol) {
    int lane = threadIdx.x & 63;
    int w = threadIdx.x >> 6;
    int row = blockIdx.x;
    const float4* base = (const float4*)(S + (size_t)row * NN + w * 768);
    float v[12];
#pragma unroll
    for (int c = 0; c < 3; c++) {
        float4 q = base[c * 64 + lane];
        v[c * 4 + 0] = q.x; v[c * 4 + 1] = q.y; v[c * 4 + 2] = q.z; v[c * 4 + 3] = q.w;
    }
    const float NEG = -3.4e38f;
    float* ov = cval + ((size_t)row * 4 + w) * 16;
    int* oc = ccol + ((size_t)row * 4 + w) * 16;
    for (int t = 0; t < TK; t++) {
        float m0[6];
#pragma unroll
        for (int i = 0; i < 6; i++) m0[i] = fmaxf(v[i], v[i + 6]);
        float m = fmaxf(fmaxf(fmaxf(m0[0], m0[1]), fmaxf(m0[2], m0[3])), fmaxf(m0[4], m0[5]));
#pragma unroll
        for (int s = 1; s < 64; s <<= 1) m = fmaxf(m, __shfl_xor(m, s));
        int cand = 0x7FFFFFFF;
#pragma unroll
        for (int i = 11; i >= 0; i--) {
            int col = w * 768 + (i >> 2) * 256 + lane * 4 + (i & 3);
            cand = (v[i] == m) ? col : cand;
        }
#pragma unroll
        for (int s = 1; s < 64; s <<= 1) cand = min(cand, __shfl_xor(cand, s));
        if (lane == 0) { ov[t] = m; oc[t] = cand; }
        int lcol = cand - w * 768;
        int owner = (lcol >> 2) & 63;
        if (lane == owner) {
            int li = ((lcol >> 8) << 2) | (lcol & 3);
#pragma unroll
            for (int i = 0; i < 12; i++)
                if (i == li) v[i] = NEG;
        }
    }
}

// stage 2: 1 wave/row merges 64 candidates (one per lane)
__global__ __launch_bounds__(256) void topk_s2(const float* __restrict__ cval,
                                               const int* __restrict__ ccol,
                                               float* __restrict__ hv,
                                               int* __restrict__ eidx) {
    int lane = threadIdx.x & 63;
    int row = blockIdx.x * 4 + (threadIdx.x >> 6);
    float v = cval[(size_t)row * 64 + lane];
    int c = ccol[(size_t)row * 64 + lane];
    for (int t = 0; t < TK; t++) {
        float bv = v; int bc = c;
#pragma unroll
        for (int s = 1; s < 64; s <<= 1) {
            float ov = __shfl_xor(bv, s);
            int oc = __shfl_xor(bc, s);
            bool b = (ov > bv) || (ov == bv && oc < bc);
            bv = b ? ov : bv;
            bc = b ? oc : bc;
        }
        if (lane == 0) {
            float sg = 1.f / (1.f + expf(-bv));
            hv[row * TK + t] = (sg > 0.5f) ? sg : 0.f;
            eidx[row * TK + t] = bc;
        }
        if (v == bv && c == bc) v = -3.4e38f;
    }
}

// ---------------------------------------------------------------- edge stats (+ zero degree arrays & msum)
__global__ void edge_stats(const float* __restrict__ hv, float* __restrict__ De,
                           float* __restrict__ ew, float* __restrict__ msum,
                           float* __restrict__ Dv, float* __restrict__ Dv2,
                           int* __restrict__ row_cnt, int* __restrict__ row_fill) {
    int e = blockIdx.x * 256 + threadIdx.x;
    if (e == 0) *msum = 0.f;
    if (e >= NN) return;
    Dv[e] = 0.f; Dv2[e] = 0.f; row_cnt[e] = 0; row_fill[e] = 0;
    float s = 0.f;
#pragma unroll
    for (int j = 0; j < TK; j++) s += hv[e * TK + j];
    De[e] = s + 1e-8f;
    ew[e] = s * (1.f / TK);
}

__global__ void scatter_deg(const int* __restrict__ eidx, const float* __restrict__ hv,
                            const float* __restrict__ ew, float* __restrict__ Dv,
                            float* __restrict__ Dv2, int* __restrict__ row_cnt) {
    int t = blockIdx.x * 256 + threadIdx.x;
    if (t >= NN * TK) return;
    int e = t >> 4;
    int v = eidx[t];
    float w = hv[t];
    atomicAdd(&Dv[v], w * ew[e]);
    atomicAdd(&Dv2[v], w);
    atomicAdd(&row_cnt[v], 1);
}

// ---------------------------------------------------------------- CSR scan + degree finalize (single block)
__global__ void scan_deg(const int* __restrict__ cnt, int* __restrict__ start,
                         const float* __restrict__ Dv, float* __restrict__ Dv2,
                         float* __restrict__ dvis) {
    __shared__ int part[256];
    int t = threadIdx.x;
    const int chunk = NN / 256;
    int s = 0;
    for (int i = t * chunk; i < (t + 1) * chunk; i++) {
        s += cnt[i];
        dvis[i] = 1.f / sqrtf(Dv[i] + 1e-8f);
        Dv2[i] += 1e-8f;
    }
    part[t] = s;
    __syncthreads();
    if (t == 0) {
        int a = 0;
        for (int i = 0; i < 256; i++) { int v = part[i]; part[i] = a; a += v; }
    }
    __syncthreads();
    int a = part[t];
    for (int i = t * chunk; i < (t + 1) * chunk; i++) { start[i] = a; a += cnt[i]; }
    if (t == 255) start[NN] = a;
}

__global__ void fill_csr(const int* __restrict__ eidx, const float* __restrict__ hv,
                         const int* __restrict__ start, int* __restrict__ fillc,
                         int* __restrict__ csr_e, float* __restrict__ csr_w) {
    int t = blockIdx.x * 256 + threadIdx.x;
    if (t >= NN * TK) return;
    int e = t >> 4;
    int v = eidx[t];
    int pos = atomicAdd(&fillc[v], 1);
    int pp = start[v] + pos;
    csr_e[pp] = e;
    csr_w[pp] = hv[t];
}

// ---------------------------------------------------------------- sparse H ops (fp32)
__global__ void edge_gather4(const int* __restrict__ eidx, const float* __restrict__ hv,
                             const float* __restrict__ De, const float* __restrict__ dvis,
                             const float* __restrict__ X, float* __restrict__ T,
                             int F4, int epb, int use_dvis) {
    int slot = threadIdx.x / F4;
    if (slot >= epb) return;
    int f = threadIdx.x - slot * F4;
    int e = blockIdx.x * epb + slot;
    const int* ei = eidx + e * TK;
    const float* hw = hv + e * TK;
    float ax = 0.f, ay = 0.f, az = 0.f, aw = 0.f;
#pragma unroll
    for (int j = 0; j < TK; j++) {
        int v = ei[j];
        float w = hw[j];
        if (use_dvis) w *= dvis[v];
        const float4 x = *(const float4*)(X + ((size_t)v * F4 + f) * 4);
        ax = fmaf(w, x.x, ax); ay = fmaf(w, x.y, ay);
        az = fmaf(w, x.z, az); aw = fmaf(w, x.w, aw);
    }
    float inv = 1.f / De[e];
    *(float4*)(T + ((size_t)e * F4 + f) * 4) = make_float4(ax * inv, ay * inv, az * inv, aw * inv);
}

__global__ void row_gather4(const int* __restrict__ start, const int* __restrict__ csr_e,
                            const float* __restrict__ csr_w, const float* __restrict__ dvis,
                            const float* __restrict__ T, const float* __restrict__ Badd,
                            float alpha, float beta, float* __restrict__ Y,
                            int F4, int epb, int use_dvis) {
    int slot = threadIdx.x / F4;
    if (slot >= epb) return;
    int f = threadIdx.x - slot * F4;
    int v = blockIdx.x * epb + slot;
    int s0 = start[v], s1 = start[v + 1];
    float ax = 0.f, ay = 0.f, az = 0.f, aw = 0.f;
    for (int p = s0; p < s1; p++) {
        float w = csr_w[p];
        const float4 x = *(const float4*)(T + ((size_t)csr_e[p] * F4 + f) * 4);
        ax = fmaf(w, x.x, ax); ay = fmaf(w, x.y, ay);
        az = fmaf(w, x.z, az); aw = fmaf(w, x.w, aw);
    }
    float sc = alpha * (use_dvis ? dvis[v] : 1.f);
    float4 o = make_float4(ax * sc, ay * sc, az * sc, aw * sc);
    if (Badd) {
        const float4 b = *(const float4*)(Badd + ((size_t)v * F4 + f) * 4);
        o.x += beta * b.x; o.y += beta * b.y; o.z += beta * b.z; o.w += beta * b.w;
    }
    *(float4*)(Y + ((size_t)v * F4 + f) * 4) = o;
}

// ---------------------------------------------------------------- cheb combine: X = relu(G0 - e1*MG1 - e2*G2 + 2*e2*MMG2 + b)
__global__ void cheb_combine(const float* __restrict__ G0, const float* __restrict__ MG1,
                             const float* __restrict__ G2, const float* __restrict__ MMG2,
                             const float* __restrict__ bias, float e1, float e2,
                             float* __restrict__ Xf, short* __restrict__ Xc,
                             int Fw, int total4) {
    int i = blockIdx.x * 256 + threadIdx.x;
    if (i >= total4) return;
    int F4 = Fw >> 2;
    int m = i / F4, n4 = i - m * F4;
    float4 g0 = *(const float4*)(G0 + (size_t)i * 4);
    float4 g1 = *(const float4*)(MG1 + (size_t)i * 4);
    float4 g2 = *(const float4*)(G2 + (size_t)i * 4);
    float4 g3 = *(const float4*)(MMG2 + (size_t)i * 4);
    float4 b = *(const float4*)(bias + n4 * 4);
    float4 x;
    x.x = fmaxf(g0.x - e1 * g1.x - e2 * g2.x + 2.f * e2 * g3.x + b.x, 0.f);
    x.y = fmaxf(g0.y - e1 * g1.y - e2 * g2.y + 2.f * e2 * g3.y + b.y, 0.f);
    x.z = fmaxf(g0.z - e1 * g1.z - e2 * g2.z + 2.f * e2 * g3.z + b.z, 0.f);
    x.w = fmaxf(g0.w - e1 * g1.w - e2 * g2.w + 2.f * e2 * g3.w + b.w, 0.f);
    if (Xf) *(float4*)(Xf + (size_t)i * 4) = x;
    if (Xc) {
        unsigned short h0 = f2bf(x.x), h1 = f2bf(x.y), h2 = f2bf(x.z), h3 = f2bf(x.w);
        *(short4*)(Xc + (size_t)m * 2 * Fw + n4 * 4) =
            make_short4((short)h0, (short)h1, (short)h2, (short)h3);
        *(short4*)(Xc + (size_t)m * 2 * Fw + Fw + n4 * 4) =
            make_short4((short)f2bf(x.x - bf2f(h0)), (short)f2bf(x.y - bf2f(h1)),
                        (short)f2bf(x.z - bf2f(h2)), (short)f2bf(x.w - bf2f(h3)));
    }
}

// ---------------------------------------------------------------- reductions
__global__ void mse_reduce4(const float* __restrict__ a, const float* __restrict__ b,
                            float* __restrict__ sum) {
    __shared__ float rs[256];
    float s = 0.f;
    const int n4 = NN * FEAT / 4;
    for (int i = blockIdx.x * 256 + threadIdx.x; i < n4; i += gridDim.x * 256) {
        const float4 x = *(const float4*)(a + (size_t)i * 4);
        const float4 y = *(const float4*)(b + (size_t)i * 4);
        float dx = x.x - y.x, dy = x.y - y.y, dz = x.z - y.z, dw = x.w - y.w;
        s += dx * dx + dy * dy + dz * dz + dw * dw;
    }
    rs[threadIdx.x] = s;
    __syncthreads();
    for (int st = 128; st > 0; st >>= 1) {
        if (threadIdx.x < st) rs[threadIdx.x] += rs[threadIdx.x + st];
        __syncthreads();
    }
    if (threadIdx.x == 0) atomicAdd(sum, rs[0]);
}

__global__ void spectral_cols(const float* __restrict__ r, const float* __restrict__ y,
                              const float* __restrict__ Dv2, float* __restrict__ numb,
                              float* __restrict__ denb) {
    int c = blockIdx.x;
    __shared__ float rn[256], rd[256];
    float sn = 0.f, sd = 0.f;
    for (int i = threadIdx.x; i < NN; i += 256) {
        float rv = r[(size_t)i * 64 + c];
        float d2 = Dv2[i];
        float lcx = d2 * rv - y[(size_t)i * 64 + c];
        sn += rv * lcx;
        sd += d2 * rv * rv;
    }
    rn[threadIdx.x] = sn; rd[threadIdx.x] = sd;
    __syncthreads();
    for (int st = 128; st > 0; st >>= 1) {
        if (threadIdx.x < st) { rn[threadIdx.x] += rn[threadIdx.x + st]; rd[threadIdx.x] += rd[threadIdx.x + st]; }
        __syncthreads();
    }
    if (threadIdx.x == 0) { numb[c] = rn[0]; denb[c] = rd[0] + 1e-8f; }
}

__global__ void finals_kernel(const float* __restrict__ msum, const float* __restrict__ numb,
                              const float* __restrict__ denb, float* __restrict__ out) {
    if (threadIdx.x == 0 && blockIdx.x == 0) {
        float s = 0.f;
        for (int c = 0; c < 64; c++) s += numb[c] / denb[c];
        out[NN + 1] = s * (1.f / 64.f);
        out[NN] = msum[0] * (1.f / ((float)NN * FEAT));
    }
}

// ================================================================ launch
extern "C" void kernel_launch(void* const* d_in, const int* in_sizes, int n_in,
                              void* d_out, int out_size, void* d_ws, size_t ws_size,
                              hipStream_t stream) {
    const float* images = (const float*)d_in[0];
    const float* text   = (const float*)d_in[1];
    const float* signal = (const float*)d_in[2];
    const float* iw1 = (const float*)d_in[3];  const float* ib1 = (const float*)d_in[4];
    const float* iw2 = (const float*)d_in[5];  const float* ib2 = (const float*)d_in[6];
    const float* ig  = (const float*)d_in[7];  const float* ibeta = (const float*)d_in[8];
    const float* tw1 = (const float*)d_in[9];  const float* tb1 = (const float*)d_in[10];
    const float* tw2 = (const float*)d_in[11]; const float* tb2 = (const float*)d_in[12];
    const float* tg  = (const float*)d_in[13]; const float* tbeta = (const float*)d_in[14];
    const float* sw1 = (const float*)d_in[15]; const float* sb1 = (const float*)d_in[16];
    const float* sw2 = (const float*)d_in[17]; const float* sb2 = (const float*)d_in[18];
    const float* sg  = (const float*)d_in[19]; const float* sbeta = (const float*)d_in[20];
    const float* gw  = (const float*)d_in[21]; const float* gb = (const float*)d_in[22];
    const float* c1w = (const float*)d_in[23]; const float* c1b = (const float*)d_in[24];
    const float* c2w = (const float*)d_in[25]; const float* c2b = (const float*)d_in[26];
    const float* rw1 = (const float*)d_in[27]; const float* rb1 = (const float*)d_in[28];
    const float* rw2 = (const float*)d_in[29]; const float* rb2 = (const float*)d_in[30];
    const float* aw1 = (const float*)d_in[31]; const float* ab1 = (const float*)d_in[32];
    const float* aw2 = (const float*)d_in[33]; const float* ab2 = (const float*)d_in[34];
    const float* dw1 = (const float*)d_in[35]; const float* db1 = (const float*)d_in[36];
    const float* dw2 = (const float*)d_in[37]; const float* db2 = (const float*)d_in[38];
    float* out = (float*)d_out;

    float* wsf = (float*)d_ws;
    size_t off = 0;
    auto AF = [&](size_t n) { float* q = wsf + off; off += n; return q; };
    float* feats  = AF((size_t)NN * FEAT);
    float* simbuf = AF((size_t)NN * NN);
    float* p      = AF((size_t)NN * 192);
    float* h      = AF((size_t)NN * HIDD);
    float* z      = AF((size_t)NN * HIDD);
    float* x2     = AF((size_t)NN * 128);
    float* r      = AF((size_t)NN * 64);
    float* hv     = AF((size_t)NN * TK);
    float* ew     = AF(NN);
    float* De     = AF(NN);
    float* Dv     = AF(NN);
    float* Dv2    = AF(NN);
    float* dvis   = AF(NN);
    float* csr_w  = AF((size_t)NN * TK);
    float* numb   = AF(64);
    float* denb   = AF(64);
    float* msum   = AF(1);
    float* csum   = AF(FEAT);
    float* csum2  = AF(FEAT);
    float* bsc    = AF(FEAT);
    float* bsh    = AF(FEAT);
    short* x1c    = (short*)AF((size_t)NN * 256);     // [NN][512] shorts
    short* wcbuf  = (short*)AF(1392640);
    float* Gbuf   = AF((size_t)NN * FEAT);            // G0..G2 persist across sim
    float* cvalb  = AF((size_t)NN * 64);
    int* ccolb    = (int*)(wsf + off); off += (size_t)NN * 64;
    int* eidx     = (int*)(wsf + off); off += (size_t)NN * TK;
    int* csr_e    = (int*)(wsf + off); off += (size_t)NN * TK;
    int* row_cnt  = (int*)(wsf + off); off += NN;
    int* row_fill = (int*)(wsf + off); off += NN;
    int* row_start= (int*)(wsf + off); off += NN + 1;

    short* Zc = (short*)z;

    // weight split sub-buffers
    short* wp = wcbuf;
    auto AW = [&](size_t n) { short* q = wp; wp += n; return q; };
    short* iw1c = AW((size_t)256 * 384);
    short* tw1c = AW((size_t)256 * 1536);
    short* sw1c = AW((size_t)256 * 512);
    short* iw2c = AW((size_t)256 * 512);
    short* tw2c = AW((size_t)256 * 512);
    short* sw2c = AW((size_t)256 * 512);
    short* gwc  = AW((size_t)256 * 1536);
    short* c1wc0 = AW((size_t)256 * 1536);
    short* c1wc1 = AW((size_t)256 * 1536);
    short* c1wc2 = AW((size_t)256 * 1536);
    short* c2wc0 = AW((size_t)128 * 512);
    short* c2wc1 = AW((size_t)128 * 512);
    short* c2wc2 = AW((size_t)128 * 512);

    // pre-sim simbuf layout (shorts)
    short* sb = (short*)simbuf;
    short* pc  = sb;
    short* tc  = pc + (size_t)NN * 384;
    short* scb = tc + (size_t)NN * 1536;
    short* hc0 = scb + (size_t)NN * 512;
    short* hc1 = hc0 + (size_t)NN * 512;
    short* hc2 = hc1 + (size_t)NN * 512;
    short* featsc_pre = hc2 + (size_t)NN * 512;
    float* gpart = simbuf;   // gw split-K partials (over pc/tc/scb, dead by then)

    // G buffers (persist through sim)
    float* G0 = Gbuf;
    float* G1 = Gbuf + (size_t)NN * 256;
    float* G2 = Gbuf + (size_t)2 * NN * 256;

    // post-topk slabs in simbuf
    const size_t slab = (size_t)NN * FEAT;
    float* MG1  = simbuf + slab;
    float* MG2  = simbuf + slab + (size_t)NN * 256;
    float* MMG2 = simbuf + slab + (size_t)2 * NN * 256;
    float* et   = simbuf + 2 * slab;
    float* recon = simbuf;                      // slab0 (dead H region) post-cheb
    float* H0 = simbuf;                         // cheb2 GEMM outputs (NN*128 each)
    float* H1 = simbuf + (size_t)NN * 128;
    float* H2 = simbuf + (size_t)2 * NN * 128;
    float* hpart = simbuf + slab;               // head split-K partials (post-cheb)
    float* et3 = simbuf + 2 * slab;
    float* yspec = x2;  // careful: yspec used after x2's consumers

    dim3 blk(256);
    auto gemmF = [&](const float* A, const float* B, const float* bias, float* C,
                     int M, int Nc, int K, int lda, int ldb, int ldc,
                     float alpha, int act, int acc, int KS, float* part) {
        int nk = K / 32;
        int ks = KS < nk ? KS : nk; if (ks < 1) ks = 1;
        int kc = ((nk + ks - 1) / ks) * 32;
        int ksp = (K + kc - 1) / kc;
        gemm_mf<<<dim3(Nc / 64, M / 128, ksp), blk, 0, stream>>>(
            A, B, bias, C, part, M, Nc, K, lda, ldb, ldc, kc, alpha, act, acc);
        if (ksp > 1)
            gemm_epi<<<((size_t)M * Nc + 255) / 256, blk, 0, stream>>>(
                part, bias, C, nullptr, M, Nc, ldc, 0, ksp, alpha, act, acc);
    };
    auto gemmSm = [&](const float* A, const float* B, const float* bias, float* C,
                      int M, int Nc, int K, int lda, int ldb, int ldc,
                      float alpha, int act, int acc, int KS, float* part) {
        int nk = K / 32;
        int ks = KS < nk ? KS : nk; if (ks < 1) ks = 1;
        int kc = ((nk + ks - 1) / ks) * 32;
        int ksp = (K + kc - 1) / kc;
        gemm2<<<dim3((Nc + 63) / 64, M / 64, ksp), blk, 0, stream>>>(A, B, part, M, Nc, K, lda, ldb, kc);
        gemm_epi<<<((size_t)M * Nc + 255) / 256, blk, 0, stream>>>(
            part, bias, C, nullptr, M, Nc, ldc, 0, ksp, alpha, act, acc);
    };
    auto eg4 = [&](const float* X, float* T, int F, int use_dvis) {
        int F4 = F / 4, epb = 256 / F4 < 1 ? 1 : 256 / F4;
        edge_gather4<<<NN / epb, dim3(F4 * epb), 0, stream>>>(eidx, hv, De, dvis, X, T, F4, epb, use_dvis);
    };
    auto rg4 = [&](const float* T, const float* Badd, float alpha, float beta, float* Y,
                   int F, int use_dvis) {
        int F4 = F / 4, epb = 256 / F4 < 1 ? 1 : 256 / F4;
        row_gather4<<<NN / epb, dim3(F4 * epb), 0, stream>>>(row_start, csr_e, csr_w, dvis, T, Badd,
                                                             alpha, beta, Y, F4, epb, use_dvis);
    };

    const float E1 = 0.60653065971f;  // exp(-0.5)
    const float E2 = 0.36787944117f;  // exp(-1.0)

    // ---- pool + conversions ----
    pool_kernel<<<(NN * 192 + 255) / 256, blk, 0, stream>>>(images, p);
    {
        WJobs wj{};
        wj.j[0] = {iw1, iw1c, 192, 256};
        wj.j[1] = {tw1, tw1c, 768, 256};
        wj.j[2] = {sw1, sw1c, 256, 256};
        wj.j[3] = {iw2, iw2c, 256, 256};
        wj.j[4] = {tw2, tw2c, 256, 256};
        wj.j[5] = {sw2, sw2c, 256, 256};
        wj.j[6] = {gw,  gwc,  768, 256};
        wj.j[7] = {c1w, c1wc0, 768, 256};
        wj.j[8] = {c1w + (size_t)FEAT * HIDD, c1wc1, 768, 256};
        wj.j[9] = {c1w + (size_t)2 * FEAT * HIDD, c1wc2, 768, 256};
        wj.j[10] = {c2w, c2wc0, 256, 128};
        wj.j[11] = {c2w + (size_t)HIDD * 128, c2wc1, 256, 128};
        wj.j[12] = {c2w + (size_t)2 * HIDD * 128, c2wc2, 256, 128};
        wsplitT<<<dim3(24, 8, 13), blk, 0, stream>>>(wj);
    }
    split_rows<<<(NN * 48 + 255) / 256, blk, 0, stream>>>(p, pc, 192, NN * 48);
    split_rows<<<(NN * 192 + 255) / 256, blk, 0, stream>>>(text, tc, 768, NN * 192);
    split_rows<<<(NN * 64 + 255) / 256, blk, 0, stream>>>(signal, scb, 256, NN * 64);
    hipMemsetAsync(csum, 0, 2 * FEAT * sizeof(float), stream);

    // ---- MLP layer 1 + 2 (z-batched bf16) ----
    {
        BT bt{};
        bt.A[0] = pc;   bt.A[1] = tc;   bt.A[2] = scb;
        bt.Bw[0] = iw1c; bt.Bw[1] = tw1c; bt.Bw[2] = sw1c;
        bt.bias[0] = ib1; bt.bias[1] = tb1; bt.bias[2] = sb1;
        bt.Cc[0] = hc0; bt.Cc[1] = hc1; bt.Cc[2] = hc2;
        bt.Ka[0] = 384; bt.Ka[1] = 1536; bt.Ka[2] = 512;
        bt.ccW = 256;
        gemm_bt<<<dim3(4, 24, 3), blk, 0, stream>>>(bt, nullptr, NN, 256, 1, 1, 0);
    }
    {
        BT bt{};
        bt.A[0] = hc0;  bt.A[1] = hc1;  bt.A[2] = hc2;
        bt.Bw[0] = iw2c; bt.Bw[1] = tw2c; bt.Bw[2] = sw2c;
        bt.bias[0] = ib2; bt.bias[1] = tb2; bt.bias[2] = sb2;
        bt.Cf[0] = feats; bt.Cf[1] = feats + 256; bt.Cf[2] = feats + 512;
        bt.Ka[0] = bt.Ka[1] = bt.Ka[2] = 512;
        bt.ldc = FEAT;
        gemm_bt<<<dim3(4, 24, 3), blk, 0, stream>>>(bt, nullptr, NN, 256, 0, 1, 0);
    }
    bn_stats<<<NN / 16, blk, 0, stream>>>(feats, csum, csum2);
    bn_fin<<<3, blk, 0, stream>>>(csum, csum2, ig, tg, sg, ibeta, tbeta, sbeta, bsc, bsh);
    bn_norm<<<1024, blk, 0, stream>>>(feats, bsc, bsh, featsc_pre);

    // ---- generator GEMM + cheb1 G-GEMMs (graph-independent; featsc_pre dies with sim) ----
    {
        BT bt{};
        bt.A[0] = featsc_pre; bt.Bw[0] = gwc;
        bt.Ka[0] = 1536; bt.scale[0] = 1.f;
        gemm_bt<<<dim3(4, 24, 4), blk, 0, stream>>>(bt, gpart, NN, 256, 0, 4, 384);
        gemm_epi<<<((size_t)NN * 256 + 255) / 256, blk, 0, stream>>>(
            gpart, gb, z, nullptr, NN, 256, 256, 0, 4, 1.f, 2, 0);
    }
    {
        BT bt{};
        bt.A[0] = featsc_pre; bt.A[1] = featsc_pre; bt.A[2] = featsc_pre;
        bt.Bw[0] = c1wc0; bt.Bw[1] = c1wc1; bt.Bw[2] = c1wc2;
        bt.Cf[0] = G0; bt.Cf[1] = G1; bt.Cf[2] = G2;
        bt.Ka[0] = bt.Ka[1] = bt.Ka[2] = 1536;
        bt.ldc = 256;
        gemm_bt<<<dim3(4, 24, 3), blk, 0, stream>>>(bt, nullptr, NN, 256, 0, 1, 0);
    }
    rownorm_kernel<<<NN, blk, 0, stream>>>(z, Zc);
    sim_mfma<<<dim3(NN / 128, NN / 128), blk, 0, stream>>>(Zc, simbuf);
    topk_s1<<<NN, blk, 0, stream>>>(simbuf, cvalb, ccolb);
    topk_s2<<<NN / 4, blk, 0, stream>>>(cvalb, ccolb, hv, eidx);

    // ---- degrees + CSR ----
    edge_stats<<<NN / 256, blk, 0, stream>>>(hv, De, ew, msum, Dv, Dv2, row_cnt, row_fill);
    scatter_deg<<<NN * TK / 256, blk, 0, stream>>>(eidx, hv, ew, Dv, Dv2, row_cnt);
    scan_deg<<<1, blk, 0, stream>>>(row_cnt, row_start, Dv, Dv2, dvis);
    fill_csr<<<NN * TK / 256, blk, 0, stream>>>(eidx, hv, row_start, row_fill, csr_e, csr_w);

    // ---- cheb conv 1: apply M to 256-wide GEMM outputs ----
    eg4(G1, et, 256, 1);  rg4(et, nullptr, 1.f, 0.f, MG1, 256, 1);
    eg4(G2, et, 256, 1);  rg4(et, nullptr, 1.f, 0.f, MG2, 256, 1);
    eg4(MG2, et, 256, 1); rg4(et, nullptr, 1.f, 0.f, MMG2, 256, 1);
    cheb_combine<<<(NN * 64 + 255) / 256, blk, 0, stream>>>(
        G0, MG1, G2, MMG2, c1b, E1, E2, nullptr, x1c, 256, NN * 64);

    // ---- cheb conv 2: GEMM on x1c, then M on 128-wide ----
    {
        BT bt{};
        bt.A[0] = x1c; bt.A[1] = x1c; bt.A[2] = x1c;
        bt.Bw[0] = c2wc0; bt.Bw[1] = c2wc1; bt.Bw[2] = c2wc2;
        bt.Cf[0] = H0; bt.Cf[1] = H1; bt.Cf[2] = H2;
        bt.Ka[0] = bt.Ka[1] = bt.Ka[2] = 512;
        bt.ldc = 128;
        gemm_bt<<<dim3(2, 24, 3), blk, 0, stream>>>(bt, nullptr, NN, 128, 0, 1, 0);
    }
    float* MH1  = simbuf + slab;
    float* MH2  = simbuf + slab + (size_t)NN * 128;
    float* MMH2 = simbuf + slab + (size_t)2 * NN * 128;
    eg4(H1, et, 128, 1);  rg4(et, nullptr, 1.f, 0.f, MH1, 128, 1);
    eg4(H2, et, 128, 1);  rg4(et, nullptr, 1.f, 0.f, MH2, 128, 1);
    eg4(MH2, et, 128, 1); rg4(et, nullptr, 1.f, 0.f, MMH2, 128, 1);
    cheb_combine<<<(NN * 32 + 255) / 256, blk, 0, stream>>>(
        H0, MH1, H2, MMH2, c2b, E1, E2, x2, nullptr, 128, NN * 32);

    // ---- heads ----
    gemmF(x2, rw1, rb1, h, NN, 64, 128, 128, 64, 64, 1.f, 1, 0, 2, hpart);
    gemmF(h,  rw2, rb2, r, NN, 64, 64, 64, 64, 64, 1.f, 0, 0, 2, hpart);
    gemmSm(r,  aw1, ab1, h, NN, 32, 64, 64, 32, 32, 1.f, 1, 0, 2, hpart);
    gemmSm(h,  aw2, ab2, out, NN, 1, 32, 32, 1, 1, 1.f, 3, 0, 1, hpart);
    gemmF(r,  dw1, db1, h, NN, HIDD, 64, 64, HIDD, HIDD, 1.f, 1, 0, 2, hpart);
    gemmF(h,  dw2, db2, recon, NN, FEAT, HIDD, HIDD, FEAT, FEAT, 1.f, 0, 0, 1, nullptr);
    mse_reduce4<<<512, blk, 0, stream>>>(recon, feats, msum);

    // ---- spectral cut ----
    eg4(r, et3, 64, 0);
    rg4(et3, nullptr, 1.f, 0.f, yspec, 64, 0);
    spectral_cols<<<64, blk, 0, stream>>>(r, yspec, Dv2, numb, denb);
    finals_kernel<<<1, 64, 0, stream>>>(msum, numb, denb, out);
}

// Round 10
// 463.696 us; speedup vs baseline: 1.8586x; 1.1016x over previous
//
#include <hip/hip_runtime.h>
#include <cmath>

#define NN   3072
#define HIDD 256
#define TK   16
#define FEAT 768   // 3*HID

typedef __attribute__((ext_vector_type(8))) short bf16x8;
typedef __attribute__((ext_vector_type(4))) float f32x4;

__device__ inline unsigned short f2bf(float x) {
    unsigned u = __float_as_uint(x);
    unsigned r = (u + 0x7FFFu + ((u >> 16) & 1u)) >> 16;   // RNE
    return (unsigned short)r;
}
__device__ inline float bf2f(unsigned short h) {
    return __uint_as_float(((unsigned)h) << 16);
}

// ---------------------------------------------------------------- pool
__global__ void pool_kernel(const float* __restrict__ img, float* __restrict__ p) {
    int idx = blockIdx.x * 256 + threadIdx.x;
    if (idx >= NN * 192) return;
    int b = idx / 192, rem = idx % 192;
    int c = rem >> 6, oy = (rem >> 3) & 7, ox = rem & 7;
    const float* base = img + (((size_t)b * 3 + c) * 32 + oy * 4) * 32 + ox * 4;
    float s = 0.f;
#pragma unroll
    for (int iy = 0; iy < 4; iy++)
#pragma unroll
        for (int ix = 0; ix < 4; ix++) s += base[iy * 32 + ix];
    p[idx] = s * 0.0625f;
}

// ---------------------------------------------------------------- split fp32 rows -> [hi | lo] bf16
__global__ void split_rows(const float* __restrict__ X, short* __restrict__ Xc,
                           int K, int total4) {
    int i = blockIdx.x * 256 + threadIdx.x;
    if (i >= total4) return;
    int K4 = K >> 2;
    int m = i / K4, f = i - m * K4;
    float4 v = *(const float4*)(X + (size_t)m * K + f * 4);
    unsigned short h0 = f2bf(v.x), h1 = f2bf(v.y), h2 = f2bf(v.z), h3 = f2bf(v.w);
    short4 hi = make_short4((short)h0, (short)h1, (short)h2, (short)h3);
    short4 lo = make_short4((short)f2bf(v.x - bf2f(h0)), (short)f2bf(v.y - bf2f(h1)),
                            (short)f2bf(v.z - bf2f(h2)), (short)f2bf(v.w - bf2f(h3)));
    *(short4*)(Xc + (size_t)m * 2 * K + f * 4) = hi;
    *(short4*)(Xc + (size_t)m * 2 * K + K + f * 4) = lo;
}

// ---------------------------------------------------------------- batched weight transpose+split: W[KxN] -> Wc[N][2K]
struct WJ { const float* W; short* Wc; int K; int N; };
struct WJobs { WJ j[14]; };

__global__ void wsplitT(WJobs js) {
    WJ jb = js.j[blockIdx.z];
    int tk = blockIdx.x * 32, tn = blockIdx.y * 32;
    if (tk >= jb.K || tn >= jb.N) return;
    __shared__ float t[32][33];
    int kk = threadIdx.x >> 3, nn = (threadIdx.x & 7) * 4;
    float4 v = *(const float4*)(jb.W + (size_t)(tk + kk) * jb.N + tn + nn);
    t[kk][nn + 0] = v.x; t[kk][nn + 1] = v.y; t[kk][nn + 2] = v.z; t[kk][nn + 3] = v.w;
    __syncthreads();
    int n2 = threadIdx.x >> 3, k2 = (threadIdx.x & 7) * 4;
    float a = t[k2 + 0][n2], b = t[k2 + 1][n2], c = t[k2 + 2][n2], d = t[k2 + 3][n2];
    unsigned short h0 = f2bf(a), h1 = f2bf(b), h2 = f2bf(c), h3 = f2bf(d);
    short4 hi = make_short4((short)h0, (short)h1, (short)h2, (short)h3);
    short4 lo = make_short4((short)f2bf(a - bf2f(h0)), (short)f2bf(b - bf2f(h1)),
                            (short)f2bf(c - bf2f(h2)), (short)f2bf(d - bf2f(h3)));
    size_t rowb = (size_t)(tn + n2) * 2 * jb.K;
    *(short4*)(jb.Wc + rowb + tk + k2) = hi;
    *(short4*)(jb.Wc + rowb + jb.K + tk + k2) = lo;
}

// ---------------------------------------------------------------- pure bf16 NT GEMM (z-batched + split-K)
struct BT {
    const short* A[3];
    const short* Bw[3];
    const float* bias[3];
    float* Cf[3];
    short* Cc[3];
    int Ka[3];
    float scale[3];
    int ldc;
    int ccW;
};

__global__ __launch_bounds__(256) void gemm_bt(BT bt, float* __restrict__ P,
        int M, int Nc, int act, int KS, int Kc) {
    __shared__ short As[128 * 64];
    __shared__ short Bs[64 * 64];
    int zz = blockIdx.z, s = 0;
    if (KS > 1) { zz = blockIdx.z / KS; s = blockIdx.z % KS; }
    const short* A = bt.A[zz];
    const short* B = bt.Bw[zz];
    int Ka = bt.Ka[zz];
    int kbeg = s * Kc;
    int kend = (KS > 1) ? min(Ka, kbeg + Kc) : Ka;
    int tid = threadIdx.x, wave = tid >> 6, lane = tid & 63;
    int wm = (wave >> 1) * 64, wn = (wave & 1) * 32;
    int lrow = lane & 15, lk = lane >> 4;
    int m0 = blockIdx.y * 128, n0 = blockIdx.x * 64;
    f32x4 acc[4][2] = {};

    for (int k0 = kbeg; k0 < kend; k0 += 64) {
#pragma unroll
        for (int i = 0; i < 4; i++) {
            int q = tid + i * 256;
            int row = q >> 3, c = q & 7;
            int dst = row * 128 + ((c ^ (row & 7)) << 4);
            *(float4*)((char*)As + dst) =
                *(const float4*)((const char*)A + (((size_t)(m0 + row) * Ka + k0) << 1) + (c << 4));
        }
#pragma unroll
        for (int i = 0; i < 2; i++) {
            int q = tid + i * 256;
            int row = q >> 3, c = q & 7;
            int dst = row * 128 + ((c ^ (row & 7)) << 4);
            *(float4*)((char*)Bs + dst) =
                *(const float4*)((const char*)B + (((size_t)(n0 + row) * Ka + k0) << 1) + (c << 4));
        }
        __syncthreads();
#pragma unroll
        for (int kk = 0; kk < 2; kk++) {
            int ck = kk * 4 + lk;
            bf16x8 af[4], bg[2];
#pragma unroll
            for (int t = 0; t < 4; t++) {
                int ra = wm + t * 16 + lrow;
                af[t] = *(const bf16x8*)((const char*)As + ra * 128 + ((ck ^ (ra & 7)) << 4));
            }
#pragma unroll
            for (int u = 0; u < 2; u++) {
                int rb = wn + u * 16 + lrow;
                bg[u] = *(const bf16x8*)((const char*)Bs + rb * 128 + ((ck ^ (rb & 7)) << 4));
            }
#pragma unroll
            for (int i2 = 0; i2 < 4; i2++)
#pragma unroll
                for (int j2 = 0; j2 < 2; j2++)
                    acc[i2][j2] = __builtin_amdgcn_mfma_f32_16x16x32_bf16(af[i2], bg[j2], acc[i2][j2], 0, 0, 0);
        }
        __syncthreads();
    }

    if (P) {
        float sc = bt.scale[zz];
        float* Pp = P + (size_t)(zz * KS + s) * M * Nc;
#pragma unroll
        for (int i2 = 0; i2 < 4; i2++) {
            int gmb = m0 + wm + i2 * 16 + lk * 4;
#pragma unroll
            for (int j2 = 0; j2 < 2; j2++) {
                int gn = n0 + wn + j2 * 16 + lrow;
#pragma unroll
                for (int rg = 0; rg < 4; rg++)
                    Pp[(size_t)(gmb + rg) * Nc + gn] = sc * acc[i2][j2][rg];
            }
        }
    } else {
        const float* bias = bt.bias[zz];
        float* Cf = bt.Cf[zz];
        short* Cc = bt.Cc[zz];
#pragma unroll
        for (int i2 = 0; i2 < 4; i2++) {
            int gmb = m0 + wm + i2 * 16 + lk * 4;
#pragma unroll
            for (int j2 = 0; j2 < 2; j2++) {
                int gn = n0 + wn + j2 * 16 + lrow;
#pragma unroll
                for (int rg = 0; rg < 4; rg++) {
                    int gm = gmb + rg;
                    float x = acc[i2][j2][rg];
                    if (bias) x += bias[gn];
                    if (act == 1) x = fmaxf(x, 0.f);
                    else if (act == 2) x = tanhf(x);
                    if (Cf) Cf[(size_t)gm * bt.ldc + gn] = x;
                    if (Cc) {
                        unsigned short hi2 = f2bf(x);
                        Cc[(size_t)gm * 2 * bt.ccW + gn] = (short)hi2;
                        Cc[(size_t)gm * 2 * bt.ccW + bt.ccW + gn] = (short)f2bf(x - bf2f(hi2));
                    }
                }
            }
        }
    }
}

// ---------------------------------------------------------------- MFMA split-bf16 GEMM (fp32 in; dw1 only)
__global__ __launch_bounds__(256) void gemm_mf(
        const float* __restrict__ A, const float* __restrict__ B,
        const float* __restrict__ bias, float* __restrict__ C, float* __restrict__ P,
        int M, int Nc, int K, int lda, int ldb, int ldc, int Kc,
        float alpha, int act, int accf) {
    __shared__ short Ah[128 * 40];
    __shared__ short Al[128 * 40];
    __shared__ short Bh[64 * 40];
    __shared__ short Bl[64 * 40];
    int tid = threadIdx.x, wave = tid >> 6, lane = tid & 63;
    int wm = (wave >> 1) * 64, wn = (wave & 1) * 32;
    int lrow = lane & 15, lk = lane >> 4;
    int m0 = blockIdx.y * 128, n0 = blockIdx.x * 64;
    int kbeg = blockIdx.z * Kc, kend = min(K, kbeg + Kc);
    f32x4 acc[4][2] = {};

    for (int k0 = kbeg; k0 < kend; k0 += 32) {
#pragma unroll
        for (int i = 0; i < 4; i++) {
            int q = tid + i * 256;
            int rowm = q >> 3, kq = q & 7;
            float4 vv = *(const float4*)(A + (size_t)(m0 + rowm) * lda + k0 + kq * 4);
            unsigned short h0 = f2bf(vv.x), h1 = f2bf(vv.y), h2 = f2bf(vv.z), h3 = f2bf(vv.w);
            unsigned short l0 = f2bf(vv.x - bf2f(h0)), l1 = f2bf(vv.y - bf2f(h1));
            unsigned short l2 = f2bf(vv.z - bf2f(h2)), l3 = f2bf(vv.w - bf2f(h3));
            *(short4*)&Ah[rowm * 40 + kq * 4] = make_short4((short)h0, (short)h1, (short)h2, (short)h3);
            *(short4*)&Al[rowm * 40 + kq * 4] = make_short4((short)l0, (short)l1, (short)l2, (short)l3);
        }
#pragma unroll
        for (int i = 0; i < 2; i++) {
            int q = tid + i * 256;
            int kk2 = q >> 4, nq = q & 15;
            float4 vv = *(const float4*)(B + (size_t)(k0 + kk2) * ldb + n0 + nq * 4);
            unsigned short h0 = f2bf(vv.x), h1 = f2bf(vv.y), h2 = f2bf(vv.z), h3 = f2bf(vv.w);
            unsigned short l0 = f2bf(vv.x - bf2f(h0)), l1 = f2bf(vv.y - bf2f(h1));
            unsigned short l2 = f2bf(vv.z - bf2f(h2)), l3 = f2bf(vv.w - bf2f(h3));
            Bh[(nq * 4 + 0) * 40 + kk2] = (short)h0;  Bl[(nq * 4 + 0) * 40 + kk2] = (short)l0;
            Bh[(nq * 4 + 1) * 40 + kk2] = (short)h1;  Bl[(nq * 4 + 1) * 40 + kk2] = (short)l1;
            Bh[(nq * 4 + 2) * 40 + kk2] = (short)h2;  Bl[(nq * 4 + 2) * 40 + kk2] = (short)l2;
            Bh[(nq * 4 + 3) * 40 + kk2] = (short)h3;  Bl[(nq * 4 + 3) * 40 + kk2] = (short)l3;
        }
        __syncthreads();
        bf16x8 ah[4], al[4], bh[2], bl[2];
#pragma unroll
        for (int t2 = 0; t2 < 4; t2++) {
            int ra = wm + t2 * 16 + lrow;
            ah[t2] = *(const bf16x8*)&Ah[ra * 40 + lk * 8];
            al[t2] = *(const bf16x8*)&Al[ra * 40 + lk * 8];
        }
#pragma unroll
        for (int u = 0; u < 2; u++) {
            int rb = wn + u * 16 + lrow;
            bh[u] = *(const bf16x8*)&Bh[rb * 40 + lk * 8];
            bl[u] = *(const bf16x8*)&Bl[rb * 40 + lk * 8];
        }
#pragma unroll
        for (int i2 = 0; i2 < 4; i2++)
#pragma unroll
            for (int j2 = 0; j2 < 2; j2++) {
                acc[i2][j2] = __builtin_amdgcn_mfma_f32_16x16x32_bf16(ah[i2], bh[j2], acc[i2][j2], 0, 0, 0);
                acc[i2][j2] = __builtin_amdgcn_mfma_f32_16x16x32_bf16(ah[i2], bl[j2], acc[i2][j2], 0, 0, 0);
                acc[i2][j2] = __builtin_amdgcn_mfma_f32_16x16x32_bf16(al[i2], bh[j2], acc[i2][j2], 0, 0, 0);
            }
        __syncthreads();
    }

    float* Pp = P + (size_t)blockIdx.z * M * Nc;
#pragma unroll
    for (int i2 = 0; i2 < 4; i2++) {
        int gmb = m0 + wm + i2 * 16 + lk * 4;
#pragma unroll
        for (int j2 = 0; j2 < 2; j2++) {
            int gn = n0 + wn + j2 * 16 + lrow;
#pragma unroll
            for (int rg = 0; rg < 4; rg++)
                Pp[(size_t)(gmb + rg) * Nc + gn] = acc[i2][j2][rg];
        }
    }
}

// epilogue (split-K sum + bias/act; optional split-bf16 out)
__global__ void gemm_epi(const float* __restrict__ P, const float* __restrict__ bias,
                         float* __restrict__ C, short* __restrict__ Cc,
                         int M, int Nc, int ldc, int ccW, int KS,
                         float alpha, int act, int acc) {
    int idx = blockIdx.x * 256 + threadIdx.x;
    if (idx >= M * Nc) return;
    int m = idx / Nc, n = idx - m * Nc;
    float v = 0.f;
    for (int s = 0; s < KS; s++) v += P[(size_t)s * M * Nc + idx];
    v *= alpha;
    if (bias) v += bias[n];
    if (acc) v += C[(size_t)m * ldc + n];
    if (act == 1) v = fmaxf(v, 0.f);
    else if (act == 2) v = tanhf(v);
    else if (act == 3) v = 1.f / (1.f + expf(-v));
    if (C) C[(size_t)m * ldc + n] = v;
    if (Cc) {
        unsigned short hi = f2bf(v);
        Cc[(size_t)m * 2 * ccW + n] = (short)hi;
        Cc[(size_t)m * 2 * ccW + ccW + n] = (short)f2bf(v - bf2f(hi));
    }
}

// ---------------------------------------------------------------- sim = Zc @ Zc^T
__global__ __launch_bounds__(256) void sim_mfma(const short* __restrict__ Zc,
                                                float* __restrict__ S) {
    __shared__ short As[128 * 64];
    __shared__ short Bs[128 * 64];
    int tid = threadIdx.x;
    int wave = tid >> 6, lane = tid & 63;
    int wm = (wave >> 1) * 64, wn = (wave & 1) * 64;
    int m0 = blockIdx.y * 128, n0 = blockIdx.x * 128;
    int lrow = lane & 15, lk = lane >> 4;
    f32x4 acc[4][4] = {};

    for (int k0 = 0; k0 < 512; k0 += 64) {
#pragma unroll
        for (int i = 0; i < 4; i++) {
            int q = tid + i * 256;
            int row = q >> 3, c = q & 7;
            int dstoff = row * 128 + ((c ^ (row & 7)) << 4);
            const char* pa = (const char*)Zc + (((size_t)(m0 + row) * 512 + k0) << 1) + (c << 4);
            *(float4*)((char*)As + dstoff) = *(const float4*)pa;
            const char* pb = (const char*)Zc + (((size_t)(n0 + row) * 512 + k0) << 1) + (c << 4);
            *(float4*)((char*)Bs + dstoff) = *(const float4*)pb;
        }
        __syncthreads();
#pragma unroll
        for (int kk = 0; kk < 2; kk++) {
            int ck = kk * 4 + lk;
            bf16x8 af[4], bg[4];
#pragma unroll
            for (int t = 0; t < 4; t++) {
                int ra = wm + t * 16 + lrow;
                af[t] = *(const bf16x8*)((const char*)As + ra * 128 + ((ck ^ (ra & 7)) << 4));
                int rb = wn + t * 16 + lrow;
                bg[t] = *(const bf16x8*)((const char*)Bs + rb * 128 + ((ck ^ (rb & 7)) << 4));
            }
#pragma unroll
            for (int i2 = 0; i2 < 4; i2++)
#pragma unroll
                for (int j2 = 0; j2 < 4; j2++)
                    acc[i2][j2] = __builtin_amdgcn_mfma_f32_16x16x32_bf16(
                        af[i2], bg[j2], acc[i2][j2], 0, 0, 0);
        }
        __syncthreads();
    }
#pragma unroll
    for (int i2 = 0; i2 < 4; i2++) {
#pragma unroll
        for (int j2 = 0; j2 < 4; j2++) {
            int col = n0 + wn + j2 * 16 + lrow;
            int rowb = m0 + wm + i2 * 16 + lk * 4;
#pragma unroll
            for (int rg = 0; rg < 4; rg++)
                S[(size_t)(rowb + rg) * NN + col] = acc[i2][j2][rg];
        }
    }
}

// ---------------------------------------------------------------- BatchNorm, row-major 3-phase
__global__ void bn_stats(const float* __restrict__ Y, float* __restrict__ csum,
                         float* __restrict__ csum2) {
    int t = threadIdx.x;
    float s0 = 0.f, s1 = 0.f, s2v = 0.f;
    float q0 = 0.f, q1 = 0.f, q2 = 0.f;
    int r0 = blockIdx.x * 16;
    for (int i = r0; i < r0 + 16; i++) {
        const float* row = Y + (size_t)i * FEAT;
        float a = row[t], b = row[t + 256], c = row[t + 512];
        s0 += a; q0 += a * a;
        s1 += b; q1 += b * b;
        s2v += c; q2 += c * c;
    }
    atomicAdd(&csum[t], s0);        atomicAdd(&csum2[t], q0);
    atomicAdd(&csum[t + 256], s1);  atomicAdd(&csum2[t + 256], q1);
    atomicAdd(&csum[t + 512], s2v); atomicAdd(&csum2[t + 512], q2);
}

__global__ void bn_fin(const float* __restrict__ csum, const float* __restrict__ csum2,
                       const float* __restrict__ g0, const float* __restrict__ g1,
                       const float* __restrict__ g2, const float* __restrict__ b0,
                       const float* __restrict__ b1, const float* __restrict__ b2,
                       float* __restrict__ scale, float* __restrict__ shift) {
    int j = blockIdx.x * 256 + threadIdx.x;
    if (j >= FEAT) return;
    float mean = csum[j] * (1.f / NN);
    float var = fmaxf(csum2[j] * (1.f / NN) - mean * mean, 0.f);
    int m = j >> 8, jj = j & 255;
    const float* g = (m == 0) ? g0 : (m == 1) ? g1 : g2;
    const float* bt = (m == 0) ? b0 : (m == 1) ? b1 : b2;
    float sc = g[jj] / sqrtf(var + 1e-5f);
    scale[j] = sc;
    shift[j] = bt[jj] - mean * sc;
}

__global__ void bn_norm(float* __restrict__ Y, const float* __restrict__ scale,
                        const float* __restrict__ shift, short* __restrict__ Yc) {
    __shared__ float sc[FEAT], sh[FEAT];
    for (int j = threadIdx.x; j < FEAT; j += 256) { sc[j] = scale[j]; sh[j] = shift[j]; }
    __syncthreads();
    const int n4 = NN * FEAT / 4;
    for (int i = blockIdx.x * 256 + threadIdx.x; i < n4; i += gridDim.x * 256) {
        float4 v = *(const float4*)(Y + (size_t)i * 4);
        int m = i / 192;
        int c = (i - m * 192) * 4;
        v.x = v.x * sc[c + 0] + sh[c + 0];
        v.y = v.y * sc[c + 1] + sh[c + 1];
        v.z = v.z * sc[c + 2] + sh[c + 2];
        v.w = v.w * sc[c + 3] + sh[c + 3];
        *(float4*)(Y + (size_t)i * 4) = v;
        if (Yc) {
            unsigned short h0 = f2bf(v.x), h1 = f2bf(v.y), h2 = f2bf(v.z), h3 = f2bf(v.w);
            *(short4*)(Yc + (size_t)m * 1536 + c) =
                make_short4((short)h0, (short)h1, (short)h2, (short)h3);
            *(short4*)(Yc + (size_t)m * 1536 + 768 + c) =
                make_short4((short)f2bf(v.x - bf2f(h0)), (short)f2bf(v.y - bf2f(h1)),
                            (short)f2bf(v.z - bf2f(h2)), (short)f2bf(v.w - bf2f(h3)));
        }
    }
}

// ---------------------------------------------------------------- row normalize z -> split-bf16 Zc
__global__ void rownorm_kernel(const float* __restrict__ Zin, short* __restrict__ Zc) {
    int i = blockIdx.x;
    int c = threadIdx.x;
    __shared__ float rs[256];
    __shared__ float inv;
    float v = Zin[(size_t)i * HIDD + c];
    rs[c] = v * v;
    __syncthreads();
    for (int st = 128; st > 0; st >>= 1) {
        if (c < st) rs[c] += rs[c + st];
        __syncthreads();
    }
    if (c == 0) inv = 1.f / (sqrtf(rs[0]) + 1e-8f);
    __syncthreads();
    float vn = v * inv;
    unsigned short hi = f2bf(vn);
    float lo = vn - bf2f(hi);
    Zc[(size_t)i * 512 + c] = (short)hi;
    Zc[(size_t)i * 512 + 256 + c] = (short)f2bf(lo);
}

// ---------------------------------------------------------------- top-k stage 1 v2: single lex butterfly per extraction
__global__ __launch_bounds__(256) void topk_s1(const float* __restrict__ S,
                                               float* __restrict__ cval,
                                               int* __restrict__ ccol) {
    int lane = threadIdx.x & 63;
    int w = threadIdx.x >> 6;
    int row = blockIdx.x;
    const float4* base = (const float4*)(S + (size_t)row * NN + w * 768);
    float v[12];
#pragma unroll
    for (int c = 0; c < 3; c++) {
        float4 q = base[c * 64 + lane];
        v[c * 4 + 0] = q.x; v[c * 4 + 1] = q.y; v[c * 4 + 2] = q.z; v[c * 4 + 3] = q.w;
    }
    const float NEG = -3.4e38f;
    float* ov = cval + ((size_t)row * 4 + w) * 16;
    int* oc = ccol + ((size_t)row * 4 + w) * 16;
    for (int t = 0; t < TK; t++) {
        // local value tree (ILP)
        float m0[6];
#pragma unroll
        for (int i = 0; i < 6; i++) m0[i] = fmaxf(v[i], v[i + 6]);
        float m = fmaxf(fmaxf(fmaxf(m0[0], m0[1]), fmaxf(m0[2], m0[3])), fmaxf(m0[4], m0[5]));
        // local index via monotone reverse scan (col monotone in i per lane)
        int li = 0;
#pragma unroll
        for (int i = 11; i >= 0; i--) li = (v[i] == m) ? i : li;
        int col = w * 768 + ((li >> 2) << 8) + lane * 4 + (li & 3);
        // single combined (val,col) lex butterfly
#pragma unroll
        for (int s = 1; s < 64; s <<= 1) {
            float om = __shfl_xor(m, s);
            int ocv = __shfl_xor(col, s);
            bool b = (om > m) || (om == m && ocv < col);
            m = b ? om : m;
            col = b ? ocv : col;
        }
        if (lane == 0) { ov[t] = m; oc[t] = col; }
        int lcol = col - w * 768;
        int owner = (lcol >> 2) & 63;
        if (lane == owner) {
            int li2 = ((lcol >> 8) << 2) | (lcol & 3);
#pragma unroll
            for (int i = 0; i < 12; i++)
                if (i == li2) v[i] = NEG;
        }
    }
}

// stage 2: 1 wave/row merges 64 candidates
__global__ __launch_bounds__(256) void topk_s2(const float* __restrict__ cval,
                                               const int* __restrict__ ccol,
                                               float* __restrict__ hv,
                                               int* __restrict__ eidx) {
    int lane = threadIdx.x & 63;
    int row = blockIdx.x * 4 + (threadIdx.x >> 6);
    float v = cval[(size_t)row * 64 + lane];
    int c = ccol[(size_t)row * 64 + lane];
    for (int t = 0; t < TK; t++) {
        float bv = v; int bc = c;
#pragma unroll
        for (int s = 1; s < 64; s <<= 1) {
            float ov = __shfl_xor(bv, s);
            int oc = __shfl_xor(bc, s);
            bool b = (ov > bv) || (ov == bv && oc < bc);
            bv = b ? ov : bv;
            bc = b ? oc : bc;
        }
        if (lane == 0) {
            float sg = 1.f / (1.f + expf(-bv));
            hv[row * TK + t] = (sg > 0.5f) ? sg : 0.f;
            eidx[row * TK + t] = bc;
        }
        if (v == bv && c == bc) v = -3.4e38f;
    }
}

// ---------------------------------------------------------------- edge stats (+ zeroing)
__global__ void edge_stats(const float* __restrict__ hv, float* __restrict__ De,
                           float* __restrict__ ew, float* __restrict__ msum,
                           float* __restrict__ Dv, float* __restrict__ Dv2,
                           int* __restrict__ row_cnt, int* __restrict__ row_fill) {
    int e = blockIdx.x * 256 + threadIdx.x;
    if (e == 0) *msum = 0.f;
    if (e >= NN) return;
    Dv[e] = 0.f; Dv2[e] = 0.f; row_cnt[e] = 0; row_fill[e] = 0;
    float s = 0.f;
#pragma unroll
    for (int j = 0; j < TK; j++) s += hv[e * TK + j];
    De[e] = s + 1e-8f;
    ew[e] = s * (1.f / TK);
}

__global__ void scatter_deg(const int* __restrict__ eidx, const float* __restrict__ hv,
                            const float* __restrict__ ew, float* __restrict__ Dv,
                            float* __restrict__ Dv2, int* __restrict__ row_cnt) {
    int t = blockIdx.x * 256 + threadIdx.x;
    if (t >= NN * TK) return;
    int e = t >> 4;
    int v = eidx[t];
    float w = hv[t];
    atomicAdd(&Dv[v], w * ew[e]);
    atomicAdd(&Dv2[v], w);
    atomicAdd(&row_cnt[v], 1);
}

__global__ void scan_deg(const int* __restrict__ cnt, int* __restrict__ start,
                         const float* __restrict__ Dv, float* __restrict__ Dv2,
                         float* __restrict__ dvis) {
    __shared__ int part[256];
    int t = threadIdx.x;
    const int chunk = NN / 256;
    int s = 0;
    for (int i = t * chunk; i < (t + 1) * chunk; i++) {
        s += cnt[i];
        dvis[i] = 1.f / sqrtf(Dv[i] + 1e-8f);
        Dv2[i] += 1e-8f;
    }
    part[t] = s;
    __syncthreads();
    if (t == 0) {
        int a = 0;
        for (int i = 0; i < 256; i++) { int v = part[i]; part[i] = a; a += v; }
    }
    __syncthreads();
    int a = part[t];
    for (int i = t * chunk; i < (t + 1) * chunk; i++) { start[i] = a; a += cnt[i]; }
    if (t == 255) start[NN] = a;
}

__global__ void fill_csr(const int* __restrict__ eidx, const float* __restrict__ hv,
                         const int* __restrict__ start, int* __restrict__ fillc,
                         int* __restrict__ csr_e, float* __restrict__ csr_w) {
    int t = blockIdx.x * 256 + threadIdx.x;
    if (t >= NN * TK) return;
    int e = t >> 4;
    int v = eidx[t];
    int pos = atomicAdd(&fillc[v], 1);
    int pp = start[v] + pos;
    csr_e[pp] = e;
    csr_w[pp] = hv[t];
}

// ---------------------------------------------------------------- sparse H ops (ld-parameterized, f4 units)
__global__ void edge_gather4(const int* __restrict__ eidx, const float* __restrict__ hv,
                             const float* __restrict__ De, const float* __restrict__ dvis,
                             const float* __restrict__ X, float* __restrict__ T,
                             int F4, int ldx4, int ldt4, int epb, int use_dvis) {
    int slot = threadIdx.x / F4;
    if (slot >= epb) return;
    int f = threadIdx.x - slot * F4;
    int e = blockIdx.x * epb + slot;
    const int* ei = eidx + e * TK;
    const float* hw = hv + e * TK;
    float ax = 0.f, ay = 0.f, az = 0.f, aw = 0.f;
#pragma unroll
    for (int j = 0; j < TK; j++) {
        int v = ei[j];
        float w = hw[j];
        if (use_dvis) w *= dvis[v];
        const float4 x = *(const float4*)(X + ((size_t)v * ldx4 + f) * 4);
        ax = fmaf(w, x.x, ax); ay = fmaf(w, x.y, ay);
        az = fmaf(w, x.z, az); aw = fmaf(w, x.w, aw);
    }
    float inv = 1.f / De[e];
    *(float4*)(T + ((size_t)e * ldt4 + f) * 4) = make_float4(ax * inv, ay * inv, az * inv, aw * inv);
}

__global__ void row_gather4(const int* __restrict__ start, const int* __restrict__ csr_e,
                            const float* __restrict__ csr_w, const float* __restrict__ dvis,
                            const float* __restrict__ T, float* __restrict__ Y,
                            int F4, int ldt4, int ldy4, int epb, int use_dvis) {
    int slot = threadIdx.x / F4;
    if (slot >= epb) return;
    int f = threadIdx.x - slot * F4;
    int v = blockIdx.x * epb + slot;
    int s0 = start[v], s1 = start[v + 1];
    float ax = 0.f, ay = 0.f, az = 0.f, aw = 0.f;
    for (int p = s0; p < s1; p++) {
        float w = csr_w[p];
        const float4 x = *(const float4*)(T + ((size_t)csr_e[p] * ldt4 + f) * 4);
        ax = fmaf(w, x.x, ax); ay = fmaf(w, x.y, ay);
        az = fmaf(w, x.z, az); aw = fmaf(w, x.w, aw);
    }
    float sc = use_dvis ? dvis[v] : 1.f;
    *(float4*)(Y + ((size_t)v * ldy4 + f) * 4) =
        make_float4(ax * sc, ay * sc, az * sc, aw * sc);
}

// ---------------------------------------------------------------- cheb combine: relu(A0 - e1*A1 - e2*A2 + 2*e2*A3 + b)
__global__ void cheb_combine(const float* __restrict__ A0, int ld0,
                             const float* __restrict__ A1, int ld1,
                             const float* __restrict__ A2, int ld2,
                             const float* __restrict__ A3, int ld3,
                             const float* __restrict__ bias, float e1, float e2,
                             float* __restrict__ Xf, int ldf, short* __restrict__ Xc,
                             int Fw, int total4) {
    int i = blockIdx.x * 256 + threadIdx.x;
    if (i >= total4) return;
    int F4 = Fw >> 2;
    int m = i / F4, n4 = i - m * F4;
    float4 g0 = *(const float4*)(A0 + ((size_t)m * ld0 + n4) * 4);
    float4 g1 = *(const float4*)(A1 + ((size_t)m * ld1 + n4) * 4);
    float4 g2 = *(const float4*)(A2 + ((size_t)m * ld2 + n4) * 4);
    float4 g3 = *(const float4*)(A3 + ((size_t)m * ld3 + n4) * 4);
    float4 b = *(const float4*)(bias + n4 * 4);
    float4 x;
    x.x = fmaxf(g0.x - e1 * g1.x - e2 * g2.x + 2.f * e2 * g3.x + b.x, 0.f);
    x.y = fmaxf(g0.y - e1 * g1.y - e2 * g2.y + 2.f * e2 * g3.y + b.y, 0.f);
    x.z = fmaxf(g0.z - e1 * g1.z - e2 * g2.z + 2.f * e2 * g3.z + b.z, 0.f);
    x.w = fmaxf(g0.w - e1 * g1.w - e2 * g2.w + 2.f * e2 * g3.w + b.w, 0.f);
    if (Xf) *(float4*)(Xf + ((size_t)m * ldf + n4) * 4) = x;
    if (Xc) {
        unsigned short h0 = f2bf(x.x), h1 = f2bf(x.y), h2 = f2bf(x.z), h3 = f2bf(x.w);
        *(short4*)(Xc + (size_t)m * 2 * Fw + n4 * 4) =
            make_short4((short)h0, (short)h1, (short)h2, (short)h3);
        *(short4*)(Xc + (size_t)m * 2 * Fw + Fw + n4 * 4) =
            make_short4((short)f2bf(x.x - bf2f(h0)), (short)f2bf(x.y - bf2f(h1)),
                        (short)f2bf(x.z - bf2f(h2)), (short)f2bf(x.w - bf2f(h3)));
    }
}

// ---------------------------------------------------------------- fused heads
// r = (relu(x2@rw1+rb1))@rw2 + rb2      x2:[NN][128] -> r:[NN][64]
__global__ __launch_bounds__(256) void rhead(const float* __restrict__ x2,
        const float* __restrict__ rw1, const float* __restrict__ rb1,
        const float* __restrict__ rw2, const float* __restrict__ rb2,
        float* __restrict__ r) {
    __shared__ float w1[128 * 64];
    __shared__ float w2[64 * 64];
    __shared__ float xr[4][128];
    int tid = threadIdx.x;
    for (int i = tid; i < 128 * 64 / 4; i += 256)
        *(float4*)&w1[i * 4] = *(const float4*)&rw1[i * 4];
    for (int i = tid; i < 64 * 64 / 4; i += 256)
        *(float4*)&w2[i * 4] = *(const float4*)&rw2[i * 4];
    __syncthreads();
    int wave = tid >> 6, lane = tid & 63;
    for (int rr = 0; rr < 4; rr++) {
        int row = blockIdx.x * 16 + rr * 4 + wave;
        *(float2*)&xr[wave][lane * 2] = *(const float2*)&x2[(size_t)row * 128 + lane * 2];
        float hacc = rb1[lane];
#pragma unroll 8
        for (int k = 0; k < 128; k++) hacc = fmaf(xr[wave][k], w1[k * 64 + lane], hacc);
        hacc = fmaxf(hacc, 0.f);
        xr[wave][lane] = hacc;   // wave-synchronous reuse
        float racc = rb2[lane];
#pragma unroll 8
        for (int k = 0; k < 64; k++) racc = fmaf(xr[wave][k], w2[k * 64 + lane], racc);
        r[(size_t)row * 64 + lane] = racc;
    }
}

// out = sigmoid(relu(r@aw1+ab1)@aw2+ab2)   r:[NN][64] -> out:[NN]
__global__ __launch_bounds__(256) void ahead(const float* __restrict__ r,
        const float* __restrict__ aw1, const float* __restrict__ ab1,
        const float* __restrict__ aw2, const float* __restrict__ ab2,
        float* __restrict__ out) {
    __shared__ float w1[64 * 32];
    __shared__ float w2s[32];
    __shared__ float rr[4][2][64];
    int tid = threadIdx.x;
    for (int i = tid; i < 64 * 32 / 4; i += 256)
        *(float4*)&w1[i * 4] = *(const float4*)&aw1[i * 4];
    if (tid < 32) w2s[tid] = aw2[tid];
    __syncthreads();
    int wave = tid >> 6, lane = tid & 63;
    int g = lane >> 5, j = lane & 31;
    for (int it = 0; it < 4; it++) {
        int row = blockIdx.x * 32 + it * 8 + wave * 2 + g;
        *(float2*)&rr[wave][g][j * 2] = *(const float2*)&r[(size_t)row * 64 + j * 2];
        float h = ab1[j];
#pragma unroll 8
        for (int k = 0; k < 64; k++) h = fmaf(rr[wave][g][k], w1[k * 32 + j], h);
        h = fmaxf(h, 0.f) * w2s[j];
#pragma unroll
        for (int s = 1; s < 32; s <<= 1) h += __shfl_xor(h, s);
        if (j == 0) out[row] = 1.f / (1.f + expf(-(h + ab2[0])));
    }
}

// ---------------------------------------------------------------- reductions
__global__ void mse_reduce4(const float* __restrict__ a, const float* __restrict__ b,
                            float* __restrict__ sum) {
    __shared__ float rs[256];
    float s = 0.f;
    const int n4 = NN * FEAT / 4;
    for (int i = blockIdx.x * 256 + threadIdx.x; i < n4; i += gridDim.x * 256) {
        const float4 x = *(const float4*)(a + (size_t)i * 4);
        const float4 y = *(const float4*)(b + (size_t)i * 4);
        float dx = x.x - y.x, dy = x.y - y.y, dz = x.z - y.z, dw = x.w - y.w;
        s += dx * dx + dy * dy + dz * dz + dw * dw;
    }
    rs[threadIdx.x] = s;
    __syncthreads();
    for (int st = 128; st > 0; st >>= 1) {
        if (threadIdx.x < st) rs[threadIdx.x] += rs[threadIdx.x + st];
        __syncthreads();
    }
    if (threadIdx.x == 0) atomicAdd(sum, rs[0]);
}

__global__ void spectral_cols(const float* __restrict__ r, const float* __restrict__ y,
                              const float* __restrict__ Dv2, float* __restrict__ numb,
                              float* __restrict__ denb) {
    int c = blockIdx.x;
    __shared__ float rn[256], rd[256];
    float sn = 0.f, sd = 0.f;
    for (int i = threadIdx.x; i < NN; i += 256) {
        float rv = r[(size_t)i * 64 + c];
        float d2 = Dv2[i];
        float lcx = d2 * rv - y[(size_t)i * 64 + c];
        sn += rv * lcx;
        sd += d2 * rv * rv;
    }
    rn[threadIdx.x] = sn; rd[threadIdx.x] = sd;
    __syncthreads();
    for (int st = 128; st > 0; st >>= 1) {
        if (threadIdx.x < st) { rn[threadIdx.x] += rn[threadIdx.x + st]; rd[threadIdx.x] += rd[threadIdx.x + st]; }
        __syncthreads();
    }
    if (threadIdx.x == 0) { numb[c] = rn[0]; denb[c] = rd[0] + 1e-8f; }
}

__global__ void finals_kernel(const float* __restrict__ msum, const float* __restrict__ numb,
                              const float* __restrict__ denb, float* __restrict__ out) {
    if (threadIdx.x == 0 && blockIdx.x == 0) {
        float s = 0.f;
        for (int c = 0; c < 64; c++) s += numb[c] / denb[c];
        out[NN + 1] = s * (1.f / 64.f);
        out[NN] = msum[0] * (1.f / ((float)NN * FEAT));
    }
}

// ================================================================ launch
extern "C" void kernel_launch(void* const* d_in, const int* in_sizes, int n_in,
                              void* d_out, int out_size, void* d_ws, size_t ws_size,
                              hipStream_t stream) {
    const float* images = (const float*)d_in[0];
    const float* text   = (const float*)d_in[1];
    const float* signal = (const float*)d_in[2];
    const float* iw1 = (const float*)d_in[3];  const float* ib1 = (const float*)d_in[4];
    const float* iw2 = (const float*)d_in[5];  const float* ib2 = (const float*)d_in[6];
    const float* ig  = (const float*)d_in[7];  const float* ibeta = (const float*)d_in[8];
    const float* tw1 = (const float*)d_in[9];  const float* tb1 = (const float*)d_in[10];
    const float* tw2 = (const float*)d_in[11]; const float* tb2 = (const float*)d_in[12];
    const float* tg  = (const float*)d_in[13]; const float* tbeta = (const float*)d_in[14];
    const float* sw1 = (const float*)d_in[15]; const float* sb1 = (const float*)d_in[16];
    const float* sw2 = (const float*)d_in[17]; const float* sb2 = (const float*)d_in[18];
    const float* sg  = (const float*)d_in[19]; const float* sbeta = (const float*)d_in[20];
    const float* gw  = (const float*)d_in[21]; const float* gb = (const float*)d_in[22];
    const float* c1w = (const float*)d_in[23]; const float* c1b = (const float*)d_in[24];
    const float* c2w = (const float*)d_in[25]; const float* c2b = (const float*)d_in[26];
    const float* rw1 = (const float*)d_in[27]; const float* rb1 = (const float*)d_in[28];
    const float* rw2 = (const float*)d_in[29]; const float* rb2 = (const float*)d_in[30];
    const float* aw1 = (const float*)d_in[31]; const float* ab1 = (const float*)d_in[32];
    const float* aw2 = (const float*)d_in[33]; const float* ab2 = (const float*)d_in[34];
    const float* dw1 = (const float*)d_in[35]; const float* db1 = (const float*)d_in[36];
    const float* dw2 = (const float*)d_in[37]; const float* db2 = (const float*)d_in[38];
    float* out = (float*)d_out;

    float* wsf = (float*)d_ws;
    size_t off = 0;
    auto AF = [&](size_t n) { float* q = wsf + off; off += n; return q; };
    float* feats  = AF((size_t)NN * FEAT);
    float* simbuf = AF((size_t)NN * NN);
    float* p      = AF((size_t)NN * 192);
    float* h      = AF((size_t)NN * HIDD);
    float* z      = AF((size_t)NN * HIDD);
    float* x2     = AF((size_t)NN * 128);
    float* r      = AF((size_t)NN * 64);
    float* hv     = AF((size_t)NN * TK);
    float* ew     = AF(NN);
    float* De     = AF(NN);
    float* Dv     = AF(NN);
    float* Dv2    = AF(NN);
    float* dvis   = AF(NN);
    float* csr_w  = AF((size_t)NN * TK);
    float* numb   = AF(64);
    float* denb   = AF(64);
    float* msum   = AF(1);
    float* csum   = AF(FEAT);
    float* csum2  = AF(FEAT);
    float* bsc    = AF(FEAT);
    float* bsh    = AF(FEAT);
    short* x1c    = (short*)AF((size_t)NN * 256);     // [NN][512] shorts (also reused as hc)
    short* wcbuf  = (short*)AF(1589248);              // weight splits (3,178,496 shorts)
    float* Gbuf   = AF((size_t)NN * FEAT);            // G0|G1|G2 combined, ld 768
    float* cvalb  = AF((size_t)NN * 64);
    int* ccolb    = (int*)(wsf + off); off += (size_t)NN * 64;
    int* eidx     = (int*)(wsf + off); off += (size_t)NN * TK;
    int* csr_e    = (int*)(wsf + off); off += (size_t)NN * TK;
    int* row_cnt  = (int*)(wsf + off); off += NN;
    int* row_fill = (int*)(wsf + off); off += NN;
    int* row_start= (int*)(wsf + off); off += NN + 1;

    short* Zc = (short*)z;
    short* hc = x1c;   // reuse post-cheb2

    // weight split sub-buffers
    short* wp = wcbuf;
    auto AW = [&](size_t n) { short* q = wp; wp += n; return q; };
    short* iw1c = AW((size_t)256 * 384);
    short* tw1c = AW((size_t)256 * 1536);
    short* sw1c = AW((size_t)256 * 512);
    short* iw2c = AW((size_t)256 * 512);
    short* tw2c = AW((size_t)256 * 512);
    short* sw2c = AW((size_t)256 * 512);
    short* gwc  = AW((size_t)256 * 1536);
    short* c1wc0 = AW((size_t)256 * 1536);
    short* c1wc1 = AW((size_t)256 * 1536);
    short* c1wc2 = AW((size_t)256 * 1536);
    short* c2wc0 = AW((size_t)128 * 512);
    short* c2wc1 = AW((size_t)128 * 512);
    short* c2wc2 = AW((size_t)128 * 512);
    short* dw2c  = AW((size_t)768 * 512);

    // pre-sim simbuf layout (shorts)
    short* sb = (short*)simbuf;
    short* pc  = sb;
    short* tc  = pc + (size_t)NN * 384;
    short* scb = tc + (size_t)NN * 1536;
    short* hc0 = scb + (size_t)NN * 512;
    short* hc1 = hc0 + (size_t)NN * 512;
    short* hc2 = hc1 + (size_t)NN * 512;
    short* featsc_pre = hc2 + (size_t)NN * 512;
    float* gpart = simbuf;   // gw split-K partials (4 x NN*256 over dead pc/tc region)

    // post-topk slabs in simbuf (floats)
    float* et1   = simbuf;                              // NN*512
    float* MG12  = simbuf + (size_t)NN * 512;           // NN*512
    float* et2   = simbuf + (size_t)NN * 1024;          // NN*256
    float* MMG2  = simbuf + (size_t)NN * 1280;          // NN*256
    float* Hb    = simbuf;                              // NN*384 (cheb2, overwrites et1)
    float* et3   = simbuf + (size_t)NN * 384;           // NN*256
    float* MH12  = simbuf + (size_t)NN * 640;           // NN*256
    float* et4   = simbuf + (size_t)NN * 896;           // NN*128
    float* MMH2  = simbuf + (size_t)NN * 1024;          // NN*128
    float* dpart = simbuf + (size_t)NN * 1536;          // dw1 partials (2 x NN*256)
    float* recon = simbuf;                              // NN*768 (heads phase)
    float* et5   = simbuf + (size_t)NN * 2048;          // spectral gather NN*64
    float* yspec = x2;

    dim3 blk(256);
    auto eg = [&](const float* X, int ldx4, float* T, int ldt4, int F, int use_dvis) {
        int F4 = F / 4, epb = 256 / F4 < 1 ? 1 : 256 / F4;
        edge_gather4<<<NN / epb, dim3(F4 * epb), 0, stream>>>(
            eidx, hv, De, dvis, X, T, F4, ldx4, ldt4, epb, use_dvis);
    };
    auto rg = [&](const float* T, int ldt4, float* Y, int ldy4, int F, int use_dvis) {
        int F4 = F / 4, epb = 256 / F4 < 1 ? 1 : 256 / F4;
        row_gather4<<<NN / epb, dim3(F4 * epb), 0, stream>>>(
            row_start, csr_e, csr_w, dvis, T, Y, F4, ldt4, ldy4, epb, use_dvis);
    };

    const float E1 = 0.60653065971f;  // exp(-0.5)
    const float E2 = 0.36787944117f;  // exp(-1.0)

    // ---- pool + conversions ----
    pool_kernel<<<(NN * 192 + 255) / 256, blk, 0, stream>>>(images, p);
    {
        WJobs wj{};
        wj.j[0] = {iw1, iw1c, 192, 256};
        wj.j[1] = {tw1, tw1c, 768, 256};
        wj.j[2] = {sw1, sw1c, 256, 256};
        wj.j[3] = {iw2, iw2c, 256, 256};
        wj.j[4] = {tw2, tw2c, 256, 256};
        wj.j[5] = {sw2, sw2c, 256, 256};
        wj.j[6] = {gw,  gwc,  768, 256};
        wj.j[7] = {c1w, c1wc0, 768, 256};
        wj.j[8] = {c1w + (size_t)FEAT * HIDD, c1wc1, 768, 256};
        wj.j[9] = {c1w + (size_t)2 * FEAT * HIDD, c1wc2, 768, 256};
        wj.j[10] = {c2w, c2wc0, 256, 128};
        wj.j[11] = {c2w + (size_t)HIDD * 128, c2wc1, 256, 128};
        wj.j[12] = {c2w + (size_t)2 * HIDD * 128, c2wc2, 256, 128};
        wj.j[13] = {dw2, dw2c, 256, 768};
        wsplitT<<<dim3(24, 24, 14), blk, 0, stream>>>(wj);
    }
    split_rows<<<(NN * 48 + 255) / 256, blk, 0, stream>>>(p, pc, 192, NN * 48);
    split_rows<<<(NN * 192 + 255) / 256, blk, 0, stream>>>(text, tc, 768, NN * 192);
    split_rows<<<(NN * 64 + 255) / 256, blk, 0, stream>>>(signal, scb, 256, NN * 64);
    hipMemsetAsync(csum, 0, 2 * FEAT * sizeof(float), stream);

    // ---- MLP layer 1 + 2 ----
    {
        BT bt{};
        bt.A[0] = pc;   bt.A[1] = tc;   bt.A[2] = scb;
        bt.Bw[0] = iw1c; bt.Bw[1] = tw1c; bt.Bw[2] = sw1c;
        bt.bias[0] = ib1; bt.bias[1] = tb1; bt.bias[2] = sb1;
        bt.Cc[0] = hc0; bt.Cc[1] = hc1; bt.Cc[2] = hc2;
        bt.Ka[0] = 384; bt.Ka[1] = 1536; bt.Ka[2] = 512;
        bt.ccW = 256;
        gemm_bt<<<dim3(4, 24, 3), blk, 0, stream>>>(bt, nullptr, NN, 256, 1, 1, 0);
    }
    {
        BT bt{};
        bt.A[0] = hc0;  bt.A[1] = hc1;  bt.A[2] = hc2;
        bt.Bw[0] = iw2c; bt.Bw[1] = tw2c; bt.Bw[2] = sw2c;
        bt.bias[0] = ib2; bt.bias[1] = tb2; bt.bias[2] = sb2;
        bt.Cf[0] = feats; bt.Cf[1] = feats + 256; bt.Cf[2] = feats + 512;
        bt.Ka[0] = bt.Ka[1] = bt.Ka[2] = 512;
        bt.ldc = FEAT;
        gemm_bt<<<dim3(4, 24, 3), blk, 0, stream>>>(bt, nullptr, NN, 256, 0, 1, 0);
    }
    bn_stats<<<NN / 16, blk, 0, stream>>>(feats, csum, csum2);
    bn_fin<<<3, blk, 0, stream>>>(csum, csum2, ig, tg, sg, ibeta, tbeta, sbeta, bsc, bsh);
    bn_norm<<<1024, blk, 0, stream>>>(feats, bsc, bsh, featsc_pre);

    // ---- generator GEMM + cheb1 G-GEMMs (graph-independent, pre-sim) ----
    {
        BT bt{};
        bt.A[0] = featsc_pre; bt.Bw[0] = gwc;
        bt.Ka[0] = 1536; bt.scale[0] = 1.f;
        gemm_bt<<<dim3(4, 24, 4), blk, 0, stream>>>(bt, gpart, NN, 256, 0, 4, 384);
        gemm_epi<<<((size_t)NN * 256 + 255) / 256, blk, 0, stream>>>(
            gpart, gb, z, nullptr, NN, 256, 256, 0, 4, 1.f, 2, 0);
    }
    {
        BT bt{};
        bt.A[0] = featsc_pre; bt.A[1] = featsc_pre; bt.A[2] = featsc_pre;
        bt.Bw[0] = c1wc0; bt.Bw[1] = c1wc1; bt.Bw[2] = c1wc2;
        bt.Cf[0] = Gbuf; bt.Cf[1] = Gbuf + 256; bt.Cf[2] = Gbuf + 512;
        bt.Ka[0] = bt.Ka[1] = bt.Ka[2] = 1536;
        bt.ldc = 768;
        gemm_bt<<<dim3(4, 24, 3), blk, 0, stream>>>(bt, nullptr, NN, 256, 0, 1, 0);
    }
    rownorm_kernel<<<NN, blk, 0, stream>>>(z, Zc);
    sim_mfma<<<dim3(NN / 128, NN / 128), blk, 0, stream>>>(Zc, simbuf);
    topk_s1<<<NN, blk, 0, stream>>>(simbuf, cvalb, ccolb);
    topk_s2<<<NN / 4, blk, 0, stream>>>(cvalb, ccolb, hv, eidx);

    // ---- degrees + CSR ----
    edge_stats<<<NN / 256, blk, 0, stream>>>(hv, De, ew, msum, Dv, Dv2, row_cnt, row_fill);
    scatter_deg<<<NN * TK / 256, blk, 0, stream>>>(eidx, hv, ew, Dv, Dv2, row_cnt);
    scan_deg<<<1, blk, 0, stream>>>(row_cnt, row_start, Dv, Dv2, dvis);
    fill_csr<<<NN * TK / 256, blk, 0, stream>>>(eidx, hv, row_start, row_fill, csr_e, csr_w);

    // ---- cheb conv 1: M over [G1|G2] (F=512), then M over MG2 (F=256) ----
    eg(Gbuf + 256, 192, et1, 128, 512, 1);
    rg(et1, 128, MG12, 128, 512, 1);
    eg(MG12 + 256, 128, et2, 64, 256, 1);
    rg(et2, 64, MMG2, 64, 256, 1);
    cheb_combine<<<(NN * 64 + 255) / 256, blk, 0, stream>>>(
        Gbuf, 192, MG12, 128, Gbuf + 512, 192, MMG2, 64,
        c1b, E1, E2, nullptr, 0, x1c, 256, NN * 64);

    // ---- cheb conv 2: GEMM x1c -> H0|H1|H2 (ldc=384), then M ----
    {
        BT bt{};
        bt.A[0] = x1c; bt.A[1] = x1c; bt.A[2] = x1c;
        bt.Bw[0] = c2wc0; bt.Bw[1] = c2wc1; bt.Bw[2] = c2wc2;
        bt.Cf[0] = Hb; bt.Cf[1] = Hb + 128; bt.Cf[2] = Hb + 256;
        bt.Ka[0] = bt.Ka[1] = bt.Ka[2] = 512;
        bt.ldc = 384;
        gemm_bt<<<dim3(2, 24, 3), blk, 0, stream>>>(bt, nullptr, NN, 128, 0, 1, 0);
    }
    eg(Hb + 128, 96, et3, 64, 256, 1);
    rg(et3, 64, MH12, 64, 256, 1);
    eg(MH12 + 128, 64, et4, 32, 128, 1);
    rg(et4, 32, MMH2, 32, 128, 1);
    cheb_combine<<<(NN * 32 + 255) / 256, blk, 0, stream>>>(
        Hb, 96, MH12, 64, Hb + 256, 96, MMH2, 32,
        c2b, E1, E2, x2, 32, nullptr, 128, NN * 32);

    // ---- heads ----
    rhead<<<NN / 16, blk, 0, stream>>>(x2, rw1, rb1, rw2, rb2, r);
    ahead<<<NN / 32, blk, 0, stream>>>(r, aw1, ab1, aw2, ab2, out);
    gemm_mf<<<dim3(4, 24, 2), blk, 0, stream>>>(
        r, dw1, nullptr, nullptr, dpart, NN, 256, 64, 64, 256, 256, 32, 1.f, 0, 0);
    gemm_epi<<<((size_t)NN * 256 + 255) / 256, blk, 0, stream>>>(
        dpart, db1, h, hc, NN, 256, 256, 256, 2, 1.f, 1, 0);
    {
        BT bt{};
        bt.A[0] = hc; bt.Bw[0] = dw2c;
        bt.bias[0] = db2; bt.Cf[0] = recon;
        bt.Ka[0] = 512; bt.ldc = 768;
        gemm_bt<<<dim3(12, 24, 1), blk, 0, stream>>>(bt, nullptr, NN, 768, 0, 1, 0);
    }
    mse_reduce4<<<512, blk, 0, stream>>>(recon, feats, msum);

    // ---- spectral cut ----
    eg(r, 16, et5, 16, 64, 0);
    rg(et5, 16, yspec, 16, 64, 0);
    spectral_cols<<<64, blk, 0, stream>>>(r, yspec, Dv2, numb, denb);
    finals_kernel<<<1, 64, 0, stream>>>(msum, numb, denb, out);
}

// Round 11
// 409.546 us; speedup vs baseline: 2.1043x; 1.1322x over previous
//
#include <hip/hip_runtime.h>
#include <cmath>

#define NN   3072
#define HIDD 256
#define TK   16
#define FEAT 768   // 3*HID

typedef __attribute__((ext_vector_type(8))) short bf16x8;
typedef __attribute__((ext_vector_type(4))) float f32x4;

__device__ inline unsigned short f2bf(float x) {
    unsigned u = __float_as_uint(x);
    unsigned r = (u + 0x7FFFu + ((u >> 16) & 1u)) >> 16;   // RNE
    return (unsigned short)r;
}
__device__ inline float bf2f(unsigned short h) {
    return __uint_as_float(((unsigned)h) << 16);
}

// ---------------------------------------------------------------- pool (+ all zero-init)
__global__ void pool_kernel(const float* __restrict__ img, float* __restrict__ p,
                            float* __restrict__ Dv, float* __restrict__ Dv2,
                            int* __restrict__ row_cnt, int* __restrict__ row_fill,
                            float* __restrict__ csum, float* __restrict__ numb,
                            float* __restrict__ msum) {
    int idx = blockIdx.x * 256 + threadIdx.x;
    if (idx < NN) { Dv[idx] = 0.f; Dv2[idx] = 0.f; row_cnt[idx] = 0; row_fill[idx] = 0; }
    if (idx < 2 * FEAT) csum[idx] = 0.f;     // csum | csum2 contiguous
    if (idx < 128) numb[idx] = 0.f;          // numb | denb contiguous
    if (idx == 0) msum[0] = 0.f;
    if (idx >= NN * 192) return;
    int b = idx / 192, rem = idx % 192;
    int c = rem >> 6, oy = (rem >> 3) & 7, ox = rem & 7;
    const float* base = img + (((size_t)b * 3 + c) * 32 + oy * 4) * 32 + ox * 4;
    float s = 0.f;
#pragma unroll
    for (int iy = 0; iy < 4; iy++)
#pragma unroll
        for (int ix = 0; ix < 4; ix++) s += base[iy * 32 + ix];
    p[idx] = s * 0.0625f;
}

// ---------------------------------------------------------------- batched input split (3 jobs)
__global__ void split_rows3(const float* __restrict__ X0, short* __restrict__ C0,
                            const float* __restrict__ X1, short* __restrict__ C1,
                            const float* __restrict__ X2, short* __restrict__ C2) {
    int i = blockIdx.x * 256 + threadIdx.x;
    const float* X; short* Xc; int K;
    if (i < NN * 48) { X = X0; Xc = C0; K = 192; }
    else if (i < NN * 240) { X = X1; Xc = C1; K = 768; i -= NN * 48; }
    else if (i < NN * 304) { X = X2; Xc = C2; K = 256; i -= NN * 240; }
    else return;
    int K4 = K >> 2;
    int m = i / K4, f = i - m * K4;
    float4 v = *(const float4*)(X + (size_t)m * K + f * 4);
    unsigned short h0 = f2bf(v.x), h1 = f2bf(v.y), h2 = f2bf(v.z), h3 = f2bf(v.w);
    *(short4*)(Xc + (size_t)m * 2 * K + f * 4) =
        make_short4((short)h0, (short)h1, (short)h2, (short)h3);
    *(short4*)(Xc + (size_t)m * 2 * K + K + f * 4) =
        make_short4((short)f2bf(v.x - bf2f(h0)), (short)f2bf(v.y - bf2f(h1)),
                    (short)f2bf(v.z - bf2f(h2)), (short)f2bf(v.w - bf2f(h3)));
}

// ---------------------------------------------------------------- batched weight transpose+split
struct WJ { const float* W; short* Wc; int K; int N; };
struct WJobs { WJ j[14]; };

__global__ void wsplitT(WJobs js) {
    WJ jb = js.j[blockIdx.z];
    int tk = blockIdx.x * 32, tn = blockIdx.y * 32;
    if (tk >= jb.K || tn >= jb.N) return;
    __shared__ float t[32][33];
    int kk = threadIdx.x >> 3, nn = (threadIdx.x & 7) * 4;
    float4 v = *(const float4*)(jb.W + (size_t)(tk + kk) * jb.N + tn + nn);
    t[kk][nn + 0] = v.x; t[kk][nn + 1] = v.y; t[kk][nn + 2] = v.z; t[kk][nn + 3] = v.w;
    __syncthreads();
    int n2 = threadIdx.x >> 3, k2 = (threadIdx.x & 7) * 4;
    float a = t[k2 + 0][n2], b = t[k2 + 1][n2], c = t[k2 + 2][n2], d = t[k2 + 3][n2];
    unsigned short h0 = f2bf(a), h1 = f2bf(b), h2 = f2bf(c), h3 = f2bf(d);
    size_t rowb = (size_t)(tn + n2) * 2 * jb.K;
    *(short4*)(jb.Wc + rowb + tk + k2) =
        make_short4((short)h0, (short)h1, (short)h2, (short)h3);
    *(short4*)(jb.Wc + rowb + jb.K + tk + k2) =
        make_short4((short)f2bf(a - bf2f(h0)), (short)f2bf(b - bf2f(h1)),
                    (short)f2bf(c - bf2f(h2)), (short)f2bf(d - bf2f(h3)));
}

// ---------------------------------------------------------------- pure bf16 NT GEMM (z-batched + split-K)
struct BT {
    const short* A[3];
    const short* Bw[3];
    const float* bias[3];
    float* Cf[3];
    short* Cc[3];
    int Ka[3];
    float scale[3];
    int ldc;
    int ccW;
};

__global__ __launch_bounds__(256) void gemm_bt(BT bt, float* __restrict__ P,
        int M, int Nc, int act, int KS, int Kc) {
    __shared__ short As[128 * 64];
    __shared__ short Bs[64 * 64];
    int zz = blockIdx.z, s = 0;
    if (KS > 1) { zz = blockIdx.z / KS; s = blockIdx.z % KS; }
    const short* A = bt.A[zz];
    const short* B = bt.Bw[zz];
    int Ka = bt.Ka[zz];
    int kbeg = s * Kc;
    int kend = (KS > 1) ? min(Ka, kbeg + Kc) : Ka;
    int tid = threadIdx.x, wave = tid >> 6, lane = tid & 63;
    int wm = (wave >> 1) * 64, wn = (wave & 1) * 32;
    int lrow = lane & 15, lk = lane >> 4;
    int m0 = blockIdx.y * 128, n0 = blockIdx.x * 64;
    f32x4 acc[4][2] = {};

    for (int k0 = kbeg; k0 < kend; k0 += 64) {
#pragma unroll
        for (int i = 0; i < 4; i++) {
            int q = tid + i * 256;
            int row = q >> 3, c = q & 7;
            int dst = row * 128 + ((c ^ (row & 7)) << 4);
            *(float4*)((char*)As + dst) =
                *(const float4*)((const char*)A + (((size_t)(m0 + row) * Ka + k0) << 1) + (c << 4));
        }
#pragma unroll
        for (int i = 0; i < 2; i++) {
            int q = tid + i * 256;
            int row = q >> 3, c = q & 7;
            int dst = row * 128 + ((c ^ (row & 7)) << 4);
            *(float4*)((char*)Bs + dst) =
                *(const float4*)((const char*)B + (((size_t)(n0 + row) * Ka + k0) << 1) + (c << 4));
        }
        __syncthreads();
#pragma unroll
        for (int kk = 0; kk < 2; kk++) {
            int ck = kk * 4 + lk;
            bf16x8 af[4], bg[2];
#pragma unroll
            for (int t = 0; t < 4; t++) {
                int ra = wm + t * 16 + lrow;
                af[t] = *(const bf16x8*)((const char*)As + ra * 128 + ((ck ^ (ra & 7)) << 4));
            }
#pragma unroll
            for (int u = 0; u < 2; u++) {
                int rb = wn + u * 16 + lrow;
                bg[u] = *(const bf16x8*)((const char*)Bs + rb * 128 + ((ck ^ (rb & 7)) << 4));
            }
#pragma unroll
            for (int i2 = 0; i2 < 4; i2++)
#pragma unroll
                for (int j2 = 0; j2 < 2; j2++)
                    acc[i2][j2] = __builtin_amdgcn_mfma_f32_16x16x32_bf16(af[i2], bg[j2], acc[i2][j2], 0, 0, 0);
        }
        __syncthreads();
    }

    if (P) {
        float sc = bt.scale[zz];
        float* Pp = P + (size_t)(zz * KS + s) * M * Nc;
#pragma unroll
        for (int i2 = 0; i2 < 4; i2++) {
            int gmb = m0 + wm + i2 * 16 + lk * 4;
#pragma unroll
            for (int j2 = 0; j2 < 2; j2++) {
                int gn = n0 + wn + j2 * 16 + lrow;
#pragma unroll
                for (int rg = 0; rg < 4; rg++)
                    Pp[(size_t)(gmb + rg) * Nc + gn] = sc * acc[i2][j2][rg];
            }
        }
    } else {
        const float* bias = bt.bias[zz];
        float* Cf = bt.Cf[zz];
        short* Cc = bt.Cc[zz];
#pragma unroll
        for (int i2 = 0; i2 < 4; i2++) {
            int gmb = m0 + wm + i2 * 16 + lk * 4;
#pragma unroll
            for (int j2 = 0; j2 < 2; j2++) {
                int gn = n0 + wn + j2 * 16 + lrow;
#pragma unroll
                for (int rg = 0; rg < 4; rg++) {
                    int gm = gmb + rg;
                    float x = acc[i2][j2][rg];
                    if (bias) x += bias[gn];
                    if (act == 1) x = fmaxf(x, 0.f);
                    else if (act == 2) x = tanhf(x);
                    if (Cf) Cf[(size_t)gm * bt.ldc + gn] = x;
                    if (Cc) {
                        unsigned short hi2 = f2bf(x);
                        Cc[(size_t)gm * 2 * bt.ccW + gn] = (short)hi2;
                        Cc[(size_t)gm * 2 * bt.ccW + bt.ccW + gn] = (short)f2bf(x - bf2f(hi2));
                    }
                }
            }
        }
    }
}

// ---------------------------------------------------------------- split-bf16 GEMM fp32-in, fused epilogue (dw1)
__global__ __launch_bounds__(256) void gemm_mf(
        const float* __restrict__ A, const float* __restrict__ B,
        const float* __restrict__ bias, short* __restrict__ Cc,
        int M, int Nc, int K, int lda, int ldb, int ccW) {
    __shared__ short Ah[128 * 40];
    __shared__ short Al[128 * 40];
    __shared__ short Bh[64 * 40];
    __shared__ short Bl[64 * 40];
    int tid = threadIdx.x, wave = tid >> 6, lane = tid & 63;
    int wm = (wave >> 1) * 64, wn = (wave & 1) * 32;
    int lrow = lane & 15, lk = lane >> 4;
    int m0 = blockIdx.y * 128, n0 = blockIdx.x * 64;
    f32x4 acc[4][2] = {};

    for (int k0 = 0; k0 < K; k0 += 32) {
#pragma unroll
        for (int i = 0; i < 4; i++) {
            int q = tid + i * 256;
            int rowm = q >> 3, kq = q & 7;
            float4 vv = *(const float4*)(A + (size_t)(m0 + rowm) * lda + k0 + kq * 4);
            unsigned short h0 = f2bf(vv.x), h1 = f2bf(vv.y), h2 = f2bf(vv.z), h3 = f2bf(vv.w);
            *(short4*)&Ah[rowm * 40 + kq * 4] = make_short4((short)h0, (short)h1, (short)h2, (short)h3);
            *(short4*)&Al[rowm * 40 + kq * 4] =
                make_short4((short)f2bf(vv.x - bf2f(h0)), (short)f2bf(vv.y - bf2f(h1)),
                            (short)f2bf(vv.z - bf2f(h2)), (short)f2bf(vv.w - bf2f(h3)));
        }
#pragma unroll
        for (int i = 0; i < 2; i++) {
            int q = tid + i * 256;
            int kk2 = q >> 4, nq = q & 15;
            float4 vv = *(const float4*)(B + (size_t)(k0 + kk2) * ldb + n0 + nq * 4);
            unsigned short h0 = f2bf(vv.x), h1 = f2bf(vv.y), h2 = f2bf(vv.z), h3 = f2bf(vv.w);
            Bh[(nq * 4 + 0) * 40 + kk2] = (short)h0;  Bl[(nq * 4 + 0) * 40 + kk2] = (short)f2bf(vv.x - bf2f(h0));
            Bh[(nq * 4 + 1) * 40 + kk2] = (short)h1;  Bl[(nq * 4 + 1) * 40 + kk2] = (short)f2bf(vv.y - bf2f(h1));
            Bh[(nq * 4 + 2) * 40 + kk2] = (short)h2;  Bl[(nq * 4 + 2) * 40 + kk2] = (short)f2bf(vv.z - bf2f(h2));
            Bh[(nq * 4 + 3) * 40 + kk2] = (short)h3;  Bl[(nq * 4 + 3) * 40 + kk2] = (short)f2bf(vv.w - bf2f(h3));
        }
        __syncthreads();
        bf16x8 ah[4], al[4], bh[2], bl[2];
#pragma unroll
        for (int t2 = 0; t2 < 4; t2++) {
            int ra = wm + t2 * 16 + lrow;
            ah[t2] = *(const bf16x8*)&Ah[ra * 40 + lk * 8];
            al[t2] = *(const bf16x8*)&Al[ra * 40 + lk * 8];
        }
#pragma unroll
        for (int u = 0; u < 2; u++) {
            int rb = wn + u * 16 + lrow;
            bh[u] = *(const bf16x8*)&Bh[rb * 40 + lk * 8];
            bl[u] = *(const bf16x8*)&Bl[rb * 40 + lk * 8];
        }
#pragma unroll
        for (int i2 = 0; i2 < 4; i2++)
#pragma unroll
            for (int j2 = 0; j2 < 2; j2++) {
                acc[i2][j2] = __builtin_amdgcn_mfma_f32_16x16x32_bf16(ah[i2], bh[j2], acc[i2][j2], 0, 0, 0);
                acc[i2][j2] = __builtin_amdgcn_mfma_f32_16x16x32_bf16(ah[i2], bl[j2], acc[i2][j2], 0, 0, 0);
                acc[i2][j2] = __builtin_amdgcn_mfma_f32_16x16x32_bf16(al[i2], bh[j2], acc[i2][j2], 0, 0, 0);
            }
        __syncthreads();
    }
#pragma unroll
    for (int i2 = 0; i2 < 4; i2++) {
        int gmb = m0 + wm + i2 * 16 + lk * 4;
#pragma unroll
        for (int j2 = 0; j2 < 2; j2++) {
            int gn = n0 + wn + j2 * 16 + lrow;
#pragma unroll
            for (int rg = 0; rg < 4; rg++) {
                float x = fmaxf(acc[i2][j2][rg] + bias[gn], 0.f);
                unsigned short hi2 = f2bf(x);
                Cc[(size_t)(gmb + rg) * 2 * ccW + gn] = (short)hi2;
                Cc[(size_t)(gmb + rg) * 2 * ccW + ccW + gn] = (short)f2bf(x - bf2f(hi2));
            }
        }
    }
}

// epilogue (gw split-K only)
__global__ void gemm_epi(const float* __restrict__ P, const float* __restrict__ bias,
                         float* __restrict__ C, int M, int Nc, int ldc, int KS,
                         int act) {
    int idx = blockIdx.x * 256 + threadIdx.x;
    if (idx >= M * Nc) return;
    int m = idx / Nc, n = idx - m * Nc;
    float v = 0.f;
    for (int s = 0; s < KS; s++) v += P[(size_t)s * M * Nc + idx];
    v += bias[n];
    if (act == 1) v = fmaxf(v, 0.f);
    else if (act == 2) v = tanhf(v);
    C[(size_t)m * ldc + n] = v;
}

// ---------------------------------------------------------------- sim = Zc @ Zc^T
__global__ __launch_bounds__(256) void sim_mfma(const short* __restrict__ Zc,
                                                float* __restrict__ S) {
    __shared__ short As[128 * 64];
    __shared__ short Bs[128 * 64];
    int tid = threadIdx.x;
    int wave = tid >> 6, lane = tid & 63;
    int wm = (wave >> 1) * 64, wn = (wave & 1) * 64;
    int m0 = blockIdx.y * 128, n0 = blockIdx.x * 128;
    int lrow = lane & 15, lk = lane >> 4;
    f32x4 acc[4][4] = {};

    for (int k0 = 0; k0 < 512; k0 += 64) {
#pragma unroll
        for (int i = 0; i < 4; i++) {
            int q = tid + i * 256;
            int row = q >> 3, c = q & 7;
            int dstoff = row * 128 + ((c ^ (row & 7)) << 4);
            const char* pa = (const char*)Zc + (((size_t)(m0 + row) * 512 + k0) << 1) + (c << 4);
            *(float4*)((char*)As + dstoff) = *(const float4*)pa;
            const char* pb = (const char*)Zc + (((size_t)(n0 + row) * 512 + k0) << 1) + (c << 4);
            *(float4*)((char*)Bs + dstoff) = *(const float4*)pb;
        }
        __syncthreads();
#pragma unroll
        for (int kk = 0; kk < 2; kk++) {
            int ck = kk * 4 + lk;
            bf16x8 af[4], bg[4];
#pragma unroll
            for (int t = 0; t < 4; t++) {
                int ra = wm + t * 16 + lrow;
                af[t] = *(const bf16x8*)((const char*)As + ra * 128 + ((ck ^ (ra & 7)) << 4));
                int rb = wn + t * 16 + lrow;
                bg[t] = *(const bf16x8*)((const char*)Bs + rb * 128 + ((ck ^ (rb & 7)) << 4));
            }
#pragma unroll
            for (int i2 = 0; i2 < 4; i2++)
#pragma unroll
                for (int j2 = 0; j2 < 4; j2++)
                    acc[i2][j2] = __builtin_amdgcn_mfma_f32_16x16x32_bf16(
                        af[i2], bg[j2], acc[i2][j2], 0, 0, 0);
        }
        __syncthreads();
    }
#pragma unroll
    for (int i2 = 0; i2 < 4; i2++) {
#pragma unroll
        for (int j2 = 0; j2 < 4; j2++) {
            int col = n0 + wn + j2 * 16 + lrow;
            int rowb = m0 + wm + i2 * 16 + lk * 4;
#pragma unroll
            for (int rg = 0; rg < 4; rg++)
                S[(size_t)(rowb + rg) * NN + col] = acc[i2][j2][rg];
        }
    }
}

// ---------------------------------------------------------------- BatchNorm
__global__ void bn_stats(const float* __restrict__ Y, float* __restrict__ csum,
                         float* __restrict__ csum2) {
    int t = threadIdx.x;
    float s0 = 0.f, s1 = 0.f, s2v = 0.f;
    float q0 = 0.f, q1 = 0.f, q2 = 0.f;
    int r0 = blockIdx.x * 16;
    for (int i = r0; i < r0 + 16; i++) {
        const float* row = Y + (size_t)i * FEAT;
        float a = row[t], b = row[t + 256], c = row[t + 512];
        s0 += a; q0 += a * a;
        s1 += b; q1 += b * b;
        s2v += c; q2 += c * c;
    }
    atomicAdd(&csum[t], s0);        atomicAdd(&csum2[t], q0);
    atomicAdd(&csum[t + 256], s1);  atomicAdd(&csum2[t + 256], q1);
    atomicAdd(&csum[t + 512], s2v); atomicAdd(&csum2[t + 512], q2);
}

__global__ void bn_fin(const float* __restrict__ csum, const float* __restrict__ csum2,
                       const float* __restrict__ g0, const float* __restrict__ g1,
                       const float* __restrict__ g2, const float* __restrict__ b0,
                       const float* __restrict__ b1, const float* __restrict__ b2,
                       float* __restrict__ scale, float* __restrict__ shift) {
    int j = blockIdx.x * 256 + threadIdx.x;
    if (j >= FEAT) return;
    float mean = csum[j] * (1.f / NN);
    float var = fmaxf(csum2[j] * (1.f / NN) - mean * mean, 0.f);
    int m = j >> 8, jj = j & 255;
    const float* g = (m == 0) ? g0 : (m == 1) ? g1 : g2;
    const float* bt = (m == 0) ? b0 : (m == 1) ? b1 : b2;
    float sc = g[jj] / sqrtf(var + 1e-5f);
    scale[j] = sc;
    shift[j] = bt[jj] - mean * sc;
}

__global__ void bn_norm(float* __restrict__ Y, const float* __restrict__ scale,
                        const float* __restrict__ shift, short* __restrict__ Yc) {
    __shared__ float sc[FEAT], sh[FEAT];
    for (int j = threadIdx.x; j < FEAT; j += 256) { sc[j] = scale[j]; sh[j] = shift[j]; }
    __syncthreads();
    const int n4 = NN * FEAT / 4;
    for (int i = blockIdx.x * 256 + threadIdx.x; i < n4; i += gridDim.x * 256) {
        float4 v = *(const float4*)(Y + (size_t)i * 4);
        int m = i / 192;
        int c = (i - m * 192) * 4;
        v.x = v.x * sc[c + 0] + sh[c + 0];
        v.y = v.y * sc[c + 1] + sh[c + 1];
        v.z = v.z * sc[c + 2] + sh[c + 2];
        v.w = v.w * sc[c + 3] + sh[c + 3];
        *(float4*)(Y + (size_t)i * 4) = v;
        unsigned short h0 = f2bf(v.x), h1 = f2bf(v.y), h2 = f2bf(v.z), h3 = f2bf(v.w);
        *(short4*)(Yc + (size_t)m * 1536 + c) =
            make_short4((short)h0, (short)h1, (short)h2, (short)h3);
        *(short4*)(Yc + (size_t)m * 1536 + 768 + c) =
            make_short4((short)f2bf(v.x - bf2f(h0)), (short)f2bf(v.y - bf2f(h1)),
                        (short)f2bf(v.z - bf2f(h2)), (short)f2bf(v.w - bf2f(h3)));
    }
}

// ---------------------------------------------------------------- row normalize z -> split-bf16 Zc
__global__ void rownorm_kernel(const float* __restrict__ Zin, short* __restrict__ Zc) {
    int i = blockIdx.x;
    int c = threadIdx.x;
    __shared__ float rs[256];
    __shared__ float inv;
    float v = Zin[(size_t)i * HIDD + c];
    rs[c] = v * v;
    __syncthreads();
    for (int st = 128; st > 0; st >>= 1) {
        if (c < st) rs[c] += rs[c + st];
        __syncthreads();
    }
    if (c == 0) inv = 1.f / (sqrtf(rs[0]) + 1e-8f);
    __syncthreads();
    float vn = v * inv;
    unsigned short hi = f2bf(vn);
    Zc[(size_t)i * 512 + c] = (short)hi;
    Zc[(size_t)i * 512 + 256 + c] = (short)f2bf(vn - bf2f(hi));
}

// ---------------------------------------------------------------- top-k via radix select (1 block/row)
// fuses: top-16 selection + sigmoid/threshold + De/ew + degree scatter
__global__ __launch_bounds__(256) void topk_hist(const float* __restrict__ S,
        float* __restrict__ hv, int* __restrict__ eidx,
        float* __restrict__ De, float* __restrict__ ew,
        float* __restrict__ Dv, float* __restrict__ Dv2, int* __restrict__ row_cnt) {
    int row = blockIdx.x, tid = threadIdx.x, wave = tid >> 6;
    __shared__ unsigned hist[4][256];
    __shared__ unsigned suf[256];
    __shared__ int sb, sAbove, scand;
    __shared__ unsigned ckey[128];
    __shared__ int ccol[128];
    __shared__ int ccnt;
    __shared__ float wsum;
    const float4* base = (const float4*)(S + (size_t)row * NN);
    unsigned key[12];
#pragma unroll
    for (int c = 0; c < 3; c++) {
        float4 q = base[tid + c * 256];
        unsigned u0 = __float_as_uint(q.x), u1 = __float_as_uint(q.y);
        unsigned u2 = __float_as_uint(q.z), u3 = __float_as_uint(q.w);
        key[c * 4 + 0] = u0 ^ ((((int)u0) >> 31) | 0x80000000u);
        key[c * 4 + 1] = u1 ^ ((((int)u1) >> 31) | 0x80000000u);
        key[c * 4 + 2] = u2 ^ ((((int)u2) >> 31) | 0x80000000u);
        key[c * 4 + 3] = u3 ^ ((((int)u3) >> 31) | 0x80000000u);
    }
    if (tid == 0) { ccnt = 0; wsum = 0.f; }
    unsigned prefix = 0;
    int cAbove = 0, shift = 24;
    for (int level = 0; level < 4; level++) {
        shift = 24 - 8 * level;
#pragma unroll
        for (int w2 = 0; w2 < 4; w2++) hist[w2][tid] = 0;
        __syncthreads();
#pragma unroll
        for (int i = 0; i < 12; i++) {
            bool in = (level == 0) || ((key[i] >> (shift + 8)) == prefix);
            if (in) atomicAdd(&hist[wave][(key[i] >> shift) & 255], 1u);
        }
        __syncthreads();
        suf[tid] = hist[0][tid] + hist[1][tid] + hist[2][tid] + hist[3][tid];
        __syncthreads();
        for (int s2 = 1; s2 < 256; s2 <<= 1) {
            unsigned a = (tid + s2 < 256) ? suf[tid + s2] : 0u;
            __syncthreads();
            suf[tid] += a;
            __syncthreads();
        }
        int need = 16 - cAbove;
        unsigned nxt = (tid < 255) ? suf[tid + 1] : 0u;
        if ((int)suf[tid] >= need && (tid == 255 || (int)nxt < need)) {
            sb = tid;
            sAbove = cAbove + (int)nxt;
            scand = cAbove + (int)suf[tid];
        }
        __syncthreads();
        prefix = (prefix << 8) | (unsigned)sb;
        cAbove = sAbove;
        if (scand <= 112 || shift == 0) break;
        __syncthreads();
    }
    __syncthreads();
#pragma unroll
    for (int i = 0; i < 12; i++) {
        if ((key[i] >> shift) >= prefix) {
            int idx = atomicAdd(&ccnt, 1);
            if (idx < 128) {
                ckey[idx] = key[i];
                ccol[idx] = tid * 4 + ((i >> 2) << 10) + (i & 3);
            }
        }
    }
    __syncthreads();
    int n = min(ccnt, 128);
    float w = 0.f;
    int mycol = 0, myrank = 1 << 30;
    if (tid < n) {
        unsigned ki = ckey[tid];
        int ci = ccol[tid];
        int rank = 0;
        for (int j = 0; j < n; j++) {
            unsigned kj = ckey[j];
            int cj = ccol[j];
            rank += (kj > ki) || (kj == ki && cj < ci);
        }
        if (rank < TK) {
            unsigned u = (ki & 0x80000000u) ? (ki ^ 0x80000000u) : ~ki;
            float val = __uint_as_float(u);
            float sg = 1.f / (1.f + expf(-val));
            w = (sg > 0.5f) ? sg : 0.f;
            hv[row * TK + rank] = w;
            eidx[row * TK + rank] = ci;
            myrank = rank; mycol = ci;
            atomicAdd(&wsum, w);
        }
    }
    __syncthreads();
    float s = wsum;
    if (tid == 0) { De[row] = s + 1e-8f; ew[row] = s * (1.f / TK); }
    float ewv = s * (1.f / TK);
    if (myrank < TK) {
        atomicAdd(&Dv[mycol], w * ewv);
        atomicAdd(&Dv2[mycol], w);
        atomicAdd(&row_cnt[mycol], 1);
    }
}

// ---------------------------------------------------------------- CSR scan + degree finalize
__global__ void scan_deg(const int* __restrict__ cnt, int* __restrict__ start,
                         const float* __restrict__ Dv, float* __restrict__ Dv2,
                         float* __restrict__ dvis) {
    __shared__ int part[256];
    int t = threadIdx.x;
    const int chunk = NN / 256;
    int s = 0;
    for (int i = t * chunk; i < (t + 1) * chunk; i++) {
        s += cnt[i];
        dvis[i] = 1.f / sqrtf(Dv[i] + 1e-8f);
        Dv2[i] += 1e-8f;
    }
    part[t] = s;
    __syncthreads();
    if (t == 0) {
        int a = 0;
        for (int i = 0; i < 256; i++) { int v = part[i]; part[i] = a; a += v; }
    }
    __syncthreads();
    int a = part[t];
    for (int i = t * chunk; i < (t + 1) * chunk; i++) { start[i] = a; a += cnt[i]; }
    if (t == 255) start[NN] = a;
}

__global__ void fill_csr(const int* __restrict__ eidx, const float* __restrict__ hv,
                         const int* __restrict__ start, int* __restrict__ fillc,
                         int* __restrict__ csr_e, float* __restrict__ csr_w) {
    int t = blockIdx.x * 256 + threadIdx.x;
    if (t >= NN * TK) return;
    int e = t >> 4;
    int v = eidx[t];
    int pos = atomicAdd(&fillc[v], 1);
    int pp = start[v] + pos;
    csr_e[pp] = e;
    csr_w[pp] = hv[t];
}

// ---------------------------------------------------------------- sparse H ops (ld-parameterized)
__global__ void edge_gather4(const int* __restrict__ eidx, const float* __restrict__ hv,
                             const float* __restrict__ De, const float* __restrict__ dvis,
                             const float* __restrict__ X, float* __restrict__ T,
                             int F4, int ldx4, int ldt4, int epb, int use_dvis) {
    int slot = threadIdx.x / F4;
    if (slot >= epb) return;
    int f = threadIdx.x - slot * F4;
    int e = blockIdx.x * epb + slot;
    const int* ei = eidx + e * TK;
    const float* hw = hv + e * TK;
    float ax = 0.f, ay = 0.f, az = 0.f, aw = 0.f;
#pragma unroll
    for (int j = 0; j < TK; j++) {
        int v = ei[j];
        float w = hw[j];
        if (use_dvis) w *= dvis[v];
        const float4 x = *(const float4*)(X + ((size_t)v * ldx4 + f) * 4);
        ax = fmaf(w, x.x, ax); ay = fmaf(w, x.y, ay);
        az = fmaf(w, x.z, az); aw = fmaf(w, x.w, aw);
    }
    float inv = 1.f / De[e];
    *(float4*)(T + ((size_t)e * ldt4 + f) * 4) = make_float4(ax * inv, ay * inv, az * inv, aw * inv);
}

__global__ void row_gather4(const int* __restrict__ start, const int* __restrict__ csr_e,
                            const float* __restrict__ csr_w, const float* __restrict__ dvis,
                            const float* __restrict__ T, float* __restrict__ Y,
                            int F4, int ldt4, int ldy4, int epb, int use_dvis) {
    int slot = threadIdx.x / F4;
    if (slot >= epb) return;
    int f = threadIdx.x - slot * F4;
    int v = blockIdx.x * epb + slot;
    int s0 = start[v], s1 = start[v + 1];
    float ax = 0.f, ay = 0.f, az = 0.f, aw = 0.f;
    for (int p = s0; p < s1; p++) {
        float w = csr_w[p];
        const float4 x = *(const float4*)(T + ((size_t)csr_e[p] * ldt4 + f) * 4);
        ax = fmaf(w, x.x, ax); ay = fmaf(w, x.y, ay);
        az = fmaf(w, x.z, az); aw = fmaf(w, x.w, aw);
    }
    float sc = use_dvis ? dvis[v] : 1.f;
    *(float4*)(Y + ((size_t)v * ldy4 + f) * 4) =
        make_float4(ax * sc, ay * sc, az * sc, aw * sc);
}

// spectral: row_gather (F=64, no dvis) fused with Rayleigh column sums
__global__ void rg_spec(const int* __restrict__ start, const int* __restrict__ csr_e,
                        const float* __restrict__ csr_w, const float* __restrict__ T,
                        const float* __restrict__ r, const float* __restrict__ Dv2,
                        float* __restrict__ numb, float* __restrict__ denb) {
    __shared__ float lsn[64], lsd[64];
    int tid = threadIdx.x;
    if (tid < 64) { lsn[tid] = 0.f; lsd[tid] = 0.f; }
    __syncthreads();
    int slot = tid >> 4, f = tid & 15;
    int v = blockIdx.x * 16 + slot;
    int s0 = start[v], s1 = start[v + 1];
    float ax = 0.f, ay = 0.f, az = 0.f, aw = 0.f;
    for (int p = s0; p < s1; p++) {
        float w = csr_w[p];
        const float4 x = *(const float4*)(T + ((size_t)csr_e[p] * 16 + f) * 4);
        ax = fmaf(w, x.x, ax); ay = fmaf(w, x.y, ay);
        az = fmaf(w, x.z, az); aw = fmaf(w, x.w, aw);
    }
    float d2 = Dv2[v];
    const float4 rv = *(const float4*)(r + (size_t)v * 64 + f * 4);
    atomicAdd(&lsn[f * 4 + 0], rv.x * (d2 * rv.x - ax));
    atomicAdd(&lsn[f * 4 + 1], rv.y * (d2 * rv.y - ay));
    atomicAdd(&lsn[f * 4 + 2], rv.z * (d2 * rv.z - az));
    atomicAdd(&lsn[f * 4 + 3], rv.w * (d2 * rv.w - aw));
    atomicAdd(&lsd[f * 4 + 0], d2 * rv.x * rv.x);
    atomicAdd(&lsd[f * 4 + 1], d2 * rv.y * rv.y);
    atomicAdd(&lsd[f * 4 + 2], d2 * rv.z * rv.z);
    atomicAdd(&lsd[f * 4 + 3], d2 * rv.w * rv.w);
    __syncthreads();
    if (tid < 64) {
        atomicAdd(&numb[tid], lsn[tid]);
        atomicAdd(&denb[tid], lsd[tid]);
    }
}

// ---------------------------------------------------------------- cheb combine
__global__ void cheb_combine(const float* __restrict__ A0, int ld0,
                             const float* __restrict__ A1, int ld1,
                             const float* __restrict__ A2, int ld2,
                             const float* __restrict__ A3, int ld3,
                             const float* __restrict__ bias, float e1, float e2,
                             float* __restrict__ Xf, int ldf, short* __restrict__ Xc,
                             int Fw, int total4) {
    int i = blockIdx.x * 256 + threadIdx.x;
    if (i >= total4) return;
    int F4 = Fw >> 2;
    int m = i / F4, n4 = i - m * F4;
    float4 g0 = *(const float4*)(A0 + ((size_t)m * ld0 + n4) * 4);
    float4 g1 = *(const float4*)(A1 + ((size_t)m * ld1 + n4) * 4);
    float4 g2 = *(const float4*)(A2 + ((size_t)m * ld2 + n4) * 4);
    float4 g3 = *(const float4*)(A3 + ((size_t)m * ld3 + n4) * 4);
    float4 b = *(const float4*)(bias + n4 * 4);
    float4 x;
    x.x = fmaxf(g0.x - e1 * g1.x - e2 * g2.x + 2.f * e2 * g3.x + b.x, 0.f);
    x.y = fmaxf(g0.y - e1 * g1.y - e2 * g2.y + 2.f * e2 * g3.y + b.y, 0.f);
    x.z = fmaxf(g0.z - e1 * g1.z - e2 * g2.z + 2.f * e2 * g3.z + b.z, 0.f);
    x.w = fmaxf(g0.w - e1 * g1.w - e2 * g2.w + 2.f * e2 * g3.w + b.w, 0.f);
    if (Xf) *(float4*)(Xf + ((size_t)m * ldf + n4) * 4) = x;
    if (Xc) {
        unsigned short h0 = f2bf(x.x), h1 = f2bf(x.y), h2 = f2bf(x.z), h3 = f2bf(x.w);
        *(short4*)(Xc + (size_t)m * 2 * Fw + n4 * 4) =
            make_short4((short)h0, (short)h1, (short)h2, (short)h3);
        *(short4*)(Xc + (size_t)m * 2 * Fw + Fw + n4 * 4) =
            make_short4((short)f2bf(x.x - bf2f(h0)), (short)f2bf(x.y - bf2f(h1)),
                        (short)f2bf(x.z - bf2f(h2)), (short)f2bf(x.w - bf2f(h3)));
    }
}

// ---------------------------------------------------------------- fused heads: r + scores
__global__ __launch_bounds__(256) void heads_fused(const float* __restrict__ x2,
        const float* __restrict__ rw1, const float* __restrict__ rb1,
        const float* __restrict__ rw2, const float* __restrict__ rb2,
        const float* __restrict__ aw1, const float* __restrict__ ab1,
        const float* __restrict__ aw2, const float* __restrict__ ab2,
        float* __restrict__ r, float* __restrict__ out) {
    __shared__ float w1[128 * 64];
    __shared__ float w2[64 * 64];
    __shared__ float a1[64 * 32];
    __shared__ float a2s[32];
    __shared__ float xr[4][128];
    int tid = threadIdx.x;
    for (int i = tid; i < 128 * 64 / 4; i += 256)
        *(float4*)&w1[i * 4] = *(const float4*)&rw1[i * 4];
    for (int i = tid; i < 64 * 64 / 4; i += 256)
        *(float4*)&w2[i * 4] = *(const float4*)&rw2[i * 4];
    for (int i = tid; i < 64 * 32 / 4; i += 256)
        *(float4*)&a1[i * 4] = *(const float4*)&aw1[i * 4];
    if (tid < 32) a2s[tid] = aw2[tid];
    __syncthreads();
    int wave = tid >> 6, lane = tid & 63;
    float ab2v = ab2[0];
    for (int rr = 0; rr < 4; rr++) {
        int row = blockIdx.x * 16 + rr * 4 + wave;
        *(float2*)&xr[wave][lane * 2] = *(const float2*)&x2[(size_t)row * 128 + lane * 2];
        float hacc = rb1[lane];
#pragma unroll 8
        for (int k = 0; k < 128; k++) hacc = fmaf(xr[wave][k], w1[k * 64 + lane], hacc);
        hacc = fmaxf(hacc, 0.f);
        xr[wave][lane] = hacc;
        float racc = rb2[lane];
#pragma unroll 8
        for (int k = 0; k < 64; k++) racc = fmaf(xr[wave][k], w2[k * 64 + lane], racc);
        r[(size_t)row * 64 + lane] = racc;
        xr[wave][lane] = racc;
        int g = lane >> 5, j = lane & 31;
        float hp = 0.f;
#pragma unroll 8
        for (int k = 0; k < 32; k++) hp = fmaf(xr[wave][g * 32 + k], a1[(g * 32 + k) * 32 + j], hp);
        hp += __shfl_xor(hp, 32);
        float hj = fmaxf(hp + ab1[j], 0.f) * a2s[j];
#pragma unroll
        for (int s2 = 1; s2 < 32; s2 <<= 1) hj += __shfl_xor(hj, s2);
        if (lane == 0) out[row] = 1.f / (1.f + expf(-(hj + ab2v)));
    }
}

// ---------------------------------------------------------------- reductions
__global__ void mse_reduce4(const float* __restrict__ a, const float* __restrict__ b,
                            float* __restrict__ sum) {
    __shared__ float rs[256];
    float s = 0.f;
    const int n4 = NN * FEAT / 4;
    for (int i = blockIdx.x * 256 + threadIdx.x; i < n4; i += gridDim.x * 256) {
        const float4 x = *(const float4*)(a + (size_t)i * 4);
        const float4 y = *(const float4*)(b + (size_t)i * 4);
        float dx = x.x - y.x, dy = x.y - y.y, dz = x.z - y.z, dw = x.w - y.w;
        s += dx * dx + dy * dy + dz * dz + dw * dw;
    }
    rs[threadIdx.x] = s;
    __syncthreads();
    for (int st = 128; st > 0; st >>= 1) {
        if (threadIdx.x < st) rs[threadIdx.x] += rs[threadIdx.x + st];
        __syncthreads();
    }
    if (threadIdx.x == 0) atomicAdd(sum, rs[0]);
}

__global__ void finals_kernel(const float* __restrict__ msum, const float* __restrict__ numb,
                              const float* __restrict__ denb, float* __restrict__ out) {
    if (threadIdx.x == 0 && blockIdx.x == 0) {
        float s = 0.f;
        for (int c = 0; c < 64; c++) s += numb[c] / (denb[c] + 1e-8f);
        out[NN + 1] = s * (1.f / 64.f);
        out[NN] = msum[0] * (1.f / ((float)NN * FEAT));
    }
}

// ================================================================ launch
extern "C" void kernel_launch(void* const* d_in, const int* in_sizes, int n_in,
                              void* d_out, int out_size, void* d_ws, size_t ws_size,
                              hipStream_t stream) {
    const float* images = (const float*)d_in[0];
    const float* text   = (const float*)d_in[1];
    const float* signal = (const float*)d_in[2];
    const float* iw1 = (const float*)d_in[3];  const float* ib1 = (const float*)d_in[4];
    const float* iw2 = (const float*)d_in[5];  const float* ib2 = (const float*)d_in[6];
    const float* ig  = (const float*)d_in[7];  const float* ibeta = (const float*)d_in[8];
    const float* tw1 = (const float*)d_in[9];  const float* tb1 = (const float*)d_in[10];
    const float* tw2 = (const float*)d_in[11]; const float* tb2 = (const float*)d_in[12];
    const float* tg  = (const float*)d_in[13]; const float* tbeta = (const float*)d_in[14];
    const float* sw1 = (const float*)d_in[15]; const float* sb1 = (const float*)d_in[16];
    const float* sw2 = (const float*)d_in[17]; const float* sb2 = (const float*)d_in[18];
    const float* sg  = (const float*)d_in[19]; const float* sbeta = (const float*)d_in[20];
    const float* gw  = (const float*)d_in[21]; const float* gb = (const float*)d_in[22];
    const float* c1w = (const float*)d_in[23]; const float* c1b = (const float*)d_in[24];
    const float* c2w = (const float*)d_in[25]; const float* c2b = (const float*)d_in[26];
    const float* rw1 = (const float*)d_in[27]; const float* rb1 = (const float*)d_in[28];
    const float* rw2 = (const float*)d_in[29]; const float* rb2 = (const float*)d_in[30];
    const float* aw1 = (const float*)d_in[31]; const float* ab1 = (const float*)d_in[32];
    const float* aw2 = (const float*)d_in[33]; const float* ab2 = (const float*)d_in[34];
    const float* dw1 = (const float*)d_in[35]; const float* db1 = (const float*)d_in[36];
    const float* dw2 = (const float*)d_in[37]; const float* db2 = (const float*)d_in[38];
    float* out = (float*)d_out;

    float* wsf = (float*)d_ws;
    size_t off = 0;
    auto AF = [&](size_t n) { float* q = wsf + off; off += n; return q; };
    float* feats  = AF((size_t)NN * FEAT);
    float* simbuf = AF((size_t)NN * NN);
    float* p      = AF((size_t)NN * 192);
    float* z      = AF((size_t)NN * HIDD);
    float* x2     = AF((size_t)NN * 128);
    float* r      = AF((size_t)NN * 64);
    float* hv     = AF((size_t)NN * TK);
    float* ew     = AF(NN);
    float* De     = AF(NN);
    float* Dv     = AF(NN);
    float* Dv2    = AF(NN);
    float* dvis   = AF(NN);
    float* csr_w  = AF((size_t)NN * TK);
    float* numb   = AF(64);
    float* denb   = AF(64);
    float* msum   = AF(1);
    float* csum   = AF(FEAT);
    float* csum2  = AF(FEAT);
    float* bsc    = AF(FEAT);
    float* bsh    = AF(FEAT);
    short* x1c    = (short*)AF((size_t)NN * 256);     // [NN][512] shorts; also reused as hc
    short* wcbuf  = (short*)AF(1589248);
    float* Gbuf   = AF((size_t)NN * FEAT);            // G0|G1|G2, ld 768
    int* eidx     = (int*)(wsf + off); off += (size_t)NN * TK;
    int* csr_e    = (int*)(wsf + off); off += (size_t)NN * TK;
    int* row_cnt  = (int*)(wsf + off); off += NN;
    int* row_fill = (int*)(wsf + off); off += NN;
    int* row_start= (int*)(wsf + off); off += NN + 1;

    short* Zc = (short*)z;
    short* hc = x1c;   // reuse post-cheb2

    // weight split sub-buffers
    short* wp = wcbuf;
    auto AW = [&](size_t n) { short* q = wp; wp += n; return q; };
    short* iw1c = AW((size_t)256 * 384);
    short* tw1c = AW((size_t)256 * 1536);
    short* sw1c = AW((size_t)256 * 512);
    short* iw2c = AW((size_t)256 * 512);
    short* tw2c = AW((size_t)256 * 512);
    short* sw2c = AW((size_t)256 * 512);
    short* gwc  = AW((size_t)256 * 1536);
    short* c1wc0 = AW((size_t)256 * 1536);
    short* c1wc1 = AW((size_t)256 * 1536);
    short* c1wc2 = AW((size_t)256 * 1536);
    short* c2wc0 = AW((size_t)128 * 512);
    short* c2wc1 = AW((size_t)128 * 512);
    short* c2wc2 = AW((size_t)128 * 512);
    short* dw2c  = AW((size_t)768 * 512);

    // pre-sim simbuf layout (shorts)
    short* sb2_ = (short*)simbuf;
    short* pc  = sb2_;
    short* tc  = pc + (size_t)NN * 384;
    short* scb = tc + (size_t)NN * 1536;
    short* hc0 = scb + (size_t)NN * 512;
    short* hc1 = hc0 + (size_t)NN * 512;
    short* hc2 = hc1 + (size_t)NN * 512;
    short* featsc_pre = hc2 + (size_t)NN * 512;
    float* gpart = simbuf;

    // post-topk slabs (floats)
    float* et1   = simbuf;                              // NN*512
    float* MG12  = simbuf + (size_t)NN * 512;           // NN*512
    float* et2   = simbuf + (size_t)NN * 1024;          // NN*256
    float* MMG2  = simbuf + (size_t)NN * 1280;          // NN*256
    float* Hb    = simbuf;                              // NN*384 (cheb2)
    float* et3   = simbuf + (size_t)NN * 384;
    float* MH12  = simbuf + (size_t)NN * 640;
    float* et4   = simbuf + (size_t)NN * 896;
    float* MMH2  = simbuf + (size_t)NN * 1024;
    float* recon = simbuf;                              // NN*768 (heads phase)
    float* et5   = simbuf + (size_t)NN * 2048;

    dim3 blk(256);
    auto eg = [&](const float* X, int ldx4, float* T, int ldt4, int F, int use_dvis) {
        int F4 = F / 4, epb = 256 / F4 < 1 ? 1 : 256 / F4;
        edge_gather4<<<NN / epb, dim3(F4 * epb), 0, stream>>>(
            eidx, hv, De, dvis, X, T, F4, ldx4, ldt4, epb, use_dvis);
    };
    auto rg = [&](const float* T, int ldt4, float* Y, int ldy4, int F, int use_dvis) {
        int F4 = F / 4, epb = 256 / F4 < 1 ? 1 : 256 / F4;
        row_gather4<<<NN / epb, dim3(F4 * epb), 0, stream>>>(
            row_start, csr_e, csr_w, dvis, T, Y, F4, ldt4, ldy4, epb, use_dvis);
    };

    const float E1 = 0.60653065971f;  // exp(-0.5)
    const float E2 = 0.36787944117f;  // exp(-1.0)

    // ---- pool + zero-init + conversions ----
    pool_kernel<<<(NN * 192 + 255) / 256, blk, 0, stream>>>(
        images, p, Dv, Dv2, row_cnt, row_fill, csum, numb, msum);
    {
        WJobs wj{};
        wj.j[0] = {iw1, iw1c, 192, 256};
        wj.j[1] = {tw1, tw1c, 768, 256};
        wj.j[2] = {sw1, sw1c, 256, 256};
        wj.j[3] = {iw2, iw2c, 256, 256};
        wj.j[4] = {tw2, tw2c, 256, 256};
        wj.j[5] = {sw2, sw2c, 256, 256};
        wj.j[6] = {gw,  gwc,  768, 256};
        wj.j[7] = {c1w, c1wc0, 768, 256};
        wj.j[8] = {c1w + (size_t)FEAT * HIDD, c1wc1, 768, 256};
        wj.j[9] = {c1w + (size_t)2 * FEAT * HIDD, c1wc2, 768, 256};
        wj.j[10] = {c2w, c2wc0, 256, 128};
        wj.j[11] = {c2w + (size_t)HIDD * 128, c2wc1, 256, 128};
        wj.j[12] = {c2w + (size_t)2 * HIDD * 128, c2wc2, 256, 128};
        wj.j[13] = {dw2, dw2c, 256, 768};
        wsplitT<<<dim3(24, 24, 14), blk, 0, stream>>>(wj);
    }
    split_rows3<<<(NN * 304 + 255) / 256, blk, 0, stream>>>(p, pc, text, tc, signal, scb);

    // ---- MLP layer 1 + 2 ----
    {
        BT bt{};
        bt.A[0] = pc;   bt.A[1] = tc;   bt.A[2] = scb;
        bt.Bw[0] = iw1c; bt.Bw[1] = tw1c; bt.Bw[2] = sw1c;
        bt.bias[0] = ib1; bt.bias[1] = tb1; bt.bias[2] = sb1;
        bt.Cc[0] = hc0; bt.Cc[1] = hc1; bt.Cc[2] = hc2;
        bt.Ka[0] = 384; bt.Ka[1] = 1536; bt.Ka[2] = 512;
        bt.ccW = 256;
        gemm_bt<<<dim3(4, 24, 3), blk, 0, stream>>>(bt, nullptr, NN, 256, 1, 1, 0);
    }
    {
        BT bt{};
        bt.A[0] = hc0;  bt.A[1] = hc1;  bt.A[2] = hc2;
        bt.Bw[0] = iw2c; bt.Bw[1] = tw2c; bt.Bw[2] = sw2c;
        bt.bias[0] = ib2; bt.bias[1] = tb2; bt.bias[2] = sb2;
        bt.Cf[0] = feats; bt.Cf[1] = feats + 256; bt.Cf[2] = feats + 512;
        bt.Ka[0] = bt.Ka[1] = bt.Ka[2] = 512;
        bt.ldc = FEAT;
        gemm_bt<<<dim3(4, 24, 3), blk, 0, stream>>>(bt, nullptr, NN, 256, 0, 1, 0);
    }
    bn_stats<<<NN / 16, blk, 0, stream>>>(feats, csum, csum2);
    bn_fin<<<3, blk, 0, stream>>>(csum, csum2, ig, tg, sg, ibeta, tbeta, sbeta, bsc, bsh);
    bn_norm<<<1024, blk, 0, stream>>>(feats, bsc, bsh, featsc_pre);

    // ---- generator GEMM + cheb1 G-GEMMs (pre-sim) ----
    {
        BT bt{};
        bt.A[0] = featsc_pre; bt.Bw[0] = gwc;
        bt.Ka[0] = 1536; bt.scale[0] = 1.f;
        gemm_bt<<<dim3(4, 24, 4), blk, 0, stream>>>(bt, gpart, NN, 256, 0, 4, 384);
        gemm_epi<<<((size_t)NN * 256 + 255) / 256, blk, 0, stream>>>(
            gpart, gb, z, NN, 256, 256, 4, 2);
    }
    {
        BT bt{};
        bt.A[0] = featsc_pre; bt.A[1] = featsc_pre; bt.A[2] = featsc_pre;
        bt.Bw[0] = c1wc0; bt.Bw[1] = c1wc1; bt.Bw[2] = c1wc2;
        bt.Cf[0] = Gbuf; bt.Cf[1] = Gbuf + 256; bt.Cf[2] = Gbuf + 512;
        bt.Ka[0] = bt.Ka[1] = bt.Ka[2] = 1536;
        bt.ldc = 768;
        gemm_bt<<<dim3(4, 24, 3), blk, 0, stream>>>(bt, nullptr, NN, 256, 0, 1, 0);
    }
    rownorm_kernel<<<NN, blk, 0, stream>>>(z, Zc);
    sim_mfma<<<dim3(NN / 128, NN / 128), blk, 0, stream>>>(Zc, simbuf);
    topk_hist<<<NN, blk, 0, stream>>>(simbuf, hv, eidx, De, ew, Dv, Dv2, row_cnt);

    // ---- CSR ----
    scan_deg<<<1, blk, 0, stream>>>(row_cnt, row_start, Dv, Dv2, dvis);
    fill_csr<<<NN * TK / 256, blk, 0, stream>>>(eidx, hv, row_start, row_fill, csr_e, csr_w);

    // ---- cheb conv 1 ----
    eg(Gbuf + 256, 192, et1, 128, 512, 1);
    rg(et1, 128, MG12, 128, 512, 1);
    eg(MG12 + 256, 128, et2, 64, 256, 1);
    rg(et2, 64, MMG2, 64, 256, 1);
    cheb_combine<<<(NN * 64 + 255) / 256, blk, 0, stream>>>(
        Gbuf, 192, MG12, 128, Gbuf + 512, 192, MMG2, 64,
        c1b, E1, E2, nullptr, 0, x1c, 256, NN * 64);

    // ---- cheb conv 2 ----
    {
        BT bt{};
        bt.A[0] = x1c; bt.A[1] = x1c; bt.A[2] = x1c;
        bt.Bw[0] = c2wc0; bt.Bw[1] = c2wc1; bt.Bw[2] = c2wc2;
        bt.Cf[0] = Hb; bt.Cf[1] = Hb + 128; bt.Cf[2] = Hb + 256;
        bt.Ka[0] = bt.Ka[1] = bt.Ka[2] = 512;
        bt.ldc = 384;
        gemm_bt<<<dim3(2, 24, 3), blk, 0, stream>>>(bt, nullptr, NN, 128, 0, 1, 0);
    }
    eg(Hb + 128, 96, et3, 64, 256, 1);
    rg(et3, 64, MH12, 64, 256, 1);
    eg(MH12 + 128, 64, et4, 32, 128, 1);
    rg(et4, 32, MMH2, 32, 128, 1);
    cheb_combine<<<(NN * 32 + 255) / 256, blk, 0, stream>>>(
        Hb, 96, MH12, 64, Hb + 256, 96, MMH2, 32,
        c2b, E1, E2, x2, 32, nullptr, 128, NN * 32);

    // ---- heads ----
    heads_fused<<<NN / 16, blk, 0, stream>>>(x2, rw1, rb1, rw2, rb2,
                                             aw1, ab1, aw2, ab2, r, out);
    gemm_mf<<<dim3(4, 24), blk, 0, stream>>>(r, dw1, db1, hc, NN, 256, 64, 64, 256, 256);
    {
        BT bt{};
        bt.A[0] = hc; bt.Bw[0] = dw2c;
        bt.bias[0] = db2; bt.Cf[0] = recon;
        bt.Ka[0] = 512; bt.ldc = 768;
        gemm_bt<<<dim3(12, 24, 1), blk, 0, stream>>>(bt, nullptr, NN, 768, 0, 1, 0);
    }
    mse_reduce4<<<512, blk, 0, stream>>>(recon, feats, msum);

    // ---- spectral cut (fused) ----
    eg(r, 16, et5, 16, 64, 0);
    rg_spec<<<NN / 16, blk, 0, stream>>>(row_start, csr_e, csr_w, et5, r, Dv2, numb, denb);
    finals_kernel<<<1, 64, 0, stream>>>(msum, numb, denb, out);
}

// Round 12
// 374.305 us; speedup vs baseline: 2.3025x; 1.0942x over previous
//
#include <hip/hip_runtime.h>
#include <cmath>

#define NN   3072
#define HIDD 256
#define TK   16
#define FEAT 768   // 3*HID

typedef __attribute__((ext_vector_type(8))) short bf16x8;
typedef __attribute__((ext_vector_type(4))) float f32x4;

__device__ inline unsigned short f2bf(float x) {
    unsigned u = __float_as_uint(x);
    unsigned r = (u + 0x7FFFu + ((u >> 16) & 1u)) >> 16;   // RNE
    return (unsigned short)r;
}
__device__ inline float bf2f(unsigned short h) {
    return __uint_as_float(((unsigned)h) << 16);
}

// ---------------------------------------------------------------- pool (+ all zero-init)
__global__ void pool_kernel(const float* __restrict__ img, float* __restrict__ p,
                            float* __restrict__ Dv, float* __restrict__ Dv2,
                            int* __restrict__ row_cnt, int* __restrict__ row_fill,
                            float* __restrict__ csum, float* __restrict__ numb,
                            float* __restrict__ msum) {
    int idx = blockIdx.x * 256 + threadIdx.x;
    if (idx < NN) { Dv[idx] = 0.f; Dv2[idx] = 0.f; row_cnt[idx] = 0; row_fill[idx] = 0; }
    if (idx < 2 * FEAT) csum[idx] = 0.f;     // csum | csum2 contiguous
    if (idx < 128) numb[idx] = 0.f;          // numb | denb contiguous
    if (idx == 0) msum[0] = 0.f;
    if (idx >= NN * 192) return;
    int b = idx / 192, rem = idx % 192;
    int c = rem >> 6, oy = (rem >> 3) & 7, ox = rem & 7;
    const float* base = img + (((size_t)b * 3 + c) * 32 + oy * 4) * 32 + ox * 4;
    float s = 0.f;
#pragma unroll
    for (int iy = 0; iy < 4; iy++)
#pragma unroll
        for (int ix = 0; ix < 4; ix++) s += base[iy * 32 + ix];
    p[idx] = s * 0.0625f;
}

// ---------------------------------------------------------------- batched input split (3 jobs)
__global__ void split_rows3(const float* __restrict__ X0, short* __restrict__ C0,
                            const float* __restrict__ X1, short* __restrict__ C1,
                            const float* __restrict__ X2, short* __restrict__ C2) {
    int i = blockIdx.x * 256 + threadIdx.x;
    const float* X; short* Xc; int K;
    if (i < NN * 48) { X = X0; Xc = C0; K = 192; }
    else if (i < NN * 240) { X = X1; Xc = C1; K = 768; i -= NN * 48; }
    else if (i < NN * 304) { X = X2; Xc = C2; K = 256; i -= NN * 240; }
    else return;
    int K4 = K >> 2;
    int m = i / K4, f = i - m * K4;
    float4 v = *(const float4*)(X + (size_t)m * K + f * 4);
    unsigned short h0 = f2bf(v.x), h1 = f2bf(v.y), h2 = f2bf(v.z), h3 = f2bf(v.w);
    *(short4*)(Xc + (size_t)m * 2 * K + f * 4) =
        make_short4((short)h0, (short)h1, (short)h2, (short)h3);
    *(short4*)(Xc + (size_t)m * 2 * K + K + f * 4) =
        make_short4((short)f2bf(v.x - bf2f(h0)), (short)f2bf(v.y - bf2f(h1)),
                    (short)f2bf(v.z - bf2f(h2)), (short)f2bf(v.w - bf2f(h3)));
}

// ---------------------------------------------------------------- batched weight transpose+split
struct WJ { const float* W; short* Wc; int K; int N; };
struct WJobs { WJ j[14]; };

__global__ void wsplitT(WJobs js) {
    WJ jb = js.j[blockIdx.z];
    int tk = blockIdx.x * 32, tn = blockIdx.y * 32;
    if (tk >= jb.K || tn >= jb.N) return;
    __shared__ float t[32][33];
    int kk = threadIdx.x >> 3, nn = (threadIdx.x & 7) * 4;
    float4 v = *(const float4*)(jb.W + (size_t)(tk + kk) * jb.N + tn + nn);
    t[kk][nn + 0] = v.x; t[kk][nn + 1] = v.y; t[kk][nn + 2] = v.z; t[kk][nn + 3] = v.w;
    __syncthreads();
    int n2 = threadIdx.x >> 3, k2 = (threadIdx.x & 7) * 4;
    float a = t[k2 + 0][n2], b = t[k2 + 1][n2], c = t[k2 + 2][n2], d = t[k2 + 3][n2];
    unsigned short h0 = f2bf(a), h1 = f2bf(b), h2 = f2bf(c), h3 = f2bf(d);
    size_t rowb = (size_t)(tn + n2) * 2 * jb.K;
    *(short4*)(jb.Wc + rowb + tk + k2) =
        make_short4((short)h0, (short)h1, (short)h2, (short)h3);
    *(short4*)(jb.Wc + rowb + jb.K + tk + k2) =
        make_short4((short)f2bf(a - bf2f(h0)), (short)f2bf(b - bf2f(h1)),
                    (short)f2bf(c - bf2f(h2)), (short)f2bf(d - bf2f(h3)));
}

// ---------------------------------------------------------------- job-based bf16 NT GEMM
// Per-job: C = act(A[Koff:Koff+Klen] . B^T[Koff:..] [+bias]); partial / Cf / Cc / fused-MSE.
struct BJ {
    const short* A;      // [M][sa]
    const short* Bw;     // [N][sb]
    const float* bias;
    float* Cf;
    short* Cc;
    const float* mseRef; // if set: accumulate (x-ref)^2 into msum; no C write
    int sa, sb, Koff, Klen;
    int act;             // 0 none, 1 relu, 2 tanh
    int ldc, ccW;
    int pslot;           // >=0: raw partial to P + pslot*M*Nc (scaled)
    float scale;
};
struct BTJ { BJ j[6]; };

__global__ __launch_bounds__(256) void gemm_btj(BTJ bt, float* __restrict__ P,
        float* __restrict__ msum, int M, int Nc) {
    __shared__ short As[128 * 64];
    __shared__ short Bs[64 * 64];
    BJ j = bt.j[blockIdx.z];
    int tid = threadIdx.x, wave = tid >> 6, lane = tid & 63;
    int wm = (wave >> 1) * 64, wn = (wave & 1) * 32;
    int lrow = lane & 15, lk = lane >> 4;
    int m0 = blockIdx.y * 128, n0 = blockIdx.x * 64;
    int kend = j.Koff + j.Klen;
    f32x4 acc[4][2] = {};

    for (int k0 = j.Koff; k0 < kend; k0 += 64) {
#pragma unroll
        for (int i = 0; i < 4; i++) {
            int q = tid + i * 256;
            int row = q >> 3, c = q & 7;
            int dst = row * 128 + ((c ^ (row & 7)) << 4);
            *(float4*)((char*)As + dst) =
                *(const float4*)((const char*)j.A + (((size_t)(m0 + row) * j.sa + k0) << 1) + (c << 4));
        }
#pragma unroll
        for (int i = 0; i < 2; i++) {
            int q = tid + i * 256;
            int row = q >> 3, c = q & 7;
            int dst = row * 128 + ((c ^ (row & 7)) << 4);
            *(float4*)((char*)Bs + dst) =
                *(const float4*)((const char*)j.Bw + (((size_t)(n0 + row) * j.sb + k0) << 1) + (c << 4));
        }
        __syncthreads();
#pragma unroll
        for (int kk = 0; kk < 2; kk++) {
            int ck = kk * 4 + lk;
            bf16x8 af[4], bg[2];
#pragma unroll
            for (int t = 0; t < 4; t++) {
                int ra = wm + t * 16 + lrow;
                af[t] = *(const bf16x8*)((const char*)As + ra * 128 + ((ck ^ (ra & 7)) << 4));
            }
#pragma unroll
            for (int u = 0; u < 2; u++) {
                int rb = wn + u * 16 + lrow;
                bg[u] = *(const bf16x8*)((const char*)Bs + rb * 128 + ((ck ^ (rb & 7)) << 4));
            }
#pragma unroll
            for (int i2 = 0; i2 < 4; i2++)
#pragma unroll
                for (int j2 = 0; j2 < 2; j2++)
                    acc[i2][j2] = __builtin_amdgcn_mfma_f32_16x16x32_bf16(af[i2], bg[j2], acc[i2][j2], 0, 0, 0);
        }
        __syncthreads();
    }

    if (j.pslot >= 0) {
        float* Pp = P + (size_t)j.pslot * M * Nc;
#pragma unroll
        for (int i2 = 0; i2 < 4; i2++) {
            int gmb = m0 + wm + i2 * 16 + lk * 4;
#pragma unroll
            for (int j2 = 0; j2 < 2; j2++) {
                int gn = n0 + wn + j2 * 16 + lrow;
#pragma unroll
                for (int rg = 0; rg < 4; rg++)
                    Pp[(size_t)(gmb + rg) * Nc + gn] = j.scale * acc[i2][j2][rg];
            }
        }
    } else if (j.mseRef) {
        float lsum = 0.f;
#pragma unroll
        for (int i2 = 0; i2 < 4; i2++) {
            int gmb = m0 + wm + i2 * 16 + lk * 4;
#pragma unroll
            for (int j2 = 0; j2 < 2; j2++) {
                int gn = n0 + wn + j2 * 16 + lrow;
#pragma unroll
                for (int rg = 0; rg < 4; rg++) {
                    float x = acc[i2][j2][rg] + j.bias[gn];
                    float d = x - j.mseRef[(size_t)(gmb + rg) * Nc + gn];
                    lsum += d * d;
                }
            }
        }
        float* rs = (float*)As;   // k-loop ended with barrier; As free
        rs[tid] = lsum;
        __syncthreads();
        for (int st = 128; st > 0; st >>= 1) {
            if (tid < st) rs[tid] += rs[tid + st];
            __syncthreads();
        }
        if (tid == 0) atomicAdd(msum, rs[0]);
    } else {
#pragma unroll
        for (int i2 = 0; i2 < 4; i2++) {
            int gmb = m0 + wm + i2 * 16 + lk * 4;
#pragma unroll
            for (int j2 = 0; j2 < 2; j2++) {
                int gn = n0 + wn + j2 * 16 + lrow;
#pragma unroll
                for (int rg = 0; rg < 4; rg++) {
                    int gm = gmb + rg;
                    float x = acc[i2][j2][rg];
                    if (j.bias) x += j.bias[gn];
                    if (j.act == 1) x = fmaxf(x, 0.f);
                    else if (j.act == 2) x = tanhf(x);
                    if (j.Cf) j.Cf[(size_t)gm * j.ldc + gn] = x;
                    if (j.Cc) {
                        unsigned short hi2 = f2bf(x);
                        j.Cc[(size_t)gm * 2 * j.ccW + gn] = (short)hi2;
                        j.Cc[(size_t)gm * 2 * j.ccW + j.ccW + gn] = (short)f2bf(x - bf2f(hi2));
                    }
                }
            }
        }
    }
}

// 3-partial epilogue: relu(P0+P1+P2+bias) -> split-bf16
__global__ void epi3(const float* __restrict__ P, const float* __restrict__ bias,
                     short* __restrict__ Cc, int M, int Nc, int ccW) {
    int idx = blockIdx.x * 256 + threadIdx.x;
    if (idx >= M * Nc) return;
    int m = idx / Nc, n = idx - m * Nc;
    float v = P[idx] + P[(size_t)M * Nc + idx] + P[(size_t)2 * M * Nc + idx] + bias[n];
    v = fmaxf(v, 0.f);
    unsigned short hi = f2bf(v);
    Cc[(size_t)m * 2 * ccW + n] = (short)hi;
    Cc[(size_t)m * 2 * ccW + ccW + n] = (short)f2bf(v - bf2f(hi));
}

// ---------------------------------------------------------------- split-bf16 GEMM fp32-in, fused epilogue (dw1)
__global__ __launch_bounds__(256) void gemm_mf(
        const float* __restrict__ A, const float* __restrict__ B,
        const float* __restrict__ bias, short* __restrict__ Cc,
        int M, int Nc, int K, int lda, int ldb, int ccW) {
    __shared__ short Ah[128 * 40];
    __shared__ short Al[128 * 40];
    __shared__ short Bh[64 * 40];
    __shared__ short Bl[64 * 40];
    int tid = threadIdx.x, wave = tid >> 6, lane = tid & 63;
    int wm = (wave >> 1) * 64, wn = (wave & 1) * 32;
    int lrow = lane & 15, lk = lane >> 4;
    int m0 = blockIdx.y * 128, n0 = blockIdx.x * 64;
    f32x4 acc[4][2] = {};

    for (int k0 = 0; k0 < K; k0 += 32) {
#pragma unroll
        for (int i = 0; i < 4; i++) {
            int q = tid + i * 256;
            int rowm = q >> 3, kq = q & 7;
            float4 vv = *(const float4*)(A + (size_t)(m0 + rowm) * lda + k0 + kq * 4);
            unsigned short h0 = f2bf(vv.x), h1 = f2bf(vv.y), h2 = f2bf(vv.z), h3 = f2bf(vv.w);
            *(short4*)&Ah[rowm * 40 + kq * 4] = make_short4((short)h0, (short)h1, (short)h2, (short)h3);
            *(short4*)&Al[rowm * 40 + kq * 4] =
                make_short4((short)f2bf(vv.x - bf2f(h0)), (short)f2bf(vv.y - bf2f(h1)),
                            (short)f2bf(vv.z - bf2f(h2)), (short)f2bf(vv.w - bf2f(h3)));
        }
#pragma unroll
        for (int i = 0; i < 2; i++) {
            int q = tid + i * 256;
            int kk2 = q >> 4, nq = q & 15;
            float4 vv = *(const float4*)(B + (size_t)(k0 + kk2) * ldb + n0 + nq * 4);
            unsigned short h0 = f2bf(vv.x), h1 = f2bf(vv.y), h2 = f2bf(vv.z), h3 = f2bf(vv.w);
            Bh[(nq * 4 + 0) * 40 + kk2] = (short)h0;  Bl[(nq * 4 + 0) * 40 + kk2] = (short)f2bf(vv.x - bf2f(h0));
            Bh[(nq * 4 + 1) * 40 + kk2] = (short)h1;  Bl[(nq * 4 + 1) * 40 + kk2] = (short)f2bf(vv.y - bf2f(h1));
            Bh[(nq * 4 + 2) * 40 + kk2] = (short)h2;  Bl[(nq * 4 + 2) * 40 + kk2] = (short)f2bf(vv.z - bf2f(h2));
            Bh[(nq * 4 + 3) * 40 + kk2] = (short)h3;  Bl[(nq * 4 + 3) * 40 + kk2] = (short)f2bf(vv.w - bf2f(h3));
        }
        __syncthreads();
        bf16x8 ah[4], al[4], bh[2], bl[2];
#pragma unroll
        for (int t2 = 0; t2 < 4; t2++) {
            int ra = wm + t2 * 16 + lrow;
            ah[t2] = *(const bf16x8*)&Ah[ra * 40 + lk * 8];
            al[t2] = *(const bf16x8*)&Al[ra * 40 + lk * 8];
        }
#pragma unroll
        for (int u = 0; u < 2; u++) {
            int rb = wn + u * 16 + lrow;
            bh[u] = *(const bf16x8*)&Bh[rb * 40 + lk * 8];
            bl[u] = *(const bf16x8*)&Bl[rb * 40 + lk * 8];
        }
#pragma unroll
        for (int i2 = 0; i2 < 4; i2++)
#pragma unroll
            for (int j2 = 0; j2 < 2; j2++) {
                acc[i2][j2] = __builtin_amdgcn_mfma_f32_16x16x32_bf16(ah[i2], bh[j2], acc[i2][j2], 0, 0, 0);
                acc[i2][j2] = __builtin_amdgcn_mfma_f32_16x16x32_bf16(ah[i2], bl[j2], acc[i2][j2], 0, 0, 0);
                acc[i2][j2] = __builtin_amdgcn_mfma_f32_16x16x32_bf16(al[i2], bh[j2], acc[i2][j2], 0, 0, 0);
            }
        __syncthreads();
    }
#pragma unroll
    for (int i2 = 0; i2 < 4; i2++) {
        int gmb = m0 + wm + i2 * 16 + lk * 4;
#pragma unroll
        for (int j2 = 0; j2 < 2; j2++) {
            int gn = n0 + wn + j2 * 16 + lrow;
#pragma unroll
            for (int rg = 0; rg < 4; rg++) {
                float x = fmaxf(acc[i2][j2][rg] + bias[gn], 0.f);
                unsigned short hi2 = f2bf(x);
                Cc[(size_t)(gmb + rg) * 2 * ccW + gn] = (short)hi2;
                Cc[(size_t)(gmb + rg) * 2 * ccW + ccW + gn] = (short)f2bf(x - bf2f(hi2));
            }
        }
    }
}

// ---------------------------------------------------------------- sim = Zc @ Zc^T
__global__ __launch_bounds__(256) void sim_mfma(const short* __restrict__ Zc,
                                                float* __restrict__ S) {
    __shared__ short As[128 * 64];
    __shared__ short Bs[128 * 64];
    int tid = threadIdx.x;
    int wave = tid >> 6, lane = tid & 63;
    int wm = (wave >> 1) * 64, wn = (wave & 1) * 64;
    int m0 = blockIdx.y * 128, n0 = blockIdx.x * 128;
    int lrow = lane & 15, lk = lane >> 4;
    f32x4 acc[4][4] = {};

    for (int k0 = 0; k0 < 512; k0 += 64) {
#pragma unroll
        for (int i = 0; i < 4; i++) {
            int q = tid + i * 256;
            int row = q >> 3, c = q & 7;
            int dstoff = row * 128 + ((c ^ (row & 7)) << 4);
            const char* pa = (const char*)Zc + (((size_t)(m0 + row) * 512 + k0) << 1) + (c << 4);
            *(float4*)((char*)As + dstoff) = *(const float4*)pa;
            const char* pb = (const char*)Zc + (((size_t)(n0 + row) * 512 + k0) << 1) + (c << 4);
            *(float4*)((char*)Bs + dstoff) = *(const float4*)pb;
        }
        __syncthreads();
#pragma unroll
        for (int kk = 0; kk < 2; kk++) {
            int ck = kk * 4 + lk;
            bf16x8 af[4], bg[4];
#pragma unroll
            for (int t = 0; t < 4; t++) {
                int ra = wm + t * 16 + lrow;
                af[t] = *(const bf16x8*)((const char*)As + ra * 128 + ((ck ^ (ra & 7)) << 4));
                int rb = wn + t * 16 + lrow;
                bg[t] = *(const bf16x8*)((const char*)Bs + rb * 128 + ((ck ^ (rb & 7)) << 4));
            }
#pragma unroll
            for (int i2 = 0; i2 < 4; i2++)
#pragma unroll
                for (int j2 = 0; j2 < 4; j2++)
                    acc[i2][j2] = __builtin_amdgcn_mfma_f32_16x16x32_bf16(
                        af[i2], bg[j2], acc[i2][j2], 0, 0, 0);
        }
        __syncthreads();
    }
#pragma unroll
    for (int i2 = 0; i2 < 4; i2++) {
#pragma unroll
        for (int j2 = 0; j2 < 4; j2++) {
            int col = n0 + wn + j2 * 16 + lrow;
            int rowb = m0 + wm + i2 * 16 + lk * 4;
#pragma unroll
            for (int rg = 0; rg < 4; rg++)
                S[(size_t)(rowb + rg) * NN + col] = acc[i2][j2][rg];
        }
    }
}

// ---------------------------------------------------------------- BatchNorm
__global__ void bn_stats(const float* __restrict__ Y, float* __restrict__ csum,
                         float* __restrict__ csum2) {
    int t = threadIdx.x;
    float s0 = 0.f, s1 = 0.f, s2v = 0.f;
    float q0 = 0.f, q1 = 0.f, q2 = 0.f;
    int r0 = blockIdx.x * 16;
    for (int i = r0; i < r0 + 16; i++) {
        const float* row = Y + (size_t)i * FEAT;
        float a = row[t], b = row[t + 256], c = row[t + 512];
        s0 += a; q0 += a * a;
        s1 += b; q1 += b * b;
        s2v += c; q2 += c * c;
    }
    atomicAdd(&csum[t], s0);        atomicAdd(&csum2[t], q0);
    atomicAdd(&csum[t + 256], s1);  atomicAdd(&csum2[t + 256], q1);
    atomicAdd(&csum[t + 512], s2v); atomicAdd(&csum2[t + 512], q2);
}

// bn_norm2: derives scale/shift per block (bn_fin folded in)
__global__ void bn_norm2(float* __restrict__ Y,
                         const float* __restrict__ csum, const float* __restrict__ csum2,
                         const float* __restrict__ g0, const float* __restrict__ g1,
                         const float* __restrict__ g2, const float* __restrict__ b0,
                         const float* __restrict__ b1, const float* __restrict__ b2,
                         short* __restrict__ Yc) {
    __shared__ float sc[FEAT], sh[FEAT];
    for (int jx = threadIdx.x; jx < FEAT; jx += 256) {
        float mean = csum[jx] * (1.f / NN);
        float var = fmaxf(csum2[jx] * (1.f / NN) - mean * mean, 0.f);
        int m = jx >> 8, jj = jx & 255;
        const float* g = (m == 0) ? g0 : (m == 1) ? g1 : g2;
        const float* bt = (m == 0) ? b0 : (m == 1) ? b1 : b2;
        float s = g[jj] / sqrtf(var + 1e-5f);
        sc[jx] = s;
        sh[jx] = bt[jj] - mean * s;
    }
    __syncthreads();
    const int n4 = NN * FEAT / 4;
    for (int i = blockIdx.x * 256 + threadIdx.x; i < n4; i += gridDim.x * 256) {
        float4 v = *(const float4*)(Y + (size_t)i * 4);
        int m = i / 192;
        int c = (i - m * 192) * 4;
        v.x = v.x * sc[c + 0] + sh[c + 0];
        v.y = v.y * sc[c + 1] + sh[c + 1];
        v.z = v.z * sc[c + 2] + sh[c + 2];
        v.w = v.w * sc[c + 3] + sh[c + 3];
        *(float4*)(Y + (size_t)i * 4) = v;
        unsigned short h0 = f2bf(v.x), h1 = f2bf(v.y), h2 = f2bf(v.z), h3 = f2bf(v.w);
        *(short4*)(Yc + (size_t)m * 1536 + c) =
            make_short4((short)h0, (short)h1, (short)h2, (short)h3);
        *(short4*)(Yc + (size_t)m * 1536 + 768 + c) =
            make_short4((short)f2bf(v.x - bf2f(h0)), (short)f2bf(v.y - bf2f(h1)),
                        (short)f2bf(v.z - bf2f(h2)), (short)f2bf(v.w - bf2f(h3)));
    }
}

// ---------------------------------------------------------------- row normalize z -> split-bf16 Zc
__global__ void rownorm_kernel(const float* __restrict__ Zin, short* __restrict__ Zc) {
    int i = blockIdx.x;
    int c = threadIdx.x;
    __shared__ float rs[256];
    __shared__ float inv;
    float v = Zin[(size_t)i * HIDD + c];
    rs[c] = v * v;
    __syncthreads();
    for (int st = 128; st > 0; st >>= 1) {
        if (c < st) rs[c] += rs[c + st];
        __syncthreads();
    }
    if (c == 0) inv = 1.f / (sqrtf(rs[0]) + 1e-8f);
    __syncthreads();
    float vn = v * inv;
    unsigned short hi = f2bf(vn);
    Zc[(size_t)i * 512 + c] = (short)hi;
    Zc[(size_t)i * 512 + 256 + c] = (short)f2bf(vn - bf2f(hi));
}

// ---------------------------------------------------------------- top-k via radix select (1 block/row)
__global__ __launch_bounds__(256) void topk_hist(const float* __restrict__ S,
        float* __restrict__ hv, int* __restrict__ eidx,
        float* __restrict__ De, float* __restrict__ ew,
        float* __restrict__ Dv, float* __restrict__ Dv2, int* __restrict__ row_cnt) {
    int row = blockIdx.x, tid = threadIdx.x, wave = tid >> 6;
    __shared__ unsigned hist[4][256];
    __shared__ unsigned suf[256];
    __shared__ int sb, sAbove, scand;
    __shared__ unsigned ckey[128];
    __shared__ int ccol[128];
    __shared__ int ccnt;
    __shared__ float wsum;
    const float4* base = (const float4*)(S + (size_t)row * NN);
    unsigned key[12];
#pragma unroll
    for (int c = 0; c < 3; c++) {
        float4 q = base[tid + c * 256];
        unsigned u0 = __float_as_uint(q.x), u1 = __float_as_uint(q.y);
        unsigned u2 = __float_as_uint(q.z), u3 = __float_as_uint(q.w);
        key[c * 4 + 0] = u0 ^ ((((int)u0) >> 31) | 0x80000000u);
        key[c * 4 + 1] = u1 ^ ((((int)u1) >> 31) | 0x80000000u);
        key[c * 4 + 2] = u2 ^ ((((int)u2) >> 31) | 0x80000000u);
        key[c * 4 + 3] = u3 ^ ((((int)u3) >> 31) | 0x80000000u);
    }
    if (tid == 0) { ccnt = 0; wsum = 0.f; }
    unsigned prefix = 0;
    int cAbove = 0, shift = 24;
    for (int level = 0; level < 4; level++) {
        shift = 24 - 8 * level;
#pragma unroll
        for (int w2 = 0; w2 < 4; w2++) hist[w2][tid] = 0;
        __syncthreads();
#pragma unroll
        for (int i = 0; i < 12; i++) {
            bool in = (level == 0) || ((key[i] >> (shift + 8)) == prefix);
            if (in) atomicAdd(&hist[wave][(key[i] >> shift) & 255], 1u);
        }
        __syncthreads();
        suf[tid] = hist[0][tid] + hist[1][tid] + hist[2][tid] + hist[3][tid];
        __syncthreads();
        for (int s2 = 1; s2 < 256; s2 <<= 1) {
            unsigned a = (tid + s2 < 256) ? suf[tid + s2] : 0u;
            __syncthreads();
            suf[tid] += a;
            __syncthreads();
        }
        int need = 16 - cAbove;
        unsigned nxt = (tid < 255) ? suf[tid + 1] : 0u;
        if ((int)suf[tid] >= need && (tid == 255 || (int)nxt < need)) {
            sb = tid;
            sAbove = cAbove + (int)nxt;
            scand = cAbove + (int)suf[tid];
        }
        __syncthreads();
        prefix = (prefix << 8) | (unsigned)sb;
        cAbove = sAbove;
        if (scand <= 112 || shift == 0) break;
        __syncthreads();
    }
    __syncthreads();
#pragma unroll
    for (int i = 0; i < 12; i++) {
        if ((key[i] >> shift) >= prefix) {
            int idx = atomicAdd(&ccnt, 1);
            if (idx < 128) {
                ckey[idx] = key[i];
                ccol[idx] = tid * 4 + ((i >> 2) << 10) + (i & 3);
            }
        }
    }
    __syncthreads();
    int n = min(ccnt, 128);
    float w = 0.f;
    int mycol = 0, myrank = 1 << 30;
    if (tid < n) {
        unsigned ki = ckey[tid];
        int ci = ccol[tid];
        int rank = 0;
        for (int jx = 0; jx < n; jx++) {
            unsigned kj = ckey[jx];
            int cj = ccol[jx];
            rank += (kj > ki) || (kj == ki && cj < ci);
        }
        if (rank < TK) {
            unsigned u = (ki & 0x80000000u) ? (ki ^ 0x80000000u) : ~ki;
            float val = __uint_as_float(u);
            float sg = 1.f / (1.f + expf(-val));
            w = (sg > 0.5f) ? sg : 0.f;
            hv[row * TK + rank] = w;
            eidx[row * TK + rank] = ci;
            myrank = rank; mycol = ci;
            atomicAdd(&wsum, w);
        }
    }
    __syncthreads();
    float s = wsum;
    if (tid == 0) { De[row] = s + 1e-8f; ew[row] = s * (1.f / TK); }
    float ewv = s * (1.f / TK);
    if (myrank < TK) {
        atomicAdd(&Dv[mycol], w * ewv);
        atomicAdd(&Dv2[mycol], w);
        atomicAdd(&row_cnt[mycol], 1);
    }
}

// ---------------------------------------------------------------- CSR scan + degree finalize
__global__ void scan_deg(const int* __restrict__ cnt, int* __restrict__ start,
                         const float* __restrict__ Dv, float* __restrict__ Dv2,
                         float* __restrict__ dvis) {
    __shared__ int part[256];
    int t = threadIdx.x;
    const int chunk = NN / 256;
    int s = 0;
    for (int i = t * chunk; i < (t + 1) * chunk; i++) {
        s += cnt[i];
        dvis[i] = 1.f / sqrtf(Dv[i] + 1e-8f);
        Dv2[i] += 1e-8f;
    }
    part[t] = s;
    __syncthreads();
    if (t == 0) {
        int a = 0;
        for (int i = 0; i < 256; i++) { int v = part[i]; part[i] = a; a += v; }
    }
    __syncthreads();
    int a = part[t];
    for (int i = t * chunk; i < (t + 1) * chunk; i++) { start[i] = a; a += cnt[i]; }
    if (t == 255) start[NN] = a;
}

__global__ void fill_csr(const int* __restrict__ eidx, const float* __restrict__ hv,
                         const int* __restrict__ start, int* __restrict__ fillc,
                         int* __restrict__ csr_e, float* __restrict__ csr_w) {
    int t = blockIdx.x * 256 + threadIdx.x;
    if (t >= NN * TK) return;
    int e = t >> 4;
    int v = eidx[t];
    int pos = atomicAdd(&fillc[v], 1);
    int pp = start[v] + pos;
    csr_e[pp] = e;
    csr_w[pp] = hv[t];
}

// ---------------------------------------------------------------- sparse H ops
__global__ void edge_gather4(const int* __restrict__ eidx, const float* __restrict__ hv,
                             const float* __restrict__ De, const float* __restrict__ dvis,
                             const float* __restrict__ X, float* __restrict__ T,
                             int F4, int ldx4, int ldt4, int epb, int use_dvis) {
    int slot = threadIdx.x / F4;
    if (slot >= epb) return;
    int f = threadIdx.x - slot * F4;
    int e = blockIdx.x * epb + slot;
    const int* ei = eidx + e * TK;
    const float* hw = hv + e * TK;
    float ax = 0.f, ay = 0.f, az = 0.f, aw = 0.f;
#pragma unroll
    for (int jx = 0; jx < TK; jx++) {
        int v = ei[jx];
        float w = hw[jx];
        if (use_dvis) w *= dvis[v];
        const float4 x = *(const float4*)(X + ((size_t)v * ldx4 + f) * 4);
        ax = fmaf(w, x.x, ax); ay = fmaf(w, x.y, ay);
        az = fmaf(w, x.z, az); aw = fmaf(w, x.w, aw);
    }
    float inv = 1.f / De[e];
    *(float4*)(T + ((size_t)e * ldt4 + f) * 4) = make_float4(ax * inv, ay * inv, az * inv, aw * inv);
}

__global__ void row_gather4(const int* __restrict__ start, const int* __restrict__ csr_e,
                            const float* __restrict__ csr_w, const float* __restrict__ dvis,
                            const float* __restrict__ T, float* __restrict__ Y,
                            int F4, int ldt4, int ldy4, int epb, int use_dvis) {
    int slot = threadIdx.x / F4;
    if (slot >= epb) return;
    int f = threadIdx.x - slot * F4;
    int v = blockIdx.x * epb + slot;
    int s0 = start[v], s1 = start[v + 1];
    float ax = 0.f, ay = 0.f, az = 0.f, aw = 0.f;
    for (int p = s0; p < s1; p++) {
        float w = csr_w[p];
        const float4 x = *(const float4*)(T + ((size_t)csr_e[p] * ldt4 + f) * 4);
        ax = fmaf(w, x.x, ax); ay = fmaf(w, x.y, ay);
        az = fmaf(w, x.z, az); aw = fmaf(w, x.w, aw);
    }
    float sc = use_dvis ? dvis[v] : 1.f;
    *(float4*)(Y + ((size_t)v * ldy4 + f) * 4) =
        make_float4(ax * sc, ay * sc, az * sc, aw * sc);
}

// spectral: row_gather fused with Rayleigh sums
__global__ void rg_spec(const int* __restrict__ start, const int* __restrict__ csr_e,
                        const float* __restrict__ csr_w, const float* __restrict__ T,
                        const float* __restrict__ r, const float* __restrict__ Dv2,
                        float* __restrict__ numb, float* __restrict__ denb) {
    __shared__ float lsn[64], lsd[64];
    int tid = threadIdx.x;
    if (tid < 64) { lsn[tid] = 0.f; lsd[tid] = 0.f; }
    __syncthreads();
    int slot = tid >> 4, f = tid & 15;
    int v = blockIdx.x * 16 + slot;
    int s0 = start[v], s1 = start[v + 1];
    float ax = 0.f, ay = 0.f, az = 0.f, aw = 0.f;
    for (int p = s0; p < s1; p++) {
        float w = csr_w[p];
        const float4 x = *(const float4*)(T + ((size_t)csr_e[p] * 16 + f) * 4);
        ax = fmaf(w, x.x, ax); ay = fmaf(w, x.y, ay);
        az = fmaf(w, x.z, az); aw = fmaf(w, x.w, aw);
    }
    float d2 = Dv2[v];
    const float4 rv = *(const float4*)(r + (size_t)v * 64 + f * 4);
    atomicAdd(&lsn[f * 4 + 0], rv.x * (d2 * rv.x - ax));
    atomicAdd(&lsn[f * 4 + 1], rv.y * (d2 * rv.y - ay));
    atomicAdd(&lsn[f * 4 + 2], rv.z * (d2 * rv.z - az));
    atomicAdd(&lsn[f * 4 + 3], rv.w * (d2 * rv.w - aw));
    atomicAdd(&lsd[f * 4 + 0], d2 * rv.x * rv.x);
    atomicAdd(&lsd[f * 4 + 1], d2 * rv.y * rv.y);
    atomicAdd(&lsd[f * 4 + 2], d2 * rv.z * rv.z);
    atomicAdd(&lsd[f * 4 + 3], d2 * rv.w * rv.w);
    __syncthreads();
    if (tid < 64) {
        atomicAdd(&numb[tid], lsn[tid]);
        atomicAdd(&denb[tid], lsd[tid]);
    }
}

// ---------------------------------------------------------------- cheb combine
__global__ void cheb_combine(const float* __restrict__ A0, int ld0,
                             const float* __restrict__ A1, int ld1,
                             const float* __restrict__ A2, int ld2,
                             const float* __restrict__ A3, int ld3,
                             const float* __restrict__ bias, float e1, float e2,
                             float* __restrict__ Xf, int ldf, short* __restrict__ Xc,
                             int Fw, int total4) {
    int i = blockIdx.x * 256 + threadIdx.x;
    if (i >= total4) return;
    int F4 = Fw >> 2;
    int m = i / F4, n4 = i - m * F4;
    float4 g0 = *(const float4*)(A0 + ((size_t)m * ld0 + n4) * 4);
    float4 g1 = *(const float4*)(A1 + ((size_t)m * ld1 + n4) * 4);
    float4 g2 = *(const float4*)(A2 + ((size_t)m * ld2 + n4) * 4);
    float4 g3 = *(const float4*)(A3 + ((size_t)m * ld3 + n4) * 4);
    float4 b = *(const float4*)(bias + n4 * 4);
    float4 x;
    x.x = fmaxf(g0.x - e1 * g1.x - e2 * g2.x + 2.f * e2 * g3.x + b.x, 0.f);
    x.y = fmaxf(g0.y - e1 * g1.y - e2 * g2.y + 2.f * e2 * g3.y + b.y, 0.f);
    x.z = fmaxf(g0.z - e1 * g1.z - e2 * g2.z + 2.f * e2 * g3.z + b.z, 0.f);
    x.w = fmaxf(g0.w - e1 * g1.w - e2 * g2.w + 2.f * e2 * g3.w + b.w, 0.f);
    if (Xf) *(float4*)(Xf + ((size_t)m * ldf + n4) * 4) = x;
    if (Xc) {
        unsigned short h0 = f2bf(x.x), h1 = f2bf(x.y), h2 = f2bf(x.z), h3 = f2bf(x.w);
        *(short4*)(Xc + (size_t)m * 2 * Fw + n4 * 4) =
            make_short4((short)h0, (short)h1, (short)h2, (short)h3);
        *(short4*)(Xc + (size_t)m * 2 * Fw + Fw + n4 * 4) =
            make_short4((short)f2bf(x.x - bf2f(h0)), (short)f2bf(x.y - bf2f(h1)),
                        (short)f2bf(x.z - bf2f(h2)), (short)f2bf(x.w - bf2f(h3)));
    }
}

// ---------------------------------------------------------------- fused heads: r + scores
__global__ __launch_bounds__(256) void heads_fused(const float* __restrict__ x2,
        const float* __restrict__ rw1, const float* __restrict__ rb1,
        const float* __restrict__ rw2, const float* __restrict__ rb2,
        const float* __restrict__ aw1, const float* __restrict__ ab1,
        const float* __restrict__ aw2, const float* __restrict__ ab2,
        float* __restrict__ r, float* __restrict__ out) {
    __shared__ float w1[128 * 64];
    __shared__ float w2[64 * 64];
    __shared__ float a1[64 * 32];
    __shared__ float a2s[32];
    __shared__ float xr[4][128];
    int tid = threadIdx.x;
    for (int i = tid; i < 128 * 64 / 4; i += 256)
        *(float4*)&w1[i * 4] = *(const float4*)&rw1[i * 4];
    for (int i = tid; i < 64 * 64 / 4; i += 256)
        *(float4*)&w2[i * 4] = *(const float4*)&rw2[i * 4];
    for (int i = tid; i < 64 * 32 / 4; i += 256)
        *(float4*)&a1[i * 4] = *(const float4*)&aw1[i * 4];
    if (tid < 32) a2s[tid] = aw2[tid];
    __syncthreads();
    int wave = tid >> 6, lane = tid & 63;
    float ab2v = ab2[0];
    for (int rr = 0; rr < 4; rr++) {
        int row = blockIdx.x * 16 + rr * 4 + wave;
        *(float2*)&xr[wave][lane * 2] = *(const float2*)&x2[(size_t)row * 128 + lane * 2];
        float hacc = rb1[lane];
#pragma unroll 8
        for (int k = 0; k < 128; k++) hacc = fmaf(xr[wave][k], w1[k * 64 + lane], hacc);
        hacc = fmaxf(hacc, 0.f);
        xr[wave][lane] = hacc;
        float racc = rb2[lane];
#pragma unroll 8
        for (int k = 0; k < 64; k++) racc = fmaf(xr[wave][k], w2[k * 64 + lane], racc);
        r[(size_t)row * 64 + lane] = racc;
        xr[wave][lane] = racc;
        int g = lane >> 5, jx = lane & 31;
        float hp = 0.f;
#pragma unroll 8
        for (int k = 0; k < 32; k++) hp = fmaf(xr[wave][g * 32 + k], a1[(g * 32 + k) * 32 + jx], hp);
        hp += __shfl_xor(hp, 32);
        float hj = fmaxf(hp + ab1[jx], 0.f) * a2s[jx];
#pragma unroll
        for (int s2 = 1; s2 < 32; s2 <<= 1) hj += __shfl_xor(hj, s2);
        if (lane == 0) out[row] = 1.f / (1.f + expf(-(hj + ab2v)));
    }
}

__global__ void finals_kernel(const float* __restrict__ msum, const float* __restrict__ numb,
                              const float* __restrict__ denb, float* __restrict__ out) {
    if (threadIdx.x == 0 && blockIdx.x == 0) {
        float s = 0.f;
        for (int c = 0; c < 64; c++) s += numb[c] / (denb[c] + 1e-8f);
        out[NN + 1] = s * (1.f / 64.f);
        out[NN] = msum[0] * (1.f / ((float)NN * FEAT));
    }
}

// ================================================================ launch
extern "C" void kernel_launch(void* const* d_in, const int* in_sizes, int n_in,
                              void* d_out, int out_size, void* d_ws, size_t ws_size,
                              hipStream_t stream) {
    const float* images = (const float*)d_in[0];
    const float* text   = (const float*)d_in[1];
    const float* signal = (const float*)d_in[2];
    const float* iw1 = (const float*)d_in[3];  const float* ib1 = (const float*)d_in[4];
    const float* iw2 = (const float*)d_in[5];  const float* ib2 = (const float*)d_in[6];
    const float* ig  = (const float*)d_in[7];  const float* ibeta = (const float*)d_in[8];
    const float* tw1 = (const float*)d_in[9];  const float* tb1 = (const float*)d_in[10];
    const float* tw2 = (const float*)d_in[11]; const float* tb2 = (const float*)d_in[12];
    const float* tg  = (const float*)d_in[13]; const float* tbeta = (const float*)d_in[14];
    const float* sw1 = (const float*)d_in[15]; const float* sb1 = (const float*)d_in[16];
    const float* sw2 = (const float*)d_in[17]; const float* sb2 = (const float*)d_in[18];
    const float* sg  = (const float*)d_in[19]; const float* sbeta = (const float*)d_in[20];
    const float* gw  = (const float*)d_in[21]; const float* gb = (const float*)d_in[22];
    const float* c1w = (const float*)d_in[23]; const float* c1b = (const float*)d_in[24];
    const float* c2w = (const float*)d_in[25]; const float* c2b = (const float*)d_in[26];
    const float* rw1 = (const float*)d_in[27]; const float* rb1 = (const float*)d_in[28];
    const float* rw2 = (const float*)d_in[29]; const float* rb2 = (const float*)d_in[30];
    const float* aw1 = (const float*)d_in[31]; const float* ab1 = (const float*)d_in[32];
    const float* aw2 = (const float*)d_in[33]; const float* ab2 = (const float*)d_in[34];
    const float* dw1 = (const float*)d_in[35]; const float* db1 = (const float*)d_in[36];
    const float* dw2 = (const float*)d_in[37]; const float* db2 = (const float*)d_in[38];
    float* out = (float*)d_out;

    float* wsf = (float*)d_ws;
    size_t off = 0;
    auto AF = [&](size_t n) { float* q = wsf + off; off += n; return q; };
    float* feats  = AF((size_t)NN * FEAT);
    float* simbuf = AF((size_t)NN * NN);
    float* p      = AF((size_t)NN * 192);
    float* z      = AF((size_t)NN * HIDD);
    float* x2     = AF((size_t)NN * 128);
    float* r      = AF((size_t)NN * 64);
    float* hv     = AF((size_t)NN * TK);
    float* ew     = AF(NN);
    float* De     = AF(NN);
    float* Dv     = AF(NN);
    float* Dv2    = AF(NN);
    float* dvis   = AF(NN);
    float* csr_w  = AF((size_t)NN * TK);
    float* numb   = AF(64);
    float* denb   = AF(64);
    float* msum   = AF(1);
    float* csum   = AF(FEAT);
    float* csum2  = AF(FEAT);
    short* x1c    = (short*)AF((size_t)NN * 256);     // [NN][512] shorts; reused as hc
    short* wcbuf  = (short*)AF(1589248);
    float* Gbuf   = AF((size_t)NN * FEAT);            // MLP1 partials, then G0|G1|G2 (ld 768)
    int* eidx     = (int*)(wsf + off); off += (size_t)NN * TK;
    int* csr_e    = (int*)(wsf + off); off += (size_t)NN * TK;
    int* row_cnt  = (int*)(wsf + off); off += NN;
    int* row_fill = (int*)(wsf + off); off += NN;
    int* row_start= (int*)(wsf + off); off += NN + 1;

    short* Zc = (short*)z;
    short* hc = x1c;   // reuse post-cheb2

    // weight split sub-buffers
    short* wp = wcbuf;
    auto AW = [&](size_t n) { short* q = wp; wp += n; return q; };
    short* iw1c = AW((size_t)256 * 384);
    short* tw1c = AW((size_t)256 * 1536);
    short* sw1c = AW((size_t)256 * 512);
    short* iw2c = AW((size_t)256 * 512);
    short* tw2c = AW((size_t)256 * 512);
    short* sw2c = AW((size_t)256 * 512);
    short* gwc  = AW((size_t)256 * 1536);
    short* c1wc0 = AW((size_t)256 * 1536);
    short* c1wc1 = AW((size_t)256 * 1536);
    short* c1wc2 = AW((size_t)256 * 1536);
    short* c2wc0 = AW((size_t)128 * 512);
    short* c2wc1 = AW((size_t)128 * 512);
    short* c2wc2 = AW((size_t)128 * 512);
    short* dw2c  = AW((size_t)768 * 512);

    // pre-sim simbuf layout (shorts)
    short* sbp = (short*)simbuf;
    short* pc  = sbp;
    short* tc  = pc + (size_t)NN * 384;
    short* scb = tc + (size_t)NN * 1536;
    short* hc0 = scb + (size_t)NN * 512;
    short* hc1 = hc0 + (size_t)NN * 512;
    short* hc2 = hc1 + (size_t)NN * 512;
    short* featsc_pre = hc2 + (size_t)NN * 512;

    // post-topk slabs (floats)
    float* et1   = simbuf;                              // NN*512
    float* MG12  = simbuf + (size_t)NN * 512;           // NN*512
    float* et2   = simbuf + (size_t)NN * 1024;          // NN*256
    float* MMG2  = simbuf + (size_t)NN * 1280;          // NN*256
    float* Hb    = simbuf;                              // NN*384 (cheb2)
    float* et3   = simbuf + (size_t)NN * 384;
    float* MH12  = simbuf + (size_t)NN * 640;
    float* et4   = simbuf + (size_t)NN * 896;
    float* MMH2  = simbuf + (size_t)NN * 1024;
    float* et5   = simbuf + (size_t)NN * 2048;

    dim3 blk(256);
    auto eg = [&](const float* X, int ldx4, float* T, int ldt4, int F, int use_dvis) {
        int F4 = F / 4, epb = 256 / F4 < 1 ? 1 : 256 / F4;
        edge_gather4<<<NN / epb, dim3(F4 * epb), 0, stream>>>(
            eidx, hv, De, dvis, X, T, F4, ldx4, ldt4, epb, use_dvis);
    };
    auto rg = [&](const float* T, int ldt4, float* Y, int ldy4, int F, int use_dvis) {
        int F4 = F / 4, epb = 256 / F4 < 1 ? 1 : 256 / F4;
        row_gather4<<<NN / epb, dim3(F4 * epb), 0, stream>>>(
            row_start, csr_e, csr_w, dvis, T, Y, F4, ldt4, ldy4, epb, use_dvis);
    };
    auto mkbj = [](const short* A, const short* B, const float* bias, float* Cf, short* Cc,
                   const float* mref, int sa, int sb, int Koff, int Klen, int act,
                   int ldc, int ccW, int pslot) {
        BJ j{};
        j.A = A; j.Bw = B; j.bias = bias; j.Cf = Cf; j.Cc = Cc; j.mseRef = mref;
        j.sa = sa; j.sb = sb; j.Koff = Koff; j.Klen = Klen; j.act = act;
        j.ldc = ldc; j.ccW = ccW; j.pslot = pslot; j.scale = 1.f;
        return j;
    };

    const float E1 = 0.60653065971f;  // exp(-0.5)
    const float E2 = 0.36787944117f;  // exp(-1.0)

    // ---- pool + zero-init + conversions ----
    pool_kernel<<<(NN * 192 + 255) / 256, blk, 0, stream>>>(
        images, p, Dv, Dv2, row_cnt, row_fill, csum, numb, msum);
    {
        WJobs wj{};
        wj.j[0] = {iw1, iw1c, 192, 256};
        wj.j[1] = {tw1, tw1c, 768, 256};
        wj.j[2] = {sw1, sw1c, 256, 256};
        wj.j[3] = {iw2, iw2c, 256, 256};
        wj.j[4] = {tw2, tw2c, 256, 256};
        wj.j[5] = {sw2, sw2c, 256, 256};
        wj.j[6] = {gw,  gwc,  768, 256};
        wj.j[7] = {c1w, c1wc0, 768, 256};
        wj.j[8] = {c1w + (size_t)FEAT * HIDD, c1wc1, 768, 256};
        wj.j[9] = {c1w + (size_t)2 * FEAT * HIDD, c1wc2, 768, 256};
        wj.j[10] = {c2w, c2wc0, 256, 128};
        wj.j[11] = {c2w + (size_t)HIDD * 128, c2wc1, 256, 128};
        wj.j[12] = {c2w + (size_t)2 * HIDD * 128, c2wc2, 256, 128};
        wj.j[13] = {dw2, dw2c, 256, 768};
        wsplitT<<<dim3(24, 24, 14), blk, 0, stream>>>(wj);
    }
    split_rows3<<<(NN * 304 + 255) / 256, blk, 0, stream>>>(p, pc, text, tc, signal, scb);

    // ---- MLP1: 5 balanced jobs (text K split into 3 partials) ----
    {
        BTJ bt{};
        bt.j[0] = mkbj(pc, iw1c, ib1, nullptr, hc0, nullptr, 384, 384, 0, 384, 1, 0, 256, -1);
        bt.j[1] = mkbj(tc, tw1c, nullptr, nullptr, nullptr, nullptr, 1536, 1536, 0, 512, 0, 0, 0, 0);
        bt.j[2] = mkbj(tc, tw1c, nullptr, nullptr, nullptr, nullptr, 1536, 1536, 512, 512, 0, 0, 0, 1);
        bt.j[3] = mkbj(tc, tw1c, nullptr, nullptr, nullptr, nullptr, 1536, 1536, 1024, 512, 0, 0, 0, 2);
        bt.j[4] = mkbj(scb, sw1c, sb1, nullptr, hc2, nullptr, 512, 512, 0, 512, 1, 0, 256, -1);
        gemm_btj<<<dim3(4, 24, 5), blk, 0, stream>>>(bt, Gbuf, nullptr, NN, 256);
        epi3<<<(NN * 256 + 255) / 256, blk, 0, stream>>>(Gbuf, tb1, hc1, NN, 256, 256);
    }
    // ---- MLP2: 3 jobs ----
    {
        BTJ bt{};
        bt.j[0] = mkbj(hc0, iw2c, ib2, feats, nullptr, nullptr, 512, 512, 0, 512, 0, FEAT, 0, -1);
        bt.j[1] = mkbj(hc1, tw2c, tb2, feats + 256, nullptr, nullptr, 512, 512, 0, 512, 0, FEAT, 0, -1);
        bt.j[2] = mkbj(hc2, sw2c, sb2, feats + 512, nullptr, nullptr, 512, 512, 0, 512, 0, FEAT, 0, -1);
        gemm_btj<<<dim3(4, 24, 3), blk, 0, stream>>>(bt, nullptr, nullptr, NN, 256);
    }
    bn_stats<<<NN / 16, blk, 0, stream>>>(feats, csum, csum2);
    bn_norm2<<<1024, blk, 0, stream>>>(feats, csum, csum2, ig, tg, sg, ibeta, tbeta, sbeta, featsc_pre);

    // ---- gw + cheb1-G merged (4 jobs, all K=1536, shared A) ----
    {
        BTJ bt{};
        bt.j[0] = mkbj(featsc_pre, gwc, gb, z, nullptr, nullptr, 1536, 1536, 0, 1536, 2, 256, 0, -1);
        bt.j[1] = mkbj(featsc_pre, c1wc0, nullptr, Gbuf, nullptr, nullptr, 1536, 1536, 0, 1536, 0, 768, 0, -1);
        bt.j[2] = mkbj(featsc_pre, c1wc1, nullptr, Gbuf + 256, nullptr, nullptr, 1536, 1536, 0, 1536, 0, 768, 0, -1);
        bt.j[3] = mkbj(featsc_pre, c1wc2, nullptr, Gbuf + 512, nullptr, nullptr, 1536, 1536, 0, 1536, 0, 768, 0, -1);
        gemm_btj<<<dim3(4, 24, 4), blk, 0, stream>>>(bt, nullptr, nullptr, NN, 256);
    }
    rownorm_kernel<<<NN, blk, 0, stream>>>(z, Zc);
    sim_mfma<<<dim3(NN / 128, NN / 128), blk, 0, stream>>>(Zc, simbuf);
    topk_hist<<<NN, blk, 0, stream>>>(simbuf, hv, eidx, De, ew, Dv, Dv2, row_cnt);

    // ---- CSR ----
    scan_deg<<<1, blk, 0, stream>>>(row_cnt, row_start, Dv, Dv2, dvis);
    fill_csr<<<NN * TK / 256, blk, 0, stream>>>(eidx, hv, row_start, row_fill, csr_e, csr_w);

    // ---- cheb conv 1 ----
    eg(Gbuf + 256, 192, et1, 128, 512, 1);
    rg(et1, 128, MG12, 128, 512, 1);
    eg(MG12 + 256, 128, et2, 64, 256, 1);
    rg(et2, 64, MMG2, 64, 256, 1);
    cheb_combine<<<(NN * 64 + 255) / 256, blk, 0, stream>>>(
        Gbuf, 192, MG12, 128, Gbuf + 512, 192, MMG2, 64,
        c1b, E1, E2, nullptr, 0, x1c, 256, NN * 64);

    // ---- cheb conv 2 ----
    {
        BTJ bt{};
        bt.j[0] = mkbj(x1c, c2wc0, nullptr, Hb, nullptr, nullptr, 512, 512, 0, 512, 0, 384, 0, -1);
        bt.j[1] = mkbj(x1c, c2wc1, nullptr, Hb + 128, nullptr, nullptr, 512, 512, 0, 512, 0, 384, 0, -1);
        bt.j[2] = mkbj(x1c, c2wc2, nullptr, Hb + 256, nullptr, nullptr, 512, 512, 0, 512, 0, 384, 0, -1);
        gemm_btj<<<dim3(2, 24, 3), blk, 0, stream>>>(bt, nullptr, nullptr, NN, 128);
    }
    eg(Hb + 128, 96, et3, 64, 256, 1);
    rg(et3, 64, MH12, 64, 256, 1);
    eg(MH12 + 128, 64, et4, 32, 128, 1);
    rg(et4, 32, MMH2, 32, 128, 1);
    cheb_combine<<<(NN * 32 + 255) / 256, blk, 0, stream>>>(
        Hb, 96, MH12, 64, Hb + 256, 96, MMH2, 32,
        c2b, E1, E2, x2, 32, nullptr, 128, NN * 32);

    // ---- heads ----
    heads_fused<<<NN / 16, blk, 0, stream>>>(x2, rw1, rb1, rw2, rb2,
                                             aw1, ab1, aw2, ab2, r, out);
    gemm_mf<<<dim3(4, 24), blk, 0, stream>>>(r, dw1, db1, hc, NN, 256, 64, 64, 256, 256);
    {
        BTJ bt{};
        bt.j[0] = mkbj(hc, dw2c, db2, nullptr, nullptr, feats, 512, 512, 0, 512, 0, 0, 0, -1);
        gemm_btj<<<dim3(12, 24, 1), blk, 0, stream>>>(bt, nullptr, msum, NN, 768);
    }

    // ---- spectral cut (fused) ----
    eg(r, 16, et5, 16, 64, 0);
    rg_spec<<<NN / 16, blk, 0, stream>>>(row_start, csr_e, csr_w, et5, r, Dv2, numb, denb);
    finals_kernel<<<1, 64, 0, stream>>>(msum, numb, denb, out);
}